// Round 1
// baseline (829.409 us; speedup 1.0000x reference)
//
#include <hip/hip_runtime.h>
#include <math.h>

#define BB 2048
#define LL 512
#define DD 7
#define BD 14336   // BB*DD
#define NP 32      // patches
#define PL 16      // patch len

// ---------------- ws layout (floats) ----------------
constexpr size_t F_XP   = 0;                          // xp, later zf
constexpr size_t F_ZG   = F_XP  + (size_t)BD*512;     // z_dct -> g -> z1r
constexpr size_t F_Z1   = F_ZG  + (size_t)BD*512;     // z1
constexpr size_t F_CLK  = F_Z1  + (size_t)BD*512;     // C[l][k] * 2
constexpr size_t F_MKL  = F_CLK + 512*512;            // C[k][l] * sc[k]
constexpr size_t F_U    = F_MKL + 512*512;
constexpr size_t F_CSUM = F_U + 512;
constexpr size_t F_W2   = F_CSUM + 512;               // 96x512
constexpr size_t F_CST  = F_W2 + 96*512;
constexpr size_t F_V    = F_CST + 96;                 // 32x16x16
constexpr size_t F_C2   = F_V + 32*256;               // 32x16
constexpr size_t F_ZRES = F_C2 + 512;                 // BD x 96
constexpr size_t F_H2   = F_ZRES + (size_t)BD*96;     // BD x 48
constexpr size_t F_EN   = F_H2 + (size_t)BD*48;
constexpr size_t F_NE   = F_EN + BD;
constexpr size_t F_ATT  = F_NE + BD;
constexpr size_t F_A1   = F_ATT + BD;
constexpr size_t F_A2   = F_A1 + BD;
constexpr size_t F_RS   = F_A2 + BD;
constexpr size_t F_RQ   = F_RS + BD;
constexpr size_t F_PS   = F_RQ + BD;                  // 1792 x 32
constexpr size_t F_PQ   = F_PS + 1792*32;
constexpr size_t F_BN   = F_PQ + 1792*32;             // bn affine params
constexpr size_t F_THR  = F_BN + 256;

__device__ __forceinline__ float gelu_f(float x) {
  return 0.5f * x * (1.0f + erff(x * 0.70710678118654752440f));
}
__device__ __forceinline__ float sigm_f(float x) {
  return 1.0f / (1.0f + expf(-x));
}
__device__ __forceinline__ float wred(float v) {
#pragma unroll
  for (int o = 32; o > 0; o >>= 1) v += __shfl_down(v, o);
  return v;
}

// ---------------- constant generation ----------------
__global__ void k_gen_cos(float* __restrict__ Clk, float* __restrict__ Mkl) {
  int k = blockIdx.x;
  for (int l = threadIdx.x; l < 512; l += 256) {
    double c = cos(3.14159265358979323846 * (l + 0.5) * k / 512.0);
    Clk[(size_t)l*512 + k] = (float)(2.0 * c);
    Mkl[(size_t)k*512 + l] = (float)(c * (k == 0 ? (1.0/1024.0) : (1.0/512.0)));
  }
}

__global__ void k_ucsum(const float* __restrict__ Mkl, float* __restrict__ u,
                        float* __restrict__ csum, const float* __restrict__ wf) {
  int l = blockIdx.x*256 + threadIdx.x;
  if (l >= 512) return;
  double s = 0.0;
  for (int k = 0; k < 512; ++k) s += (double)Mkl[(size_t)k*512 + l];
  csum[l] = (float)s;
  double uu = (double)wf[0] * 45.25483399593904156 * (double)Mkl[l];      // sqrt(2048)
  for (int k = 1; k < 5; ++k) uu += (double)wf[k] * 32.0 * (double)Mkl[(size_t)k*512 + l];
  u[l] = (float)uu;
}

__global__ __launch_bounds__(256) void k_w2(const float* __restrict__ linW,
    const float* __restrict__ linb, const float* __restrict__ eW, const float* __restrict__ eb,
    float* __restrict__ W2, float* __restrict__ cst)
{
  __shared__ float sW[768];
  __shared__ float sb[48];
  __shared__ float rbuf[256];
  int o = blockIdx.x, t = threadIdx.x;
  for (int i = t; i < 768; i += 256) sW[i] = eW[i];
  if (t < 48) sb[t] = eb[t];
  __syncthreads();
  const float* lw = linW + (size_t)o * 1536;
  for (int i = t; i < 512; i += 256) {
    int n = i >> 4, p = i & 15;
    float s = 0.f;
    const float* l2 = lw + n*48;
#pragma unroll 8
    for (int m = 0; m < 48; ++m) s += l2[m] * sW[m*16 + p];
    W2[(size_t)o*512 + i] = s;
  }
  float c = 0.f;
  for (int i = t; i < 1536; i += 256) c += lw[i] * sb[i % 48];
  rbuf[t] = c; __syncthreads();
  for (int off = 128; off > 0; off >>= 1) { if (t < off) rbuf[t] += rbuf[t+off]; __syncthreads(); }
  if (t == 0) cst[o] = rbuf[0] + linb[o];
}

__global__ void k_v(const float* __restrict__ eW, const float* __restrict__ eb,
                    const float* __restrict__ dw, const float* __restrict__ db,
                    float* __restrict__ V, float* __restrict__ c2)
{
  int n = blockIdx.x, t = threadIdx.x;
  int p = t >> 4, q = t & 15;
  float s = 0.f;
#pragma unroll
  for (int j = 0; j < 3; ++j) s += eW[(p*3+j)*16 + q] * dw[n*3+j];
  V[(size_t)n*256 + p*16 + q] = s;
  if (q == 0) {
    float c = 0.f;
#pragma unroll
    for (int j = 0; j < 3; ++j) c += eb[p*3+j] * dw[n*3+j];
    c2[n*16+p] = c + db[n];
  }
}

// ---------------- transpose [B,L,D] -> [B*D, L] ----------------
__global__ __launch_bounds__(256) void k_transpose(const float* __restrict__ x, float* __restrict__ xp) {
  __shared__ float s[3584];
  int b = blockIdx.x;
  const float* src = x + (size_t)b*3584;
  for (int c = threadIdx.x; c < 896; c += 256) {
    float4 v = *(const float4*)&src[c*4];
    s[c*4+0]=v.x; s[c*4+1]=v.y; s[c*4+2]=v.z; s[c*4+3]=v.w;
  }
  __syncthreads();
  for (int c = threadIdx.x; c < 896; c += 256) {
    int d = c >> 7, cg = c & 127;
    float4 v;
    v.x = s[(cg*4+0)*7 + d]; v.y = s[(cg*4+1)*7 + d];
    v.z = s[(cg*4+2)*7 + d]; v.w = s[(cg*4+3)*7 + d];
    *(float4*)&xp[((size_t)b*7 + d)*512 + cg*4] = v;
  }
}

// ---------------- big NN GEMM: C[M,512] = A[M,512] @ B[512,512] ----------------
// 64x128 tile, BK=32, 256 threads, 4x8 frags.
// MODE 0: plain store. MODE 1: out = aR*acc + cR*csum[col] + (xp*w_d + b_d)
template<int MODE>
__global__ __launch_bounds__(256) void k_gemm_nn(
    const float* __restrict__ A, const float* __restrict__ Bm, float* __restrict__ Cc,
    const float* __restrict__ bnac, const float* __restrict__ csum,
    const float* __restrict__ xp, const float* __restrict__ cw, const float* __restrict__ cb)
{
  __shared__ float As[64][33];
  __shared__ float Bs[32][128];
  const int t = threadIdx.x;
  const int tx = t & 15, ty = t >> 4;
  const int r0 = blockIdx.x * 64, c0 = blockIdx.y * 128;
  float acc[4][8];
#pragma unroll
  for (int i = 0; i < 4; ++i)
#pragma unroll
    for (int j = 0; j < 8; ++j) acc[i][j] = 0.f;

  for (int kt = 0; kt < 512; kt += 32) {
#pragma unroll
    for (int h = 0; h < 2; ++h) {
      int c = t + h*256;
      int row = c >> 3, cg = c & 7;
      float4 v = *(const float4*)&A[(size_t)(r0+row)*512 + kt + cg*4];
      As[row][cg*4+0]=v.x; As[row][cg*4+1]=v.y; As[row][cg*4+2]=v.z; As[row][cg*4+3]=v.w;
    }
#pragma unroll
    for (int h = 0; h < 4; ++h) {
      int c = t + h*256;
      int row = c >> 5, cg = c & 31;
      *(float4*)&Bs[row][cg*4] = *(const float4*)&Bm[(size_t)(kt+row)*512 + c0 + cg*4];
    }
    __syncthreads();
#pragma unroll
    for (int kk = 0; kk < 32; ++kk) {
      float av[4];
#pragma unroll
      for (int i = 0; i < 4; ++i) av[i] = As[ty*4+i][kk];
      float4 b0 = *(const float4*)&Bs[kk][tx*4];
      float4 b1 = *(const float4*)&Bs[kk][tx*4+64];
      float bv[8] = {b0.x,b0.y,b0.z,b0.w,b1.x,b1.y,b1.z,b1.w};
#pragma unroll
      for (int i = 0; i < 4; ++i)
#pragma unroll
        for (int j = 0; j < 8; ++j) acc[i][j] += av[i]*bv[j];
    }
    __syncthreads();
  }
#pragma unroll
  for (int i = 0; i < 4; ++i) {
    const int r = r0 + ty*4 + i;
    if (MODE == 0) {
      float4 v0 = make_float4(acc[i][0],acc[i][1],acc[i][2],acc[i][3]);
      float4 v1 = make_float4(acc[i][4],acc[i][5],acc[i][6],acc[i][7]);
      *(float4*)&Cc[(size_t)r*512 + c0 + tx*4]      = v0;
      *(float4*)&Cc[(size_t)r*512 + c0 + tx*4 + 64] = v1;
    } else {
      const int d = r % 7;
      const float aR = bnac[d], cR = bnac[7+d], wv = cw[d], bvv = cb[d];
#pragma unroll
      for (int g = 0; g < 2; ++g) {
        int col = c0 + tx*4 + g*64;
        float4 xv = *(const float4*)&xp[(size_t)r*512 + col];
        float4 cs = *(const float4*)&csum[col];
        float4 v;
        v.x = aR*acc[i][g*4+0] + cR*cs.x + (xv.x*wv + bvv);
        v.y = aR*acc[i][g*4+1] + cR*cs.y + (xv.y*wv + bvv);
        v.z = aR*acc[i][g*4+2] + cR*cs.z + (xv.z*wv + bvv);
        v.w = aR*acc[i][g*4+3] + cR*cs.w + (xv.w*wv + bvv);
        *(float4*)&Cc[(size_t)r*512 + col] = v;
      }
    }
  }
}

// ---------------- NT GEMM: out[M,Ncols] = A[M,512] @ W[Ncols,512]^T + bias ----------------
// 64x64 tile, BK=32. MODE 0: store val. MODE 1: store gelu(val)*val.
// TRANS: A element -> gelu(ta[d]*x + tc[d]) at stage time.
template<int MODE, bool TRANS>
__global__ __launch_bounds__(256) void k_gemm_nt(
    const float* __restrict__ A, const float* __restrict__ W, const float* __restrict__ bias,
    float* __restrict__ out, int Ncols, int ldOut,
    const float* __restrict__ ta, const float* __restrict__ tc)
{
  __shared__ float As[64][33];
  __shared__ float Bs[32][68];
  const int t = threadIdx.x;
  const int tx = t & 15, ty = t >> 4;
  const int r0 = blockIdx.x*64, c0 = blockIdx.y*64;
  float acc[4][4];
#pragma unroll
  for (int i = 0; i < 4; ++i)
#pragma unroll
    for (int j = 0; j < 4; ++j) acc[i][j] = 0.f;

  for (int kt = 0; kt < 512; kt += 32) {
#pragma unroll
    for (int h = 0; h < 2; ++h) {
      int c = t + h*256;
      int row = c >> 3, cg = c & 7;
      float4 v = *(const float4*)&A[(size_t)(r0+row)*512 + kt + cg*4];
      if (TRANS) {
        int d = (r0 + row) % 7;
        float aa = ta[d], cc = tc[d];
        v.x = gelu_f(aa*v.x + cc); v.y = gelu_f(aa*v.y + cc);
        v.z = gelu_f(aa*v.z + cc); v.w = gelu_f(aa*v.w + cc);
      }
      As[row][cg*4+0]=v.x; As[row][cg*4+1]=v.y; As[row][cg*4+2]=v.z; As[row][cg*4+3]=v.w;
    }
#pragma unroll
    for (int h = 0; h < 2; ++h) {
      int c = t + h*256;
      int row = c >> 3, cg = c & 7;
      int o = c0 + row;
      float4 v = make_float4(0.f,0.f,0.f,0.f);
      if (o < Ncols) v = *(const float4*)&W[(size_t)o*512 + kt + cg*4];
      Bs[cg*4+0][row]=v.x; Bs[cg*4+1][row]=v.y; Bs[cg*4+2][row]=v.z; Bs[cg*4+3][row]=v.w;
    }
    __syncthreads();
#pragma unroll
    for (int kk = 0; kk < 32; ++kk) {
      float av[4];
#pragma unroll
      for (int i = 0; i < 4; ++i) av[i] = As[ty*4+i][kk];
      float4 b = *(const float4*)&Bs[kk][tx*4];
      float bv[4] = {b.x,b.y,b.z,b.w};
#pragma unroll
      for (int i = 0; i < 4; ++i)
#pragma unroll
        for (int j = 0; j < 4; ++j) acc[i][j] += av[i]*bv[j];
    }
    __syncthreads();
  }
#pragma unroll
  for (int i = 0; i < 4; ++i) {
    int r = r0 + ty*4 + i;
#pragma unroll
    for (int j = 0; j < 4; ++j) {
      int col = c0 + tx*4 + j;
      if (col < Ncols) {
        float v = acc[i][j] + bias[col];
        if (MODE == 1) { float g = gelu_f(v); v = g*v; }
        out[(size_t)r*ldOut + col] = v;
      }
    }
  }
}

// ---------------- energy / median / quantile ----------------
__global__ void k_energy(const float* __restrict__ zg, float* __restrict__ en) {
  int r = blockIdx.x*4 + (threadIdx.x >> 6);
  int lane = threadIdx.x & 63;
  const float* row = zg + (size_t)r*512;
  float s = 0.f;
  for (int i = lane; i < 512; i += 64) { float v = row[i]; s += v*v; }
  s = wred(s);
  if (lane == 0) en[r] = s;
}

__global__ void k_ne(const float* __restrict__ en, float* __restrict__ ne) {
  int b = blockIdx.x*256 + threadIdx.x;
  if (b >= 2048) return;
  float e[7], s7[7];
#pragma unroll
  for (int d = 0; d < 7; ++d) { e[d] = en[b*7+d]; s7[d] = e[d]; }
#pragma unroll
  for (int i = 1; i < 7; ++i) {
    float key = s7[i]; int j = i-1;
    while (j >= 0 && s7[j] > key) { s7[j+1] = s7[j]; --j; }
    s7[j+1] = key;
  }
  float med = s7[3] + 1e-6f;
#pragma unroll
  for (int d = 0; d < 7; ++d) ne[b*7+d] = e[d] / med;
}

// exact k-th-smallest selection via 3-level bit histogram (positive floats)
__global__ __launch_bounds__(1024) void k_thr(const float* __restrict__ ne,
                                              const float* __restrict__ qp, float* __restrict__ out)
{
  __shared__ unsigned int hist[2048];
  __shared__ unsigned int s_bin, s_cum;
  const int t = threadIdx.x;
  float q = qp[0];
  float pos = q * 14335.0f;
  int lo = (int)floorf(pos);
  if (lo < 0) lo = 0; if (lo > 14335) lo = 14335;
  int hi = lo + 1; if (hi > 14335) hi = 14335;
  float frac = pos - (float)lo;
  const int shs[3] = {21, 10, 0};
  float vals[2];
  int ranks[2] = {lo, hi};
  for (int rsel = 0; rsel < 2; ++rsel) {
    unsigned int prefix = 0;
    unsigned int R = (unsigned int)ranks[rsel];
    for (int lev = 0; lev < 3; ++lev) {
      int nb = (lev == 2) ? 1024 : 2048;
      unsigned int himask = (lev == 0) ? 0u : ((lev == 1) ? 0xFFE00000u : 0xFFFFFC00u);
      for (int i = t; i < nb; i += 1024) hist[i] = 0u;
      __syncthreads();
      for (int i = t; i < BD; i += 1024) {
        unsigned int key = __float_as_uint(ne[i]);
        if ((key & himask) == prefix) atomicAdd(&hist[(key >> shs[lev]) & (nb-1)], 1u);
      }
      __syncthreads();
      if (t == 0) {
        unsigned int cum = 0, bsel = 0;
        for (unsigned int bi = 0; bi < (unsigned int)nb; ++bi) {
          if (cum + hist[bi] > R) { bsel = bi; break; }
          cum += hist[bi];
        }
        s_bin = bsel; s_cum = cum;
      }
      __syncthreads();
      prefix |= (s_bin << shs[lev]);
      R -= s_cum;
      __syncthreads();
    }
    vals[rsel] = __uint_as_float(prefix);
  }
  if (t == 0) out[0] = vals[0]*(1.0f-frac) + vals[1]*frac;
}

// ---------------- mask + dctconv + gelu (in place) + row stats ----------------
__global__ __launch_bounds__(256) void k_mask_gelu(float* __restrict__ zg,
    const float* __restrict__ ne, const float* __restrict__ thr,
    const float* __restrict__ cw, const float* __restrict__ cb,
    float* __restrict__ rs, float* __restrict__ rq)
{
  __shared__ float sb[8];
  int r = blockIdx.x, t = threadIdx.x;
  int d = r % 7;
  float m = (ne[r] > thr[0]) ? 1.0f : 0.0f;
  float wm = cw[d] * m, bv = cb[d];
  float* row = zg + (size_t)r * 512;
  float s = 0.f, qq = 0.f;
#pragma unroll
  for (int h = 0; h < 2; ++h) {
    int i = t + h*256;
    float g = gelu_f(row[i]*wm + bv);
    row[i] = g;
    s += g; qq += g*g;
  }
  s = wred(s); qq = wred(qq);
  int lane = t & 63, w = t >> 6;
  if (lane == 0) { sb[w] = s; sb[4+w] = qq; }
  __syncthreads();
  if (t == 0) { rs[r] = sb[0]+sb[1]+sb[2]+sb[3]; rq[r] = sb[4]+sb[5]+sb[6]+sb[7]; }
}

// ---------------- BN finalize from per-row sums ----------------
__global__ __launch_bounds__(256) void k_bnfin_rows(const float* __restrict__ rs,
    const float* __restrict__ rq, int nch, int nrows, double count,
    const float* __restrict__ gamma, const float* __restrict__ beta, float* __restrict__ out)
{
  __shared__ double sd[256];
  int ch = blockIdx.x, t = threadIdx.x;
  double s = 0.0, q = 0.0;
  for (int i = ch + t*nch; i < nrows; i += 256*nch) { s += rs[i]; q += rq[i]; }
  sd[t] = s; __syncthreads();
  for (int o = 128; o > 0; o >>= 1) { if (t < o) sd[t] += sd[t+o]; __syncthreads(); }
  double S = sd[0]; __syncthreads();
  sd[t] = q; __syncthreads();
  for (int o = 128; o > 0; o >>= 1) { if (t < o) sd[t] += sd[t+o]; __syncthreads(); }
  if (t == 0) {
    double m = S / count;
    double v = sd[0] / count - m*m; if (v < 0.0) v = 0.0;
    double inv = 1.0 / sqrt(v + 1e-5);
    out[ch]       = (float)(gamma[ch] * inv);
    out[nch + ch] = (float)(beta[ch] - m * gamma[ch] * inv);
  }
}

__global__ __launch_bounds__(256) void k_bnfin_part(const float* __restrict__ pS,
    const float* __restrict__ pQ, int nparts, int nch, double count,
    const float* __restrict__ gamma, const float* __restrict__ beta, float* __restrict__ out)
{
  __shared__ double sd[256];
  int ch = blockIdx.x, t = threadIdx.x;
  double s = 0.0, q = 0.0;
  for (int i = t; i < nparts; i += 256) { s += pS[(size_t)i*nch + ch]; q += pQ[(size_t)i*nch + ch]; }
  sd[t] = s; __syncthreads();
  for (int o = 128; o > 0; o >>= 1) { if (t < o) sd[t] += sd[t+o]; __syncthreads(); }
  double S = sd[0]; __syncthreads();
  sd[t] = q; __syncthreads();
  for (int o = 128; o > 0; o >>= 1) { if (t < o) sd[t] += sd[t+o]; __syncthreads(); }
  if (t == 0) {
    double m = S / count;
    double v = sd[0] / count - m*m; if (v < 0.0) v = 0.0;
    double inv = 1.0 / sqrt(v + 1e-5);
    out[ch]       = (float)(gamma[ch] * inv);
    out[nch + ch] = (float)(beta[ch] - m * gamma[ch] * inv);
  }
}

// ---------------- patch path: z1r = V[n] @ xp-patch + c2 ----------------
__global__ __launch_bounds__(256) void k_patch(const float* __restrict__ xp,
    const float* __restrict__ V, const float* __restrict__ c2,
    float* __restrict__ z1r, float* __restrict__ pS, float* __restrict__ pQ)
{
  __shared__ float sx[8][512];
  __shared__ float aS[32], aQ[32];
  int t = threadIdx.x;
  int r0 = blockIdx.x * 8;
  for (int c = t; c < 1024; c += 256) {
    int row = c >> 7, cg = c & 127;
    *(float4*)&sx[row][cg*4] = *(const float4*)&xp[(size_t)(r0+row)*512 + cg*4];
  }
  if (t < 32) { aS[t] = 0.f; aQ[t] = 0.f; }
  __syncthreads();
  float vreg[2][16]; float cc[2]; int nn_[2], oo[2];
#pragma unroll
  for (int h = 0; h < 2; ++h) {
    int o = t + h*256;
    oo[h] = o;
    int n = o >> 4, p = o & 15;
    nn_[h] = n;
#pragma unroll
    for (int qg = 0; qg < 4; ++qg) {
      float4 v4 = *(const float4*)&V[(size_t)n*256 + p*16 + qg*4];
      vreg[h][qg*4+0]=v4.x; vreg[h][qg*4+1]=v4.y; vreg[h][qg*4+2]=v4.z; vreg[h][qg*4+3]=v4.w;
    }
    cc[h] = c2[o];
  }
  float sum[2] = {0.f,0.f}, sq[2] = {0.f,0.f};
  for (int row = 0; row < 8; ++row) {
#pragma unroll
    for (int h = 0; h < 2; ++h) {
      const float* xr = &sx[row][nn_[h]*16];
      float val = cc[h];
#pragma unroll
      for (int qq = 0; qq < 16; ++qq) val += vreg[h][qq] * xr[qq];
      z1r[(size_t)(r0+row)*512 + oo[h]] = val;
      sum[h] += val; sq[h] += val*val;
    }
  }
#pragma unroll
  for (int h = 0; h < 2; ++h) {
    atomicAdd(&aS[nn_[h]], sum[h]);
    atomicAdd(&aQ[nn_[h]], sq[h]);
  }
  __syncthreads();
  if (t < 32) { pS[(size_t)blockIdx.x*32 + t] = aS[t]; pQ[(size_t)blockIdx.x*32 + t] = aQ[t]; }
}

// ---------------- TopKFreq ----------------
__global__ void k_att(const float* __restrict__ z1, const float* __restrict__ z1r,
    const float* __restrict__ bn2, const float* __restrict__ u, const float* __restrict__ fcb,
    float* __restrict__ att)
{
  int r = blockIdx.x*4 + (threadIdx.x >> 6);
  int lane = threadIdx.x & 63;
  const float* z1p = z1 + (size_t)r*512;
  const float* zrp = z1r + (size_t)r*512;
  float s = 0.f;
  for (int i = lane; i < 512; i += 64) {
    int n = i >> 4;
    float z2 = gelu_f(bn2[n]*zrp[i] + bn2[32+n]);
    s += (z1p[i] + z2) * u[i];
  }
  s = wred(s);
  if (lane == 0) att[r] = s + fcb[0];
}

__global__ __launch_bounds__(1024) void k_tf(const float* __restrict__ att,
    const float* __restrict__ pg, const float* __restrict__ pb,
    const float* __restrict__ pwc, const float* __restrict__ pbc,
    const float* __restrict__ pfb, float* __restrict__ a1, float* __restrict__ a2)
{
  __shared__ double sd[1024];
  __shared__ float sh[4];
  const int t = threadIdx.x;
  float g = pg[0], b = pb[0], wc = pwc[0], bc = pbc[0], fb = pfb[0];
  double s = 0.0, q = 0.0;
  for (int i = t; i < BD; i += 1024) { double v = att[i]; s += v; q += v*v; }
  sd[t] = s; __syncthreads();
  for (int o = 512; o > 0; o >>= 1) { if (t < o) sd[t] += sd[t+o]; __syncthreads(); }
  double S1 = sd[0]; __syncthreads();
  sd[t] = q; __syncthreads();
  for (int o = 512; o > 0; o >>= 1) { if (t < o) sd[t] += sd[t+o]; __syncthreads(); }
  if (t == 0) {
    double m = S1 / 14336.0;
    double v = sd[0] / 14336.0 - m*m; if (v < 0.0) v = 0.0;
    sh[0] = (float)m; sh[1] = (float)(1.0 / sqrt(v + 1e-5));
  }
  __syncthreads();
  float m1 = sh[0], i1 = sh[1];
  s = 0.0; q = 0.0;
  for (int i = t; i < BD; i += 1024) {
    float v = att[i];
    float an = (v - m1) * i1 * g + b;
    float av = sigm_f(gelu_f(an) * wc + bc);
    a1[i] = av;
    float t2 = av * (v - fb) + fb;
    s += t2; q += (double)t2 * t2;
  }
  __syncthreads();
  sd[t] = s; __syncthreads();
  for (int o = 512; o > 0; o >>= 1) { if (t < o) sd[t] += sd[t+o]; __syncthreads(); }
  double S2 = sd[0]; __syncthreads();
  sd[t] = q; __syncthreads();
  for (int o = 512; o > 0; o >>= 1) { if (t < o) sd[t] += sd[t+o]; __syncthreads(); }
  if (t == 0) {
    double m = S2 / 14336.0;
    double v = sd[0] / 14336.0 - m*m; if (v < 0.0) v = 0.0;
    sh[2] = (float)m; sh[3] = (float)(1.0 / sqrt(v + 1e-5));
  }
  __syncthreads();
  float m2 = sh[2], i2 = sh[3];
  for (int i = t; i < BD; i += 1024) {
    float t2 = a1[i] * (att[i] - fb) + fb;
    float an = (t2 - m2) * i2 * g + b;
    a2[i] = sigm_f(gelu_f(an) * wc + bc);
  }
}

// ---------------- elementwise stats passes ----------------
__global__ void k_statsA(const float* __restrict__ z1, const float* __restrict__ z1r,
    const float* __restrict__ bn2, const float* __restrict__ a1,
    float* __restrict__ rs, float* __restrict__ rq)
{
  int r = blockIdx.x*4 + (threadIdx.x >> 6);
  int lane = threadIdx.x & 63;
  float av = a1[r];
  const float* z1p = z1 + (size_t)r*512;
  const float* zrp = z1r + (size_t)r*512;
  float s = 0.f, q = 0.f;
  for (int i = lane; i < 512; i += 64) {
    int n = i >> 4;
    float z2 = gelu_f(bn2[n]*zrp[i] + bn2[32+n]);
    float A = (z1p[i] + z2) * av;
    s += A; q += A*A;
  }
  s = wred(s); q = wred(q);
  if (lane == 0) { rs[r] = s; rq[r] = q; }
}

__global__ void k_statsC(const float* __restrict__ z1, const float* __restrict__ z1r,
    const float* __restrict__ bn2, const float* __restrict__ a1,
    const float* __restrict__ bn3, const float* __restrict__ cw, const float* __restrict__ cb,
    float* __restrict__ rs, float* __restrict__ rq)
{
  int r = blockIdx.x*4 + (threadIdx.x >> 6);
  int lane = threadIdx.x & 63;
  int d = r % 7;
  float av = a1[r];
  float b3a = bn3[d], b3c = bn3[7+d], wv = cw[d], bv = cb[d];
  const float* z1p = z1 + (size_t)r*512;
  const float* zrp = z1r + (size_t)r*512;
  float s = 0.f, q = 0.f;
  for (int i = lane; i < 512; i += 64) {
    int n = i >> 4;
    float z2 = gelu_f(bn2[n]*zrp[i] + bn2[32+n]);
    float A = (z1p[i] + z2) * av;
    float zB = gelu_f(b3a*A + b3c);
    float C = wv*zB + bv;
    s += C; q += C*C;
  }
  s = wred(s); q = wred(q);
  if (lane == 0) { rs[r] = s; rq[r] = q; }
}

__global__ void k_final(const float* __restrict__ z1, const float* __restrict__ z1r,
    const float* __restrict__ bn2, const float* __restrict__ a1, const float* __restrict__ a2,
    const float* __restrict__ bn3, const float* __restrict__ bn4,
    const float* __restrict__ cw, const float* __restrict__ cb,
    float* __restrict__ zf, float* __restrict__ rs, float* __restrict__ rq)
{
  int r = blockIdx.x*4 + (threadIdx.x >> 6);
  int lane = threadIdx.x & 63;
  int d = r % 7;
  float av = a1[r], a2v = a2[r];
  float b3a = bn3[d], b3c = bn3[7+d], b4a = bn4[d], b4c = bn4[7+d];
  float wv = cw[d], bv = cb[d];
  const float* z1p = z1 + (size_t)r*512;
  const float* zrp = z1r + (size_t)r*512;
  float* zfp = zf + (size_t)r*512;
  float s = 0.f, q = 0.f;
  for (int i = lane; i < 512; i += 64) {
    int n = i >> 4;
    float z1v = z1p[i] * av;
    float z2v = gelu_f(bn2[n]*zrp[i] + bn2[32+n]) * av;
    float A = z1v + z2v;
    float zB = gelu_f(b3a*A + b3c);
    float C = wv*zB + bv;
    float inter = gelu_f(b4a*C + b4c) * a2v;
    float z1n = z1v*inter + z2v;
    float z2n = z2v*inter + z1n;
    float zfv = z1n*z2n + z1n + z2n;
    zfp[i] = zfv;
    s += zfv; q += zfv*zfv;
  }
  s = wred(s); q = wred(q);
  if (lane == 0) { rs[r] = s; rq[r] = q; }
}

__global__ void k_rowstat48(const float* __restrict__ h2, float* __restrict__ rs, float* __restrict__ rq) {
  int r = blockIdx.x*4 + (threadIdx.x >> 6);
  int lane = threadIdx.x & 63;
  float v = (lane < 48) ? h2[(size_t)r*48 + lane] : 0.0f;
  float s = wred(v), q = wred(v*v);
  if (lane == 0) { rs[r] = s; rq[r] = q; }
}

// ---------------- output: fc2 + bias + z_res + transpose ----------------
__global__ __launch_bounds__(256) void k_out(const float* __restrict__ h2,
    const float* __restrict__ bn6, const float* __restrict__ w2, const float* __restrict__ b2,
    const float* __restrict__ zres, float* __restrict__ out)
{
  int idx = blockIdx.x*256 + threadIdx.x;
  int r = idx / 96, o = idx - r*96;
  int d = r % 7, b = r / 7;
  float a6 = bn6[d], c6 = bn6[7+d];
  const float* hp = h2 + (size_t)r*48;
  const float* wp = w2 + o*48;
  float s = 0.f;
#pragma unroll 8
  for (int j = 0; j < 48; ++j) s += (a6*hp[j] + c6) * wp[j];
  out[(size_t)b*672 + o*7 + d] = s + b2[o] + zres[(size_t)r*96 + o];
}

// ================= host =================
extern "C" void kernel_launch(void* const* d_in, const int* in_sizes, int n_in,
                              void* d_out, int out_size, void* d_ws, size_t ws_size,
                              hipStream_t stream) {
  const float* x          = (const float*)d_in[0];
  const float* dctconv_w  = (const float*)d_in[1];
  const float* dctconv_b  = (const float*)d_in[2];
  const float* dctnorm_g  = (const float*)d_in[3];
  const float* dctnorm_b  = (const float*)d_in[4];
  const float* threshold  = (const float*)d_in[5];
  const float* embed_W    = (const float*)d_in[6];
  const float* embed_b    = (const float*)d_in[7];
  const float* linres_W   = (const float*)d_in[8];
  const float* linres_b   = (const float*)d_in[9];
  const float* depth1_w   = (const float*)d_in[10];
  const float* depth1_b   = (const float*)d_in[11];
  const float* depthnorm_g= (const float*)d_in[12];
  const float* depthnorm_b= (const float*)d_in[13];
  const float* tf_fc_w    = (const float*)d_in[14];
  const float* tf_fc_b    = (const float*)d_in[15];
  const float* tf_norm_g  = (const float*)d_in[16];
  const float* tf_norm_b  = (const float*)d_in[17];
  const float* tf_conv_w  = (const float*)d_in[18];
  const float* tf_conv_b  = (const float*)d_in[19];
  const float* mlp_w1     = (const float*)d_in[20];
  const float* mlp_b1     = (const float*)d_in[21];
  const float* mlp_w2     = (const float*)d_in[22];
  const float* mlp_b2     = (const float*)d_in[23];
  const float* mlpnorm_g  = (const float*)d_in[24];
  const float* mlpnorm_b  = (const float*)d_in[25];
  float* out = (float*)d_out;
  float* ws  = (float*)d_ws;

  float* XP   = ws + F_XP;
  float* ZG   = ws + F_ZG;
  float* Z1   = ws + F_Z1;
  float* CLK  = ws + F_CLK;
  float* MKL  = ws + F_MKL;
  float* U    = ws + F_U;
  float* CSUM = ws + F_CSUM;
  float* W2p  = ws + F_W2;
  float* CSTp = ws + F_CST;
  float* Vp   = ws + F_V;
  float* C2p  = ws + F_C2;
  float* ZRES = ws + F_ZRES;
  float* H2p  = ws + F_H2;
  float* EN   = ws + F_EN;
  float* NEp  = ws + F_NE;
  float* ATTp = ws + F_ATT;
  float* A1p  = ws + F_A1;
  float* A2p  = ws + F_A2;
  float* RS   = ws + F_RS;
  float* RQ   = ws + F_RQ;
  float* PS   = ws + F_PS;
  float* PQ   = ws + F_PQ;
  float* BN0  = ws + F_BN;        // a[7], c[7]
  float* BN2  = ws + F_BN + 16;   // a[32], c[32]
  float* BN3  = ws + F_BN + 80;
  float* BN4  = ws + F_BN + 96;
  float* BN5  = ws + F_BN + 112;
  float* BN6  = ws + F_BN + 128;
  float* THRp = ws + F_THR;

  k_gen_cos<<<512, 256, 0, stream>>>(CLK, MKL);
  k_ucsum<<<2, 256, 0, stream>>>(MKL, U, CSUM, tf_fc_w);
  k_w2<<<96, 256, 0, stream>>>(linres_W, linres_b, embed_W, embed_b, W2p, CSTp);
  k_v<<<32, 256, 0, stream>>>(embed_W, embed_b, depth1_w, depth1_b, Vp, C2p);
  k_transpose<<<2048, 256, 0, stream>>>(x, XP);
  k_gemm_nn<0><<<dim3(224,4), 256, 0, stream>>>(XP, CLK, ZG, nullptr, nullptr, nullptr, nullptr, nullptr);
  k_energy<<<3584, 256, 0, stream>>>(ZG, EN);
  k_ne<<<8, 256, 0, stream>>>(EN, NEp);
  k_thr<<<1, 1024, 0, stream>>>(NEp, threshold, THRp);
  k_mask_gelu<<<14336, 256, 0, stream>>>(ZG, NEp, THRp, dctconv_w, dctconv_b, RS, RQ);
  k_bnfin_rows<<<7, 256, 0, stream>>>(RS, RQ, 7, BD, 1048576.0, dctnorm_g, dctnorm_b, BN0);
  k_gemm_nn<1><<<dim3(224,4), 256, 0, stream>>>(ZG, MKL, Z1, BN0, CSUM, XP, dctconv_w, dctconv_b);
  k_patch<<<1792, 256, 0, stream>>>(XP, Vp, C2p, ZG, PS, PQ);
  k_bnfin_part<<<32, 256, 0, stream>>>(PS, PQ, 1792, 32, 229376.0, depthnorm_g, depthnorm_b, BN2);
  k_gemm_nt<0,false><<<dim3(224,2), 256, 0, stream>>>(XP, W2p, CSTp, ZRES, 96, 96, nullptr, nullptr);
  k_att<<<3584, 256, 0, stream>>>(Z1, ZG, BN2, U, tf_fc_b, ATTp);
  k_tf<<<1, 1024, 0, stream>>>(ATTp, tf_norm_g, tf_norm_b, tf_conv_w, tf_conv_b, tf_fc_b, A1p, A2p);
  k_statsA<<<3584, 256, 0, stream>>>(Z1, ZG, BN2, A1p, RS, RQ);
  k_bnfin_rows<<<7, 256, 0, stream>>>(RS, RQ, 7, BD, 1048576.0, dctnorm_g, dctnorm_b, BN3);
  k_statsC<<<3584, 256, 0, stream>>>(Z1, ZG, BN2, A1p, BN3, dctconv_w, dctconv_b, RS, RQ);
  k_bnfin_rows<<<7, 256, 0, stream>>>(RS, RQ, 7, BD, 1048576.0, dctnorm_g, dctnorm_b, BN4);
  k_final<<<3584, 256, 0, stream>>>(Z1, ZG, BN2, A1p, A2p, BN3, BN4, dctconv_w, dctconv_b, XP, RS, RQ);
  k_bnfin_rows<<<7, 256, 0, stream>>>(RS, RQ, 7, BD, 1048576.0, dctnorm_g, dctnorm_b, BN5);
  k_gemm_nt<1,true><<<dim3(224,1), 256, 0, stream>>>(XP, mlp_w1, mlp_b1, H2p, 48, 48, BN5, BN5+7);
  k_rowstat48<<<3584, 256, 0, stream>>>(H2p, RS, RQ);
  k_bnfin_rows<<<7, 256, 0, stream>>>(RS, RQ, 7, BD, 98304.0, mlpnorm_g, mlpnorm_b, BN6);
  k_out<<<5376, 256, 0, stream>>>(H2p, BN6, mlp_w2, mlp_b2, ZRES, out);
}

// Round 2
// 591.362 us; speedup vs baseline: 1.4025x; 1.4025x over previous
//
#include <hip/hip_runtime.h>
#include <math.h>

#define BB 2048
#define LL 512
#define DD 7
#define BD 14336   // BB*DD
#define NP 32      // patches
#define PL 16      // patch len

// ---------------- ws layout (floats) ----------------
constexpr size_t F_XP   = 0;                          // xp, later zf
constexpr size_t F_ZG   = F_XP  + (size_t)BD*512;     // z_dct -> g -> z1r
constexpr size_t F_Z1   = F_ZG  + (size_t)BD*512;     // z1
constexpr size_t F_CLK  = F_Z1  + (size_t)BD*512;     // C[l][k] * 2
constexpr size_t F_MKL  = F_CLK + 512*512;            // C[k][l] * sc[k]
constexpr size_t F_U    = F_MKL + 512*512;
constexpr size_t F_CSUM = F_U + 512;
constexpr size_t F_W2   = F_CSUM + 512;               // 96x512
constexpr size_t F_CST  = F_W2 + 96*512;
constexpr size_t F_V    = F_CST + 96;                 // 32x16x16
constexpr size_t F_C2   = F_V + 32*256;               // 32x16
constexpr size_t F_ZRES = F_C2 + 512;                 // BD x 96
constexpr size_t F_H2   = F_ZRES + (size_t)BD*96;     // BD x 48
constexpr size_t F_EN   = F_H2 + (size_t)BD*48;
constexpr size_t F_NE   = F_EN + BD;
constexpr size_t F_ATT  = F_NE + BD;
constexpr size_t F_A1   = F_ATT + BD;
constexpr size_t F_A2   = F_A1 + BD;
constexpr size_t F_RS   = F_A2 + BD;
constexpr size_t F_RQ   = F_RS + BD;
constexpr size_t F_PS   = F_RQ + BD;                  // 1792 x 32
constexpr size_t F_PQ   = F_PS + 1792*32;
constexpr size_t F_BN   = F_PQ + 1792*32;             // bn affine params
constexpr size_t F_THR  = F_BN + 256;

__device__ __forceinline__ float gelu_f(float x) {
  return 0.5f * x * (1.0f + erff(x * 0.70710678118654752440f));
}
__device__ __forceinline__ float sigm_f(float x) {
  return 1.0f / (1.0f + expf(-x));
}
__device__ __forceinline__ float wred(float v) {
#pragma unroll
  for (int o = 32; o > 0; o >>= 1) v += __shfl_down(v, o);
  return v;
}

// ---------------- constant generation ----------------
__global__ void k_gen_cos(float* __restrict__ Clk, float* __restrict__ Mkl) {
  int k = blockIdx.x;
  for (int l = threadIdx.x; l < 512; l += 256) {
    double c = cos(3.14159265358979323846 * (l + 0.5) * k / 512.0);
    Clk[(size_t)l*512 + k] = (float)(2.0 * c);
    Mkl[(size_t)k*512 + l] = (float)(c * (k == 0 ? (1.0/1024.0) : (1.0/512.0)));
  }
}

__global__ void k_ucsum(const float* __restrict__ Mkl, float* __restrict__ u,
                        float* __restrict__ csum, const float* __restrict__ wf) {
  int l = blockIdx.x*256 + threadIdx.x;
  if (l >= 512) return;
  double s = 0.0;
  for (int k = 0; k < 512; ++k) s += (double)Mkl[(size_t)k*512 + l];
  csum[l] = (float)s;
  double uu = (double)wf[0] * 45.25483399593904156 * (double)Mkl[l];      // sqrt(2048)
  for (int k = 1; k < 5; ++k) uu += (double)wf[k] * 32.0 * (double)Mkl[(size_t)k*512 + l];
  u[l] = (float)uu;
}

__global__ __launch_bounds__(256) void k_w2(const float* __restrict__ linW,
    const float* __restrict__ linb, const float* __restrict__ eW, const float* __restrict__ eb,
    float* __restrict__ W2, float* __restrict__ cst)
{
  __shared__ float sW[768];
  __shared__ float sb[48];
  __shared__ float rbuf[256];
  int o = blockIdx.x, t = threadIdx.x;
  for (int i = t; i < 768; i += 256) sW[i] = eW[i];
  if (t < 48) sb[t] = eb[t];
  __syncthreads();
  const float* lw = linW + (size_t)o * 1536;
  for (int i = t; i < 512; i += 256) {
    int n = i >> 4, p = i & 15;
    float s = 0.f;
    const float* l2 = lw + n*48;
#pragma unroll 8
    for (int m = 0; m < 48; ++m) s += l2[m] * sW[m*16 + p];
    W2[(size_t)o*512 + i] = s;
  }
  float c = 0.f;
  for (int i = t; i < 1536; i += 256) c += lw[i] * sb[i % 48];
  rbuf[t] = c; __syncthreads();
  for (int off = 128; off > 0; off >>= 1) { if (t < off) rbuf[t] += rbuf[t+off]; __syncthreads(); }
  if (t == 0) cst[o] = rbuf[0] + linb[o];
}

__global__ void k_v(const float* __restrict__ eW, const float* __restrict__ eb,
                    const float* __restrict__ dw, const float* __restrict__ db,
                    float* __restrict__ V, float* __restrict__ c2)
{
  int n = blockIdx.x, t = threadIdx.x;
  int p = t >> 4, q = t & 15;
  float s = 0.f;
#pragma unroll
  for (int j = 0; j < 3; ++j) s += eW[(p*3+j)*16 + q] * dw[n*3+j];
  V[(size_t)n*256 + p*16 + q] = s;
  if (q == 0) {
    float c = 0.f;
#pragma unroll
    for (int j = 0; j < 3; ++j) c += eb[p*3+j] * dw[n*3+j];
    c2[n*16+p] = c + db[n];
  }
}

// ---------------- transpose [B,L,D] -> [B*D, L] ----------------
__global__ __launch_bounds__(256) void k_transpose(const float* __restrict__ x, float* __restrict__ xp) {
  __shared__ float s[3584];
  int b = blockIdx.x;
  const float* src = x + (size_t)b*3584;
  for (int c = threadIdx.x; c < 896; c += 256) {
    float4 v = *(const float4*)&src[c*4];
    s[c*4+0]=v.x; s[c*4+1]=v.y; s[c*4+2]=v.z; s[c*4+3]=v.w;
  }
  __syncthreads();
  for (int c = threadIdx.x; c < 896; c += 256) {
    int d = c >> 7, cg = c & 127;
    float4 v;
    v.x = s[(cg*4+0)*7 + d]; v.y = s[(cg*4+1)*7 + d];
    v.z = s[(cg*4+2)*7 + d]; v.w = s[(cg*4+3)*7 + d];
    *(float4*)&xp[((size_t)b*7 + d)*512 + cg*4] = v;
  }
}

// ---------------- big NN GEMM: C[M,512] = A[M,512] @ B[512,512] ----------------
// 128x128 tile, BK=32, 256 threads, 8x8 frags (rows {ty*4, ty*4+64}, cols {tx*4, tx*4+64}).
// MODE 0: plain store. MODE 1: out = aR*acc + cR*csum[col] + (xp*w_d + b_d)
template<int MODE>
__global__ __launch_bounds__(256) void k_gemm_nn(
    const float* __restrict__ A, const float* __restrict__ Bm, float* __restrict__ Cc,
    const float* __restrict__ bnac, const float* __restrict__ csum,
    const float* __restrict__ xp, const float* __restrict__ cw, const float* __restrict__ cb)
{
  __shared__ float As[128][33];
  __shared__ float Bs[32][128];
  const int t = threadIdx.x;
  const int tx = t & 15, ty = t >> 4;
  const int r0 = blockIdx.x * 128, c0 = blockIdx.y * 128;
  float acc[8][8];
#pragma unroll
  for (int i = 0; i < 8; ++i)
#pragma unroll
    for (int j = 0; j < 8; ++j) acc[i][j] = 0.f;

  for (int kt = 0; kt < 512; kt += 32) {
#pragma unroll
    for (int h = 0; h < 4; ++h) {
      int c = t + h*256;
      int row = c >> 3, cg = c & 7;
      float4 v = *(const float4*)&A[(size_t)(r0+row)*512 + kt + cg*4];
      As[row][cg*4+0]=v.x; As[row][cg*4+1]=v.y; As[row][cg*4+2]=v.z; As[row][cg*4+3]=v.w;
    }
#pragma unroll
    for (int h = 0; h < 4; ++h) {
      int c = t + h*256;
      int row = c >> 5, cg = c & 31;
      *(float4*)&Bs[row][cg*4] = *(const float4*)&Bm[(size_t)(kt+row)*512 + c0 + cg*4];
    }
    __syncthreads();
#pragma unroll
    for (int kk = 0; kk < 32; ++kk) {
      float av[8], bv[8];
#pragma unroll
      for (int i = 0; i < 4; ++i) {
        av[i]   = As[ty*4+i][kk];
        av[4+i] = As[64+ty*4+i][kk];
      }
      float4 b0 = *(const float4*)&Bs[kk][tx*4];
      float4 b1 = *(const float4*)&Bs[kk][tx*4+64];
      bv[0]=b0.x; bv[1]=b0.y; bv[2]=b0.z; bv[3]=b0.w;
      bv[4]=b1.x; bv[5]=b1.y; bv[6]=b1.z; bv[7]=b1.w;
#pragma unroll
      for (int i = 0; i < 8; ++i)
#pragma unroll
        for (int j = 0; j < 8; ++j) acc[i][j] += av[i]*bv[j];
    }
    __syncthreads();
  }
#pragma unroll
  for (int h = 0; h < 2; ++h) {
#pragma unroll
    for (int i = 0; i < 4; ++i) {
      const int r = r0 + h*64 + ty*4 + i;
      const int ai = h*4 + i;
      if (MODE == 0) {
        float4 v0 = make_float4(acc[ai][0],acc[ai][1],acc[ai][2],acc[ai][3]);
        float4 v1 = make_float4(acc[ai][4],acc[ai][5],acc[ai][6],acc[ai][7]);
        *(float4*)&Cc[(size_t)r*512 + c0 + tx*4]      = v0;
        *(float4*)&Cc[(size_t)r*512 + c0 + tx*4 + 64] = v1;
      } else {
        const int d = r % 7;
        const float aR = bnac[d], cR = bnac[7+d], wv = cw[d], bvv = cb[d];
#pragma unroll
        for (int g = 0; g < 2; ++g) {
          int col = c0 + tx*4 + g*64;
          float4 xv = *(const float4*)&xp[(size_t)r*512 + col];
          float4 cs = *(const float4*)&csum[col];
          float4 v;
          v.x = aR*acc[ai][g*4+0] + cR*cs.x + (xv.x*wv + bvv);
          v.y = aR*acc[ai][g*4+1] + cR*cs.y + (xv.y*wv + bvv);
          v.z = aR*acc[ai][g*4+2] + cR*cs.z + (xv.z*wv + bvv);
          v.w = aR*acc[ai][g*4+3] + cR*cs.w + (xv.w*wv + bvv);
          *(float4*)&Cc[(size_t)r*512 + col] = v;
        }
      }
    }
  }
}

// ---------------- NT GEMM: out[M,Ncols] = A[M,512] @ W[Ncols,512]^T + bias ----------------
// 64x64 tile, BK=32. MODE 0: store val. MODE 1: store gelu(val)*val.
// TRANS: A element -> gelu(ta[d]*x + tc[d]) at stage time.
template<int MODE, bool TRANS>
__global__ __launch_bounds__(256) void k_gemm_nt(
    const float* __restrict__ A, const float* __restrict__ W, const float* __restrict__ bias,
    float* __restrict__ out, int Ncols, int ldOut,
    const float* __restrict__ ta, const float* __restrict__ tc)
{
  __shared__ float As[64][33];
  __shared__ float Bs[32][68];
  const int t = threadIdx.x;
  const int tx = t & 15, ty = t >> 4;
  const int r0 = blockIdx.x*64, c0 = blockIdx.y*64;
  float acc[4][4];
#pragma unroll
  for (int i = 0; i < 4; ++i)
#pragma unroll
    for (int j = 0; j < 4; ++j) acc[i][j] = 0.f;

  for (int kt = 0; kt < 512; kt += 32) {
#pragma unroll
    for (int h = 0; h < 2; ++h) {
      int c = t + h*256;
      int row = c >> 3, cg = c & 7;
      float4 v = *(const float4*)&A[(size_t)(r0+row)*512 + kt + cg*4];
      if (TRANS) {
        int d = (r0 + row) % 7;
        float aa = ta[d], cc = tc[d];
        v.x = gelu_f(aa*v.x + cc); v.y = gelu_f(aa*v.y + cc);
        v.z = gelu_f(aa*v.z + cc); v.w = gelu_f(aa*v.w + cc);
      }
      As[row][cg*4+0]=v.x; As[row][cg*4+1]=v.y; As[row][cg*4+2]=v.z; As[row][cg*4+3]=v.w;
    }
#pragma unroll
    for (int h = 0; h < 2; ++h) {
      int c = t + h*256;
      int row = c >> 3, cg = c & 7;
      int o = c0 + row;
      float4 v = make_float4(0.f,0.f,0.f,0.f);
      if (o < Ncols) v = *(const float4*)&W[(size_t)o*512 + kt + cg*4];
      Bs[cg*4+0][row]=v.x; Bs[cg*4+1][row]=v.y; Bs[cg*4+2][row]=v.z; Bs[cg*4+3][row]=v.w;
    }
    __syncthreads();
#pragma unroll
    for (int kk = 0; kk < 32; ++kk) {
      float av[4];
#pragma unroll
      for (int i = 0; i < 4; ++i) av[i] = As[ty*4+i][kk];
      float4 b = *(const float4*)&Bs[kk][tx*4];
      float bv[4] = {b.x,b.y,b.z,b.w};
#pragma unroll
      for (int i = 0; i < 4; ++i)
#pragma unroll
        for (int j = 0; j < 4; ++j) acc[i][j] += av[i]*bv[j];
    }
    __syncthreads();
  }
#pragma unroll
  for (int i = 0; i < 4; ++i) {
    int r = r0 + ty*4 + i;
#pragma unroll
    for (int j = 0; j < 4; ++j) {
      int col = c0 + tx*4 + j;
      if (col < Ncols) {
        float v = acc[i][j] + bias[col];
        if (MODE == 1) { float g = gelu_f(v); v = g*v; }
        out[(size_t)r*ldOut + col] = v;
      }
    }
  }
}

// ---------------- energy / median / quantile ----------------
__global__ void k_energy(const float* __restrict__ zg, float* __restrict__ en) {
  int r = blockIdx.x*4 + (threadIdx.x >> 6);
  int lane = threadIdx.x & 63;
  const float* row = zg + (size_t)r*512;
  float s = 0.f;
  for (int i = lane; i < 512; i += 64) { float v = row[i]; s += v*v; }
  s = wred(s);
  if (lane == 0) en[r] = s;
}

__global__ void k_ne(const float* __restrict__ en, float* __restrict__ ne) {
  int b = blockIdx.x*256 + threadIdx.x;
  if (b >= 2048) return;
  float e[7], s7[7];
#pragma unroll
  for (int d = 0; d < 7; ++d) { e[d] = en[b*7+d]; s7[d] = e[d]; }
#pragma unroll
  for (int i = 1; i < 7; ++i) {
    float key = s7[i]; int j = i-1;
    while (j >= 0 && s7[j] > key) { s7[j+1] = s7[j]; --j; }
    s7[j+1] = key;
  }
  float med = s7[3] + 1e-6f;
#pragma unroll
  for (int d = 0; d < 7; ++d) ne[b*7+d] = e[d] / med;
}

// exact k-th-smallest via register-resident 4-bit radix select.
// Keys (positive floats) live in 14 VGPRs/thread; per round a 64-bit bit-sliced
// accumulator counts 16 buckets; cross-lane via packed shfl; t0 picks the bucket.
// Second order statistic s[lo+1] from one extra count/min pass.
__global__ __launch_bounds__(1024) void k_thr(const float* __restrict__ ne,
                                              const float* __restrict__ qp, float* __restrict__ out)
{
  __shared__ unsigned s_part[16][8];
  __shared__ unsigned s_bsel, s_R;
  const int t = threadIdx.x;
  const int lane = t & 63, wv = t >> 6;
  unsigned key[14];
#pragma unroll
  for (int j = 0; j < 14; ++j) key[j] = __float_as_uint(ne[t + j*1024]);

  float q = qp[0];
  float pos = q * 14335.0f;
  int lo = (int)floorf(pos);
  if (lo < 0) lo = 0; if (lo > 14335) lo = 14335;
  int hi = lo + 1; if (hi > 14335) hi = 14335;
  float frac = pos - (float)lo;

  unsigned prefix = 0;
  unsigned R = (unsigned)lo;
#pragma unroll 1
  for (int shift = 28; shift >= 0; shift -= 4) {
    unsigned pb = prefix >> shift;
    unsigned long long accb = 0ull;
#pragma unroll
    for (int j = 0; j < 14; ++j) {
      unsigned diff = (key[j] >> shift) - pb;
      accb += (diff < 16u) ? (1ull << (diff*4)) : 0ull;
    }
    unsigned pk[8];
#pragma unroll
    for (int b = 0; b < 8; ++b) {
      unsigned clo = (unsigned)(accb >> (b*4)) & 15u;
      unsigned chi = (unsigned)(accb >> (b*4+32)) & 15u;
      pk[b] = clo | (chi << 16);
    }
#pragma unroll
    for (int b = 0; b < 8; ++b)
#pragma unroll
      for (int o = 32; o > 0; o >>= 1) pk[b] += __shfl_down(pk[b], o);
    if (lane == 0) {
#pragma unroll
      for (int b = 0; b < 8; ++b) s_part[wv][b] = pk[b];
    }
    __syncthreads();
    if (t == 0) {
      unsigned tot[16];
#pragma unroll
      for (int i = 0; i < 8; ++i) {
        unsigned s = 0;
#pragma unroll
        for (int w = 0; w < 16; ++w) s += s_part[w][i];
        tot[i] = s & 0xFFFFu; tot[i+8] = s >> 16;
      }
      unsigned cum = 0, bsel = 15;
#pragma unroll 1
      for (int b = 0; b < 16; ++b) {
        if (cum + tot[b] > R) { bsel = (unsigned)b; break; }
        cum += tot[b];
      }
      s_bsel = bsel; s_R = R - cum;
    }
    __syncthreads();
    prefix |= (s_bsel << shift);
    R = s_R;
    __syncthreads();
  }
  // prefix == bit pattern of s[lo]; now get s[lo+1] via count(<=) + min(>)
  unsigned cle = 0, mn = 0xFFFFFFFFu;
#pragma unroll
  for (int j = 0; j < 14; ++j) {
    cle += (key[j] <= prefix) ? 1u : 0u;
    if (key[j] > prefix && key[j] < mn) mn = key[j];
  }
#pragma unroll
  for (int o = 32; o > 0; o >>= 1) {
    cle += __shfl_down(cle, o);
    unsigned m2 = __shfl_down(mn, o);
    mn = (m2 < mn) ? m2 : mn;
  }
  if (lane == 0) { s_part[wv][0] = cle; s_part[wv][1] = mn; }
  __syncthreads();
  if (t == 0) {
    unsigned C = 0, M = 0xFFFFFFFFu;
#pragma unroll
    for (int w = 0; w < 16; ++w) {
      C += s_part[w][0];
      if (s_part[w][1] < M) M = s_part[w][1];
    }
    unsigned vhiKey = (C > (unsigned)hi) ? prefix : M;
    if (vhiKey == 0xFFFFFFFFu) vhiKey = prefix;
    float vlo = __uint_as_float(prefix);
    float vhi = __uint_as_float(vhiKey);
    out[0] = vlo*(1.0f-frac) + vhi*frac;
  }
}

// ---------------- mask + dctconv + gelu (in place) + row stats ----------------
__global__ __launch_bounds__(256) void k_mask_gelu(float* __restrict__ zg,
    const float* __restrict__ ne, const float* __restrict__ thr,
    const float* __restrict__ cw, const float* __restrict__ cb,
    float* __restrict__ rs, float* __restrict__ rq)
{
  __shared__ float sb[8];
  int r = blockIdx.x, t = threadIdx.x;
  int d = r % 7;
  float m = (ne[r] > thr[0]) ? 1.0f : 0.0f;
  float wm = cw[d] * m, bv = cb[d];
  float* row = zg + (size_t)r * 512;
  float s = 0.f, qq = 0.f;
#pragma unroll
  for (int h = 0; h < 2; ++h) {
    int i = t + h*256;
    float g = gelu_f(row[i]*wm + bv);
    row[i] = g;
    s += g; qq += g*g;
  }
  s = wred(s); qq = wred(qq);
  int lane = t & 63, w = t >> 6;
  if (lane == 0) { sb[w] = s; sb[4+w] = qq; }
  __syncthreads();
  if (t == 0) { rs[r] = sb[0]+sb[1]+sb[2]+sb[3]; rq[r] = sb[4]+sb[5]+sb[6]+sb[7]; }
}

// ---------------- BN finalize from per-row sums ----------------
__global__ __launch_bounds__(256) void k_bnfin_rows(const float* __restrict__ rs,
    const float* __restrict__ rq, int nch, int nrows, double count,
    const float* __restrict__ gamma, const float* __restrict__ beta, float* __restrict__ out)
{
  __shared__ double sd[256];
  int ch = blockIdx.x, t = threadIdx.x;
  double s = 0.0, q = 0.0;
  for (int i = ch + t*nch; i < nrows; i += 256*nch) { s += rs[i]; q += rq[i]; }
  sd[t] = s; __syncthreads();
  for (int o = 128; o > 0; o >>= 1) { if (t < o) sd[t] += sd[t+o]; __syncthreads(); }
  double S = sd[0]; __syncthreads();
  sd[t] = q; __syncthreads();
  for (int o = 128; o > 0; o >>= 1) { if (t < o) sd[t] += sd[t+o]; __syncthreads(); }
  if (t == 0) {
    double m = S / count;
    double v = sd[0] / count - m*m; if (v < 0.0) v = 0.0;
    double inv = 1.0 / sqrt(v + 1e-5);
    out[ch]       = (float)(gamma[ch] * inv);
    out[nch + ch] = (float)(beta[ch] - m * gamma[ch] * inv);
  }
}

__global__ __launch_bounds__(256) void k_bnfin_part(const float* __restrict__ pS,
    const float* __restrict__ pQ, int nparts, int nch, double count,
    const float* __restrict__ gamma, const float* __restrict__ beta, float* __restrict__ out)
{
  __shared__ double sd[256];
  int ch = blockIdx.x, t = threadIdx.x;
  double s = 0.0, q = 0.0;
  for (int i = t; i < nparts; i += 256) { s += pS[(size_t)i*nch + ch]; q += pQ[(size_t)i*nch + ch]; }
  sd[t] = s; __syncthreads();
  for (int o = 128; o > 0; o >>= 1) { if (t < o) sd[t] += sd[t+o]; __syncthreads(); }
  double S = sd[0]; __syncthreads();
  sd[t] = q; __syncthreads();
  for (int o = 128; o > 0; o >>= 1) { if (t < o) sd[t] += sd[t+o]; __syncthreads(); }
  if (t == 0) {
    double m = S / count;
    double v = sd[0] / count - m*m; if (v < 0.0) v = 0.0;
    double inv = 1.0 / sqrt(v + 1e-5);
    out[ch]       = (float)(gamma[ch] * inv);
    out[nch + ch] = (float)(beta[ch] - m * gamma[ch] * inv);
  }
}

// ---------------- patch path: z1r = V[n] @ xp-patch + c2 ----------------
__global__ __launch_bounds__(256) void k_patch(const float* __restrict__ xp,
    const float* __restrict__ V, const float* __restrict__ c2,
    float* __restrict__ z1r, float* __restrict__ pS, float* __restrict__ pQ)
{
  __shared__ float sx[8][512];
  __shared__ float aS[32], aQ[32];
  int t = threadIdx.x;
  int r0 = blockIdx.x * 8;
  for (int c = t; c < 1024; c += 256) {
    int row = c >> 7, cg = c & 127;
    *(float4*)&sx[row][cg*4] = *(const float4*)&xp[(size_t)(r0+row)*512 + cg*4];
  }
  if (t < 32) { aS[t] = 0.f; aQ[t] = 0.f; }
  __syncthreads();
  float vreg[2][16]; float cc[2]; int nn_[2], oo[2];
#pragma unroll
  for (int h = 0; h < 2; ++h) {
    int o = t + h*256;
    oo[h] = o;
    int n = o >> 4, p = o & 15;
    nn_[h] = n;
#pragma unroll
    for (int qg = 0; qg < 4; ++qg) {
      float4 v4 = *(const float4*)&V[(size_t)n*256 + p*16 + qg*4];
      vreg[h][qg*4+0]=v4.x; vreg[h][qg*4+1]=v4.y; vreg[h][qg*4+2]=v4.z; vreg[h][qg*4+3]=v4.w;
    }
    cc[h] = c2[o];
  }
  float sum[2] = {0.f,0.f}, sq[2] = {0.f,0.f};
  for (int row = 0; row < 8; ++row) {
#pragma unroll
    for (int h = 0; h < 2; ++h) {
      const float* xr = &sx[row][nn_[h]*16];
      float val = cc[h];
#pragma unroll
      for (int qq = 0; qq < 16; ++qq) val += vreg[h][qq] * xr[qq];
      z1r[(size_t)(r0+row)*512 + oo[h]] = val;
      sum[h] += val; sq[h] += val*val;
    }
  }
#pragma unroll
  for (int h = 0; h < 2; ++h) {
    atomicAdd(&aS[nn_[h]], sum[h]);
    atomicAdd(&aQ[nn_[h]], sq[h]);
  }
  __syncthreads();
  if (t < 32) { pS[(size_t)blockIdx.x*32 + t] = aS[t]; pQ[(size_t)blockIdx.x*32 + t] = aQ[t]; }
}

// ---------------- TopKFreq ----------------
__global__ void k_att(const float* __restrict__ z1, const float* __restrict__ z1r,
    const float* __restrict__ bn2, const float* __restrict__ u, const float* __restrict__ fcb,
    float* __restrict__ att)
{
  int r = blockIdx.x*4 + (threadIdx.x >> 6);
  int lane = threadIdx.x & 63;
  const float* z1p = z1 + (size_t)r*512;
  const float* zrp = z1r + (size_t)r*512;
  float s = 0.f;
  for (int i = lane; i < 512; i += 64) {
    int n = i >> 4;
    float z2 = gelu_f(bn2[n]*zrp[i] + bn2[32+n]);
    s += (z1p[i] + z2) * u[i];
  }
  s = wred(s);
  if (lane == 0) att[r] = s + fcb[0];
}

__global__ __launch_bounds__(1024) void k_tf(const float* __restrict__ att,
    const float* __restrict__ pg, const float* __restrict__ pb,
    const float* __restrict__ pwc, const float* __restrict__ pbc,
    const float* __restrict__ pfb, float* __restrict__ a1, float* __restrict__ a2)
{
  __shared__ double sd[1024];
  __shared__ float sh[4];
  const int t = threadIdx.x;
  float g = pg[0], b = pb[0], wc = pwc[0], bc = pbc[0], fb = pfb[0];
  double s = 0.0, q = 0.0;
  for (int i = t; i < BD; i += 1024) { double v = att[i]; s += v; q += v*v; }
  sd[t] = s; __syncthreads();
  for (int o = 512; o > 0; o >>= 1) { if (t < o) sd[t] += sd[t+o]; __syncthreads(); }
  double S1 = sd[0]; __syncthreads();
  sd[t] = q; __syncthreads();
  for (int o = 512; o > 0; o >>= 1) { if (t < o) sd[t] += sd[t+o]; __syncthreads(); }
  if (t == 0) {
    double m = S1 / 14336.0;
    double v = sd[0] / 14336.0 - m*m; if (v < 0.0) v = 0.0;
    sh[0] = (float)m; sh[1] = (float)(1.0 / sqrt(v + 1e-5));
  }
  __syncthreads();
  float m1 = sh[0], i1 = sh[1];
  s = 0.0; q = 0.0;
  for (int i = t; i < BD; i += 1024) {
    float v = att[i];
    float an = (v - m1) * i1 * g + b;
    float av = sigm_f(gelu_f(an) * wc + bc);
    a1[i] = av;
    float t2 = av * (v - fb) + fb;
    s += t2; q += (double)t2 * t2;
  }
  __syncthreads();
  sd[t] = s; __syncthreads();
  for (int o = 512; o > 0; o >>= 1) { if (t < o) sd[t] += sd[t+o]; __syncthreads(); }
  double S2 = sd[0]; __syncthreads();
  sd[t] = q; __syncthreads();
  for (int o = 512; o > 0; o >>= 1) { if (t < o) sd[t] += sd[t+o]; __syncthreads(); }
  if (t == 0) {
    double m = S2 / 14336.0;
    double v = sd[0] / 14336.0 - m*m; if (v < 0.0) v = 0.0;
    sh[2] = (float)m; sh[3] = (float)(1.0 / sqrt(v + 1e-5));
  }
  __syncthreads();
  float m2 = sh[2], i2 = sh[3];
  for (int i = t; i < BD; i += 1024) {
    float t2 = a1[i] * (att[i] - fb) + fb;
    float an = (t2 - m2) * i2 * g + b;
    a2[i] = sigm_f(gelu_f(an) * wc + bc);
  }
}

// ---------------- elementwise stats passes ----------------
__global__ void k_statsA(const float* __restrict__ z1, const float* __restrict__ z1r,
    const float* __restrict__ bn2, const float* __restrict__ a1,
    float* __restrict__ rs, float* __restrict__ rq)
{
  int r = blockIdx.x*4 + (threadIdx.x >> 6);
  int lane = threadIdx.x & 63;
  float av = a1[r];
  const float* z1p = z1 + (size_t)r*512;
  const float* zrp = z1r + (size_t)r*512;
  float s = 0.f, q = 0.f;
  for (int i = lane; i < 512; i += 64) {
    int n = i >> 4;
    float z2 = gelu_f(bn2[n]*zrp[i] + bn2[32+n]);
    float A = (z1p[i] + z2) * av;
    s += A; q += A*A;
  }
  s = wred(s); q = wred(q);
  if (lane == 0) { rs[r] = s; rq[r] = q; }
}

__global__ void k_statsC(const float* __restrict__ z1, const float* __restrict__ z1r,
    const float* __restrict__ bn2, const float* __restrict__ a1,
    const float* __restrict__ bn3, const float* __restrict__ cw, const float* __restrict__ cb,
    float* __restrict__ rs, float* __restrict__ rq)
{
  int r = blockIdx.x*4 + (threadIdx.x >> 6);
  int lane = threadIdx.x & 63;
  int d = r % 7;
  float av = a1[r];
  float b3a = bn3[d], b3c = bn3[7+d], wv = cw[d], bv = cb[d];
  const float* z1p = z1 + (size_t)r*512;
  const float* zrp = z1r + (size_t)r*512;
  float s = 0.f, q = 0.f;
  for (int i = lane; i < 512; i += 64) {
    int n = i >> 4;
    float z2 = gelu_f(bn2[n]*zrp[i] + bn2[32+n]);
    float A = (z1p[i] + z2) * av;
    float zB = gelu_f(b3a*A + b3c);
    float C = wv*zB + bv;
    s += C; q += C*C;
  }
  s = wred(s); q = wred(q);
  if (lane == 0) { rs[r] = s; rq[r] = q; }
}

__global__ void k_final(const float* __restrict__ z1, const float* __restrict__ z1r,
    const float* __restrict__ bn2, const float* __restrict__ a1, const float* __restrict__ a2,
    const float* __restrict__ bn3, const float* __restrict__ bn4,
    const float* __restrict__ cw, const float* __restrict__ cb,
    float* __restrict__ zf, float* __restrict__ rs, float* __restrict__ rq)
{
  int r = blockIdx.x*4 + (threadIdx.x >> 6);
  int lane = threadIdx.x & 63;
  int d = r % 7;
  float av = a1[r], a2v = a2[r];
  float b3a = bn3[d], b3c = bn3[7+d], b4a = bn4[d], b4c = bn4[7+d];
  float wv = cw[d], bv = cb[d];
  const float* z1p = z1 + (size_t)r*512;
  const float* zrp = z1r + (size_t)r*512;
  float* zfp = zf + (size_t)r*512;
  float s = 0.f, q = 0.f;
  for (int i = lane; i < 512; i += 64) {
    int n = i >> 4;
    float z1v = z1p[i] * av;
    float z2v = gelu_f(bn2[n]*zrp[i] + bn2[32+n]) * av;
    float A = z1v + z2v;
    float zB = gelu_f(b3a*A + b3c);
    float C = wv*zB + bv;
    float inter = gelu_f(b4a*C + b4c) * a2v;
    float z1n = z1v*inter + z2v;
    float z2n = z2v*inter + z1n;
    float zfv = z1n*z2n + z1n + z2n;
    zfp[i] = zfv;
    s += zfv; q += zfv*zfv;
  }
  s = wred(s); q = wred(q);
  if (lane == 0) { rs[r] = s; rq[r] = q; }
}

__global__ void k_rowstat48(const float* __restrict__ h2, float* __restrict__ rs, float* __restrict__ rq) {
  int r = blockIdx.x*4 + (threadIdx.x >> 6);
  int lane = threadIdx.x & 63;
  float v = (lane < 48) ? h2[(size_t)r*48 + lane] : 0.0f;
  float s = wred(v), q = wred(v*v);
  if (lane == 0) { rs[r] = s; rq[r] = q; }
}

// ---------------- output: fc2 + bias + z_res + transpose ----------------
__global__ __launch_bounds__(256) void k_out(const float* __restrict__ h2,
    const float* __restrict__ bn6, const float* __restrict__ w2, const float* __restrict__ b2,
    const float* __restrict__ zres, float* __restrict__ out)
{
  int idx = blockIdx.x*256 + threadIdx.x;
  int r = idx / 96, o = idx - r*96;
  int d = r % 7, b = r / 7;
  float a6 = bn6[d], c6 = bn6[7+d];
  const float* hp = h2 + (size_t)r*48;
  const float* wp = w2 + o*48;
  float s = 0.f;
#pragma unroll 8
  for (int j = 0; j < 48; ++j) s += (a6*hp[j] + c6) * wp[j];
  out[(size_t)b*672 + o*7 + d] = s + b2[o] + zres[(size_t)r*96 + o];
}

// ================= host =================
extern "C" void kernel_launch(void* const* d_in, const int* in_sizes, int n_in,
                              void* d_out, int out_size, void* d_ws, size_t ws_size,
                              hipStream_t stream) {
  const float* x          = (const float*)d_in[0];
  const float* dctconv_w  = (const float*)d_in[1];
  const float* dctconv_b  = (const float*)d_in[2];
  const float* dctnorm_g  = (const float*)d_in[3];
  const float* dctnorm_b  = (const float*)d_in[4];
  const float* threshold  = (const float*)d_in[5];
  const float* embed_W    = (const float*)d_in[6];
  const float* embed_b    = (const float*)d_in[7];
  const float* linres_W   = (const float*)d_in[8];
  const float* linres_b   = (const float*)d_in[9];
  const float* depth1_w   = (const float*)d_in[10];
  const float* depth1_b   = (const float*)d_in[11];
  const float* depthnorm_g= (const float*)d_in[12];
  const float* depthnorm_b= (const float*)d_in[13];
  const float* tf_fc_w    = (const float*)d_in[14];
  const float* tf_fc_b    = (const float*)d_in[15];
  const float* tf_norm_g  = (const float*)d_in[16];
  const float* tf_norm_b  = (const float*)d_in[17];
  const float* tf_conv_w  = (const float*)d_in[18];
  const float* tf_conv_b  = (const float*)d_in[19];
  const float* mlp_w1     = (const float*)d_in[20];
  const float* mlp_b1     = (const float*)d_in[21];
  const float* mlp_w2     = (const float*)d_in[22];
  const float* mlp_b2     = (const float*)d_in[23];
  const float* mlpnorm_g  = (const float*)d_in[24];
  const float* mlpnorm_b  = (const float*)d_in[25];
  float* out = (float*)d_out;
  float* ws  = (float*)d_ws;

  float* XP   = ws + F_XP;
  float* ZG   = ws + F_ZG;
  float* Z1   = ws + F_Z1;
  float* CLK  = ws + F_CLK;
  float* MKL  = ws + F_MKL;
  float* U    = ws + F_U;
  float* CSUM = ws + F_CSUM;
  float* W2p  = ws + F_W2;
  float* CSTp = ws + F_CST;
  float* Vp   = ws + F_V;
  float* C2p  = ws + F_C2;
  float* ZRES = ws + F_ZRES;
  float* H2p  = ws + F_H2;
  float* EN   = ws + F_EN;
  float* NEp  = ws + F_NE;
  float* ATTp = ws + F_ATT;
  float* A1p  = ws + F_A1;
  float* A2p  = ws + F_A2;
  float* RS   = ws + F_RS;
  float* RQ   = ws + F_RQ;
  float* PS   = ws + F_PS;
  float* PQ   = ws + F_PQ;
  float* BN0  = ws + F_BN;        // a[7], c[7]
  float* BN2  = ws + F_BN + 16;   // a[32], c[32]
  float* BN3  = ws + F_BN + 80;
  float* BN4  = ws + F_BN + 96;
  float* BN5  = ws + F_BN + 112;
  float* BN6  = ws + F_BN + 128;
  float* THRp = ws + F_THR;

  k_gen_cos<<<512, 256, 0, stream>>>(CLK, MKL);
  k_ucsum<<<2, 256, 0, stream>>>(MKL, U, CSUM, tf_fc_w);
  k_w2<<<96, 256, 0, stream>>>(linres_W, linres_b, embed_W, embed_b, W2p, CSTp);
  k_v<<<32, 256, 0, stream>>>(embed_W, embed_b, depth1_w, depth1_b, Vp, C2p);
  k_transpose<<<2048, 256, 0, stream>>>(x, XP);
  k_gemm_nn<0><<<dim3(112,4), 256, 0, stream>>>(XP, CLK, ZG, nullptr, nullptr, nullptr, nullptr, nullptr);
  k_energy<<<3584, 256, 0, stream>>>(ZG, EN);
  k_ne<<<8, 256, 0, stream>>>(EN, NEp);
  k_thr<<<1, 1024, 0, stream>>>(NEp, threshold, THRp);
  k_mask_gelu<<<14336, 256, 0, stream>>>(ZG, NEp, THRp, dctconv_w, dctconv_b, RS, RQ);
  k_bnfin_rows<<<7, 256, 0, stream>>>(RS, RQ, 7, BD, 1048576.0, dctnorm_g, dctnorm_b, BN0);
  k_gemm_nn<1><<<dim3(112,4), 256, 0, stream>>>(ZG, MKL, Z1, BN0, CSUM, XP, dctconv_w, dctconv_b);
  k_patch<<<1792, 256, 0, stream>>>(XP, Vp, C2p, ZG, PS, PQ);
  k_bnfin_part<<<32, 256, 0, stream>>>(PS, PQ, 1792, 32, 229376.0, depthnorm_g, depthnorm_b, BN2);
  k_gemm_nt<0,false><<<dim3(224,2), 256, 0, stream>>>(XP, W2p, CSTp, ZRES, 96, 96, nullptr, nullptr);
  k_att<<<3584, 256, 0, stream>>>(Z1, ZG, BN2, U, tf_fc_b, ATTp);
  k_tf<<<1, 1024, 0, stream>>>(ATTp, tf_norm_g, tf_norm_b, tf_conv_w, tf_conv_b, tf_fc_b, A1p, A2p);
  k_statsA<<<3584, 256, 0, stream>>>(Z1, ZG, BN2, A1p, RS, RQ);
  k_bnfin_rows<<<7, 256, 0, stream>>>(RS, RQ, 7, BD, 1048576.0, dctnorm_g, dctnorm_b, BN3);
  k_statsC<<<3584, 256, 0, stream>>>(Z1, ZG, BN2, A1p, BN3, dctconv_w, dctconv_b, RS, RQ);
  k_bnfin_rows<<<7, 256, 0, stream>>>(RS, RQ, 7, BD, 1048576.0, dctnorm_g, dctnorm_b, BN4);
  k_final<<<3584, 256, 0, stream>>>(Z1, ZG, BN2, A1p, A2p, BN3, BN4, dctconv_w, dctconv_b, XP, RS, RQ);
  k_bnfin_rows<<<7, 256, 0, stream>>>(RS, RQ, 7, BD, 1048576.0, dctnorm_g, dctnorm_b, BN5);
  k_gemm_nt<1,true><<<dim3(224,1), 256, 0, stream>>>(XP, mlp_w1, mlp_b1, H2p, 48, 48, BN5, BN5+7);
  k_rowstat48<<<3584, 256, 0, stream>>>(H2p, RS, RQ);
  k_bnfin_rows<<<7, 256, 0, stream>>>(RS, RQ, 7, BD, 98304.0, mlpnorm_g, mlpnorm_b, BN6);
  k_out<<<5376, 256, 0, stream>>>(H2p, BN6, mlp_w2, mlp_b2, ZRES, out);
}

// Round 3
// 573.753 us; speedup vs baseline: 1.4456x; 1.0307x over previous
//
#include <hip/hip_runtime.h>
#include <math.h>

#define BB 2048
#define LL 512
#define DD 7
#define BD 14336   // BB*DD
#define NP 32      // patches
#define PL 16      // patch len

// ---------------- ws layout (floats) ----------------
constexpr size_t F_XP   = 0;                          // xp, later zf
constexpr size_t F_ZG   = F_XP  + (size_t)BD*512;     // z_dct -> g -> z1r
constexpr size_t F_Z1   = F_ZG  + (size_t)BD*512;     // z1
constexpr size_t F_CLK  = F_Z1  + (size_t)BD*512;     // C[l][k] * 2
constexpr size_t F_MKL  = F_CLK + 512*512;            // C[k][l] * sc[k]
constexpr size_t F_U    = F_MKL + 512*512;
constexpr size_t F_CSUM = F_U + 512;
constexpr size_t F_W2   = F_CSUM + 512;               // 96x512
constexpr size_t F_CST  = F_W2 + 96*512;
constexpr size_t F_V    = F_CST + 96;                 // 32x16x16
constexpr size_t F_C2   = F_V + 32*256;               // 32x16
constexpr size_t F_ZRES = F_C2 + 512;                 // BD x 96
constexpr size_t F_H2   = F_ZRES + (size_t)BD*96;     // BD x 48
constexpr size_t F_EN   = F_H2 + (size_t)BD*48;
constexpr size_t F_NE   = F_EN + BD;
constexpr size_t F_ATT  = F_NE + BD;
constexpr size_t F_A1   = F_ATT + BD;
constexpr size_t F_A2   = F_A1 + BD;
constexpr size_t F_RS   = F_A2 + BD;
constexpr size_t F_RQ   = F_RS + BD;                  // must stay adjacent to F_RS (one memset)
constexpr size_t F_PS   = F_RQ + BD;                  // 1792 x 32
constexpr size_t F_PQ   = F_PS + 1792*32;
constexpr size_t F_BN   = F_PQ + 1792*32;             // bn affine params
constexpr size_t F_THR  = F_BN + 256;

__device__ __forceinline__ float gelu_f(float x) {
  return 0.5f * x * (1.0f + erff(x * 0.70710678118654752440f));
}
__device__ __forceinline__ float sigm_f(float x) {
  return 1.0f / (1.0f + expf(-x));
}
__device__ __forceinline__ float wred(float v) {
#pragma unroll
  for (int o = 32; o > 0; o >>= 1) v += __shfl_down(v, o);
  return v;
}

// ---------------- constant generation ----------------
__global__ void k_gen_cos(float* __restrict__ Clk, float* __restrict__ Mkl) {
  int k = blockIdx.x;
  for (int l = threadIdx.x; l < 512; l += 256) {
    double c = cos(3.14159265358979323846 * (l + 0.5) * k / 512.0);
    Clk[(size_t)l*512 + k] = (float)(2.0 * c);
    Mkl[(size_t)k*512 + l] = (float)(c * (k == 0 ? (1.0/1024.0) : (1.0/512.0)));
  }
}

__global__ void k_ucsum(const float* __restrict__ Mkl, float* __restrict__ u,
                        float* __restrict__ csum, const float* __restrict__ wf) {
  int l = blockIdx.x*256 + threadIdx.x;
  if (l >= 512) return;
  double s = 0.0;
  for (int k = 0; k < 512; ++k) s += (double)Mkl[(size_t)k*512 + l];
  csum[l] = (float)s;
  double uu = (double)wf[0] * 45.25483399593904156 * (double)Mkl[l];      // sqrt(2048)
  for (int k = 1; k < 5; ++k) uu += (double)wf[k] * 32.0 * (double)Mkl[(size_t)k*512 + l];
  u[l] = (float)uu;
}

__global__ __launch_bounds__(256) void k_w2(const float* __restrict__ linW,
    const float* __restrict__ linb, const float* __restrict__ eW, const float* __restrict__ eb,
    float* __restrict__ W2, float* __restrict__ cst)
{
  __shared__ float sW[768];
  __shared__ float sb[48];
  __shared__ float rbuf[256];
  int o = blockIdx.x, t = threadIdx.x;
  for (int i = t; i < 768; i += 256) sW[i] = eW[i];
  if (t < 48) sb[t] = eb[t];
  __syncthreads();
  const float* lw = linW + (size_t)o * 1536;
  for (int i = t; i < 512; i += 256) {
    int n = i >> 4, p = i & 15;
    float s = 0.f;
    const float* l2 = lw + n*48;
#pragma unroll 8
    for (int m = 0; m < 48; ++m) s += l2[m] * sW[m*16 + p];
    W2[(size_t)o*512 + i] = s;
  }
  float c = 0.f;
  for (int i = t; i < 1536; i += 256) c += lw[i] * sb[i % 48];
  rbuf[t] = c; __syncthreads();
  for (int off = 128; off > 0; off >>= 1) { if (t < off) rbuf[t] += rbuf[t+off]; __syncthreads(); }
  if (t == 0) cst[o] = rbuf[0] + linb[o];
}

__global__ void k_v(const float* __restrict__ eW, const float* __restrict__ eb,
                    const float* __restrict__ dw, const float* __restrict__ db,
                    float* __restrict__ V, float* __restrict__ c2)
{
  int n = blockIdx.x, t = threadIdx.x;
  int p = t >> 4, q = t & 15;
  float s = 0.f;
#pragma unroll
  for (int j = 0; j < 3; ++j) s += eW[(p*3+j)*16 + q] * dw[n*3+j];
  V[(size_t)n*256 + p*16 + q] = s;
  if (q == 0) {
    float c = 0.f;
#pragma unroll
    for (int j = 0; j < 3; ++j) c += eb[p*3+j] * dw[n*3+j];
    c2[n*16+p] = c + db[n];
  }
}

// ---------------- transpose [B,L,D] -> [B*D, L] ----------------
__global__ __launch_bounds__(256) void k_transpose(const float* __restrict__ x, float* __restrict__ xp) {
  __shared__ float s[3584];
  int b = blockIdx.x;
  const float* src = x + (size_t)b*3584;
  for (int c = threadIdx.x; c < 896; c += 256) {
    float4 v = *(const float4*)&src[c*4];
    s[c*4+0]=v.x; s[c*4+1]=v.y; s[c*4+2]=v.z; s[c*4+3]=v.w;
  }
  __syncthreads();
  for (int c = threadIdx.x; c < 896; c += 256) {
    int d = c >> 7, cg = c & 127;
    float4 v;
    v.x = s[(cg*4+0)*7 + d]; v.y = s[(cg*4+1)*7 + d];
    v.z = s[(cg*4+2)*7 + d]; v.w = s[(cg*4+3)*7 + d];
    *(float4*)&xp[((size_t)b*7 + d)*512 + cg*4] = v;
  }
}

// ---------------- big NN GEMM: C[M,512] = A[M,512] @ B[512,512] ----------------
// 128x128 tile, BK=32, 256 threads, 8x8 frags. A staged TRANSPOSED in LDS so the
// inner loop is 4x ds_read_b128 + 64 FMA per k-step.
// MODE 1: out = aR*acc + cR*csum[col] + (xp*w_d + b_d)      (idct epilogue)
// MODE 2: g = gelu((acc*mask_r)*w_d + b_d); store g; row-sum atomics to rs/rq
template<int MODE>
__global__ __launch_bounds__(256) void k_gemm_nn(
    const float* __restrict__ A, const float* __restrict__ Bm, float* __restrict__ Cc,
    const float* __restrict__ bnac, const float* __restrict__ csum,
    const float* __restrict__ xp, const float* __restrict__ cw, const float* __restrict__ cb,
    const float* __restrict__ ne, const float* __restrict__ thr,
    float* __restrict__ rs, float* __restrict__ rq)
{
  __shared__ float AsT[32][132];
  __shared__ float Bs[32][128];
  const int t = threadIdx.x;
  const int tx = t & 15, ty = t >> 4;
  const int r0 = blockIdx.x * 128, c0 = blockIdx.y * 128;
  float acc[8][8];
#pragma unroll
  for (int i = 0; i < 8; ++i)
#pragma unroll
    for (int j = 0; j < 8; ++j) acc[i][j] = 0.f;

  for (int kt = 0; kt < 512; kt += 32) {
#pragma unroll
    for (int h = 0; h < 4; ++h) {
      int c = t + h*256;
      int row = c >> 3, cg = c & 7;
      float4 v = *(const float4*)&A[(size_t)(r0+row)*512 + kt + cg*4];
      AsT[cg*4+0][row] = v.x; AsT[cg*4+1][row] = v.y;
      AsT[cg*4+2][row] = v.z; AsT[cg*4+3][row] = v.w;
    }
#pragma unroll
    for (int h = 0; h < 4; ++h) {
      int c = t + h*256;
      int row = c >> 5, cg = c & 31;
      *(float4*)&Bs[row][cg*4] = *(const float4*)&Bm[(size_t)(kt+row)*512 + c0 + cg*4];
    }
    __syncthreads();
#pragma unroll
    for (int kk = 0; kk < 32; ++kk) {
      float4 a0 = *(const float4*)&AsT[kk][ty*4];
      float4 a1 = *(const float4*)&AsT[kk][64 + ty*4];
      float4 b0 = *(const float4*)&Bs[kk][tx*4];
      float4 b1 = *(const float4*)&Bs[kk][tx*4+64];
      float av[8] = {a0.x,a0.y,a0.z,a0.w,a1.x,a1.y,a1.z,a1.w};
      float bv[8] = {b0.x,b0.y,b0.z,b0.w,b1.x,b1.y,b1.z,b1.w};
#pragma unroll
      for (int i = 0; i < 8; ++i)
#pragma unroll
        for (int j = 0; j < 8; ++j) acc[i][j] += av[i]*bv[j];
    }
    __syncthreads();
  }
#pragma unroll
  for (int h = 0; h < 2; ++h) {
#pragma unroll
    for (int i = 0; i < 4; ++i) {
      const int r = r0 + h*64 + ty*4 + i;
      const int ai = h*4 + i;
      const int d = r % 7;
      if (MODE == 1) {
        const float aR = bnac[d], cR = bnac[7+d], wv = cw[d], bvv = cb[d];
#pragma unroll
        for (int g = 0; g < 2; ++g) {
          int col = c0 + tx*4 + g*64;
          float4 xv = *(const float4*)&xp[(size_t)r*512 + col];
          float4 cs = *(const float4*)&csum[col];
          float4 v;
          v.x = aR*acc[ai][g*4+0] + cR*cs.x + (xv.x*wv + bvv);
          v.y = aR*acc[ai][g*4+1] + cR*cs.y + (xv.y*wv + bvv);
          v.z = aR*acc[ai][g*4+2] + cR*cs.z + (xv.z*wv + bvv);
          v.w = aR*acc[ai][g*4+3] + cR*cs.w + (xv.w*wv + bvv);
          *(float4*)&Cc[(size_t)r*512 + col] = v;
        }
      } else {
        float m = (ne[r] > thr[0]) ? 1.0f : 0.0f;
        float wm = cw[d] * m, bvv = cb[d];
        float s = 0.f, q = 0.f;
#pragma unroll
        for (int g = 0; g < 2; ++g) {
          int col = c0 + tx*4 + g*64;
          float4 v;
          v.x = gelu_f(acc[ai][g*4+0]*wm + bvv);
          v.y = gelu_f(acc[ai][g*4+1]*wm + bvv);
          v.z = gelu_f(acc[ai][g*4+2]*wm + bvv);
          v.w = gelu_f(acc[ai][g*4+3]*wm + bvv);
          *(float4*)&Cc[(size_t)r*512 + col] = v;
          s += v.x+v.y+v.z+v.w;
          q += v.x*v.x+v.y*v.y+v.z*v.z+v.w*v.w;
        }
#pragma unroll
        for (int off = 8; off > 0; off >>= 1) {
          s += __shfl_down(s, off, 16);
          q += __shfl_down(q, off, 16);
        }
        if (tx == 0) { atomicAdd(&rs[r], s); atomicAdd(&rq[r], q); }
      }
    }
  }
}

// ---------------- NT GEMM: out[M,Ncols] = A[M,512] @ W[Ncols,512]^T + bias ----------------
// 64x64 tile, BK=32. MODE 0: store val. MODE 1: store gelu(val)*val.
// TRANS: A element -> gelu(ta[d]*x + tc[d]) at stage time.
// STATS: per-row sum/sumsq direct store (requires Ncols <= 64, gridDim.y == 1).
template<int MODE, bool TRANS, bool STATS>
__global__ __launch_bounds__(256) void k_gemm_nt(
    const float* __restrict__ A, const float* __restrict__ W, const float* __restrict__ bias,
    float* __restrict__ out, int Ncols, int ldOut,
    const float* __restrict__ ta, const float* __restrict__ tc,
    float* __restrict__ rs, float* __restrict__ rq)
{
  __shared__ float As[64][33];
  __shared__ float Bs[32][68];
  const int t = threadIdx.x;
  const int tx = t & 15, ty = t >> 4;
  const int r0 = blockIdx.x*64, c0 = blockIdx.y*64;
  float acc[4][4];
#pragma unroll
  for (int i = 0; i < 4; ++i)
#pragma unroll
    for (int j = 0; j < 4; ++j) acc[i][j] = 0.f;

  for (int kt = 0; kt < 512; kt += 32) {
#pragma unroll
    for (int h = 0; h < 2; ++h) {
      int c = t + h*256;
      int row = c >> 3, cg = c & 7;
      float4 v = *(const float4*)&A[(size_t)(r0+row)*512 + kt + cg*4];
      if (TRANS) {
        int d = (r0 + row) % 7;
        float aa = ta[d], cc = tc[d];
        v.x = gelu_f(aa*v.x + cc); v.y = gelu_f(aa*v.y + cc);
        v.z = gelu_f(aa*v.z + cc); v.w = gelu_f(aa*v.w + cc);
      }
      As[row][cg*4+0]=v.x; As[row][cg*4+1]=v.y; As[row][cg*4+2]=v.z; As[row][cg*4+3]=v.w;
    }
#pragma unroll
    for (int h = 0; h < 2; ++h) {
      int c = t + h*256;
      int row = c >> 3, cg = c & 7;
      int o = c0 + row;
      float4 v = make_float4(0.f,0.f,0.f,0.f);
      if (o < Ncols) v = *(const float4*)&W[(size_t)o*512 + kt + cg*4];
      Bs[cg*4+0][row]=v.x; Bs[cg*4+1][row]=v.y; Bs[cg*4+2][row]=v.z; Bs[cg*4+3][row]=v.w;
    }
    __syncthreads();
#pragma unroll
    for (int kk = 0; kk < 32; ++kk) {
      float av[4];
#pragma unroll
      for (int i = 0; i < 4; ++i) av[i] = As[ty*4+i][kk];
      float4 b = *(const float4*)&Bs[kk][tx*4];
      float bv[4] = {b.x,b.y,b.z,b.w};
#pragma unroll
      for (int i = 0; i < 4; ++i)
#pragma unroll
        for (int j = 0; j < 4; ++j) acc[i][j] += av[i]*bv[j];
    }
    __syncthreads();
  }
#pragma unroll
  for (int i = 0; i < 4; ++i) {
    int r = r0 + ty*4 + i;
    float s = 0.f, q = 0.f;
#pragma unroll
    for (int j = 0; j < 4; ++j) {
      int col = c0 + tx*4 + j;
      if (col < Ncols) {
        float v = acc[i][j] + bias[col];
        if (MODE == 1) { float g = gelu_f(v); v = g*v; }
        out[(size_t)r*ldOut + col] = v;
        if (STATS) { s += v; q += v*v; }
      }
    }
    if (STATS) {
#pragma unroll
      for (int off = 8; off > 0; off >>= 1) {
        s += __shfl_down(s, off, 16);
        q += __shfl_down(q, off, 16);
      }
      if (tx == 0) { rs[r] = s; rq[r] = q; }
    }
  }
}

// ---------------- analytic DCT energy (Parseval): 2L*sum(x^2) + 2*(sum x)^2 ----------------
__global__ void k_energy_an(const float* __restrict__ xp, float* __restrict__ en) {
  int r = blockIdx.x*4 + (threadIdx.x >> 6);
  int lane = threadIdx.x & 63;
  const float* row = xp + (size_t)r*512;
  double s = 0.0, q = 0.0;
  for (int i = lane; i < 512; i += 64) { double v = row[i]; s += v; q += v*v; }
#pragma unroll
  for (int o = 32; o > 0; o >>= 1) { s += __shfl_down(s, o); q += __shfl_down(q, o); }
  if (lane == 0) en[r] = (float)(1024.0*q + 2.0*s*s);
}

__global__ void k_ne(const float* __restrict__ en, float* __restrict__ ne) {
  int b = blockIdx.x*256 + threadIdx.x;
  if (b >= 2048) return;
  float e[7], s7[7];
#pragma unroll
  for (int d = 0; d < 7; ++d) { e[d] = en[b*7+d]; s7[d] = e[d]; }
#pragma unroll
  for (int i = 1; i < 7; ++i) {
    float key = s7[i]; int j = i-1;
    while (j >= 0 && s7[j] > key) { s7[j+1] = s7[j]; --j; }
    s7[j+1] = key;
  }
  float med = s7[3] + 1e-6f;
#pragma unroll
  for (int d = 0; d < 7; ++d) ne[b*7+d] = e[d] / med;
}

// exact k-th-smallest via register-resident 4-bit radix select.
__global__ __launch_bounds__(1024) void k_thr(const float* __restrict__ ne,
                                              const float* __restrict__ qp, float* __restrict__ out)
{
  __shared__ unsigned s_part[16][8];
  __shared__ unsigned s_bsel, s_R;
  const int t = threadIdx.x;
  const int lane = t & 63, wv = t >> 6;
  unsigned key[14];
#pragma unroll
  for (int j = 0; j < 14; ++j) key[j] = __float_as_uint(ne[t + j*1024]);

  float q = qp[0];
  float pos = q * 14335.0f;
  int lo = (int)floorf(pos);
  if (lo < 0) lo = 0; if (lo > 14335) lo = 14335;
  int hi = lo + 1; if (hi > 14335) hi = 14335;
  float frac = pos - (float)lo;

  unsigned prefix = 0;
  unsigned R = (unsigned)lo;
#pragma unroll 1
  for (int shift = 28; shift >= 0; shift -= 4) {
    unsigned pb = prefix >> shift;
    unsigned long long accb = 0ull;
#pragma unroll
    for (int j = 0; j < 14; ++j) {
      unsigned diff = (key[j] >> shift) - pb;
      accb += (diff < 16u) ? (1ull << (diff*4)) : 0ull;
    }
    unsigned pk[8];
#pragma unroll
    for (int b = 0; b < 8; ++b) {
      unsigned clo = (unsigned)(accb >> (b*4)) & 15u;
      unsigned chi = (unsigned)(accb >> (b*4+32)) & 15u;
      pk[b] = clo | (chi << 16);
    }
#pragma unroll
    for (int b = 0; b < 8; ++b)
#pragma unroll
      for (int o = 32; o > 0; o >>= 1) pk[b] += __shfl_down(pk[b], o);
    if (lane == 0) {
#pragma unroll
      for (int b = 0; b < 8; ++b) s_part[wv][b] = pk[b];
    }
    __syncthreads();
    if (t == 0) {
      unsigned tot[16];
#pragma unroll
      for (int i = 0; i < 8; ++i) {
        unsigned s = 0;
#pragma unroll
        for (int w = 0; w < 16; ++w) s += s_part[w][i];
        tot[i] = s & 0xFFFFu; tot[i+8] = s >> 16;
      }
      unsigned cum = 0, bsel = 15;
#pragma unroll 1
      for (int b = 0; b < 16; ++b) {
        if (cum + tot[b] > R) { bsel = (unsigned)b; break; }
        cum += tot[b];
      }
      s_bsel = bsel; s_R = R - cum;
    }
    __syncthreads();
    prefix |= (s_bsel << shift);
    R = s_R;
    __syncthreads();
  }
  unsigned cle = 0, mn = 0xFFFFFFFFu;
#pragma unroll
  for (int j = 0; j < 14; ++j) {
    cle += (key[j] <= prefix) ? 1u : 0u;
    if (key[j] > prefix && key[j] < mn) mn = key[j];
  }
#pragma unroll
  for (int o = 32; o > 0; o >>= 1) {
    cle += __shfl_down(cle, o);
    unsigned m2 = __shfl_down(mn, o);
    mn = (m2 < mn) ? m2 : mn;
  }
  if (lane == 0) { s_part[wv][0] = cle; s_part[wv][1] = mn; }
  __syncthreads();
  if (t == 0) {
    unsigned C = 0, M = 0xFFFFFFFFu;
#pragma unroll
    for (int w = 0; w < 16; ++w) {
      C += s_part[w][0];
      if (s_part[w][1] < M) M = s_part[w][1];
    }
    unsigned vhiKey = (C > (unsigned)hi) ? prefix : M;
    if (vhiKey == 0xFFFFFFFFu) vhiKey = prefix;
    float vlo = __uint_as_float(prefix);
    float vhi = __uint_as_float(vhiKey);
    out[0] = vlo*(1.0f-frac) + vhi*frac;
  }
}

// ---------------- BN finalize from per-row sums ----------------
__global__ __launch_bounds__(256) void k_bnfin_rows(const float* __restrict__ rs,
    const float* __restrict__ rq, int nch, int nrows, double count,
    const float* __restrict__ gamma, const float* __restrict__ beta, float* __restrict__ out)
{
  __shared__ double sd[256];
  int ch = blockIdx.x, t = threadIdx.x;
  double s = 0.0, q = 0.0;
  for (int i = ch + t*nch; i < nrows; i += 256*nch) { s += rs[i]; q += rq[i]; }
  sd[t] = s; __syncthreads();
  for (int o = 128; o > 0; o >>= 1) { if (t < o) sd[t] += sd[t+o]; __syncthreads(); }
  double S = sd[0]; __syncthreads();
  sd[t] = q; __syncthreads();
  for (int o = 128; o > 0; o >>= 1) { if (t < o) sd[t] += sd[t+o]; __syncthreads(); }
  if (t == 0) {
    double m = S / count;
    double v = sd[0] / count - m*m; if (v < 0.0) v = 0.0;
    double inv = 1.0 / sqrt(v + 1e-5);
    out[ch]       = (float)(gamma[ch] * inv);
    out[nch + ch] = (float)(beta[ch] - m * gamma[ch] * inv);
  }
}

__global__ __launch_bounds__(256) void k_bnfin_part(const float* __restrict__ pS,
    const float* __restrict__ pQ, int nparts, int nch, double count,
    const float* __restrict__ gamma, const float* __restrict__ beta, float* __restrict__ out)
{
  __shared__ double sd[256];
  int ch = blockIdx.x, t = threadIdx.x;
  double s = 0.0, q = 0.0;
  for (int i = t; i < nparts; i += 256) { s += pS[(size_t)i*nch + ch]; q += pQ[(size_t)i*nch + ch]; }
  sd[t] = s; __syncthreads();
  for (int o = 128; o > 0; o >>= 1) { if (t < o) sd[t] += sd[t+o]; __syncthreads(); }
  double S = sd[0]; __syncthreads();
  sd[t] = q; __syncthreads();
  for (int o = 128; o > 0; o >>= 1) { if (t < o) sd[t] += sd[t+o]; __syncthreads(); }
  if (t == 0) {
    double m = S / count;
    double v = sd[0] / count - m*m; if (v < 0.0) v = 0.0;
    double inv = 1.0 / sqrt(v + 1e-5);
    out[ch]       = (float)(gamma[ch] * inv);
    out[nch + ch] = (float)(beta[ch] - m * gamma[ch] * inv);
  }
}

// ---------------- patch path: z1r = V[n] @ xp-patch + c2 ----------------
__global__ __launch_bounds__(256) void k_patch(const float* __restrict__ xp,
    const float* __restrict__ V, const float* __restrict__ c2,
    float* __restrict__ z1r, float* __restrict__ pS, float* __restrict__ pQ)
{
  __shared__ float sx[8][512];
  __shared__ float aS[32], aQ[32];
  int t = threadIdx.x;
  int r0 = blockIdx.x * 8;
  for (int c = t; c < 1024; c += 256) {
    int row = c >> 7, cg = c & 127;
    *(float4*)&sx[row][cg*4] = *(const float4*)&xp[(size_t)(r0+row)*512 + cg*4];
  }
  if (t < 32) { aS[t] = 0.f; aQ[t] = 0.f; }
  __syncthreads();
  float vreg[2][16]; float cc[2]; int nn_[2], oo[2];
#pragma unroll
  for (int h = 0; h < 2; ++h) {
    int o = t + h*256;
    oo[h] = o;
    int n = o >> 4, p = o & 15;
    nn_[h] = n;
#pragma unroll
    for (int qg = 0; qg < 4; ++qg) {
      float4 v4 = *(const float4*)&V[(size_t)n*256 + p*16 + qg*4];
      vreg[h][qg*4+0]=v4.x; vreg[h][qg*4+1]=v4.y; vreg[h][qg*4+2]=v4.z; vreg[h][qg*4+3]=v4.w;
    }
    cc[h] = c2[o];
  }
  float sum[2] = {0.f,0.f}, sq[2] = {0.f,0.f};
  for (int row = 0; row < 8; ++row) {
#pragma unroll
    for (int h = 0; h < 2; ++h) {
      const float* xr = &sx[row][nn_[h]*16];
      float val = cc[h];
#pragma unroll
      for (int qq = 0; qq < 16; ++qq) val += vreg[h][qq] * xr[qq];
      z1r[(size_t)(r0+row)*512 + oo[h]] = val;
      sum[h] += val; sq[h] += val*val;
    }
  }
#pragma unroll
  for (int h = 0; h < 2; ++h) {
    atomicAdd(&aS[nn_[h]], sum[h]);
    atomicAdd(&aQ[nn_[h]], sq[h]);
  }
  __syncthreads();
  if (t < 32) { pS[(size_t)blockIdx.x*32 + t] = aS[t]; pQ[(size_t)blockIdx.x*32 + t] = aQ[t]; }
}

// ---------------- TopKFreq ----------------
__global__ void k_att(const float* __restrict__ z1, const float* __restrict__ z1r,
    const float* __restrict__ bn2, const float* __restrict__ u, const float* __restrict__ fcb,
    float* __restrict__ att)
{
  int r = blockIdx.x*4 + (threadIdx.x >> 6);
  int lane = threadIdx.x & 63;
  const float* z1p = z1 + (size_t)r*512;
  const float* zrp = z1r + (size_t)r*512;
  float s = 0.f;
#pragma unroll
  for (int h = 0; h < 2; ++h) {
    int i = lane*4 + h*256;
    int n = i >> 4;
    float a2n = bn2[n], c2n = bn2[32+n];
    float4 zr = *(const float4*)&zrp[i];
    float4 zv = *(const float4*)&z1p[i];
    float4 uv = *(const float4*)&u[i];
    s += (zv.x + gelu_f(a2n*zr.x + c2n)) * uv.x;
    s += (zv.y + gelu_f(a2n*zr.y + c2n)) * uv.y;
    s += (zv.z + gelu_f(a2n*zr.z + c2n)) * uv.z;
    s += (zv.w + gelu_f(a2n*zr.w + c2n)) * uv.w;
  }
  s = wred(s);
  if (lane == 0) att[r] = s + fcb[0];
}

__global__ __launch_bounds__(1024) void k_tf(const float* __restrict__ att,
    const float* __restrict__ pg, const float* __restrict__ pb,
    const float* __restrict__ pwc, const float* __restrict__ pbc,
    const float* __restrict__ pfb, float* __restrict__ a1, float* __restrict__ a2)
{
  __shared__ double sd[1024];
  __shared__ float sh[4];
  const int t = threadIdx.x;
  float g = pg[0], b = pb[0], wc = pwc[0], bc = pbc[0], fb = pfb[0];
  double s = 0.0, q = 0.0;
  for (int i = t; i < BD; i += 1024) { double v = att[i]; s += v; q += v*v; }
  sd[t] = s; __syncthreads();
  for (int o = 512; o > 0; o >>= 1) { if (t < o) sd[t] += sd[t+o]; __syncthreads(); }
  double S1 = sd[0]; __syncthreads();
  sd[t] = q; __syncthreads();
  for (int o = 512; o > 0; o >>= 1) { if (t < o) sd[t] += sd[t+o]; __syncthreads(); }
  if (t == 0) {
    double m = S1 / 14336.0;
    double v = sd[0] / 14336.0 - m*m; if (v < 0.0) v = 0.0;
    sh[0] = (float)m; sh[1] = (float)(1.0 / sqrt(v + 1e-5));
  }
  __syncthreads();
  float m1 = sh[0], i1 = sh[1];
  s = 0.0; q = 0.0;
  for (int i = t; i < BD; i += 1024) {
    float v = att[i];
    float an = (v - m1) * i1 * g + b;
    float av = sigm_f(gelu_f(an) * wc + bc);
    a1[i] = av;
    float t2 = av * (v - fb) + fb;
    s += t2; q += (double)t2 * t2;
  }
  __syncthreads();
  sd[t] = s; __syncthreads();
  for (int o = 512; o > 0; o >>= 1) { if (t < o) sd[t] += sd[t+o]; __syncthreads(); }
  double S2 = sd[0]; __syncthreads();
  sd[t] = q; __syncthreads();
  for (int o = 512; o > 0; o >>= 1) { if (t < o) sd[t] += sd[t+o]; __syncthreads(); }
  if (t == 0) {
    double m = S2 / 14336.0;
    double v = sd[0] / 14336.0 - m*m; if (v < 0.0) v = 0.0;
    sh[2] = (float)m; sh[3] = (float)(1.0 / sqrt(v + 1e-5));
  }
  __syncthreads();
  float m2 = sh[2], i2 = sh[3];
  for (int i = t; i < BD; i += 1024) {
    float t2 = a1[i] * (att[i] - fb) + fb;
    float an = (t2 - m2) * i2 * g + b;
    a2[i] = sigm_f(gelu_f(an) * wc + bc);
  }
}

// ---------------- elementwise stats passes (float4) ----------------
__global__ void k_statsA(const float* __restrict__ z1, const float* __restrict__ z1r,
    const float* __restrict__ bn2, const float* __restrict__ a1,
    float* __restrict__ rs, float* __restrict__ rq)
{
  int r = blockIdx.x*4 + (threadIdx.x >> 6);
  int lane = threadIdx.x & 63;
  float av = a1[r];
  const float* z1p = z1 + (size_t)r*512;
  const float* zrp = z1r + (size_t)r*512;
  float s = 0.f, q = 0.f;
#pragma unroll
  for (int h = 0; h < 2; ++h) {
    int i = lane*4 + h*256;
    int n = i >> 4;
    float a2n = bn2[n], c2n = bn2[32+n];
    float4 zr = *(const float4*)&zrp[i];
    float4 zv = *(const float4*)&z1p[i];
    float A0 = (zv.x + gelu_f(a2n*zr.x + c2n)) * av;
    float A1 = (zv.y + gelu_f(a2n*zr.y + c2n)) * av;
    float A2 = (zv.z + gelu_f(a2n*zr.z + c2n)) * av;
    float A3 = (zv.w + gelu_f(a2n*zr.w + c2n)) * av;
    s += A0+A1+A2+A3; q += A0*A0+A1*A1+A2*A2+A3*A3;
  }
  s = wred(s); q = wred(q);
  if (lane == 0) { rs[r] = s; rq[r] = q; }
}

__global__ void k_statsC(const float* __restrict__ z1, const float* __restrict__ z1r,
    const float* __restrict__ bn2, const float* __restrict__ a1,
    const float* __restrict__ bn3, const float* __restrict__ cw, const float* __restrict__ cb,
    float* __restrict__ rs, float* __restrict__ rq)
{
  int r = blockIdx.x*4 + (threadIdx.x >> 6);
  int lane = threadIdx.x & 63;
  int d = r % 7;
  float av = a1[r];
  float b3a = bn3[d], b3c = bn3[7+d], wv = cw[d], bv = cb[d];
  const float* z1p = z1 + (size_t)r*512;
  const float* zrp = z1r + (size_t)r*512;
  float s = 0.f, q = 0.f;
#pragma unroll
  for (int h = 0; h < 2; ++h) {
    int i = lane*4 + h*256;
    int n = i >> 4;
    float a2n = bn2[n], c2n = bn2[32+n];
    float4 zr = *(const float4*)&zrp[i];
    float4 zv = *(const float4*)&z1p[i];
#pragma unroll
    for (int e = 0; e < 4; ++e) {
      float ze = (e==0?zr.x:e==1?zr.y:e==2?zr.z:zr.w);
      float z1e = (e==0?zv.x:e==1?zv.y:e==2?zv.z:zv.w);
      float A = (z1e + gelu_f(a2n*ze + c2n)) * av;
      float C = wv*gelu_f(b3a*A + b3c) + bv;
      s += C; q += C*C;
    }
  }
  s = wred(s); q = wred(q);
  if (lane == 0) { rs[r] = s; rq[r] = q; }
}

__global__ void k_final(const float* __restrict__ z1, const float* __restrict__ z1r,
    const float* __restrict__ bn2, const float* __restrict__ a1, const float* __restrict__ a2,
    const float* __restrict__ bn3, const float* __restrict__ bn4,
    const float* __restrict__ cw, const float* __restrict__ cb,
    float* __restrict__ zf, float* __restrict__ rs, float* __restrict__ rq)
{
  int r = blockIdx.x*4 + (threadIdx.x >> 6);
  int lane = threadIdx.x & 63;
  int d = r % 7;
  float av = a1[r], a2v = a2[r];
  float b3a = bn3[d], b3c = bn3[7+d], b4a = bn4[d], b4c = bn4[7+d];
  float wv = cw[d], bv = cb[d];
  const float* z1p = z1 + (size_t)r*512;
  const float* zrp = z1r + (size_t)r*512;
  float* zfp = zf + (size_t)r*512;
  float s = 0.f, q = 0.f;
#pragma unroll
  for (int h = 0; h < 2; ++h) {
    int i = lane*4 + h*256;
    int n = i >> 4;
    float a2n = bn2[n], c2n = bn2[32+n];
    float4 zr = *(const float4*)&zrp[i];
    float4 zv = *(const float4*)&z1p[i];
    float4 ov;
#pragma unroll
    for (int e = 0; e < 4; ++e) {
      float ze = (e==0?zr.x:e==1?zr.y:e==2?zr.z:zr.w);
      float z1e = (e==0?zv.x:e==1?zv.y:e==2?zv.z:zv.w);
      float z1v = z1e * av;
      float z2v = gelu_f(a2n*ze + c2n) * av;
      float A = z1v + z2v;
      float C = wv*gelu_f(b3a*A + b3c) + bv;
      float inter = gelu_f(b4a*C + b4c) * a2v;
      float z1n = z1v*inter + z2v;
      float z2n = z2v*inter + z1n;
      float zfv = z1n*z2n + z1n + z2n;
      (e==0?ov.x:e==1?ov.y:e==2?ov.z:ov.w) = zfv;
      s += zfv; q += zfv*zfv;
    }
    *(float4*)&zfp[i] = ov;
  }
  s = wred(s); q = wred(q);
  if (lane == 0) { rs[r] = s; rq[r] = q; }
}

// ---------------- output: fc2 + bias + z_res + transpose ----------------
__global__ __launch_bounds__(256) void k_out(const float* __restrict__ h2,
    const float* __restrict__ bn6, const float* __restrict__ w2, const float* __restrict__ b2,
    const float* __restrict__ zres, float* __restrict__ out)
{
  int idx = blockIdx.x*256 + threadIdx.x;
  int r = idx / 96, o = idx - r*96;
  int d = r % 7, b = r / 7;
  float a6 = bn6[d], c6 = bn6[7+d];
  const float* hp = h2 + (size_t)r*48;
  const float* wp = w2 + o*48;
  float s = 0.f;
#pragma unroll
  for (int j4 = 0; j4 < 12; ++j4) {
    float4 hv = *(const float4*)&hp[j4*4];
    float4 wv = *(const float4*)&wp[j4*4];
    s += (a6*hv.x + c6)*wv.x + (a6*hv.y + c6)*wv.y
       + (a6*hv.z + c6)*wv.z + (a6*hv.w + c6)*wv.w;
  }
  out[(size_t)b*672 + o*7 + d] = s + b2[o] + zres[(size_t)r*96 + o];
}

// ================= host =================
extern "C" void kernel_launch(void* const* d_in, const int* in_sizes, int n_in,
                              void* d_out, int out_size, void* d_ws, size_t ws_size,
                              hipStream_t stream) {
  const float* x          = (const float*)d_in[0];
  const float* dctconv_w  = (const float*)d_in[1];
  const float* dctconv_b  = (const float*)d_in[2];
  const float* dctnorm_g  = (const float*)d_in[3];
  const float* dctnorm_b  = (const float*)d_in[4];
  const float* threshold  = (const float*)d_in[5];
  const float* embed_W    = (const float*)d_in[6];
  const float* embed_b    = (const float*)d_in[7];
  const float* linres_W   = (const float*)d_in[8];
  const float* linres_b   = (const float*)d_in[9];
  const float* depth1_w   = (const float*)d_in[10];
  const float* depth1_b   = (const float*)d_in[11];
  const float* depthnorm_g= (const float*)d_in[12];
  const float* depthnorm_b= (const float*)d_in[13];
  const float* tf_fc_w    = (const float*)d_in[14];
  const float* tf_fc_b    = (const float*)d_in[15];
  const float* tf_norm_g  = (const float*)d_in[16];
  const float* tf_norm_b  = (const float*)d_in[17];
  const float* tf_conv_w  = (const float*)d_in[18];
  const float* tf_conv_b  = (const float*)d_in[19];
  const float* mlp_w1     = (const float*)d_in[20];
  const float* mlp_b1     = (const float*)d_in[21];
  const float* mlp_w2     = (const float*)d_in[22];
  const float* mlp_b2     = (const float*)d_in[23];
  const float* mlpnorm_g  = (const float*)d_in[24];
  const float* mlpnorm_b  = (const float*)d_in[25];
  float* out = (float*)d_out;
  float* ws  = (float*)d_ws;

  float* XP   = ws + F_XP;
  float* ZG   = ws + F_ZG;
  float* Z1   = ws + F_Z1;
  float* CLK  = ws + F_CLK;
  float* MKL  = ws + F_MKL;
  float* U    = ws + F_U;
  float* CSUM = ws + F_CSUM;
  float* W2p  = ws + F_W2;
  float* CSTp = ws + F_CST;
  float* Vp   = ws + F_V;
  float* C2p  = ws + F_C2;
  float* ZRES = ws + F_ZRES;
  float* H2p  = ws + F_H2;
  float* EN   = ws + F_EN;
  float* NEp  = ws + F_NE;
  float* ATTp = ws + F_ATT;
  float* A1p  = ws + F_A1;
  float* A2p  = ws + F_A2;
  float* RS   = ws + F_RS;
  float* RQ   = ws + F_RQ;
  float* PS   = ws + F_PS;
  float* PQ   = ws + F_PQ;
  float* BN0  = ws + F_BN;        // a[7], c[7]
  float* BN2  = ws + F_BN + 16;   // a[32], c[32]
  float* BN3  = ws + F_BN + 80;
  float* BN4  = ws + F_BN + 96;
  float* BN5  = ws + F_BN + 112;
  float* BN6  = ws + F_BN + 128;
  float* THRp = ws + F_THR;

  k_gen_cos<<<512, 256, 0, stream>>>(CLK, MKL);
  k_ucsum<<<2, 256, 0, stream>>>(MKL, U, CSUM, tf_fc_w);
  k_w2<<<96, 256, 0, stream>>>(linres_W, linres_b, embed_W, embed_b, W2p, CSTp);
  k_v<<<32, 256, 0, stream>>>(embed_W, embed_b, depth1_w, depth1_b, Vp, C2p);
  k_transpose<<<2048, 256, 0, stream>>>(x, XP);
  k_energy_an<<<3584, 256, 0, stream>>>(XP, EN);
  k_ne<<<8, 256, 0, stream>>>(EN, NEp);
  k_thr<<<1, 1024, 0, stream>>>(NEp, threshold, THRp);
  hipMemsetAsync(RS, 0, 2*BD*sizeof(float), stream);
  k_gemm_nn<2><<<dim3(112,4), 256, 0, stream>>>(XP, CLK, ZG, nullptr, nullptr,
      nullptr, dctconv_w, dctconv_b, NEp, THRp, RS, RQ);
  k_bnfin_rows<<<7, 256, 0, stream>>>(RS, RQ, 7, BD, 1048576.0, dctnorm_g, dctnorm_b, BN0);
  k_gemm_nn<1><<<dim3(112,4), 256, 0, stream>>>(ZG, MKL, Z1, BN0, CSUM,
      XP, dctconv_w, dctconv_b, nullptr, nullptr, nullptr, nullptr);
  k_patch<<<1792, 256, 0, stream>>>(XP, Vp, C2p, ZG, PS, PQ);
  k_bnfin_part<<<32, 256, 0, stream>>>(PS, PQ, 1792, 32, 229376.0, depthnorm_g, depthnorm_b, BN2);
  k_gemm_nt<0,false,false><<<dim3(224,2), 256, 0, stream>>>(XP, W2p, CSTp, ZRES, 96, 96,
      nullptr, nullptr, nullptr, nullptr);
  k_att<<<3584, 256, 0, stream>>>(Z1, ZG, BN2, U, tf_fc_b, ATTp);
  k_tf<<<1, 1024, 0, stream>>>(ATTp, tf_norm_g, tf_norm_b, tf_conv_w, tf_conv_b, tf_fc_b, A1p, A2p);
  k_statsA<<<3584, 256, 0, stream>>>(Z1, ZG, BN2, A1p, RS, RQ);
  k_bnfin_rows<<<7, 256, 0, stream>>>(RS, RQ, 7, BD, 1048576.0, dctnorm_g, dctnorm_b, BN3);
  k_statsC<<<3584, 256, 0, stream>>>(Z1, ZG, BN2, A1p, BN3, dctconv_w, dctconv_b, RS, RQ);
  k_bnfin_rows<<<7, 256, 0, stream>>>(RS, RQ, 7, BD, 1048576.0, dctnorm_g, dctnorm_b, BN4);
  k_final<<<3584, 256, 0, stream>>>(Z1, ZG, BN2, A1p, A2p, BN3, BN4, dctconv_w, dctconv_b, XP, RS, RQ);
  k_bnfin_rows<<<7, 256, 0, stream>>>(RS, RQ, 7, BD, 1048576.0, dctnorm_g, dctnorm_b, BN5);
  k_gemm_nt<1,true,true><<<dim3(224,1), 256, 0, stream>>>(XP, mlp_w1, mlp_b1, H2p, 48, 48,
      BN5, BN5+7, RS, RQ);
  k_bnfin_rows<<<7, 256, 0, stream>>>(RS, RQ, 7, BD, 98304.0, mlpnorm_g, mlpnorm_b, BN6);
  k_out<<<5376, 256, 0, stream>>>(H2p, BN6, mlp_w2, mlp_b2, ZRES, out);
}

// Round 4
// 520.261 us; speedup vs baseline: 1.5942x; 1.1028x over previous
//
#include <hip/hip_runtime.h>
#include <math.h>

#define BB 2048
#define LL 512
#define DD 7
#define BD 14336   // BB*DD

// ---------------- ws layout (floats) ----------------
constexpr size_t F_XP   = 0;                          // xp, later zf
constexpr size_t F_ZG   = F_XP  + (size_t)BD*512;     // ZGH/ZGL planes -> z1r f32
constexpr size_t F_Z1   = F_ZG  + (size_t)BD*512;     // z1
constexpr size_t F_CLK  = F_Z1  + (size_t)BD*512;     // B1H/B1L (ushort planes)
constexpr size_t F_MKL  = F_CLK + 512*512;            // B2H/B2L (ushort planes)
constexpr size_t F_U    = F_MKL + 512*512;
constexpr size_t F_CSUM = F_U + 512;
constexpr size_t F_W2   = F_CSUM + 512;               // 96x512
constexpr size_t F_CST  = F_W2 + 96*512;
constexpr size_t F_V    = F_CST + 96;                 // 32x16x16
constexpr size_t F_C2   = F_V + 32*256;               // 32x16
constexpr size_t F_ZRES = F_C2 + 512;                 // BD x 96
constexpr size_t F_H2   = F_ZRES + (size_t)BD*96;     // BD x 48
constexpr size_t F_EN   = F_H2 + (size_t)BD*48;
constexpr size_t F_NE   = F_EN + BD;
constexpr size_t F_ATT  = F_NE + BD;
constexpr size_t F_A1   = F_ATT + BD;
constexpr size_t F_A2   = F_A1 + BD;
constexpr size_t F_RS   = F_A2 + BD;
constexpr size_t F_RQ   = F_RS + BD;                  // adjacent to F_RS (one memset)
constexpr size_t F_PS   = F_RQ + BD;                  // 1792 x 32
constexpr size_t F_PQ   = F_PS + 1792*32;
constexpr size_t F_BN   = F_PQ + 1792*32;             // bn affine params
constexpr size_t F_THR  = F_BN + 256;

typedef __attribute__((ext_vector_type(8))) short bf8;
typedef __attribute__((ext_vector_type(4))) float f4;

__device__ __forceinline__ float gelu_f(float x) {
  return 0.5f * x * (1.0f + erff(x * 0.70710678118654752440f));
}
__device__ __forceinline__ float sigm_f(float x) {
  return 1.0f / (1.0f + expf(-x));
}
__device__ __forceinline__ float wred(float v) {
#pragma unroll
  for (int o = 32; o > 0; o >>= 1) v += __shfl_down(v, o);
  return v;
}
__device__ __forceinline__ unsigned bfh_u(float v) {
  unsigned u = __float_as_uint(v);
  return (u + 0x7FFFu + ((u >> 16) & 1u)) >> 16;
}
__device__ __forceinline__ float bf2f(unsigned h) { return __uint_as_float(h << 16); }

// ---------------- constant generation ----------------
// B1T[c][r] = 2*cos(pi*(r+0.5)*c/512)        (DCT,  reduction index r)
// B2T[c][r] = cos(pi*(c+0.5)*r/512)*sc[r]    (iDCT, reduction index r), sc0=1/1024 else 1/512
__global__ void k_gen_b(ushort* __restrict__ B1H, ushort* __restrict__ B1L,
                        ushort* __restrict__ B2H, ushort* __restrict__ B2L) {
  int c = blockIdx.x;
  for (int r = threadIdx.x; r < 512; r += 256) {
    double c1 = cos(3.14159265358979323846 * (r + 0.5) * c / 512.0);
    float v1 = (float)(2.0 * c1);
    unsigned h = bfh_u(v1);
    B1H[(size_t)c*512 + r] = (ushort)h;
    B1L[(size_t)c*512 + r] = (ushort)bfh_u(v1 - bf2f(h));
    double c2 = cos(3.14159265358979323846 * (c + 0.5) * r / 512.0);
    float v2 = (float)(c2 * (r == 0 ? (1.0/1024.0) : (1.0/512.0)));
    h = bfh_u(v2);
    B2H[(size_t)c*512 + r] = (ushort)h;
    B2L[(size_t)c*512 + r] = (ushort)bfh_u(v2 - bf2f(h));
  }
}

__global__ void k_ucsum2(float* __restrict__ u, float* __restrict__ csum,
                         const float* __restrict__ wf) {
  int l = blockIdx.x*256 + threadIdx.x;
  if (l >= 512) return;
  double s = 1.0/1024.0;
  for (int k = 1; k < 512; ++k) s += cos(3.14159265358979323846*(l+0.5)*k/512.0) / 512.0;
  csum[l] = (float)s;
  double uu = (double)wf[0] * 45.25483399593904156 / 1024.0;      // sqrt(2048)*M[0][l]
  for (int k = 1; k < 5; ++k)
    uu += (double)wf[k] * 32.0 * cos(3.14159265358979323846*(l+0.5)*k/512.0) / 512.0;
  u[l] = (float)uu;
}

__global__ __launch_bounds__(256) void k_w2(const float* __restrict__ linW,
    const float* __restrict__ linb, const float* __restrict__ eW, const float* __restrict__ eb,
    float* __restrict__ W2, float* __restrict__ cst)
{
  __shared__ float sW[768];
  __shared__ float sb[48];
  __shared__ float rbuf[256];
  int o = blockIdx.x, t = threadIdx.x;
  for (int i = t; i < 768; i += 256) sW[i] = eW[i];
  if (t < 48) sb[t] = eb[t];
  __syncthreads();
  const float* lw = linW + (size_t)o * 1536;
  for (int i = t; i < 512; i += 256) {
    int n = i >> 4, p = i & 15;
    float s = 0.f;
    const float* l2 = lw + n*48;
#pragma unroll 8
    for (int m = 0; m < 48; ++m) s += l2[m] * sW[m*16 + p];
    W2[(size_t)o*512 + i] = s;
  }
  float c = 0.f;
  for (int i = t; i < 1536; i += 256) c += lw[i] * sb[i % 48];
  rbuf[t] = c; __syncthreads();
  for (int off = 128; off > 0; off >>= 1) { if (t < off) rbuf[t] += rbuf[t+off]; __syncthreads(); }
  if (t == 0) cst[o] = rbuf[0] + linb[o];
}

__global__ void k_v(const float* __restrict__ eW, const float* __restrict__ eb,
                    const float* __restrict__ dw, const float* __restrict__ db,
                    float* __restrict__ V, float* __restrict__ c2)
{
  int n = blockIdx.x, t = threadIdx.x;
  int p = t >> 4, q = t & 15;
  float s = 0.f;
#pragma unroll
  for (int j = 0; j < 3; ++j) s += eW[(p*3+j)*16 + q] * dw[n*3+j];
  V[(size_t)n*256 + p*16 + q] = s;
  if (q == 0) {
    float c = 0.f;
#pragma unroll
    for (int j = 0; j < 3; ++j) c += eb[p*3+j] * dw[n*3+j];
    c2[n*16+p] = c + db[n];
  }
}

// ---------------- transpose [B,L,D] -> [B*D, L] ----------------
__global__ __launch_bounds__(256) void k_transpose(const float* __restrict__ x, float* __restrict__ xp) {
  __shared__ float s[3584];
  int b = blockIdx.x;
  const float* src = x + (size_t)b*3584;
  for (int c = threadIdx.x; c < 896; c += 256) {
    float4 v = *(const float4*)&src[c*4];
    s[c*4+0]=v.x; s[c*4+1]=v.y; s[c*4+2]=v.z; s[c*4+3]=v.w;
  }
  __syncthreads();
  for (int c = threadIdx.x; c < 896; c += 256) {
    int d = c >> 7, cg = c & 127;
    float4 v;
    v.x = s[(cg*4+0)*7 + d]; v.y = s[(cg*4+1)*7 + d];
    v.z = s[(cg*4+2)*7 + d]; v.w = s[(cg*4+3)*7 + d];
    *(float4*)&xp[((size_t)b*7 + d)*512 + cg*4] = v;
  }
}

// ---------------- MFMA bf16-split GEMM: C[M,512] = A[M,512] @ B[512,512] ----------------
// BM=64, BN=256, BK=32; 4 waves, each 64x64 (4x4 frags of 16x16x32); 3-term bf16 split.
// MODE 2: A from f32 (split at stage); epilogue g=gelu(acc*mask*w+b) -> GH/GL planes + row stats
// MODE 1: A from GH/GL planes; epilogue z1 = aR*acc + cR*csum + xp*w + b -> f32
template<int MODE>
__global__ __launch_bounds__(256) void k_mfma(
    const float* __restrict__ Af32,
    const ushort* __restrict__ AHg, const ushort* __restrict__ ALg,
    const ushort* __restrict__ BHg, const ushort* __restrict__ BLg,
    float* __restrict__ z1out, ushort* __restrict__ GH, ushort* __restrict__ GL,
    const float* __restrict__ bnac, const float* __restrict__ csum,
    const float* __restrict__ xp,
    const float* __restrict__ cw, const float* __restrict__ cb,
    const float* __restrict__ ne, const float* __restrict__ thr,
    float* __restrict__ rs, float* __restrict__ rq)
{
  __shared__ ushort AhS[64*40], AlS[64*40];
  __shared__ ushort BhS[256*40], BlS[256*40];
  const int t = threadIdx.x;
  const int lane = t & 63, w = t >> 6;
  const int l15 = lane & 15, l4 = lane >> 4;
  const int r0 = blockIdx.x * 64, c0 = blockIdx.y * 256;

  f4 acc[4][4];
#pragma unroll
  for (int i = 0; i < 4; ++i)
#pragma unroll
    for (int j = 0; j < 4; ++j) acc[i][j] = (f4){0.f,0.f,0.f,0.f};

  const int arow = t >> 2, ak0 = (t & 3) * 8;

  for (int kt = 0; kt < 512; kt += 32) {
    // ---- stage A (64x32) ----
    if (MODE == 2) {
      const float* src = Af32 + (size_t)(r0+arow)*512 + kt + ak0;
      float4 v0 = *(const float4*)src;
      float4 v1 = *(const float4*)(src+4);
      float va[8] = {v0.x,v0.y,v0.z,v0.w,v1.x,v1.y,v1.z,v1.w};
      bf8 hv, lv;
#pragma unroll
      for (int j = 0; j < 8; ++j) {
        unsigned hb = bfh_u(va[j]);
        hv[j] = (short)hb;
        lv[j] = (short)bfh_u(va[j] - bf2f(hb));
      }
      *(bf8*)&AhS[arow*40 + ak0] = hv;
      *(bf8*)&AlS[arow*40 + ak0] = lv;
    } else {
      *(bf8*)&AhS[arow*40 + ak0] = *(const bf8*)&AHg[(size_t)(r0+arow)*512 + kt + ak0];
      *(bf8*)&AlS[arow*40 + ak0] = *(const bf8*)&ALg[(size_t)(r0+arow)*512 + kt + ak0];
    }
    // ---- stage B (256 cols x 32 k, transposed source) ----
#pragma unroll
    for (int h = 0; h < 4; ++h) {
      int c = t + h*256;
      int brow = c >> 2, bk0 = (c & 3) * 8;
      *(bf8*)&BhS[brow*40 + bk0] = *(const bf8*)&BHg[(size_t)(c0+brow)*512 + kt + bk0];
      *(bf8*)&BlS[brow*40 + bk0] = *(const bf8*)&BLg[(size_t)(c0+brow)*512 + kt + bk0];
    }
    __syncthreads();
    // ---- compute ----
    bf8 ah[4], al[4], bh[4], bl[4];
#pragma unroll
    for (int fr = 0; fr < 4; ++fr) {
      int off = (fr*16 + l15)*40 + l4*8;
      ah[fr] = *(const bf8*)&AhS[off];
      al[fr] = *(const bf8*)&AlS[off];
    }
#pragma unroll
    for (int fc = 0; fc < 4; ++fc) {
      int off = (w*64 + fc*16 + l15)*40 + l4*8;
      bh[fc] = *(const bf8*)&BhS[off];
      bl[fc] = *(const bf8*)&BlS[off];
    }
#pragma unroll
    for (int fr = 0; fr < 4; ++fr)
#pragma unroll
      for (int fc = 0; fc < 4; ++fc) {
        acc[fr][fc] = __builtin_amdgcn_mfma_f32_16x16x32_bf16(ah[fr], bh[fc], acc[fr][fc], 0, 0, 0);
        acc[fr][fc] = __builtin_amdgcn_mfma_f32_16x16x32_bf16(ah[fr], bl[fc], acc[fr][fc], 0, 0, 0);
        acc[fr][fc] = __builtin_amdgcn_mfma_f32_16x16x32_bf16(al[fr], bh[fc], acc[fr][fc], 0, 0, 0);
      }
    __syncthreads();
  }

  // ---- epilogue ----
  const float thv = (MODE == 2) ? thr[0] : 0.f;
#pragma unroll
  for (int fr = 0; fr < 4; ++fr)
#pragma unroll
    for (int j = 0; j < 4; ++j) {
      const int r = r0 + fr*16 + l4*4 + j;
      const int d = r % 7;
      if (MODE == 1) {
        const float aR = bnac[d], cR = bnac[7+d], wv = cw[d], bvv = cb[d];
#pragma unroll
        for (int fc = 0; fc < 4; ++fc) {
          int col = c0 + w*64 + fc*16 + l15;
          float val = acc[fr][fc][j];
          z1out[(size_t)r*512 + col] = aR*val + cR*csum[col] + xp[(size_t)r*512 + col]*wv + bvv;
        }
      } else {
        float m = (ne[r] > thv) ? 1.0f : 0.0f;
        float wm = cw[d] * m, bvv = cb[d];
        float s = 0.f, q = 0.f;
#pragma unroll
        for (int fc = 0; fc < 4; ++fc) {
          int col = c0 + w*64 + fc*16 + l15;
          float g = gelu_f(acc[fr][fc][j]*wm + bvv);
          unsigned hb = bfh_u(g);
          GH[(size_t)r*512 + col] = (ushort)hb;
          GL[(size_t)r*512 + col] = (ushort)bfh_u(g - bf2f(hb));
          s += g; q += g*g;
        }
#pragma unroll
        for (int off = 8; off > 0; off >>= 1) {
          s += __shfl_down(s, off, 16);
          q += __shfl_down(q, off, 16);
        }
        if (l15 == 0) { atomicAdd(&rs[r], s); atomicAdd(&rq[r], q); }
      }
    }
}

// ---------------- NT GEMM: out[M,Ncols] = A[M,512] @ W[Ncols,512]^T + bias ----------------
template<int MODE, bool TRANS, bool STATS>
__global__ __launch_bounds__(256) void k_gemm_nt(
    const float* __restrict__ A, const float* __restrict__ W, const float* __restrict__ bias,
    float* __restrict__ out, int Ncols, int ldOut,
    const float* __restrict__ ta, const float* __restrict__ tc,
    float* __restrict__ rs, float* __restrict__ rq)
{
  __shared__ float As[64][33];
  __shared__ float Bs[32][68];
  const int t = threadIdx.x;
  const int tx = t & 15, ty = t >> 4;
  const int r0 = blockIdx.x*64, c0 = blockIdx.y*64;
  float acc[4][4];
#pragma unroll
  for (int i = 0; i < 4; ++i)
#pragma unroll
    for (int j = 0; j < 4; ++j) acc[i][j] = 0.f;

  for (int kt = 0; kt < 512; kt += 32) {
#pragma unroll
    for (int h = 0; h < 2; ++h) {
      int c = t + h*256;
      int row = c >> 3, cg = c & 7;
      float4 v = *(const float4*)&A[(size_t)(r0+row)*512 + kt + cg*4];
      if (TRANS) {
        int d = (r0 + row) % 7;
        float aa = ta[d], cc = tc[d];
        v.x = gelu_f(aa*v.x + cc); v.y = gelu_f(aa*v.y + cc);
        v.z = gelu_f(aa*v.z + cc); v.w = gelu_f(aa*v.w + cc);
      }
      As[row][cg*4+0]=v.x; As[row][cg*4+1]=v.y; As[row][cg*4+2]=v.z; As[row][cg*4+3]=v.w;
    }
#pragma unroll
    for (int h = 0; h < 2; ++h) {
      int c = t + h*256;
      int row = c >> 3, cg = c & 7;
      int o = c0 + row;
      float4 v = make_float4(0.f,0.f,0.f,0.f);
      if (o < Ncols) v = *(const float4*)&W[(size_t)o*512 + kt + cg*4];
      Bs[cg*4+0][row]=v.x; Bs[cg*4+1][row]=v.y; Bs[cg*4+2][row]=v.z; Bs[cg*4+3][row]=v.w;
    }
    __syncthreads();
#pragma unroll
    for (int kk = 0; kk < 32; ++kk) {
      float av[4];
#pragma unroll
      for (int i = 0; i < 4; ++i) av[i] = As[ty*4+i][kk];
      float4 b = *(const float4*)&Bs[kk][tx*4];
      float bv[4] = {b.x,b.y,b.z,b.w};
#pragma unroll
      for (int i = 0; i < 4; ++i)
#pragma unroll
        for (int j = 0; j < 4; ++j) acc[i][j] += av[i]*bv[j];
    }
    __syncthreads();
  }
#pragma unroll
  for (int i = 0; i < 4; ++i) {
    int r = r0 + ty*4 + i;
    float s = 0.f, q = 0.f;
#pragma unroll
    for (int j = 0; j < 4; ++j) {
      int col = c0 + tx*4 + j;
      if (col < Ncols) {
        float v = acc[i][j] + bias[col];
        if (MODE == 1) { float g = gelu_f(v); v = g*v; }
        out[(size_t)r*ldOut + col] = v;
        if (STATS) { s += v; q += v*v; }
      }
    }
    if (STATS) {
#pragma unroll
      for (int off = 8; off > 0; off >>= 1) {
        s += __shfl_down(s, off, 16);
        q += __shfl_down(q, off, 16);
      }
      if (tx == 0) { rs[r] = s; rq[r] = q; }
    }
  }
}

// ---------------- analytic DCT energy (Parseval): 2L*sum(x^2) + 2*(sum x)^2 ----------------
__global__ void k_energy_an(const float* __restrict__ xp, float* __restrict__ en) {
  int r = blockIdx.x*4 + (threadIdx.x >> 6);
  int lane = threadIdx.x & 63;
  const float* row = xp + (size_t)r*512;
  double s = 0.0, q = 0.0;
  for (int i = lane; i < 512; i += 64) { double v = row[i]; s += v; q += v*v; }
#pragma unroll
  for (int o = 32; o > 0; o >>= 1) { s += __shfl_down(s, o); q += __shfl_down(q, o); }
  if (lane == 0) en[r] = (float)(1024.0*q + 2.0*s*s);
}

__global__ void k_ne(const float* __restrict__ en, float* __restrict__ ne) {
  int b = blockIdx.x*256 + threadIdx.x;
  if (b >= 2048) return;
  float e[7], s7[7];
#pragma unroll
  for (int d = 0; d < 7; ++d) { e[d] = en[b*7+d]; s7[d] = e[d]; }
#pragma unroll
  for (int i = 1; i < 7; ++i) {
    float key = s7[i]; int j = i-1;
    while (j >= 0 && s7[j] > key) { s7[j+1] = s7[j]; --j; }
    s7[j+1] = key;
  }
  float med = s7[3] + 1e-6f;
#pragma unroll
  for (int d = 0; d < 7; ++d) ne[b*7+d] = e[d] / med;
}

// exact k-th-smallest via register-resident 4-bit radix select.
__global__ __launch_bounds__(1024) void k_thr(const float* __restrict__ ne,
                                              const float* __restrict__ qp, float* __restrict__ out)
{
  __shared__ unsigned s_part[16][8];
  __shared__ unsigned s_bsel, s_R;
  const int t = threadIdx.x;
  const int lane = t & 63, wv = t >> 6;
  unsigned key[14];
#pragma unroll
  for (int j = 0; j < 14; ++j) key[j] = __float_as_uint(ne[t + j*1024]);

  float q = qp[0];
  float pos = q * 14335.0f;
  int lo = (int)floorf(pos);
  if (lo < 0) lo = 0; if (lo > 14335) lo = 14335;
  int hi = lo + 1; if (hi > 14335) hi = 14335;
  float frac = pos - (float)lo;

  unsigned prefix = 0;
  unsigned R = (unsigned)lo;
#pragma unroll 1
  for (int shift = 28; shift >= 0; shift -= 4) {
    unsigned pb = prefix >> shift;
    unsigned long long accb = 0ull;
#pragma unroll
    for (int j = 0; j < 14; ++j) {
      unsigned diff = (key[j] >> shift) - pb;
      accb += (diff < 16u) ? (1ull << (diff*4)) : 0ull;
    }
    unsigned pk[8];
#pragma unroll
    for (int b = 0; b < 8; ++b) {
      unsigned clo = (unsigned)(accb >> (b*4)) & 15u;
      unsigned chi = (unsigned)(accb >> (b*4+32)) & 15u;
      pk[b] = clo | (chi << 16);
    }
#pragma unroll
    for (int b = 0; b < 8; ++b)
#pragma unroll
      for (int o = 32; o > 0; o >>= 1) pk[b] += __shfl_down(pk[b], o);
    if (lane == 0) {
#pragma unroll
      for (int b = 0; b < 8; ++b) s_part[wv][b] = pk[b];
    }
    __syncthreads();
    if (t == 0) {
      unsigned tot[16];
#pragma unroll
      for (int i = 0; i < 8; ++i) {
        unsigned s = 0;
#pragma unroll
        for (int w2 = 0; w2 < 16; ++w2) s += s_part[w2][i];
        tot[i] = s & 0xFFFFu; tot[i+8] = s >> 16;
      }
      unsigned cum = 0, bsel = 15;
#pragma unroll 1
      for (int b = 0; b < 16; ++b) {
        if (cum + tot[b] > R) { bsel = (unsigned)b; break; }
        cum += tot[b];
      }
      s_bsel = bsel; s_R = R - cum;
    }
    __syncthreads();
    prefix |= (s_bsel << shift);
    R = s_R;
    __syncthreads();
  }
  unsigned cle = 0, mn = 0xFFFFFFFFu;
#pragma unroll
  for (int j = 0; j < 14; ++j) {
    cle += (key[j] <= prefix) ? 1u : 0u;
    if (key[j] > prefix && key[j] < mn) mn = key[j];
  }
#pragma unroll
  for (int o = 32; o > 0; o >>= 1) {
    cle += __shfl_down(cle, o);
    unsigned m2 = __shfl_down(mn, o);
    mn = (m2 < mn) ? m2 : mn;
  }
  if (lane == 0) { s_part[wv][0] = cle; s_part[wv][1] = mn; }
  __syncthreads();
  if (t == 0) {
    unsigned C = 0, M = 0xFFFFFFFFu;
#pragma unroll
    for (int w2 = 0; w2 < 16; ++w2) {
      C += s_part[w2][0];
      if (s_part[w2][1] < M) M = s_part[w2][1];
    }
    unsigned vhiKey = (C > (unsigned)hi) ? prefix : M;
    if (vhiKey == 0xFFFFFFFFu) vhiKey = prefix;
    float vlo = __uint_as_float(prefix);
    float vhi = __uint_as_float(vhiKey);
    out[0] = vlo*(1.0f-frac) + vhi*frac;
  }
}

// ---------------- BN finalize from per-row sums ----------------
__global__ __launch_bounds__(256) void k_bnfin_rows(const float* __restrict__ rs,
    const float* __restrict__ rq, int nch, int nrows, double count,
    const float* __restrict__ gamma, const float* __restrict__ beta, float* __restrict__ out)
{
  __shared__ double sd[256];
  int ch = blockIdx.x, t = threadIdx.x;
  double s = 0.0, q = 0.0;
  for (int i = ch + t*nch; i < nrows; i += 256*nch) { s += rs[i]; q += rq[i]; }
  sd[t] = s; __syncthreads();
  for (int o = 128; o > 0; o >>= 1) { if (t < o) sd[t] += sd[t+o]; __syncthreads(); }
  double S = sd[0]; __syncthreads();
  sd[t] = q; __syncthreads();
  for (int o = 128; o > 0; o >>= 1) { if (t < o) sd[t] += sd[t+o]; __syncthreads(); }
  if (t == 0) {
    double m = S / count;
    double v = sd[0] / count - m*m; if (v < 0.0) v = 0.0;
    double inv = 1.0 / sqrt(v + 1e-5);
    out[ch]       = (float)(gamma[ch] * inv);
    out[nch + ch] = (float)(beta[ch] - m * gamma[ch] * inv);
  }
}

__global__ __launch_bounds__(256) void k_bnfin_part(const float* __restrict__ pS,
    const float* __restrict__ pQ, int nparts, int nch, double count,
    const float* __restrict__ gamma, const float* __restrict__ beta, float* __restrict__ out)
{
  __shared__ double sd[256];
  int ch = blockIdx.x, t = threadIdx.x;
  double s = 0.0, q = 0.0;
  for (int i = t; i < nparts; i += 256) { s += pS[(size_t)i*nch + ch]; q += pQ[(size_t)i*nch + ch]; }
  sd[t] = s; __syncthreads();
  for (int o = 128; o > 0; o >>= 1) { if (t < o) sd[t] += sd[t+o]; __syncthreads(); }
  double S = sd[0]; __syncthreads();
  sd[t] = q; __syncthreads();
  for (int o = 128; o > 0; o >>= 1) { if (t < o) sd[t] += sd[t+o]; __syncthreads(); }
  if (t == 0) {
    double m = S / count;
    double v = sd[0] / count - m*m; if (v < 0.0) v = 0.0;
    double inv = 1.0 / sqrt(v + 1e-5);
    out[ch]       = (float)(gamma[ch] * inv);
    out[nch + ch] = (float)(beta[ch] - m * gamma[ch] * inv);
  }
}

// ---------------- patch path: z1r = V[n] @ xp-patch + c2 ----------------
__global__ __launch_bounds__(256) void k_patch(const float* __restrict__ xp,
    const float* __restrict__ V, const float* __restrict__ c2,
    float* __restrict__ z1r, float* __restrict__ pS, float* __restrict__ pQ)
{
  __shared__ float sx[8][512];
  __shared__ float aS[32], aQ[32];
  int t = threadIdx.x;
  int r0 = blockIdx.x * 8;
  for (int c = t; c < 1024; c += 256) {
    int row = c >> 7, cg = c & 127;
    *(float4*)&sx[row][cg*4] = *(const float4*)&xp[(size_t)(r0+row)*512 + cg*4];
  }
  if (t < 32) { aS[t] = 0.f; aQ[t] = 0.f; }
  __syncthreads();
  float vreg[2][16]; float cc[2]; int nn_[2], oo[2];
#pragma unroll
  for (int h = 0; h < 2; ++h) {
    int o = t + h*256;
    oo[h] = o;
    int n = o >> 4, p = o & 15;
    nn_[h] = n;
#pragma unroll
    for (int qg = 0; qg < 4; ++qg) {
      float4 v4 = *(const float4*)&V[(size_t)n*256 + p*16 + qg*4];
      vreg[h][qg*4+0]=v4.x; vreg[h][qg*4+1]=v4.y; vreg[h][qg*4+2]=v4.z; vreg[h][qg*4+3]=v4.w;
    }
    cc[h] = c2[o];
  }
  float sum[2] = {0.f,0.f}, sq[2] = {0.f,0.f};
  for (int row = 0; row < 8; ++row) {
#pragma unroll
    for (int h = 0; h < 2; ++h) {
      const float* xr = &sx[row][nn_[h]*16];
      float val = cc[h];
#pragma unroll
      for (int qq = 0; qq < 16; ++qq) val += vreg[h][qq] * xr[qq];
      z1r[(size_t)(r0+row)*512 + oo[h]] = val;
      sum[h] += val; sq[h] += val*val;
    }
  }
#pragma unroll
  for (int h = 0; h < 2; ++h) {
    atomicAdd(&aS[nn_[h]], sum[h]);
    atomicAdd(&aQ[nn_[h]], sq[h]);
  }
  __syncthreads();
  if (t < 32) { pS[(size_t)blockIdx.x*32 + t] = aS[t]; pQ[(size_t)blockIdx.x*32 + t] = aQ[t]; }
}

// ---------------- TopKFreq ----------------
__global__ void k_att(const float* __restrict__ z1, const float* __restrict__ z1r,
    const float* __restrict__ bn2, const float* __restrict__ u, const float* __restrict__ fcb,
    float* __restrict__ att)
{
  int r = blockIdx.x*4 + (threadIdx.x >> 6);
  int lane = threadIdx.x & 63;
  const float* z1p = z1 + (size_t)r*512;
  const float* zrp = z1r + (size_t)r*512;
  float s = 0.f;
#pragma unroll
  for (int h = 0; h < 2; ++h) {
    int i = lane*4 + h*256;
    int n = i >> 4;
    float a2n = bn2[n], c2n = bn2[32+n];
    float4 zr = *(const float4*)&zrp[i];
    float4 zv = *(const float4*)&z1p[i];
    float4 uv = *(const float4*)&u[i];
    s += (zv.x + gelu_f(a2n*zr.x + c2n)) * uv.x;
    s += (zv.y + gelu_f(a2n*zr.y + c2n)) * uv.y;
    s += (zv.z + gelu_f(a2n*zr.z + c2n)) * uv.z;
    s += (zv.w + gelu_f(a2n*zr.w + c2n)) * uv.w;
  }
  s = wred(s);
  if (lane == 0) att[r] = s + fcb[0];
}

__global__ __launch_bounds__(1024) void k_tf(const float* __restrict__ att,
    const float* __restrict__ pg, const float* __restrict__ pb,
    const float* __restrict__ pwc, const float* __restrict__ pbc,
    const float* __restrict__ pfb, float* __restrict__ a1, float* __restrict__ a2)
{
  __shared__ double sd[1024];
  __shared__ float sh[4];
  const int t = threadIdx.x;
  float g = pg[0], b = pb[0], wc = pwc[0], bc = pbc[0], fb = pfb[0];
  double s = 0.0, q = 0.0;
  for (int i = t; i < BD; i += 1024) { double v = att[i]; s += v; q += v*v; }
  sd[t] = s; __syncthreads();
  for (int o = 512; o > 0; o >>= 1) { if (t < o) sd[t] += sd[t+o]; __syncthreads(); }
  double S1 = sd[0]; __syncthreads();
  sd[t] = q; __syncthreads();
  for (int o = 512; o > 0; o >>= 1) { if (t < o) sd[t] += sd[t+o]; __syncthreads(); }
  if (t == 0) {
    double m = S1 / 14336.0;
    double v = sd[0] / 14336.0 - m*m; if (v < 0.0) v = 0.0;
    sh[0] = (float)m; sh[1] = (float)(1.0 / sqrt(v + 1e-5));
  }
  __syncthreads();
  float m1 = sh[0], i1 = sh[1];
  s = 0.0; q = 0.0;
  for (int i = t; i < BD; i += 1024) {
    float v = att[i];
    float an = (v - m1) * i1 * g + b;
    float av = sigm_f(gelu_f(an) * wc + bc);
    a1[i] = av;
    float t2 = av * (v - fb) + fb;
    s += t2; q += (double)t2 * t2;
  }
  __syncthreads();
  sd[t] = s; __syncthreads();
  for (int o = 512; o > 0; o >>= 1) { if (t < o) sd[t] += sd[t+o]; __syncthreads(); }
  double S2 = sd[0]; __syncthreads();
  sd[t] = q; __syncthreads();
  for (int o = 512; o > 0; o >>= 1) { if (t < o) sd[t] += sd[t+o]; __syncthreads(); }
  if (t == 0) {
    double m = S2 / 14336.0;
    double v = sd[0] / 14336.0 - m*m; if (v < 0.0) v = 0.0;
    sh[2] = (float)m; sh[3] = (float)(1.0 / sqrt(v + 1e-5));
  }
  __syncthreads();
  float m2 = sh[2], i2 = sh[3];
  for (int i = t; i < BD; i += 1024) {
    float t2 = a1[i] * (att[i] - fb) + fb;
    float an = (t2 - m2) * i2 * g + b;
    a2[i] = sigm_f(gelu_f(an) * wc + bc);
  }
}

// ---------------- elementwise stats passes (float4) ----------------
__global__ void k_statsA(const float* __restrict__ z1, const float* __restrict__ z1r,
    const float* __restrict__ bn2, const float* __restrict__ a1,
    float* __restrict__ rs, float* __restrict__ rq)
{
  int r = blockIdx.x*4 + (threadIdx.x >> 6);
  int lane = threadIdx.x & 63;
  float av = a1[r];
  const float* z1p = z1 + (size_t)r*512;
  const float* zrp = z1r + (size_t)r*512;
  float s = 0.f, q = 0.f;
#pragma unroll
  for (int h = 0; h < 2; ++h) {
    int i = lane*4 + h*256;
    int n = i >> 4;
    float a2n = bn2[n], c2n = bn2[32+n];
    float4 zr = *(const float4*)&zrp[i];
    float4 zv = *(const float4*)&z1p[i];
    float A0 = (zv.x + gelu_f(a2n*zr.x + c2n)) * av;
    float A1 = (zv.y + gelu_f(a2n*zr.y + c2n)) * av;
    float A2 = (zv.z + gelu_f(a2n*zr.z + c2n)) * av;
    float A3 = (zv.w + gelu_f(a2n*zr.w + c2n)) * av;
    s += A0+A1+A2+A3; q += A0*A0+A1*A1+A2*A2+A3*A3;
  }
  s = wred(s); q = wred(q);
  if (lane == 0) { rs[r] = s; rq[r] = q; }
}

__global__ void k_statsC(const float* __restrict__ z1, const float* __restrict__ z1r,
    const float* __restrict__ bn2, const float* __restrict__ a1,
    const float* __restrict__ bn3, const float* __restrict__ cw, const float* __restrict__ cb,
    float* __restrict__ rs, float* __restrict__ rq)
{
  int r = blockIdx.x*4 + (threadIdx.x >> 6);
  int lane = threadIdx.x & 63;
  int d = r % 7;
  float av = a1[r];
  float b3a = bn3[d], b3c = bn3[7+d], wv = cw[d], bv = cb[d];
  const float* z1p = z1 + (size_t)r*512;
  const float* zrp = z1r + (size_t)r*512;
  float s = 0.f, q = 0.f;
#pragma unroll
  for (int h = 0; h < 2; ++h) {
    int i = lane*4 + h*256;
    int n = i >> 4;
    float a2n = bn2[n], c2n = bn2[32+n];
    float4 zr = *(const float4*)&zrp[i];
    float4 zv = *(const float4*)&z1p[i];
#pragma unroll
    for (int e = 0; e < 4; ++e) {
      float ze = (e==0?zr.x:e==1?zr.y:e==2?zr.z:zr.w);
      float z1e = (e==0?zv.x:e==1?zv.y:e==2?zv.z:zv.w);
      float A = (z1e + gelu_f(a2n*ze + c2n)) * av;
      float C = wv*gelu_f(b3a*A + b3c) + bv;
      s += C; q += C*C;
    }
  }
  s = wred(s); q = wred(q);
  if (lane == 0) { rs[r] = s; rq[r] = q; }
}

__global__ void k_final(const float* __restrict__ z1, const float* __restrict__ z1r,
    const float* __restrict__ bn2, const float* __restrict__ a1, const float* __restrict__ a2,
    const float* __restrict__ bn3, const float* __restrict__ bn4,
    const float* __restrict__ cw, const float* __restrict__ cb,
    float* __restrict__ zf, float* __restrict__ rs, float* __restrict__ rq)
{
  int r = blockIdx.x*4 + (threadIdx.x >> 6);
  int lane = threadIdx.x & 63;
  int d = r % 7;
  float av = a1[r], a2v = a2[r];
  float b3a = bn3[d], b3c = bn3[7+d], b4a = bn4[d], b4c = bn4[7+d];
  float wv = cw[d], bv = cb[d];
  const float* z1p = z1 + (size_t)r*512;
  const float* zrp = z1r + (size_t)r*512;
  float* zfp = zf + (size_t)r*512;
  float s = 0.f, q = 0.f;
#pragma unroll
  for (int h = 0; h < 2; ++h) {
    int i = lane*4 + h*256;
    int n = i >> 4;
    float a2n = bn2[n], c2n = bn2[32+n];
    float4 zr = *(const float4*)&zrp[i];
    float4 zv = *(const float4*)&z1p[i];
    float4 ov;
#pragma unroll
    for (int e = 0; e < 4; ++e) {
      float ze = (e==0?zr.x:e==1?zr.y:e==2?zr.z:zr.w);
      float z1e = (e==0?zv.x:e==1?zv.y:e==2?zv.z:zv.w);
      float z1v = z1e * av;
      float z2v = gelu_f(a2n*ze + c2n) * av;
      float A = z1v + z2v;
      float C = wv*gelu_f(b3a*A + b3c) + bv;
      float inter = gelu_f(b4a*C + b4c) * a2v;
      float z1n = z1v*inter + z2v;
      float z2n = z2v*inter + z1n;
      float zfv = z1n*z2n + z1n + z2n;
      (e==0?ov.x:e==1?ov.y:e==2?ov.z:ov.w) = zfv;
      s += zfv; q += zfv*zfv;
    }
    *(float4*)&zfp[i] = ov;
  }
  s = wred(s); q = wred(q);
  if (lane == 0) { rs[r] = s; rq[r] = q; }
}

// ---------------- output: fc2 + bias + z_res + transpose ----------------
__global__ __launch_bounds__(256) void k_out(const float* __restrict__ h2,
    const float* __restrict__ bn6, const float* __restrict__ w2, const float* __restrict__ b2,
    const float* __restrict__ zres, float* __restrict__ out)
{
  int idx = blockIdx.x*256 + threadIdx.x;
  int r = idx / 96, o = idx - r*96;
  int d = r % 7, b = r / 7;
  float a6 = bn6[d], c6 = bn6[7+d];
  const float* hp = h2 + (size_t)r*48;
  const float* wp = w2 + o*48;
  float s = 0.f;
#pragma unroll
  for (int j4 = 0; j4 < 12; ++j4) {
    float4 hv = *(const float4*)&hp[j4*4];
    float4 wv = *(const float4*)&wp[j4*4];
    s += (a6*hv.x + c6)*wv.x + (a6*hv.y + c6)*wv.y
       + (a6*hv.z + c6)*wv.z + (a6*hv.w + c6)*wv.w;
  }
  out[(size_t)b*672 + o*7 + d] = s + b2[o] + zres[(size_t)r*96 + o];
}

// ================= host =================
extern "C" void kernel_launch(void* const* d_in, const int* in_sizes, int n_in,
                              void* d_out, int out_size, void* d_ws, size_t ws_size,
                              hipStream_t stream) {
  const float* x          = (const float*)d_in[0];
  const float* dctconv_w  = (const float*)d_in[1];
  const float* dctconv_b  = (const float*)d_in[2];
  const float* dctnorm_g  = (const float*)d_in[3];
  const float* dctnorm_b  = (const float*)d_in[4];
  const float* threshold  = (const float*)d_in[5];
  const float* embed_W    = (const float*)d_in[6];
  const float* embed_b    = (const float*)d_in[7];
  const float* linres_W   = (const float*)d_in[8];
  const float* linres_b   = (const float*)d_in[9];
  const float* depth1_w   = (const float*)d_in[10];
  const float* depth1_b   = (const float*)d_in[11];
  const float* depthnorm_g= (const float*)d_in[12];
  const float* depthnorm_b= (const float*)d_in[13];
  const float* tf_fc_w    = (const float*)d_in[14];
  const float* tf_fc_b    = (const float*)d_in[15];
  const float* tf_norm_g  = (const float*)d_in[16];
  const float* tf_norm_b  = (const float*)d_in[17];
  const float* tf_conv_w  = (const float*)d_in[18];
  const float* tf_conv_b  = (const float*)d_in[19];
  const float* mlp_w1     = (const float*)d_in[20];
  const float* mlp_b1     = (const float*)d_in[21];
  const float* mlp_w2     = (const float*)d_in[22];
  const float* mlp_b2     = (const float*)d_in[23];
  const float* mlpnorm_g  = (const float*)d_in[24];
  const float* mlpnorm_b  = (const float*)d_in[25];
  float* out = (float*)d_out;
  float* ws  = (float*)d_ws;

  float* XP   = ws + F_XP;
  float* ZG   = ws + F_ZG;        // z1r f32 (after GEMM2); GH/GL planes before
  ushort* ZGH = (ushort*)(ws + F_ZG);
  ushort* ZGL = ZGH + (size_t)BD*512;
  float* Z1   = ws + F_Z1;
  ushort* B1H = (ushort*)(ws + F_CLK);
  ushort* B1L = B1H + 512*512;
  ushort* B2H = (ushort*)(ws + F_MKL);
  ushort* B2L = B2H + 512*512;
  float* U    = ws + F_U;
  float* CSUM = ws + F_CSUM;
  float* W2p  = ws + F_W2;
  float* CSTp = ws + F_CST;
  float* Vp   = ws + F_V;
  float* C2p  = ws + F_C2;
  float* ZRES = ws + F_ZRES;
  float* H2p  = ws + F_H2;
  float* EN   = ws + F_EN;
  float* NEp  = ws + F_NE;
  float* ATTp = ws + F_ATT;
  float* A1p  = ws + F_A1;
  float* A2p  = ws + F_A2;
  float* RS   = ws + F_RS;
  float* RQ   = ws + F_RQ;
  float* PS   = ws + F_PS;
  float* PQ   = ws + F_PQ;
  float* BN0  = ws + F_BN;        // a[7], c[7]
  float* BN2  = ws + F_BN + 16;   // a[32], c[32]
  float* BN3  = ws + F_BN + 80;
  float* BN4  = ws + F_BN + 96;
  float* BN5  = ws + F_BN + 112;
  float* BN6  = ws + F_BN + 128;
  float* THRp = ws + F_THR;

  k_gen_b<<<512, 256, 0, stream>>>(B1H, B1L, B2H, B2L);
  k_ucsum2<<<2, 256, 0, stream>>>(U, CSUM, tf_fc_w);
  k_w2<<<96, 256, 0, stream>>>(linres_W, linres_b, embed_W, embed_b, W2p, CSTp);
  k_v<<<32, 256, 0, stream>>>(embed_W, embed_b, depth1_w, depth1_b, Vp, C2p);
  k_transpose<<<2048, 256, 0, stream>>>(x, XP);
  k_energy_an<<<3584, 256, 0, stream>>>(XP, EN);
  k_ne<<<8, 256, 0, stream>>>(EN, NEp);
  k_thr<<<1, 1024, 0, stream>>>(NEp, threshold, THRp);
  hipMemsetAsync(RS, 0, 2*BD*sizeof(float), stream);
  // GEMM1: z_dct -> masked dctconv -> gelu -> GH/GL planes (+ row stats)
  k_mfma<2><<<dim3(224,2), 256, 0, stream>>>(XP, nullptr, nullptr, B1H, B1L,
      nullptr, ZGH, ZGL, nullptr, nullptr, nullptr, dctconv_w, dctconv_b,
      NEp, THRp, RS, RQ);
  k_bnfin_rows<<<7, 256, 0, stream>>>(RS, RQ, 7, BD, 1048576.0, dctnorm_g, dctnorm_b, BN0);
  // GEMM2: z1 = BN(g) @ M + x_res  (BN folded via column sums)
  k_mfma<1><<<dim3(224,2), 256, 0, stream>>>(nullptr, ZGH, ZGL, B2H, B2L,
      Z1, nullptr, nullptr, BN0, CSUM, XP, dctconv_w, dctconv_b,
      nullptr, nullptr, nullptr, nullptr);
  k_patch<<<1792, 256, 0, stream>>>(XP, Vp, C2p, ZG, PS, PQ);
  k_bnfin_part<<<32, 256, 0, stream>>>(PS, PQ, 1792, 32, 229376.0, depthnorm_g, depthnorm_b, BN2);
  k_gemm_nt<0,false,false><<<dim3(224,2), 256, 0, stream>>>(XP, W2p, CSTp, ZRES, 96, 96,
      nullptr, nullptr, nullptr, nullptr);
  k_att<<<3584, 256, 0, stream>>>(Z1, ZG, BN2, U, tf_fc_b, ATTp);
  k_tf<<<1, 1024, 0, stream>>>(ATTp, tf_norm_g, tf_norm_b, tf_conv_w, tf_conv_b, tf_fc_b, A1p, A2p);
  k_statsA<<<3584, 256, 0, stream>>>(Z1, ZG, BN2, A1p, RS, RQ);
  k_bnfin_rows<<<7, 256, 0, stream>>>(RS, RQ, 7, BD, 1048576.0, dctnorm_g, dctnorm_b, BN3);
  k_statsC<<<3584, 256, 0, stream>>>(Z1, ZG, BN2, A1p, BN3, dctconv_w, dctconv_b, RS, RQ);
  k_bnfin_rows<<<7, 256, 0, stream>>>(RS, RQ, 7, BD, 1048576.0, dctnorm_g, dctnorm_b, BN4);
  k_final<<<3584, 256, 0, stream>>>(Z1, ZG, BN2, A1p, A2p, BN3, BN4, dctconv_w, dctconv_b, XP, RS, RQ);
  k_bnfin_rows<<<7, 256, 0, stream>>>(RS, RQ, 7, BD, 1048576.0, dctnorm_g, dctnorm_b, BN5);
  k_gemm_nt<1,true,true><<<dim3(224,1), 256, 0, stream>>>(XP, mlp_w1, mlp_b1, H2p, 48, 48,
      BN5, BN5+7, RS, RQ);
  k_bnfin_rows<<<7, 256, 0, stream>>>(RS, RQ, 7, BD, 98304.0, mlpnorm_g, mlpnorm_b, BN6);
  k_out<<<5376, 256, 0, stream>>>(H2p, BN6, mlp_w2, mlp_b2, ZRES, out);
}

// Round 5
// 432.281 us; speedup vs baseline: 1.9187x; 1.2035x over previous
//
#include <hip/hip_runtime.h>
#include <math.h>

#define BB 2048
#define LL 512
#define DD 7
#define BD 14336   // BB*DD

// ---------------- ws layout (floats) ----------------
constexpr size_t F_XP   = 0;                          // xp, later zf
constexpr size_t F_ZG   = F_XP  + (size_t)BD*512;     // ZGH/ZGL planes -> z1r f32
constexpr size_t F_Z1   = F_ZG  + (size_t)BD*512;     // z1
constexpr size_t F_CLK  = F_Z1  + (size_t)BD*512;     // B1H/B1L (ushort planes)
constexpr size_t F_MKL  = F_CLK + 512*512;            // B2H/B2L (ushort planes)
constexpr size_t F_U    = F_MKL + 512*512;
constexpr size_t F_CSUM = F_U + 512;
constexpr size_t F_W2   = F_CSUM + 512;               // 96x512
constexpr size_t F_CST  = F_W2 + 96*512;
constexpr size_t F_V    = F_CST + 96;                 // 32x16x16
constexpr size_t F_C2   = F_V + 32*256;               // 32x16
constexpr size_t F_ZRES = F_C2 + 512;                 // BD x 96
constexpr size_t F_H2   = F_ZRES + (size_t)BD*96;     // BD x 48
constexpr size_t F_EN   = F_H2 + (size_t)BD*48;
constexpr size_t F_NE   = F_EN + BD;
constexpr size_t F_ATT  = F_NE + BD;
constexpr size_t F_A1   = F_ATT + BD;
constexpr size_t F_A2   = F_A1 + BD;
constexpr size_t F_RS   = F_A2 + BD;
constexpr size_t F_RQ   = F_RS + BD;                  // adjacent to F_RS (one memset)
constexpr size_t F_PS   = F_RQ + BD;                  // 1792 x 32
constexpr size_t F_PQ   = F_PS + 1792*32;
constexpr size_t F_BN   = F_PQ + 1792*32;             // bn affine params
constexpr size_t F_THR  = F_BN + 256;

typedef __attribute__((ext_vector_type(8))) short bf8;
typedef __attribute__((ext_vector_type(4))) float f4;

__device__ __forceinline__ float gelu_f(float x) {
  return 0.5f * x * (1.0f + erff(x * 0.70710678118654752440f));
}
__device__ __forceinline__ float sigm_f(float x) {
  return 1.0f / (1.0f + expf(-x));
}
__device__ __forceinline__ float wred(float v) {
#pragma unroll
  for (int o = 32; o > 0; o >>= 1) v += __shfl_down(v, o);
  return v;
}
__device__ __forceinline__ unsigned bfh_u(float v) {
  unsigned u = __float_as_uint(v);
  return (u + 0x7FFFu + ((u >> 16) & 1u)) >> 16;
}
__device__ __forceinline__ float bf2f(unsigned h) { return __uint_as_float(h << 16); }

// ---------------- constant generation ----------------
// B1T[c][r] = 2*cos(pi*(r+0.5)*c/512)        (DCT,  reduction index r)
// B2T[c][r] = cos(pi*(c+0.5)*r/512)*sc[r]    (iDCT, reduction index r), sc0=1/1024 else 1/512
__global__ void k_gen_b(ushort* __restrict__ B1H, ushort* __restrict__ B1L,
                        ushort* __restrict__ B2H, ushort* __restrict__ B2L) {
  int c = blockIdx.x;
  for (int r = threadIdx.x; r < 512; r += 256) {
    double c1 = cos(3.14159265358979323846 * (r + 0.5) * c / 512.0);
    float v1 = (float)(2.0 * c1);
    unsigned h = bfh_u(v1);
    B1H[(size_t)c*512 + r] = (ushort)h;
    B1L[(size_t)c*512 + r] = (ushort)bfh_u(v1 - bf2f(h));
    double c2 = cos(3.14159265358979323846 * (c + 0.5) * r / 512.0);
    float v2 = (float)(c2 * (r == 0 ? (1.0/1024.0) : (1.0/512.0)));
    h = bfh_u(v2);
    B2H[(size_t)c*512 + r] = (ushort)h;
    B2L[(size_t)c*512 + r] = (ushort)bfh_u(v2 - bf2f(h));
  }
}

// csum[l] = sum_k M[k][l] in closed form:
//   theta = pi*(l+0.5)/512, s=(-1)^l
//   sum_{k=0}^{511} cos(k*theta) = 1/2 + s/(2*tan(theta/2))
__global__ void k_ucsum2(float* __restrict__ u, float* __restrict__ csum,
                         const float* __restrict__ wf) {
  int l = blockIdx.x*256 + threadIdx.x;
  if (l >= 512) return;
  double th2 = 3.14159265358979323846 * (double)(2*l + 1) / 2048.0;   // theta/2
  double s = (l & 1) ? -1.0 : 1.0;
  double S = 0.5*s/tan(th2) - 0.5;          // sum_{k=1}^{511} cos(k*theta)
  csum[l] = (float)(1.0/1024.0 + S/512.0);
  double uu = (double)wf[0] * 45.25483399593904156 / 1024.0;      // sqrt(2048)*M[0][l]
  for (int k = 1; k < 5; ++k)
    uu += (double)wf[k] * 32.0 * cos(3.14159265358979323846*(l+0.5)*k/512.0) / 512.0;
  u[l] = (float)uu;
}

__global__ __launch_bounds__(256) void k_w2(const float* __restrict__ linW,
    const float* __restrict__ linb, const float* __restrict__ eW, const float* __restrict__ eb,
    float* __restrict__ W2, float* __restrict__ cst)
{
  __shared__ float sW[768];
  __shared__ float sb[48];
  __shared__ float rbuf[256];
  int o = blockIdx.x, t = threadIdx.x;
  for (int i = t; i < 768; i += 256) sW[i] = eW[i];
  if (t < 48) sb[t] = eb[t];
  __syncthreads();
  const float* lw = linW + (size_t)o * 1536;
  for (int i = t; i < 512; i += 256) {
    int n = i >> 4, p = i & 15;
    float s = 0.f;
    const float* l2 = lw + n*48;
#pragma unroll 8
    for (int m = 0; m < 48; ++m) s += l2[m] * sW[m*16 + p];
    W2[(size_t)o*512 + i] = s;
  }
  float c = 0.f;
  for (int i = t; i < 1536; i += 256) c += lw[i] * sb[i % 48];
  rbuf[t] = c; __syncthreads();
  for (int off = 128; off > 0; off >>= 1) { if (t < off) rbuf[t] += rbuf[t+off]; __syncthreads(); }
  if (t == 0) cst[o] = rbuf[0] + linb[o];
}

__global__ void k_v(const float* __restrict__ eW, const float* __restrict__ eb,
                    const float* __restrict__ dw, const float* __restrict__ db,
                    float* __restrict__ V, float* __restrict__ c2)
{
  int n = blockIdx.x, t = threadIdx.x;
  int p = t >> 4, q = t & 15;
  float s = 0.f;
#pragma unroll
  for (int j = 0; j < 3; ++j) s += eW[(p*3+j)*16 + q] * dw[n*3+j];
  V[(size_t)n*256 + p*16 + q] = s;
  if (q == 0) {
    float c = 0.f;
#pragma unroll
    for (int j = 0; j < 3; ++j) c += eb[p*3+j] * dw[n*3+j];
    c2[n*16+p] = c + db[n];
  }
}

// ---------------- transpose [B,L,D] -> [B*D, L] ----------------
__global__ __launch_bounds__(256) void k_transpose(const float* __restrict__ x, float* __restrict__ xp) {
  __shared__ float s[3584];
  int b = blockIdx.x;
  const float* src = x + (size_t)b*3584;
  for (int c = threadIdx.x; c < 896; c += 256) {
    float4 v = *(const float4*)&src[c*4];
    s[c*4+0]=v.x; s[c*4+1]=v.y; s[c*4+2]=v.z; s[c*4+3]=v.w;
  }
  __syncthreads();
  for (int c = threadIdx.x; c < 896; c += 256) {
    int d = c >> 7, cg = c & 127;
    float4 v;
    v.x = s[(cg*4+0)*7 + d]; v.y = s[(cg*4+1)*7 + d];
    v.z = s[(cg*4+2)*7 + d]; v.w = s[(cg*4+3)*7 + d];
    *(float4*)&xp[((size_t)b*7 + d)*512 + cg*4] = v;
  }
}

// ---------------- MFMA bf16-split GEMM: C[M,512] = A[M,512] @ B[512,512] ----------------
// BM=64, BN=256, BK=32; 4 waves, each 64x64 (4x4 frags of 16x16x32); 3-term bf16 split.
// MODE 2: A from f32 (split at stage); epilogue g=gelu(acc*mask*w+b) -> GH/GL planes + row stats
// MODE 1: A from GH/GL planes; epilogue z1 = aR*acc + cR*csum + xp*w + b -> f32
template<int MODE>
__global__ __launch_bounds__(256) void k_mfma(
    const float* __restrict__ Af32,
    const ushort* __restrict__ AHg, const ushort* __restrict__ ALg,
    const ushort* __restrict__ BHg, const ushort* __restrict__ BLg,
    float* __restrict__ z1out, ushort* __restrict__ GH, ushort* __restrict__ GL,
    const float* __restrict__ bnac, const float* __restrict__ csum,
    const float* __restrict__ xp,
    const float* __restrict__ cw, const float* __restrict__ cb,
    const float* __restrict__ ne, const float* __restrict__ thr,
    float* __restrict__ rs, float* __restrict__ rq)
{
  __shared__ ushort AhS[64*40], AlS[64*40];
  __shared__ ushort BhS[256*40], BlS[256*40];
  const int t = threadIdx.x;
  const int lane = t & 63, w = t >> 6;
  const int l15 = lane & 15, l4 = lane >> 4;
  const int r0 = blockIdx.x * 64, c0 = blockIdx.y * 256;

  f4 acc[4][4];
#pragma unroll
  for (int i = 0; i < 4; ++i)
#pragma unroll
    for (int j = 0; j < 4; ++j) acc[i][j] = (f4){0.f,0.f,0.f,0.f};

  const int arow = t >> 2, ak0 = (t & 3) * 8;

  for (int kt = 0; kt < 512; kt += 32) {
    // ---- stage A (64x32) ----
    if (MODE == 2) {
      const float* src = Af32 + (size_t)(r0+arow)*512 + kt + ak0;
      float4 v0 = *(const float4*)src;
      float4 v1 = *(const float4*)(src+4);
      float va[8] = {v0.x,v0.y,v0.z,v0.w,v1.x,v1.y,v1.z,v1.w};
      bf8 hv, lv;
#pragma unroll
      for (int j = 0; j < 8; ++j) {
        unsigned hb = bfh_u(va[j]);
        hv[j] = (short)hb;
        lv[j] = (short)bfh_u(va[j] - bf2f(hb));
      }
      *(bf8*)&AhS[arow*40 + ak0] = hv;
      *(bf8*)&AlS[arow*40 + ak0] = lv;
    } else {
      *(bf8*)&AhS[arow*40 + ak0] = *(const bf8*)&AHg[(size_t)(r0+arow)*512 + kt + ak0];
      *(bf8*)&AlS[arow*40 + ak0] = *(const bf8*)&ALg[(size_t)(r0+arow)*512 + kt + ak0];
    }
    // ---- stage B (256 cols x 32 k, transposed source) ----
#pragma unroll
    for (int h = 0; h < 4; ++h) {
      int c = t + h*256;
      int brow = c >> 2, bk0 = (c & 3) * 8;
      *(bf8*)&BhS[brow*40 + bk0] = *(const bf8*)&BHg[(size_t)(c0+brow)*512 + kt + bk0];
      *(bf8*)&BlS[brow*40 + bk0] = *(const bf8*)&BLg[(size_t)(c0+brow)*512 + kt + bk0];
    }
    __syncthreads();
    // ---- compute ----
    bf8 ah[4], al[4], bh[4], bl[4];
#pragma unroll
    for (int fr = 0; fr < 4; ++fr) {
      int off = (fr*16 + l15)*40 + l4*8;
      ah[fr] = *(const bf8*)&AhS[off];
      al[fr] = *(const bf8*)&AlS[off];
    }
#pragma unroll
    for (int fc = 0; fc < 4; ++fc) {
      int off = (w*64 + fc*16 + l15)*40 + l4*8;
      bh[fc] = *(const bf8*)&BhS[off];
      bl[fc] = *(const bf8*)&BlS[off];
    }
#pragma unroll
    for (int fr = 0; fr < 4; ++fr)
#pragma unroll
      for (int fc = 0; fc < 4; ++fc) {
        acc[fr][fc] = __builtin_amdgcn_mfma_f32_16x16x32_bf16(ah[fr], bh[fc], acc[fr][fc], 0, 0, 0);
        acc[fr][fc] = __builtin_amdgcn_mfma_f32_16x16x32_bf16(ah[fr], bl[fc], acc[fr][fc], 0, 0, 0);
        acc[fr][fc] = __builtin_amdgcn_mfma_f32_16x16x32_bf16(al[fr], bh[fc], acc[fr][fc], 0, 0, 0);
      }
    __syncthreads();
  }

  // ---- epilogue ----
  const float thv = (MODE == 2) ? thr[0] : 0.f;
#pragma unroll
  for (int fr = 0; fr < 4; ++fr)
#pragma unroll
    for (int j = 0; j < 4; ++j) {
      const int r = r0 + fr*16 + l4*4 + j;
      const int d = r % 7;
      if (MODE == 1) {
        const float aR = bnac[d], cR = bnac[7+d], wv = cw[d], bvv = cb[d];
#pragma unroll
        for (int fc = 0; fc < 4; ++fc) {
          int col = c0 + w*64 + fc*16 + l15;
          float val = acc[fr][fc][j];
          z1out[(size_t)r*512 + col] = aR*val + cR*csum[col] + xp[(size_t)r*512 + col]*wv + bvv;
        }
      } else {
        float m = (ne[r] > thv) ? 1.0f : 0.0f;
        float wm = cw[d] * m, bvv = cb[d];
        float s = 0.f, q = 0.f;
#pragma unroll
        for (int fc = 0; fc < 4; ++fc) {
          int col = c0 + w*64 + fc*16 + l15;
          float g = gelu_f(acc[fr][fc][j]*wm + bvv);
          unsigned hb = bfh_u(g);
          GH[(size_t)r*512 + col] = (ushort)hb;
          GL[(size_t)r*512 + col] = (ushort)bfh_u(g - bf2f(hb));
          s += g; q += g*g;
        }
#pragma unroll
        for (int off = 8; off > 0; off >>= 1) {
          s += __shfl_down(s, off, 16);
          q += __shfl_down(q, off, 16);
        }
        if (l15 == 0) { atomicAdd(&rs[r], s); atomicAdd(&rq[r], q); }
      }
    }
}

// ---------------- NT GEMM: out[M,Ncols] = A[M,512] @ W[Ncols,512]^T + bias ----------------
template<int MODE, bool TRANS, bool STATS>
__global__ __launch_bounds__(256) void k_gemm_nt(
    const float* __restrict__ A, const float* __restrict__ W, const float* __restrict__ bias,
    float* __restrict__ out, int Ncols, int ldOut,
    const float* __restrict__ ta, const float* __restrict__ tc,
    float* __restrict__ rs, float* __restrict__ rq)
{
  __shared__ float As[64][33];
  __shared__ float Bs[32][68];
  const int t = threadIdx.x;
  const int tx = t & 15, ty = t >> 4;
  const int r0 = blockIdx.x*64, c0 = blockIdx.y*64;
  float acc[4][4];
#pragma unroll
  for (int i = 0; i < 4; ++i)
#pragma unroll
    for (int j = 0; j < 4; ++j) acc[i][j] = 0.f;

  for (int kt = 0; kt < 512; kt += 32) {
#pragma unroll
    for (int h = 0; h < 2; ++h) {
      int c = t + h*256;
      int row = c >> 3, cg = c & 7;
      float4 v = *(const float4*)&A[(size_t)(r0+row)*512 + kt + cg*4];
      if (TRANS) {
        int d = (r0 + row) % 7;
        float aa = ta[d], cc = tc[d];
        v.x = gelu_f(aa*v.x + cc); v.y = gelu_f(aa*v.y + cc);
        v.z = gelu_f(aa*v.z + cc); v.w = gelu_f(aa*v.w + cc);
      }
      As[row][cg*4+0]=v.x; As[row][cg*4+1]=v.y; As[row][cg*4+2]=v.z; As[row][cg*4+3]=v.w;
    }
#pragma unroll
    for (int h = 0; h < 2; ++h) {
      int c = t + h*256;
      int row = c >> 3, cg = c & 7;
      int o = c0 + row;
      float4 v = make_float4(0.f,0.f,0.f,0.f);
      if (o < Ncols) v = *(const float4*)&W[(size_t)o*512 + kt + cg*4];
      Bs[cg*4+0][row]=v.x; Bs[cg*4+1][row]=v.y; Bs[cg*4+2][row]=v.z; Bs[cg*4+3][row]=v.w;
    }
    __syncthreads();
#pragma unroll
    for (int kk = 0; kk < 32; ++kk) {
      float av[4];
#pragma unroll
      for (int i = 0; i < 4; ++i) av[i] = As[ty*4+i][kk];
      float4 b = *(const float4*)&Bs[kk][tx*4];
      float bv[4] = {b.x,b.y,b.z,b.w};
#pragma unroll
      for (int i = 0; i < 4; ++i)
#pragma unroll
        for (int j = 0; j < 4; ++j) acc[i][j] += av[i]*bv[j];
    }
    __syncthreads();
  }
#pragma unroll
  for (int i = 0; i < 4; ++i) {
    int r = r0 + ty*4 + i;
    float s = 0.f, q = 0.f;
#pragma unroll
    for (int j = 0; j < 4; ++j) {
      int col = c0 + tx*4 + j;
      if (col < Ncols) {
        float v = acc[i][j] + bias[col];
        if (MODE == 1) { float g = gelu_f(v); v = g*v; }
        out[(size_t)r*ldOut + col] = v;
        if (STATS) { s += v; q += v*v; }
      }
    }
    if (STATS) {
#pragma unroll
      for (int off = 8; off > 0; off >>= 1) {
        s += __shfl_down(s, off, 16);
        q += __shfl_down(q, off, 16);
      }
      if (tx == 0) { rs[r] = s; rq[r] = q; }
    }
  }
}

// ---------------- analytic DCT energy (Parseval): 2L*sum(x^2) + 2*(sum x)^2 ----------------
__global__ void k_energy_an(const float* __restrict__ xp, float* __restrict__ en) {
  int r = blockIdx.x*4 + (threadIdx.x >> 6);
  int lane = threadIdx.x & 63;
  const float* row = xp + (size_t)r*512;
  double s = 0.0, q = 0.0;
  for (int i = lane; i < 512; i += 64) { double v = row[i]; s += v; q += v*v; }
#pragma unroll
  for (int o = 32; o > 0; o >>= 1) { s += __shfl_down(s, o); q += __shfl_down(q, o); }
  if (lane == 0) en[r] = (float)(1024.0*q + 2.0*s*s);
}

__global__ void k_ne(const float* __restrict__ en, float* __restrict__ ne) {
  int b = blockIdx.x*256 + threadIdx.x;
  if (b >= 2048) return;
  float e[7], s7[7];
#pragma unroll
  for (int d = 0; d < 7; ++d) { e[d] = en[b*7+d]; s7[d] = e[d]; }
#pragma unroll
  for (int i = 1; i < 7; ++i) {
    float key = s7[i]; int j = i-1;
    while (j >= 0 && s7[j] > key) { s7[j+1] = s7[j]; --j; }
    s7[j+1] = key;
  }
  float med = s7[3] + 1e-6f;
#pragma unroll
  for (int d = 0; d < 7; ++d) ne[b*7+d] = e[d] / med;
}

// exact k-th-smallest via register-resident 4-bit radix select.
__global__ __launch_bounds__(1024) void k_thr(const float* __restrict__ ne,
                                              const float* __restrict__ qp, float* __restrict__ out)
{
  __shared__ unsigned s_part[16][8];
  __shared__ unsigned s_bsel, s_R;
  const int t = threadIdx.x;
  const int lane = t & 63, wv = t >> 6;
  unsigned key[14];
#pragma unroll
  for (int j = 0; j < 14; ++j) key[j] = __float_as_uint(ne[t + j*1024]);

  float q = qp[0];
  float pos = q * 14335.0f;
  int lo = (int)floorf(pos);
  if (lo < 0) lo = 0; if (lo > 14335) lo = 14335;
  int hi = lo + 1; if (hi > 14335) hi = 14335;
  float frac = pos - (float)lo;

  unsigned prefix = 0;
  unsigned R = (unsigned)lo;
#pragma unroll 1
  for (int shift = 28; shift >= 0; shift -= 4) {
    unsigned pb = prefix >> shift;
    unsigned long long accb = 0ull;
#pragma unroll
    for (int j = 0; j < 14; ++j) {
      unsigned diff = (key[j] >> shift) - pb;
      accb += (diff < 16u) ? (1ull << (diff*4)) : 0ull;
    }
    unsigned pk[8];
#pragma unroll
    for (int b = 0; b < 8; ++b) {
      unsigned clo = (unsigned)(accb >> (b*4)) & 15u;
      unsigned chi = (unsigned)(accb >> (b*4+32)) & 15u;
      pk[b] = clo | (chi << 16);
    }
#pragma unroll
    for (int b = 0; b < 8; ++b)
#pragma unroll
      for (int o = 32; o > 0; o >>= 1) pk[b] += __shfl_down(pk[b], o);
    if (lane == 0) {
#pragma unroll
      for (int b = 0; b < 8; ++b) s_part[wv][b] = pk[b];
    }
    __syncthreads();
    if (t == 0) {
      unsigned tot[16];
#pragma unroll
      for (int i = 0; i < 8; ++i) {
        unsigned s = 0;
#pragma unroll
        for (int w2 = 0; w2 < 16; ++w2) s += s_part[w2][i];
        tot[i] = s & 0xFFFFu; tot[i+8] = s >> 16;
      }
      unsigned cum = 0, bsel = 15;
#pragma unroll 1
      for (int b = 0; b < 16; ++b) {
        if (cum + tot[b] > R) { bsel = (unsigned)b; break; }
        cum += tot[b];
      }
      s_bsel = bsel; s_R = R - cum;
    }
    __syncthreads();
    prefix |= (s_bsel << shift);
    R = s_R;
    __syncthreads();
  }
  unsigned cle = 0, mn = 0xFFFFFFFFu;
#pragma unroll
  for (int j = 0; j < 14; ++j) {
    cle += (key[j] <= prefix) ? 1u : 0u;
    if (key[j] > prefix && key[j] < mn) mn = key[j];
  }
#pragma unroll
  for (int o = 32; o > 0; o >>= 1) {
    cle += __shfl_down(cle, o);
    unsigned m2 = __shfl_down(mn, o);
    mn = (m2 < mn) ? m2 : mn;
  }
  if (lane == 0) { s_part[wv][0] = cle; s_part[wv][1] = mn; }
  __syncthreads();
  if (t == 0) {
    unsigned C = 0, M = 0xFFFFFFFFu;
#pragma unroll
    for (int w2 = 0; w2 < 16; ++w2) {
      C += s_part[w2][0];
      if (s_part[w2][1] < M) M = s_part[w2][1];
    }
    unsigned vhiKey = (C > (unsigned)hi) ? prefix : M;
    if (vhiKey == 0xFFFFFFFFu) vhiKey = prefix;
    float vlo = __uint_as_float(prefix);
    float vhi = __uint_as_float(vhiKey);
    out[0] = vlo*(1.0f-frac) + vhi*frac;
  }
}

// ---------------- BN finalize from per-row sums ----------------
__global__ __launch_bounds__(256) void k_bnfin_rows(const float* __restrict__ rs,
    const float* __restrict__ rq, int nch, int nrows, double count,
    const float* __restrict__ gamma, const float* __restrict__ beta, float* __restrict__ out)
{
  __shared__ double sd[256];
  int ch = blockIdx.x, t = threadIdx.x;
  double s = 0.0, q = 0.0;
  for (int i = ch + t*nch; i < nrows; i += 256*nch) { s += rs[i]; q += rq[i]; }
  sd[t] = s; __syncthreads();
  for (int o = 128; o > 0; o >>= 1) { if (t < o) sd[t] += sd[t+o]; __syncthreads(); }
  double S = sd[0]; __syncthreads();
  sd[t] = q; __syncthreads();
  for (int o = 128; o > 0; o >>= 1) { if (t < o) sd[t] += sd[t+o]; __syncthreads(); }
  if (t == 0) {
    double m = S / count;
    double v = sd[0] / count - m*m; if (v < 0.0) v = 0.0;
    double inv = 1.0 / sqrt(v + 1e-5);
    out[ch]       = (float)(gamma[ch] * inv);
    out[nch + ch] = (float)(beta[ch] - m * gamma[ch] * inv);
  }
}

__global__ __launch_bounds__(256) void k_bnfin_part(const float* __restrict__ pS,
    const float* __restrict__ pQ, int nparts, int nch, double count,
    const float* __restrict__ gamma, const float* __restrict__ beta, float* __restrict__ out)
{
  __shared__ double sd[256];
  int ch = blockIdx.x, t = threadIdx.x;
  double s = 0.0, q = 0.0;
  for (int i = t; i < nparts; i += 256) { s += pS[(size_t)i*nch + ch]; q += pQ[(size_t)i*nch + ch]; }
  sd[t] = s; __syncthreads();
  for (int o = 128; o > 0; o >>= 1) { if (t < o) sd[t] += sd[t+o]; __syncthreads(); }
  double S = sd[0]; __syncthreads();
  sd[t] = q; __syncthreads();
  for (int o = 128; o > 0; o >>= 1) { if (t < o) sd[t] += sd[t+o]; __syncthreads(); }
  if (t == 0) {
    double m = S / count;
    double v = sd[0] / count - m*m; if (v < 0.0) v = 0.0;
    double inv = 1.0 / sqrt(v + 1e-5);
    out[ch]       = (float)(gamma[ch] * inv);
    out[nch + ch] = (float)(beta[ch] - m * gamma[ch] * inv);
  }
}

// ---------------- patch path: z1r = V[n] @ xp-patch + c2 ----------------
__global__ __launch_bounds__(256) void k_patch(const float* __restrict__ xp,
    const float* __restrict__ V, const float* __restrict__ c2,
    float* __restrict__ z1r, float* __restrict__ pS, float* __restrict__ pQ)
{
  __shared__ float sx[8][512];
  __shared__ float aS[32], aQ[32];
  int t = threadIdx.x;
  int r0 = blockIdx.x * 8;
  for (int c = t; c < 1024; c += 256) {
    int row = c >> 7, cg = c & 127;
    *(float4*)&sx[row][cg*4] = *(const float4*)&xp[(size_t)(r0+row)*512 + cg*4];
  }
  if (t < 32) { aS[t] = 0.f; aQ[t] = 0.f; }
  __syncthreads();
  float vreg[2][16]; float cc[2]; int nn_[2], oo[2];
#pragma unroll
  for (int h = 0; h < 2; ++h) {
    int o = t + h*256;
    oo[h] = o;
    int n = o >> 4, p = o & 15;
    nn_[h] = n;
#pragma unroll
    for (int qg = 0; qg < 4; ++qg) {
      float4 v4 = *(const float4*)&V[(size_t)n*256 + p*16 + qg*4];
      vreg[h][qg*4+0]=v4.x; vreg[h][qg*4+1]=v4.y; vreg[h][qg*4+2]=v4.z; vreg[h][qg*4+3]=v4.w;
    }
    cc[h] = c2[o];
  }
  float sum[2] = {0.f,0.f}, sq[2] = {0.f,0.f};
  for (int row = 0; row < 8; ++row) {
#pragma unroll
    for (int h = 0; h < 2; ++h) {
      const float* xr = &sx[row][nn_[h]*16];
      float val = cc[h];
#pragma unroll
      for (int qq = 0; qq < 16; ++qq) val += vreg[h][qq] * xr[qq];
      z1r[(size_t)(r0+row)*512 + oo[h]] = val;
      sum[h] += val; sq[h] += val*val;
    }
  }
#pragma unroll
  for (int h = 0; h < 2; ++h) {
    atomicAdd(&aS[nn_[h]], sum[h]);
    atomicAdd(&aQ[nn_[h]], sq[h]);
  }
  __syncthreads();
  if (t < 32) { pS[(size_t)blockIdx.x*32 + t] = aS[t]; pQ[(size_t)blockIdx.x*32 + t] = aQ[t]; }
}

// ---------------- TopKFreq ----------------
__global__ void k_att(const float* __restrict__ z1, const float* __restrict__ z1r,
    const float* __restrict__ bn2, const float* __restrict__ u, const float* __restrict__ fcb,
    float* __restrict__ att)
{
  int r = blockIdx.x*4 + (threadIdx.x >> 6);
  int lane = threadIdx.x & 63;
  const float* z1p = z1 + (size_t)r*512;
  const float* zrp = z1r + (size_t)r*512;
  float s = 0.f;
#pragma unroll
  for (int h = 0; h < 2; ++h) {
    int i = lane*4 + h*256;
    int n = i >> 4;
    float a2n = bn2[n], c2n = bn2[32+n];
    float4 zr = *(const float4*)&zrp[i];
    float4 zv = *(const float4*)&z1p[i];
    float4 uv = *(const float4*)&u[i];
    s += (zv.x + gelu_f(a2n*zr.x + c2n)) * uv.x;
    s += (zv.y + gelu_f(a2n*zr.y + c2n)) * uv.y;
    s += (zv.z + gelu_f(a2n*zr.z + c2n)) * uv.z;
    s += (zv.w + gelu_f(a2n*zr.w + c2n)) * uv.w;
  }
  s = wred(s);
  if (lane == 0) att[r] = s + fcb[0];
}

__global__ __launch_bounds__(1024) void k_tf(const float* __restrict__ att,
    const float* __restrict__ pg, const float* __restrict__ pb,
    const float* __restrict__ pwc, const float* __restrict__ pbc,
    const float* __restrict__ pfb, float* __restrict__ a1, float* __restrict__ a2)
{
  __shared__ double sd[1024];
  __shared__ float sh[4];
  const int t = threadIdx.x;
  float g = pg[0], b = pb[0], wc = pwc[0], bc = pbc[0], fb = pfb[0];
  double s = 0.0, q = 0.0;
  for (int i = t; i < BD; i += 1024) { double v = att[i]; s += v; q += v*v; }
  sd[t] = s; __syncthreads();
  for (int o = 512; o > 0; o >>= 1) { if (t < o) sd[t] += sd[t+o]; __syncthreads(); }
  double S1 = sd[0]; __syncthreads();
  sd[t] = q; __syncthreads();
  for (int o = 512; o > 0; o >>= 1) { if (t < o) sd[t] += sd[t+o]; __syncthreads(); }
  if (t == 0) {
    double m = S1 / 14336.0;
    double v = sd[0] / 14336.0 - m*m; if (v < 0.0) v = 0.0;
    sh[0] = (float)m; sh[1] = (float)(1.0 / sqrt(v + 1e-5));
  }
  __syncthreads();
  float m1 = sh[0], i1 = sh[1];
  s = 0.0; q = 0.0;
  for (int i = t; i < BD; i += 1024) {
    float v = att[i];
    float an = (v - m1) * i1 * g + b;
    float av = sigm_f(gelu_f(an) * wc + bc);
    a1[i] = av;
    float t2 = av * (v - fb) + fb;
    s += t2; q += (double)t2 * t2;
  }
  __syncthreads();
  sd[t] = s; __syncthreads();
  for (int o = 512; o > 0; o >>= 1) { if (t < o) sd[t] += sd[t+o]; __syncthreads(); }
  double S2 = sd[0]; __syncthreads();
  sd[t] = q; __syncthreads();
  for (int o = 512; o > 0; o >>= 1) { if (t < o) sd[t] += sd[t+o]; __syncthreads(); }
  if (t == 0) {
    double m = S2 / 14336.0;
    double v = sd[0] / 14336.0 - m*m; if (v < 0.0) v = 0.0;
    sh[2] = (float)m; sh[3] = (float)(1.0 / sqrt(v + 1e-5));
  }
  __syncthreads();
  float m2 = sh[2], i2 = sh[3];
  for (int i = t; i < BD; i += 1024) {
    float t2 = a1[i] * (att[i] - fb) + fb;
    float an = (t2 - m2) * i2 * g + b;
    a2[i] = sigm_f(gelu_f(an) * wc + bc);
  }
}

// ---------------- elementwise stats passes (float4) ----------------
__global__ void k_statsA(const float* __restrict__ z1, const float* __restrict__ z1r,
    const float* __restrict__ bn2, const float* __restrict__ a1,
    float* __restrict__ rs, float* __restrict__ rq)
{
  int r = blockIdx.x*4 + (threadIdx.x >> 6);
  int lane = threadIdx.x & 63;
  float av = a1[r];
  const float* z1p = z1 + (size_t)r*512;
  const float* zrp = z1r + (size_t)r*512;
  float s = 0.f, q = 0.f;
#pragma unroll
  for (int h = 0; h < 2; ++h) {
    int i = lane*4 + h*256;
    int n = i >> 4;
    float a2n = bn2[n], c2n = bn2[32+n];
    float4 zr = *(const float4*)&zrp[i];
    float4 zv = *(const float4*)&z1p[i];
    float A0 = (zv.x + gelu_f(a2n*zr.x + c2n)) * av;
    float A1 = (zv.y + gelu_f(a2n*zr.y + c2n)) * av;
    float A2 = (zv.z + gelu_f(a2n*zr.z + c2n)) * av;
    float A3 = (zv.w + gelu_f(a2n*zr.w + c2n)) * av;
    s += A0+A1+A2+A3; q += A0*A0+A1*A1+A2*A2+A3*A3;
  }
  s = wred(s); q = wred(q);
  if (lane == 0) { rs[r] = s; rq[r] = q; }
}

__global__ void k_statsC(const float* __restrict__ z1, const float* __restrict__ z1r,
    const float* __restrict__ bn2, const float* __restrict__ a1,
    const float* __restrict__ bn3, const float* __restrict__ cw, const float* __restrict__ cb,
    float* __restrict__ rs, float* __restrict__ rq)
{
  int r = blockIdx.x*4 + (threadIdx.x >> 6);
  int lane = threadIdx.x & 63;
  int d = r % 7;
  float av = a1[r];
  float b3a = bn3[d], b3c = bn3[7+d], wv = cw[d], bv = cb[d];
  const float* z1p = z1 + (size_t)r*512;
  const float* zrp = z1r + (size_t)r*512;
  float s = 0.f, q = 0.f;
#pragma unroll
  for (int h = 0; h < 2; ++h) {
    int i = lane*4 + h*256;
    int n = i >> 4;
    float a2n = bn2[n], c2n = bn2[32+n];
    float4 zr = *(const float4*)&zrp[i];
    float4 zv = *(const float4*)&z1p[i];
#pragma unroll
    for (int e = 0; e < 4; ++e) {
      float ze = (e==0?zr.x:e==1?zr.y:e==2?zr.z:zr.w);
      float z1e = (e==0?zv.x:e==1?zv.y:e==2?zv.z:zv.w);
      float A = (z1e + gelu_f(a2n*ze + c2n)) * av;
      float C = wv*gelu_f(b3a*A + b3c) + bv;
      s += C; q += C*C;
    }
  }
  s = wred(s); q = wred(q);
  if (lane == 0) { rs[r] = s; rq[r] = q; }
}

__global__ void k_final(const float* __restrict__ z1, const float* __restrict__ z1r,
    const float* __restrict__ bn2, const float* __restrict__ a1, const float* __restrict__ a2,
    const float* __restrict__ bn3, const float* __restrict__ bn4,
    const float* __restrict__ cw, const float* __restrict__ cb,
    float* __restrict__ zf, float* __restrict__ rs, float* __restrict__ rq)
{
  int r = blockIdx.x*4 + (threadIdx.x >> 6);
  int lane = threadIdx.x & 63;
  int d = r % 7;
  float av = a1[r], a2v = a2[r];
  float b3a = bn3[d], b3c = bn3[7+d], b4a = bn4[d], b4c = bn4[7+d];
  float wv = cw[d], bv = cb[d];
  const float* z1p = z1 + (size_t)r*512;
  const float* zrp = z1r + (size_t)r*512;
  float* zfp = zf + (size_t)r*512;
  float s = 0.f, q = 0.f;
#pragma unroll
  for (int h = 0; h < 2; ++h) {
    int i = lane*4 + h*256;
    int n = i >> 4;
    float a2n = bn2[n], c2n = bn2[32+n];
    float4 zr = *(const float4*)&zrp[i];
    float4 zv = *(const float4*)&z1p[i];
    float4 ov;
#pragma unroll
    for (int e = 0; e < 4; ++e) {
      float ze = (e==0?zr.x:e==1?zr.y:e==2?zr.z:zr.w);
      float z1e = (e==0?zv.x:e==1?zv.y:e==2?zv.z:zv.w);
      float z1v = z1e * av;
      float z2v = gelu_f(a2n*ze + c2n) * av;
      float A = z1v + z2v;
      float C = wv*gelu_f(b3a*A + b3c) + bv;
      float inter = gelu_f(b4a*C + b4c) * a2v;
      float z1n = z1v*inter + z2v;
      float z2n = z2v*inter + z1n;
      float zfv = z1n*z2n + z1n + z2n;
      (e==0?ov.x:e==1?ov.y:e==2?ov.z:ov.w) = zfv;
      s += zfv; q += zfv*zfv;
    }
    *(float4*)&zfp[i] = ov;
  }
  s = wred(s); q = wred(q);
  if (lane == 0) { rs[r] = s; rq[r] = q; }
}

// ---------------- output: fc2 + bias + z_res + transpose ----------------
__global__ __launch_bounds__(256) void k_out(const float* __restrict__ h2,
    const float* __restrict__ bn6, const float* __restrict__ w2, const float* __restrict__ b2,
    const float* __restrict__ zres, float* __restrict__ out)
{
  int idx = blockIdx.x*256 + threadIdx.x;
  int r = idx / 96, o = idx - r*96;
  int d = r % 7, b = r / 7;
  float a6 = bn6[d], c6 = bn6[7+d];
  const float* hp = h2 + (size_t)r*48;
  const float* wp = w2 + o*48;
  float s = 0.f;
#pragma unroll
  for (int j4 = 0; j4 < 12; ++j4) {
    float4 hv = *(const float4*)&hp[j4*4];
    float4 wv = *(const float4*)&wp[j4*4];
    s += (a6*hv.x + c6)*wv.x + (a6*hv.y + c6)*wv.y
       + (a6*hv.z + c6)*wv.z + (a6*hv.w + c6)*wv.w;
  }
  out[(size_t)b*672 + o*7 + d] = s + b2[o] + zres[(size_t)r*96 + o];
}

// ================= host =================
extern "C" void kernel_launch(void* const* d_in, const int* in_sizes, int n_in,
                              void* d_out, int out_size, void* d_ws, size_t ws_size,
                              hipStream_t stream) {
  const float* x          = (const float*)d_in[0];
  const float* dctconv_w  = (const float*)d_in[1];
  const float* dctconv_b  = (const float*)d_in[2];
  const float* dctnorm_g  = (const float*)d_in[3];
  const float* dctnorm_b  = (const float*)d_in[4];
  const float* threshold  = (const float*)d_in[5];
  const float* embed_W    = (const float*)d_in[6];
  const float* embed_b    = (const float*)d_in[7];
  const float* linres_W   = (const float*)d_in[8];
  const float* linres_b   = (const float*)d_in[9];
  const float* depth1_w   = (const float*)d_in[10];
  const float* depth1_b   = (const float*)d_in[11];
  const float* depthnorm_g= (const float*)d_in[12];
  const float* depthnorm_b= (const float*)d_in[13];
  const float* tf_fc_w    = (const float*)d_in[14];
  const float* tf_fc_b    = (const float*)d_in[15];
  const float* tf_norm_g  = (const float*)d_in[16];
  const float* tf_norm_b  = (const float*)d_in[17];
  const float* tf_conv_w  = (const float*)d_in[18];
  const float* tf_conv_b  = (const float*)d_in[19];
  const float* mlp_w1     = (const float*)d_in[20];
  const float* mlp_b1     = (const float*)d_in[21];
  const float* mlp_w2     = (const float*)d_in[22];
  const float* mlp_b2     = (const float*)d_in[23];
  const float* mlpnorm_g  = (const float*)d_in[24];
  const float* mlpnorm_b  = (const float*)d_in[25];
  float* out = (float*)d_out;
  float* ws  = (float*)d_ws;

  float* XP   = ws + F_XP;
  float* ZG   = ws + F_ZG;        // z1r f32 (after GEMM2); GH/GL planes before
  ushort* ZGH = (ushort*)(ws + F_ZG);
  ushort* ZGL = ZGH + (size_t)BD*512;
  float* Z1   = ws + F_Z1;
  ushort* B1H = (ushort*)(ws + F_CLK);
  ushort* B1L = B1H + 512*512;
  ushort* B2H = (ushort*)(ws + F_MKL);
  ushort* B2L = B2H + 512*512;
  float* U    = ws + F_U;
  float* CSUM = ws + F_CSUM;
  float* W2p  = ws + F_W2;
  float* CSTp = ws + F_CST;
  float* Vp   = ws + F_V;
  float* C2p  = ws + F_C2;
  float* ZRES = ws + F_ZRES;
  float* H2p  = ws + F_H2;
  float* EN   = ws + F_EN;
  float* NEp  = ws + F_NE;
  float* ATTp = ws + F_ATT;
  float* A1p  = ws + F_A1;
  float* A2p  = ws + F_A2;
  float* RS   = ws + F_RS;
  float* RQ   = ws + F_RQ;
  float* PS   = ws + F_PS;
  float* PQ   = ws + F_PQ;
  float* BN0  = ws + F_BN;        // a[7], c[7]
  float* BN2  = ws + F_BN + 16;   // a[32], c[32]
  float* BN3  = ws + F_BN + 80;
  float* BN4  = ws + F_BN + 96;
  float* BN5  = ws + F_BN + 112;
  float* BN6  = ws + F_BN + 128;
  float* THRp = ws + F_THR;

  k_gen_b<<<512, 256, 0, stream>>>(B1H, B1L, B2H, B2L);
  k_ucsum2<<<2, 256, 0, stream>>>(U, CSUM, tf_fc_w);
  k_w2<<<96, 256, 0, stream>>>(linres_W, linres_b, embed_W, embed_b, W2p, CSTp);
  k_v<<<32, 256, 0, stream>>>(embed_W, embed_b, depth1_w, depth1_b, Vp, C2p);
  k_transpose<<<2048, 256, 0, stream>>>(x, XP);
  k_energy_an<<<3584, 256, 0, stream>>>(XP, EN);
  k_ne<<<8, 256, 0, stream>>>(EN, NEp);
  k_thr<<<1, 1024, 0, stream>>>(NEp, threshold, THRp);
  hipMemsetAsync(RS, 0, 2*BD*sizeof(float), stream);
  // GEMM1: z_dct -> masked dctconv -> gelu -> GH/GL planes (+ row stats)
  k_mfma<2><<<dim3(224,2), 256, 0, stream>>>(XP, nullptr, nullptr, B1H, B1L,
      nullptr, ZGH, ZGL, nullptr, nullptr, nullptr, dctconv_w, dctconv_b,
      NEp, THRp, RS, RQ);
  k_bnfin_rows<<<7, 256, 0, stream>>>(RS, RQ, 7, BD, 1048576.0, dctnorm_g, dctnorm_b, BN0);
  // GEMM2: z1 = BN(g) @ M + x_res  (BN folded via column sums)
  k_mfma<1><<<dim3(224,2), 256, 0, stream>>>(nullptr, ZGH, ZGL, B2H, B2L,
      Z1, nullptr, nullptr, BN0, CSUM, XP, dctconv_w, dctconv_b,
      nullptr, nullptr, nullptr, nullptr);
  k_patch<<<1792, 256, 0, stream>>>(XP, Vp, C2p, ZG, PS, PQ);
  k_bnfin_part<<<32, 256, 0, stream>>>(PS, PQ, 1792, 32, 229376.0, depthnorm_g, depthnorm_b, BN2);
  k_gemm_nt<0,false,false><<<dim3(224,2), 256, 0, stream>>>(XP, W2p, CSTp, ZRES, 96, 96,
      nullptr, nullptr, nullptr, nullptr);
  k_att<<<3584, 256, 0, stream>>>(Z1, ZG, BN2, U, tf_fc_b, ATTp);
  k_tf<<<1, 1024, 0, stream>>>(ATTp, tf_norm_g, tf_norm_b, tf_conv_w, tf_conv_b, tf_fc_b, A1p, A2p);
  k_statsA<<<3584, 256, 0, stream>>>(Z1, ZG, BN2, A1p, RS, RQ);
  k_bnfin_rows<<<7, 256, 0, stream>>>(RS, RQ, 7, BD, 1048576.0, dctnorm_g, dctnorm_b, BN3);
  k_statsC<<<3584, 256, 0, stream>>>(Z1, ZG, BN2, A1p, BN3, dctconv_w, dctconv_b, RS, RQ);
  k_bnfin_rows<<<7, 256, 0, stream>>>(RS, RQ, 7, BD, 1048576.0, dctnorm_g, dctnorm_b, BN4);
  k_final<<<3584, 256, 0, stream>>>(Z1, ZG, BN2, A1p, A2p, BN3, BN4, dctconv_w, dctconv_b, XP, RS, RQ);
  k_bnfin_rows<<<7, 256, 0, stream>>>(RS, RQ, 7, BD, 1048576.0, dctnorm_g, dctnorm_b, BN5);
  k_gemm_nt<1,true,true><<<dim3(224,1), 256, 0, stream>>>(XP, mlp_w1, mlp_b1, H2p, 48, 48,
      BN5, BN5+7, RS, RQ);
  k_bnfin_rows<<<7, 256, 0, stream>>>(RS, RQ, 7, BD, 98304.0, mlpnorm_g, mlpnorm_b, BN6);
  k_out<<<5376, 256, 0, stream>>>(H2p, BN6, mlp_w2, mlp_b2, ZRES, out);
}

// Round 6
// 385.674 us; speedup vs baseline: 2.1505x; 1.1208x over previous
//
#include <hip/hip_runtime.h>
#include <math.h>

#define BB 2048
#define LL 512
#define DD 7
#define BD 14336   // BB*DD

// ---------------- ws layout (floats) ----------------
constexpr size_t F_XP   = 0;                          // xp, later zf
constexpr size_t F_ZG   = F_XP  + (size_t)BD*512;     // ZGH/ZGL planes -> z1r f32
constexpr size_t F_Z1   = F_ZG  + (size_t)BD*512;     // z1
constexpr size_t F_CLK  = F_Z1  + (size_t)BD*512;     // B1H/B1L planes; upper half: W2/W1 planes
constexpr size_t F_MKL  = F_CLK + 512*512;            // B2H/B2L (ushort planes)
constexpr size_t F_U    = F_MKL + 512*512;
constexpr size_t F_CSUM = F_U + 512;
constexpr size_t F_W2   = F_CSUM + 512;               // (spare)
constexpr size_t F_CST  = F_W2 + 96*512;
constexpr size_t F_V    = F_CST + 96;                 // 32x16x16
constexpr size_t F_C2   = F_V + 32*256;               // 32x16
constexpr size_t F_ZRES = F_C2 + 512;                 // BD x 96
constexpr size_t F_H2   = F_ZRES + (size_t)BD*96;     // BD x 48
constexpr size_t F_EN   = F_H2 + (size_t)BD*48;
constexpr size_t F_NE   = F_EN + BD;
constexpr size_t F_ATT  = F_NE + BD;
constexpr size_t F_A1   = F_ATT + BD;
constexpr size_t F_A2   = F_A1 + BD;
constexpr size_t F_RS   = F_A2 + BD;
constexpr size_t F_RQ   = F_RS + BD;                  // adjacent to F_RS (one memset)
constexpr size_t F_PS   = F_RQ + BD;                  // 1792 x 32
constexpr size_t F_PQ   = F_PS + 1792*32;
constexpr size_t F_BN   = F_PQ + 1792*32;             // bn affine params
constexpr size_t F_THR  = F_BN + 256;

typedef __attribute__((ext_vector_type(8))) short bf8;
typedef __attribute__((ext_vector_type(4))) float f4;

__device__ __forceinline__ float gelu_f(float x) {
  return 0.5f * x * (1.0f + erff(x * 0.70710678118654752440f));
}
__device__ __forceinline__ float sigm_f(float x) {
  return 1.0f / (1.0f + expf(-x));
}
__device__ __forceinline__ float wred(float v) {
#pragma unroll
  for (int o = 32; o > 0; o >>= 1) v += __shfl_down(v, o);
  return v;
}
__device__ __forceinline__ unsigned bfh_u(float v) {
  unsigned u = __float_as_uint(v);
  return (u + 0x7FFFu + ((u >> 16) & 1u)) >> 16;
}
__device__ __forceinline__ float bf2f(unsigned h) { return __uint_as_float(h << 16); }

// ---------------- constant generation ----------------
// B1T[c][r] = 2*cos(pi*(r+0.5)*c/512)        (DCT,  reduction index r)
// B2T[c][r] = cos(pi*(c+0.5)*r/512)*sc[r]    (iDCT, reduction index r), sc0=1/1024 else 1/512
__global__ void k_gen_b(ushort* __restrict__ B1H, ushort* __restrict__ B1L,
                        ushort* __restrict__ B2H, ushort* __restrict__ B2L) {
  int c = blockIdx.x;
  for (int r = threadIdx.x; r < 512; r += 256) {
    double c1 = cos(3.14159265358979323846 * (r + 0.5) * c / 512.0);
    float v1 = (float)(2.0 * c1);
    unsigned h = bfh_u(v1);
    B1H[(size_t)c*512 + r] = (ushort)h;
    B1L[(size_t)c*512 + r] = (ushort)bfh_u(v1 - bf2f(h));
    double c2 = cos(3.14159265358979323846 * (c + 0.5) * r / 512.0);
    float v2 = (float)(c2 * (r == 0 ? (1.0/1024.0) : (1.0/512.0)));
    h = bfh_u(v2);
    B2H[(size_t)c*512 + r] = (ushort)h;
    B2L[(size_t)c*512 + r] = (ushort)bfh_u(v2 - bf2f(h));
  }
}

// csum[l] closed form: theta = pi*(l+0.5)/512, s=(-1)^l
//   sum_{k=0}^{511} cos(k*theta) = 1/2 + s/(2*tan(theta/2))
__global__ void k_ucsum2(float* __restrict__ u, float* __restrict__ csum,
                         const float* __restrict__ wf) {
  int l = blockIdx.x*256 + threadIdx.x;
  if (l >= 512) return;
  double th2 = 3.14159265358979323846 * (double)(2*l + 1) / 2048.0;   // theta/2
  double s = (l & 1) ? -1.0 : 1.0;
  double S = 0.5*s/tan(th2) - 0.5;          // sum_{k=1}^{511} cos(k*theta)
  csum[l] = (float)(1.0/1024.0 + S/512.0);
  double uu = (double)wf[0] * 45.25483399593904156 / 1024.0;      // sqrt(2048)*M[0][l]
  for (int k = 1; k < 5; ++k)
    uu += (double)wf[k] * 32.0 * cos(3.14159265358979323846*(l+0.5)*k/512.0) / 512.0;
  u[l] = (float)uu;
}

// W2 = fold(embed, linres) -> bf16 hi/lo planes + constant vector
__global__ __launch_bounds__(256) void k_w2(const float* __restrict__ linW,
    const float* __restrict__ linb, const float* __restrict__ eW, const float* __restrict__ eb,
    ushort* __restrict__ W2H, ushort* __restrict__ W2L, float* __restrict__ cst)
{
  __shared__ float sW[768];
  __shared__ float sb[48];
  __shared__ float rbuf[256];
  int o = blockIdx.x, t = threadIdx.x;
  for (int i = t; i < 768; i += 256) sW[i] = eW[i];
  if (t < 48) sb[t] = eb[t];
  __syncthreads();
  const float* lw = linW + (size_t)o * 1536;
  for (int i = t; i < 512; i += 256) {
    int n = i >> 4, p = i & 15;
    float s = 0.f;
    const float* l2 = lw + n*48;
#pragma unroll 8
    for (int m = 0; m < 48; ++m) s += l2[m] * sW[m*16 + p];
    unsigned hb = bfh_u(s);
    W2H[(size_t)o*512 + i] = (ushort)hb;
    W2L[(size_t)o*512 + i] = (ushort)bfh_u(s - bf2f(hb));
  }
  float c = 0.f;
  for (int i = t; i < 1536; i += 256) c += lw[i] * sb[i % 48];
  rbuf[t] = c; __syncthreads();
  for (int off = 128; off > 0; off >>= 1) { if (t < off) rbuf[t] += rbuf[t+off]; __syncthreads(); }
  if (t == 0) cst[o] = rbuf[0] + linb[o];
}

__global__ void k_splitw(const float* __restrict__ src, ushort* __restrict__ H,
                         ushort* __restrict__ L, int n) {
  int i = blockIdx.x*256 + threadIdx.x;
  if (i < n) {
    float v = src[i];
    unsigned hb = bfh_u(v);
    H[i] = (ushort)hb;
    L[i] = (ushort)bfh_u(v - bf2f(hb));
  }
}

__global__ void k_v(const float* __restrict__ eW, const float* __restrict__ eb,
                    const float* __restrict__ dw, const float* __restrict__ db,
                    float* __restrict__ V, float* __restrict__ c2)
{
  int n = blockIdx.x, t = threadIdx.x;
  int p = t >> 4, q = t & 15;
  float s = 0.f;
#pragma unroll
  for (int j = 0; j < 3; ++j) s += eW[(p*3+j)*16 + q] * dw[n*3+j];
  V[(size_t)n*256 + p*16 + q] = s;
  if (q == 0) {
    float c = 0.f;
#pragma unroll
    for (int j = 0; j < 3; ++j) c += eb[p*3+j] * dw[n*3+j];
    c2[n*16+p] = c + db[n];
  }
}

// ---------------- transpose [B,L,D] -> [B*D, L] ----------------
__global__ __launch_bounds__(256) void k_transpose(const float* __restrict__ x, float* __restrict__ xp) {
  __shared__ float s[3584];
  int b = blockIdx.x;
  const float* src = x + (size_t)b*3584;
  for (int c = threadIdx.x; c < 896; c += 256) {
    float4 v = *(const float4*)&src[c*4];
    s[c*4+0]=v.x; s[c*4+1]=v.y; s[c*4+2]=v.z; s[c*4+3]=v.w;
  }
  __syncthreads();
  for (int c = threadIdx.x; c < 896; c += 256) {
    int d = c >> 7, cg = c & 127;
    float4 v;
    v.x = s[(cg*4+0)*7 + d]; v.y = s[(cg*4+1)*7 + d];
    v.z = s[(cg*4+2)*7 + d]; v.w = s[(cg*4+3)*7 + d];
    *(float4*)&xp[((size_t)b*7 + d)*512 + cg*4] = v;
  }
}

// ---------------- MFMA bf16-split GEMM: C[M,512] = A[M,512] @ B[512,512] ----------------
// BM=64, BN=256, BK=32; 4 waves, each 64x64 (4x4 frags of 16x16x32); 3-term bf16 split.
// MODE 2: A from f32 (split at stage); epilogue g=gelu(acc*mask*w+b) -> GH/GL planes + row stats
// MODE 1: A from GH/GL planes; epilogue z1 = aR*acc + cR*csum + xp*w + b -> f32
template<int MODE>
__global__ __launch_bounds__(256) void k_mfma(
    const float* __restrict__ Af32,
    const ushort* __restrict__ AHg, const ushort* __restrict__ ALg,
    const ushort* __restrict__ BHg, const ushort* __restrict__ BLg,
    float* __restrict__ z1out, ushort* __restrict__ GH, ushort* __restrict__ GL,
    const float* __restrict__ bnac, const float* __restrict__ csum,
    const float* __restrict__ xp,
    const float* __restrict__ cw, const float* __restrict__ cb,
    const float* __restrict__ ne, const float* __restrict__ thr,
    float* __restrict__ rs, float* __restrict__ rq)
{
  __shared__ ushort AhS[64*40], AlS[64*40];
  __shared__ ushort BhS[256*40], BlS[256*40];
  const int t = threadIdx.x;
  const int lane = t & 63, w = t >> 6;
  const int l15 = lane & 15, l4 = lane >> 4;
  const int r0 = blockIdx.x * 64, c0 = blockIdx.y * 256;

  f4 acc[4][4];
#pragma unroll
  for (int i = 0; i < 4; ++i)
#pragma unroll
    for (int j = 0; j < 4; ++j) acc[i][j] = (f4){0.f,0.f,0.f,0.f};

  const int arow = t >> 2, ak0 = (t & 3) * 8;

  for (int kt = 0; kt < 512; kt += 32) {
    // ---- stage A (64x32) ----
    if (MODE == 2) {
      const float* src = Af32 + (size_t)(r0+arow)*512 + kt + ak0;
      float4 v0 = *(const float4*)src;
      float4 v1 = *(const float4*)(src+4);
      float va[8] = {v0.x,v0.y,v0.z,v0.w,v1.x,v1.y,v1.z,v1.w};
      bf8 hv, lv;
#pragma unroll
      for (int j = 0; j < 8; ++j) {
        unsigned hb = bfh_u(va[j]);
        hv[j] = (short)hb;
        lv[j] = (short)bfh_u(va[j] - bf2f(hb));
      }
      *(bf8*)&AhS[arow*40 + ak0] = hv;
      *(bf8*)&AlS[arow*40 + ak0] = lv;
    } else {
      *(bf8*)&AhS[arow*40 + ak0] = *(const bf8*)&AHg[(size_t)(r0+arow)*512 + kt + ak0];
      *(bf8*)&AlS[arow*40 + ak0] = *(const bf8*)&ALg[(size_t)(r0+arow)*512 + kt + ak0];
    }
    // ---- stage B (256 cols x 32 k, transposed source) ----
#pragma unroll
    for (int h = 0; h < 4; ++h) {
      int c = t + h*256;
      int brow = c >> 2, bk0 = (c & 3) * 8;
      *(bf8*)&BhS[brow*40 + bk0] = *(const bf8*)&BHg[(size_t)(c0+brow)*512 + kt + bk0];
      *(bf8*)&BlS[brow*40 + bk0] = *(const bf8*)&BLg[(size_t)(c0+brow)*512 + kt + bk0];
    }
    __syncthreads();
    // ---- compute ----
    bf8 ah[4], al[4], bh[4], bl[4];
#pragma unroll
    for (int fr = 0; fr < 4; ++fr) {
      int off = (fr*16 + l15)*40 + l4*8;
      ah[fr] = *(const bf8*)&AhS[off];
      al[fr] = *(const bf8*)&AlS[off];
    }
#pragma unroll
    for (int fc = 0; fc < 4; ++fc) {
      int off = (w*64 + fc*16 + l15)*40 + l4*8;
      bh[fc] = *(const bf8*)&BhS[off];
      bl[fc] = *(const bf8*)&BlS[off];
    }
#pragma unroll
    for (int fr = 0; fr < 4; ++fr)
#pragma unroll
      for (int fc = 0; fc < 4; ++fc) {
        acc[fr][fc] = __builtin_amdgcn_mfma_f32_16x16x32_bf16(ah[fr], bh[fc], acc[fr][fc], 0, 0, 0);
        acc[fr][fc] = __builtin_amdgcn_mfma_f32_16x16x32_bf16(ah[fr], bl[fc], acc[fr][fc], 0, 0, 0);
        acc[fr][fc] = __builtin_amdgcn_mfma_f32_16x16x32_bf16(al[fr], bh[fc], acc[fr][fc], 0, 0, 0);
      }
    __syncthreads();
  }

  // ---- epilogue ----
  const float thv = (MODE == 2) ? thr[0] : 0.f;
#pragma unroll
  for (int fr = 0; fr < 4; ++fr)
#pragma unroll
    for (int j = 0; j < 4; ++j) {
      const int r = r0 + fr*16 + l4*4 + j;
      const int d = r % 7;
      if (MODE == 1) {
        const float aR = bnac[d], cR = bnac[7+d], wv = cw[d], bvv = cb[d];
#pragma unroll
        for (int fc = 0; fc < 4; ++fc) {
          int col = c0 + w*64 + fc*16 + l15;
          float val = acc[fr][fc][j];
          z1out[(size_t)r*512 + col] = aR*val + cR*csum[col] + xp[(size_t)r*512 + col]*wv + bvv;
        }
      } else {
        float m = (ne[r] > thv) ? 1.0f : 0.0f;
        float wm = cw[d] * m, bvv = cb[d];
        float s = 0.f, q = 0.f;
#pragma unroll
        for (int fc = 0; fc < 4; ++fc) {
          int col = c0 + w*64 + fc*16 + l15;
          float g = gelu_f(acc[fr][fc][j]*wm + bvv);
          unsigned hb = bfh_u(g);
          GH[(size_t)r*512 + col] = (ushort)hb;
          GL[(size_t)r*512 + col] = (ushort)bfh_u(g - bf2f(hb));
          s += g; q += g*g;
        }
#pragma unroll
        for (int off = 8; off > 0; off >>= 1) {
          s += __shfl_down(s, off, 16);
          q += __shfl_down(q, off, 16);
        }
        if (l15 == 0) { atomicAdd(&rs[r], s); atomicAdd(&rq[r], q); }
      }
    }
}

// ---------------- MFMA bf16-split NT GEMM: out[M,NCOLS] = A[M,512] @ W[NCOLS,512]^T + bias ----
// BM=64 (4 waves x 16 rows), all NCOLS/16 col-frags per wave, BK=32, 3-term split.
// MODE 0: plain store (ZRES). MODE 1: A <- gelu(ta[d]*x+tc[d]) at stage; out gelu(v)*v; row stats.
template<int NCOLS, int MODE>
__global__ __launch_bounds__(256) void k_mfma_nt(
    const float* __restrict__ Af32,
    const ushort* __restrict__ WH, const ushort* __restrict__ WL,
    const float* __restrict__ bias, float* __restrict__ outp,
    const float* __restrict__ ta, const float* __restrict__ tc,
    float* __restrict__ rs, float* __restrict__ rq)
{
  constexpr int NF = NCOLS / 16;
  __shared__ ushort AhS[64*40], AlS[64*40];
  __shared__ ushort BhS[NCOLS*40], BlS[NCOLS*40];
  const int t = threadIdx.x;
  const int lane = t & 63, w = t >> 6;
  const int l15 = lane & 15, l4 = lane >> 4;
  const int r0 = blockIdx.x * 64;

  f4 acc[NF];
#pragma unroll
  for (int fc = 0; fc < NF; ++fc) acc[fc] = (f4){0.f,0.f,0.f,0.f};

  const int arow = t >> 2, ak0 = (t & 3) * 8;
  float taa = 0.f, tcc = 0.f;
  if (MODE == 1) { int d = (r0 + arow) % 7; taa = ta[d]; tcc = tc[d]; }

  for (int kt = 0; kt < 512; kt += 32) {
    // ---- stage A (64x32), split (+ optional gelu transform) ----
    {
      const float* src = Af32 + (size_t)(r0+arow)*512 + kt + ak0;
      float4 v0 = *(const float4*)src;
      float4 v1 = *(const float4*)(src+4);
      float va[8] = {v0.x,v0.y,v0.z,v0.w,v1.x,v1.y,v1.z,v1.w};
      bf8 hv, lv;
#pragma unroll
      for (int j = 0; j < 8; ++j) {
        float x = va[j];
        if (MODE == 1) x = gelu_f(taa*x + tcc);
        unsigned hb = bfh_u(x);
        hv[j] = (short)hb;
        lv[j] = (short)bfh_u(x - bf2f(hb));
      }
      *(bf8*)&AhS[arow*40 + ak0] = hv;
      *(bf8*)&AlS[arow*40 + ak0] = lv;
    }
    // ---- stage B (NCOLS x 32) ----
    for (int c = t; c < NCOLS*4; c += 256) {
      int brow = c >> 2, bk0 = (c & 3) * 8;
      *(bf8*)&BhS[brow*40 + bk0] = *(const bf8*)&WH[(size_t)brow*512 + kt + bk0];
      *(bf8*)&BlS[brow*40 + bk0] = *(const bf8*)&WL[(size_t)brow*512 + kt + bk0];
    }
    __syncthreads();
    // ---- compute: wave w owns rows w*16..w*16+15 ----
    bf8 ah, al;
    {
      int off = (w*16 + l15)*40 + l4*8;
      ah = *(const bf8*)&AhS[off];
      al = *(const bf8*)&AlS[off];
    }
#pragma unroll
    for (int fc = 0; fc < NF; ++fc) {
      int off = (fc*16 + l15)*40 + l4*8;
      bf8 bh = *(const bf8*)&BhS[off];
      bf8 bl = *(const bf8*)&BlS[off];
      acc[fc] = __builtin_amdgcn_mfma_f32_16x16x32_bf16(ah, bh, acc[fc], 0, 0, 0);
      acc[fc] = __builtin_amdgcn_mfma_f32_16x16x32_bf16(ah, bl, acc[fc], 0, 0, 0);
      acc[fc] = __builtin_amdgcn_mfma_f32_16x16x32_bf16(al, bh, acc[fc], 0, 0, 0);
    }
    __syncthreads();
  }

  // ---- epilogue ----
#pragma unroll
  for (int j = 0; j < 4; ++j) {
    const int r = r0 + w*16 + l4*4 + j;
    float s = 0.f, q = 0.f;
#pragma unroll
    for (int fc = 0; fc < NF; ++fc) {
      int col = fc*16 + l15;
      float v = acc[fc][j] + bias[col];
      if (MODE == 1) { float g = gelu_f(v); v = g*v; }
      outp[(size_t)r*NCOLS + col] = v;
      if (MODE == 1) { s += v; q += v*v; }
    }
    if (MODE == 1) {
#pragma unroll
      for (int off = 8; off > 0; off >>= 1) {
        s += __shfl_down(s, off, 16);
        q += __shfl_down(q, off, 16);
      }
      if (l15 == 0) { rs[r] = s; rq[r] = q; }
    }
  }
}

// ---------------- analytic DCT energy (Parseval): 2L*sum(x^2) + 2*(sum x)^2 ----------------
__global__ void k_energy_an(const float* __restrict__ xp, float* __restrict__ en) {
  int r = blockIdx.x*4 + (threadIdx.x >> 6);
  int lane = threadIdx.x & 63;
  const float* row = xp + (size_t)r*512;
  double s = 0.0, q = 0.0;
  for (int i = lane; i < 512; i += 64) { double v = row[i]; s += v; q += v*v; }
#pragma unroll
  for (int o = 32; o > 0; o >>= 1) { s += __shfl_down(s, o); q += __shfl_down(q, o); }
  if (lane == 0) en[r] = (float)(1024.0*q + 2.0*s*s);
}

__global__ void k_ne(const float* __restrict__ en, float* __restrict__ ne) {
  int b = blockIdx.x*256 + threadIdx.x;
  if (b >= 2048) return;
  float e[7], s7[7];
#pragma unroll
  for (int d = 0; d < 7; ++d) { e[d] = en[b*7+d]; s7[d] = e[d]; }
#pragma unroll
  for (int i = 1; i < 7; ++i) {
    float key = s7[i]; int j = i-1;
    while (j >= 0 && s7[j] > key) { s7[j+1] = s7[j]; --j; }
    s7[j+1] = key;
  }
  float med = s7[3] + 1e-6f;
#pragma unroll
  for (int d = 0; d < 7; ++d) ne[b*7+d] = e[d] / med;
}

// exact k-th-smallest via register-resident 4-bit radix select.
__global__ __launch_bounds__(1024) void k_thr(const float* __restrict__ ne,
                                              const float* __restrict__ qp, float* __restrict__ out)
{
  __shared__ unsigned s_part[16][8];
  __shared__ unsigned s_bsel, s_R;
  const int t = threadIdx.x;
  const int lane = t & 63, wv = t >> 6;
  unsigned key[14];
#pragma unroll
  for (int j = 0; j < 14; ++j) key[j] = __float_as_uint(ne[t + j*1024]);

  float q = qp[0];
  float pos = q * 14335.0f;
  int lo = (int)floorf(pos);
  if (lo < 0) lo = 0; if (lo > 14335) lo = 14335;
  int hi = lo + 1; if (hi > 14335) hi = 14335;
  float frac = pos - (float)lo;

  unsigned prefix = 0;
  unsigned R = (unsigned)lo;
#pragma unroll 1
  for (int shift = 28; shift >= 0; shift -= 4) {
    unsigned pb = prefix >> shift;
    unsigned long long accb = 0ull;
#pragma unroll
    for (int j = 0; j < 14; ++j) {
      unsigned diff = (key[j] >> shift) - pb;
      accb += (diff < 16u) ? (1ull << (diff*4)) : 0ull;
    }
    unsigned pk[8];
#pragma unroll
    for (int b = 0; b < 8; ++b) {
      unsigned clo = (unsigned)(accb >> (b*4)) & 15u;
      unsigned chi = (unsigned)(accb >> (b*4+32)) & 15u;
      pk[b] = clo | (chi << 16);
    }
#pragma unroll
    for (int b = 0; b < 8; ++b)
#pragma unroll
      for (int o = 32; o > 0; o >>= 1) pk[b] += __shfl_down(pk[b], o);
    if (lane == 0) {
#pragma unroll
      for (int b = 0; b < 8; ++b) s_part[wv][b] = pk[b];
    }
    __syncthreads();
    if (t == 0) {
      unsigned tot[16];
#pragma unroll
      for (int i = 0; i < 8; ++i) {
        unsigned s = 0;
#pragma unroll
        for (int w2 = 0; w2 < 16; ++w2) s += s_part[w2][i];
        tot[i] = s & 0xFFFFu; tot[i+8] = s >> 16;
      }
      unsigned cum = 0, bsel = 15;
#pragma unroll 1
      for (int b = 0; b < 16; ++b) {
        if (cum + tot[b] > R) { bsel = (unsigned)b; break; }
        cum += tot[b];
      }
      s_bsel = bsel; s_R = R - cum;
    }
    __syncthreads();
    prefix |= (s_bsel << shift);
    R = s_R;
    __syncthreads();
  }
  unsigned cle = 0, mn = 0xFFFFFFFFu;
#pragma unroll
  for (int j = 0; j < 14; ++j) {
    cle += (key[j] <= prefix) ? 1u : 0u;
    if (key[j] > prefix && key[j] < mn) mn = key[j];
  }
#pragma unroll
  for (int o = 32; o > 0; o >>= 1) {
    cle += __shfl_down(cle, o);
    unsigned m2 = __shfl_down(mn, o);
    mn = (m2 < mn) ? m2 : mn;
  }
  if (lane == 0) { s_part[wv][0] = cle; s_part[wv][1] = mn; }
  __syncthreads();
  if (t == 0) {
    unsigned C = 0, M = 0xFFFFFFFFu;
#pragma unroll
    for (int w2 = 0; w2 < 16; ++w2) {
      C += s_part[w2][0];
      if (s_part[w2][1] < M) M = s_part[w2][1];
    }
    unsigned vhiKey = (C > (unsigned)hi) ? prefix : M;
    if (vhiKey == 0xFFFFFFFFu) vhiKey = prefix;
    float vlo = __uint_as_float(prefix);
    float vhi = __uint_as_float(vhiKey);
    out[0] = vlo*(1.0f-frac) + vhi*frac;
  }
}

// ---------------- BN finalize from per-row sums ----------------
__global__ __launch_bounds__(256) void k_bnfin_rows(const float* __restrict__ rs,
    const float* __restrict__ rq, int nch, int nrows, double count,
    const float* __restrict__ gamma, const float* __restrict__ beta, float* __restrict__ out)
{
  __shared__ double sd[256];
  int ch = blockIdx.x, t = threadIdx.x;
  double s = 0.0, q = 0.0;
  for (int i = ch + t*nch; i < nrows; i += 256*nch) { s += rs[i]; q += rq[i]; }
  sd[t] = s; __syncthreads();
  for (int o = 128; o > 0; o >>= 1) { if (t < o) sd[t] += sd[t+o]; __syncthreads(); }
  double S = sd[0]; __syncthreads();
  sd[t] = q; __syncthreads();
  for (int o = 128; o > 0; o >>= 1) { if (t < o) sd[t] += sd[t+o]; __syncthreads(); }
  if (t == 0) {
    double m = S / count;
    double v = sd[0] / count - m*m; if (v < 0.0) v = 0.0;
    double inv = 1.0 / sqrt(v + 1e-5);
    out[ch]       = (float)(gamma[ch] * inv);
    out[nch + ch] = (float)(beta[ch] - m * gamma[ch] * inv);
  }
}

__global__ __launch_bounds__(256) void k_bnfin_part(const float* __restrict__ pS,
    const float* __restrict__ pQ, int nparts, int nch, double count,
    const float* __restrict__ gamma, const float* __restrict__ beta, float* __restrict__ out)
{
  __shared__ double sd[256];
  int ch = blockIdx.x, t = threadIdx.x;
  double s = 0.0, q = 0.0;
  for (int i = t; i < nparts; i += 256) { s += pS[(size_t)i*nch + ch]; q += pQ[(size_t)i*nch + ch]; }
  sd[t] = s; __syncthreads();
  for (int o = 128; o > 0; o >>= 1) { if (t < o) sd[t] += sd[t+o]; __syncthreads(); }
  double S = sd[0]; __syncthreads();
  sd[t] = q; __syncthreads();
  for (int o = 128; o > 0; o >>= 1) { if (t < o) sd[t] += sd[t+o]; __syncthreads(); }
  if (t == 0) {
    double m = S / count;
    double v = sd[0] / count - m*m; if (v < 0.0) v = 0.0;
    double inv = 1.0 / sqrt(v + 1e-5);
    out[ch]       = (float)(gamma[ch] * inv);
    out[nch + ch] = (float)(beta[ch] - m * gamma[ch] * inv);
  }
}

// ---------------- patch path: z1r = V[n] @ xp-patch + c2 ----------------
__global__ __launch_bounds__(256) void k_patch(const float* __restrict__ xp,
    const float* __restrict__ V, const float* __restrict__ c2,
    float* __restrict__ z1r, float* __restrict__ pS, float* __restrict__ pQ)
{
  __shared__ float sx[8][512];
  __shared__ float aS[32], aQ[32];
  int t = threadIdx.x;
  int r0 = blockIdx.x * 8;
  for (int c = t; c < 1024; c += 256) {
    int row = c >> 7, cg = c & 127;
    *(float4*)&sx[row][cg*4] = *(const float4*)&xp[(size_t)(r0+row)*512 + cg*4];
  }
  if (t < 32) { aS[t] = 0.f; aQ[t] = 0.f; }
  __syncthreads();
  float vreg[2][16]; float cc[2]; int nn_[2], oo[2];
#pragma unroll
  for (int h = 0; h < 2; ++h) {
    int o = t + h*256;
    oo[h] = o;
    int n = o >> 4, p = o & 15;
    nn_[h] = n;
#pragma unroll
    for (int qg = 0; qg < 4; ++qg) {
      float4 v4 = *(const float4*)&V[(size_t)n*256 + p*16 + qg*4];
      vreg[h][qg*4+0]=v4.x; vreg[h][qg*4+1]=v4.y; vreg[h][qg*4+2]=v4.z; vreg[h][qg*4+3]=v4.w;
    }
    cc[h] = c2[o];
  }
  float sum[2] = {0.f,0.f}, sq[2] = {0.f,0.f};
  for (int row = 0; row < 8; ++row) {
#pragma unroll
    for (int h = 0; h < 2; ++h) {
      const float* xr = &sx[row][nn_[h]*16];
      float val = cc[h];
#pragma unroll
      for (int qq = 0; qq < 16; ++qq) val += vreg[h][qq] * xr[qq];
      z1r[(size_t)(r0+row)*512 + oo[h]] = val;
      sum[h] += val; sq[h] += val*val;
    }
  }
#pragma unroll
  for (int h = 0; h < 2; ++h) {
    atomicAdd(&aS[nn_[h]], sum[h]);
    atomicAdd(&aQ[nn_[h]], sq[h]);
  }
  __syncthreads();
  if (t < 32) { pS[(size_t)blockIdx.x*32 + t] = aS[t]; pQ[(size_t)blockIdx.x*32 + t] = aQ[t]; }
}

// ---------------- TopKFreq ----------------
__global__ void k_att(const float* __restrict__ z1, const float* __restrict__ z1r,
    const float* __restrict__ bn2, const float* __restrict__ u, const float* __restrict__ fcb,
    float* __restrict__ att)
{
  int r = blockIdx.x*4 + (threadIdx.x >> 6);
  int lane = threadIdx.x & 63;
  const float* z1p = z1 + (size_t)r*512;
  const float* zrp = z1r + (size_t)r*512;
  float s = 0.f;
#pragma unroll
  for (int h = 0; h < 2; ++h) {
    int i = lane*4 + h*256;
    int n = i >> 4;
    float a2n = bn2[n], c2n = bn2[32+n];
    float4 zr = *(const float4*)&zrp[i];
    float4 zv = *(const float4*)&z1p[i];
    float4 uv = *(const float4*)&u[i];
    s += (zv.x + gelu_f(a2n*zr.x + c2n)) * uv.x;
    s += (zv.y + gelu_f(a2n*zr.y + c2n)) * uv.y;
    s += (zv.z + gelu_f(a2n*zr.z + c2n)) * uv.z;
    s += (zv.w + gelu_f(a2n*zr.w + c2n)) * uv.w;
  }
  s = wred(s);
  if (lane == 0) att[r] = s + fcb[0];
}

__global__ __launch_bounds__(1024) void k_tf(const float* __restrict__ att,
    const float* __restrict__ pg, const float* __restrict__ pb,
    const float* __restrict__ pwc, const float* __restrict__ pbc,
    const float* __restrict__ pfb, float* __restrict__ a1, float* __restrict__ a2)
{
  __shared__ double sd[1024];
  __shared__ float sh[4];
  const int t = threadIdx.x;
  float g = pg[0], b = pb[0], wc = pwc[0], bc = pbc[0], fb = pfb[0];
  double s = 0.0, q = 0.0;
  for (int i = t; i < BD; i += 1024) { double v = att[i]; s += v; q += v*v; }
  sd[t] = s; __syncthreads();
  for (int o = 512; o > 0; o >>= 1) { if (t < o) sd[t] += sd[t+o]; __syncthreads(); }
  double S1 = sd[0]; __syncthreads();
  sd[t] = q; __syncthreads();
  for (int o = 512; o > 0; o >>= 1) { if (t < o) sd[t] += sd[t+o]; __syncthreads(); }
  if (t == 0) {
    double m = S1 / 14336.0;
    double v = sd[0] / 14336.0 - m*m; if (v < 0.0) v = 0.0;
    sh[0] = (float)m; sh[1] = (float)(1.0 / sqrt(v + 1e-5));
  }
  __syncthreads();
  float m1 = sh[0], i1 = sh[1];
  s = 0.0; q = 0.0;
  for (int i = t; i < BD; i += 1024) {
    float v = att[i];
    float an = (v - m1) * i1 * g + b;
    float av = sigm_f(gelu_f(an) * wc + bc);
    a1[i] = av;
    float t2 = av * (v - fb) + fb;
    s += t2; q += (double)t2 * t2;
  }
  __syncthreads();
  sd[t] = s; __syncthreads();
  for (int o = 512; o > 0; o >>= 1) { if (t < o) sd[t] += sd[t+o]; __syncthreads(); }
  double S2 = sd[0]; __syncthreads();
  sd[t] = q; __syncthreads();
  for (int o = 512; o > 0; o >>= 1) { if (t < o) sd[t] += sd[t+o]; __syncthreads(); }
  if (t == 0) {
    double m = S2 / 14336.0;
    double v = sd[0] / 14336.0 - m*m; if (v < 0.0) v = 0.0;
    sh[2] = (float)m; sh[3] = (float)(1.0 / sqrt(v + 1e-5));
  }
  __syncthreads();
  float m2 = sh[2], i2 = sh[3];
  for (int i = t; i < BD; i += 1024) {
    float t2 = a1[i] * (att[i] - fb) + fb;
    float an = (t2 - m2) * i2 * g + b;
    a2[i] = sigm_f(gelu_f(an) * wc + bc);
  }
}

// ---------------- elementwise stats passes (float4) ----------------
__global__ void k_statsA(const float* __restrict__ z1, const float* __restrict__ z1r,
    const float* __restrict__ bn2, const float* __restrict__ a1,
    float* __restrict__ rs, float* __restrict__ rq)
{
  int r = blockIdx.x*4 + (threadIdx.x >> 6);
  int lane = threadIdx.x & 63;
  float av = a1[r];
  const float* z1p = z1 + (size_t)r*512;
  const float* zrp = z1r + (size_t)r*512;
  float s = 0.f, q = 0.f;
#pragma unroll
  for (int h = 0; h < 2; ++h) {
    int i = lane*4 + h*256;
    int n = i >> 4;
    float a2n = bn2[n], c2n = bn2[32+n];
    float4 zr = *(const float4*)&zrp[i];
    float4 zv = *(const float4*)&z1p[i];
    float A0 = (zv.x + gelu_f(a2n*zr.x + c2n)) * av;
    float A1 = (zv.y + gelu_f(a2n*zr.y + c2n)) * av;
    float A2 = (zv.z + gelu_f(a2n*zr.z + c2n)) * av;
    float A3 = (zv.w + gelu_f(a2n*zr.w + c2n)) * av;
    s += A0+A1+A2+A3; q += A0*A0+A1*A1+A2*A2+A3*A3;
  }
  s = wred(s); q = wred(q);
  if (lane == 0) { rs[r] = s; rq[r] = q; }
}

__global__ void k_statsC(const float* __restrict__ z1, const float* __restrict__ z1r,
    const float* __restrict__ bn2, const float* __restrict__ a1,
    const float* __restrict__ bn3, const float* __restrict__ cw, const float* __restrict__ cb,
    float* __restrict__ rs, float* __restrict__ rq)
{
  int r = blockIdx.x*4 + (threadIdx.x >> 6);
  int lane = threadIdx.x & 63;
  int d = r % 7;
  float av = a1[r];
  float b3a = bn3[d], b3c = bn3[7+d], wv = cw[d], bv = cb[d];
  const float* z1p = z1 + (size_t)r*512;
  const float* zrp = z1r + (size_t)r*512;
  float s = 0.f, q = 0.f;
#pragma unroll
  for (int h = 0; h < 2; ++h) {
    int i = lane*4 + h*256;
    int n = i >> 4;
    float a2n = bn2[n], c2n = bn2[32+n];
    float4 zr = *(const float4*)&zrp[i];
    float4 zv = *(const float4*)&z1p[i];
#pragma unroll
    for (int e = 0; e < 4; ++e) {
      float ze = (e==0?zr.x:e==1?zr.y:e==2?zr.z:zr.w);
      float z1e = (e==0?zv.x:e==1?zv.y:e==2?zv.z:zv.w);
      float A = (z1e + gelu_f(a2n*ze + c2n)) * av;
      float C = wv*gelu_f(b3a*A + b3c) + bv;
      s += C; q += C*C;
    }
  }
  s = wred(s); q = wred(q);
  if (lane == 0) { rs[r] = s; rq[r] = q; }
}

__global__ void k_final(const float* __restrict__ z1, const float* __restrict__ z1r,
    const float* __restrict__ bn2, const float* __restrict__ a1, const float* __restrict__ a2,
    const float* __restrict__ bn3, const float* __restrict__ bn4,
    const float* __restrict__ cw, const float* __restrict__ cb,
    float* __restrict__ zf, float* __restrict__ rs, float* __restrict__ rq)
{
  int r = blockIdx.x*4 + (threadIdx.x >> 6);
  int lane = threadIdx.x & 63;
  int d = r % 7;
  float av = a1[r], a2v = a2[r];
  float b3a = bn3[d], b3c = bn3[7+d], b4a = bn4[d], b4c = bn4[7+d];
  float wv = cw[d], bv = cb[d];
  const float* z1p = z1 + (size_t)r*512;
  const float* zrp = z1r + (size_t)r*512;
  float* zfp = zf + (size_t)r*512;
  float s = 0.f, q = 0.f;
#pragma unroll
  for (int h = 0; h < 2; ++h) {
    int i = lane*4 + h*256;
    int n = i >> 4;
    float a2n = bn2[n], c2n = bn2[32+n];
    float4 zr = *(const float4*)&zrp[i];
    float4 zv = *(const float4*)&z1p[i];
    float4 ov;
#pragma unroll
    for (int e = 0; e < 4; ++e) {
      float ze = (e==0?zr.x:e==1?zr.y:e==2?zr.z:zr.w);
      float z1e = (e==0?zv.x:e==1?zv.y:e==2?zv.z:zv.w);
      float z1v = z1e * av;
      float z2v = gelu_f(a2n*ze + c2n) * av;
      float A = z1v + z2v;
      float C = wv*gelu_f(b3a*A + b3c) + bv;
      float inter = gelu_f(b4a*C + b4c) * a2v;
      float z1n = z1v*inter + z2v;
      float z2n = z2v*inter + z1n;
      float zfv = z1n*z2n + z1n + z2n;
      (e==0?ov.x:e==1?ov.y:e==2?ov.z:ov.w) = zfv;
      s += zfv; q += zfv*zfv;
    }
    *(float4*)&zfp[i] = ov;
  }
  s = wred(s); q = wred(q);
  if (lane == 0) { rs[r] = s; rq[r] = q; }
}

// ---------------- output: fc2 + bias + z_res + transpose ----------------
__global__ __launch_bounds__(256) void k_out(const float* __restrict__ h2,
    const float* __restrict__ bn6, const float* __restrict__ w2, const float* __restrict__ b2,
    const float* __restrict__ zres, float* __restrict__ out)
{
  int idx = blockIdx.x*256 + threadIdx.x;
  int r = idx / 96, o = idx - r*96;
  int d = r % 7, b = r / 7;
  float a6 = bn6[d], c6 = bn6[7+d];
  const float* hp = h2 + (size_t)r*48;
  const float* wp = w2 + o*48;
  float s = 0.f;
#pragma unroll
  for (int j4 = 0; j4 < 12; ++j4) {
    float4 hv = *(const float4*)&hp[j4*4];
    float4 wv = *(const float4*)&wp[j4*4];
    s += (a6*hv.x + c6)*wv.x + (a6*hv.y + c6)*wv.y
       + (a6*hv.z + c6)*wv.z + (a6*hv.w + c6)*wv.w;
  }
  out[(size_t)b*672 + o*7 + d] = s + b2[o] + zres[(size_t)r*96 + o];
}

// ================= host =================
extern "C" void kernel_launch(void* const* d_in, const int* in_sizes, int n_in,
                              void* d_out, int out_size, void* d_ws, size_t ws_size,
                              hipStream_t stream) {
  const float* x          = (const float*)d_in[0];
  const float* dctconv_w  = (const float*)d_in[1];
  const float* dctconv_b  = (const float*)d_in[2];
  const float* dctnorm_g  = (const float*)d_in[3];
  const float* dctnorm_b  = (const float*)d_in[4];
  const float* threshold  = (const float*)d_in[5];
  const float* embed_W    = (const float*)d_in[6];
  const float* embed_b    = (const float*)d_in[7];
  const float* linres_W   = (const float*)d_in[8];
  const float* linres_b   = (const float*)d_in[9];
  const float* depth1_w   = (const float*)d_in[10];
  const float* depth1_b   = (const float*)d_in[11];
  const float* depthnorm_g= (const float*)d_in[12];
  const float* depthnorm_b= (const float*)d_in[13];
  const float* tf_fc_w    = (const float*)d_in[14];
  const float* tf_fc_b    = (const float*)d_in[15];
  const float* tf_norm_g  = (const float*)d_in[16];
  const float* tf_norm_b  = (const float*)d_in[17];
  const float* tf_conv_w  = (const float*)d_in[18];
  const float* tf_conv_b  = (const float*)d_in[19];
  const float* mlp_w1     = (const float*)d_in[20];
  const float* mlp_b1     = (const float*)d_in[21];
  const float* mlp_w2     = (const float*)d_in[22];
  const float* mlp_b2     = (const float*)d_in[23];
  const float* mlpnorm_g  = (const float*)d_in[24];
  const float* mlpnorm_b  = (const float*)d_in[25];
  float* out = (float*)d_out;
  float* ws  = (float*)d_ws;

  float* XP   = ws + F_XP;
  float* ZG   = ws + F_ZG;        // z1r f32 (after GEMM2); GH/GL planes before
  ushort* ZGH = (ushort*)(ws + F_ZG);
  ushort* ZGL = ZGH + (size_t)BD*512;
  float* Z1   = ws + F_Z1;
  ushort* B1H = (ushort*)(ws + F_CLK);
  ushort* B1L = B1H + 512*512;
  // upper half of CLK region (B1 planes use only 131072 of 262144 floats): W split planes
  ushort* W2H = (ushort*)(ws + F_CLK + 131072);
  ushort* W2L = W2H + 96*512;
  ushort* W1H = W2L + 96*512;
  ushort* W1L = W1H + 48*512;
  ushort* B2H = (ushort*)(ws + F_MKL);
  ushort* B2L = B2H + 512*512;
  float* U    = ws + F_U;
  float* CSUM = ws + F_CSUM;
  float* CSTp = ws + F_CST;
  float* Vp   = ws + F_V;
  float* C2p  = ws + F_C2;
  float* ZRES = ws + F_ZRES;
  float* H2p  = ws + F_H2;
  float* EN   = ws + F_EN;
  float* NEp  = ws + F_NE;
  float* ATTp = ws + F_ATT;
  float* A1p  = ws + F_A1;
  float* A2p  = ws + F_A2;
  float* RS   = ws + F_RS;
  float* RQ   = ws + F_RQ;
  float* PS   = ws + F_PS;
  float* PQ   = ws + F_PQ;
  float* BN0  = ws + F_BN;        // a[7], c[7]
  float* BN2  = ws + F_BN + 16;   // a[32], c[32]
  float* BN3  = ws + F_BN + 80;
  float* BN4  = ws + F_BN + 96;
  float* BN5  = ws + F_BN + 112;
  float* BN6  = ws + F_BN + 128;
  float* THRp = ws + F_THR;

  k_gen_b<<<512, 256, 0, stream>>>(B1H, B1L, B2H, B2L);
  k_ucsum2<<<2, 256, 0, stream>>>(U, CSUM, tf_fc_w);
  k_w2<<<96, 256, 0, stream>>>(linres_W, linres_b, embed_W, embed_b, W2H, W2L, CSTp);
  k_splitw<<<96, 256, 0, stream>>>(mlp_w1, W1H, W1L, 48*512);
  k_v<<<32, 256, 0, stream>>>(embed_W, embed_b, depth1_w, depth1_b, Vp, C2p);
  k_transpose<<<2048, 256, 0, stream>>>(x, XP);
  k_energy_an<<<3584, 256, 0, stream>>>(XP, EN);
  k_ne<<<8, 256, 0, stream>>>(EN, NEp);
  k_thr<<<1, 1024, 0, stream>>>(NEp, threshold, THRp);
  hipMemsetAsync(RS, 0, 2*BD*sizeof(float), stream);
  // GEMM1: z_dct -> masked dctconv -> gelu -> GH/GL planes (+ row stats)
  k_mfma<2><<<dim3(224,2), 256, 0, stream>>>(XP, nullptr, nullptr, B1H, B1L,
      nullptr, ZGH, ZGL, nullptr, nullptr, nullptr, dctconv_w, dctconv_b,
      NEp, THRp, RS, RQ);
  k_bnfin_rows<<<7, 256, 0, stream>>>(RS, RQ, 7, BD, 1048576.0, dctnorm_g, dctnorm_b, BN0);
  // GEMM2: z1 = BN(g) @ M + x_res  (BN folded via column sums)
  k_mfma<1><<<dim3(224,2), 256, 0, stream>>>(nullptr, ZGH, ZGL, B2H, B2L,
      Z1, nullptr, nullptr, BN0, CSUM, XP, dctconv_w, dctconv_b,
      nullptr, nullptr, nullptr, nullptr);
  k_patch<<<1792, 256, 0, stream>>>(XP, Vp, C2p, ZG, PS, PQ);
  k_bnfin_part<<<32, 256, 0, stream>>>(PS, PQ, 1792, 32, 229376.0, depthnorm_g, depthnorm_b, BN2);
  // ZRES = XP @ W2^T + cst   (MFMA bf16-split)
  k_mfma_nt<96,0><<<224, 256, 0, stream>>>(XP, W2H, W2L, CSTp, ZRES,
      nullptr, nullptr, nullptr, nullptr);
  k_att<<<3584, 256, 0, stream>>>(Z1, ZG, BN2, U, tf_fc_b, ATTp);
  k_tf<<<1, 1024, 0, stream>>>(ATTp, tf_norm_g, tf_norm_b, tf_conv_w, tf_conv_b, tf_fc_b, A1p, A2p);
  k_statsA<<<3584, 256, 0, stream>>>(Z1, ZG, BN2, A1p, RS, RQ);
  k_bnfin_rows<<<7, 256, 0, stream>>>(RS, RQ, 7, BD, 1048576.0, dctnorm_g, dctnorm_b, BN3);
  k_statsC<<<3584, 256, 0, stream>>>(Z1, ZG, BN2, A1p, BN3, dctconv_w, dctconv_b, RS, RQ);
  k_bnfin_rows<<<7, 256, 0, stream>>>(RS, RQ, 7, BD, 1048576.0, dctnorm_g, dctnorm_b, BN4);
  k_final<<<3584, 256, 0, stream>>>(Z1, ZG, BN2, A1p, A2p, BN3, BN4, dctconv_w, dctconv_b, XP, RS, RQ);
  k_bnfin_rows<<<7, 256, 0, stream>>>(RS, RQ, 7, BD, 1048576.0, dctnorm_g, dctnorm_b, BN5);
  // MLP fc1: h2 = gelu(v)*v with v = gelu(BN5(zf)) @ w1^T + b1   (MFMA bf16-split, fused stats)
  k_mfma_nt<48,1><<<224, 256, 0, stream>>>(XP, W1H, W1L, mlp_b1, H2p,
      BN5, BN5+7, RS, RQ);
  k_bnfin_rows<<<7, 256, 0, stream>>>(RS, RQ, 7, BD, 98304.0, mlpnorm_g, mlpnorm_b, BN6);
  k_out<<<5376, 256, 0, stream>>>(H2p, BN6, mlp_w2, mlp_b2, ZRES, out);
}

// Round 7
// 379.804 us; speedup vs baseline: 2.1838x; 1.0155x over previous
//
#include <hip/hip_runtime.h>
#include <math.h>

#define BB 2048
#define LL 512
#define DD 7
#define BD 14336   // BB*DD

// ---------------- ws layout (floats) ----------------
constexpr size_t F_XP   = 0;                          // xp, later zf
constexpr size_t F_ZG   = F_XP  + (size_t)BD*512;     // ZGH/ZGL planes -> z1r f32
constexpr size_t F_Z1   = F_ZG  + (size_t)BD*512;     // z1
constexpr size_t F_CLK  = F_Z1  + (size_t)BD*512;     // B1H/B1L planes; upper half: W2/W1 planes
constexpr size_t F_MKL  = F_CLK + 512*512;            // B2H/B2L (ushort planes)
constexpr size_t F_U    = F_MKL + 512*512;
constexpr size_t F_CSUM = F_U + 512;
constexpr size_t F_W2   = F_CSUM + 512;               // (spare)
constexpr size_t F_CST  = F_W2 + 96*512;
constexpr size_t F_V    = F_CST + 96;                 // 32x16x16
constexpr size_t F_C2   = F_V + 32*256;               // 32x16
constexpr size_t F_ZRES = F_C2 + 512;                 // BD x 96
constexpr size_t F_H2   = F_ZRES + (size_t)BD*96;     // BD x 48
constexpr size_t F_EN   = F_H2 + (size_t)BD*48;
constexpr size_t F_NE   = F_EN + BD;
constexpr size_t F_ATT  = F_NE + BD;
constexpr size_t F_A1   = F_ATT + BD;
constexpr size_t F_A2   = F_A1 + BD;
constexpr size_t F_RS   = F_A2 + BD;
constexpr size_t F_RQ   = F_RS + BD;                  // adjacent to F_RS (one memset)
constexpr size_t F_PS   = F_RQ + BD;                  // 1792 x 32
constexpr size_t F_PQ   = F_PS + 1792*32;
constexpr size_t F_BN   = F_PQ + 1792*32;             // bn affine params
constexpr size_t F_THR  = F_BN + 256;

typedef __attribute__((ext_vector_type(8))) short bf8;
typedef __attribute__((ext_vector_type(4))) short sh4;
typedef __attribute__((ext_vector_type(4))) float f4;

__device__ __forceinline__ float gelu_f(float x) {
  return 0.5f * x * (1.0f + erff(x * 0.70710678118654752440f));
}
__device__ __forceinline__ float sigm_f(float x) {
  return 1.0f / (1.0f + expf(-x));
}
__device__ __forceinline__ float wred(float v) {
#pragma unroll
  for (int o = 32; o > 0; o >>= 1) v += __shfl_down(v, o);
  return v;
}
__device__ __forceinline__ unsigned bfh_u(float v) {
  unsigned u = __float_as_uint(v);
  return (u + 0x7FFFu + ((u >> 16) & 1u)) >> 16;
}
__device__ __forceinline__ float bf2f(unsigned h) { return __uint_as_float(h << 16); }

// ---------------- constant generation ----------------
// B1T[c][r] = 2*cos(pi*(r+0.5)*c/512)        (DCT,  reduction index r)
// B2T[c][r] = cos(pi*(c+0.5)*r/512)*sc[r]    (iDCT, reduction index r), sc0=1/1024 else 1/512
__global__ void k_gen_b(ushort* __restrict__ B1H, ushort* __restrict__ B1L,
                        ushort* __restrict__ B2H, ushort* __restrict__ B2L) {
  int c = blockIdx.x;
  for (int r = threadIdx.x; r < 512; r += 256) {
    double c1 = cos(3.14159265358979323846 * (r + 0.5) * c / 512.0);
    float v1 = (float)(2.0 * c1);
    unsigned h = bfh_u(v1);
    B1H[(size_t)c*512 + r] = (ushort)h;
    B1L[(size_t)c*512 + r] = (ushort)bfh_u(v1 - bf2f(h));
    double c2 = cos(3.14159265358979323846 * (c + 0.5) * r / 512.0);
    float v2 = (float)(c2 * (r == 0 ? (1.0/1024.0) : (1.0/512.0)));
    h = bfh_u(v2);
    B2H[(size_t)c*512 + r] = (ushort)h;
    B2L[(size_t)c*512 + r] = (ushort)bfh_u(v2 - bf2f(h));
  }
}

// csum[l] closed form: theta = pi*(l+0.5)/512, s=(-1)^l
//   sum_{k=0}^{511} cos(k*theta) = 1/2 + s/(2*tan(theta/2))
__global__ void k_ucsum2(float* __restrict__ u, float* __restrict__ csum,
                         const float* __restrict__ wf) {
  int l = blockIdx.x*256 + threadIdx.x;
  if (l >= 512) return;
  double th2 = 3.14159265358979323846 * (double)(2*l + 1) / 2048.0;   // theta/2
  double s = (l & 1) ? -1.0 : 1.0;
  double S = 0.5*s/tan(th2) - 0.5;          // sum_{k=1}^{511} cos(k*theta)
  csum[l] = (float)(1.0/1024.0 + S/512.0);
  double uu = (double)wf[0] * 45.25483399593904156 / 1024.0;      // sqrt(2048)*M[0][l]
  for (int k = 1; k < 5; ++k)
    uu += (double)wf[k] * 32.0 * cos(3.14159265358979323846*(l+0.5)*k/512.0) / 512.0;
  u[l] = (float)uu;
}

// W2 = fold(embed, linres) -> bf16 hi/lo planes + constant vector
__global__ __launch_bounds__(256) void k_w2(const float* __restrict__ linW,
    const float* __restrict__ linb, const float* __restrict__ eW, const float* __restrict__ eb,
    ushort* __restrict__ W2H, ushort* __restrict__ W2L, float* __restrict__ cst)
{
  __shared__ float sW[768];
  __shared__ float sb[48];
  __shared__ float rbuf[256];
  int o = blockIdx.x, t = threadIdx.x;
  for (int i = t; i < 768; i += 256) sW[i] = eW[i];
  if (t < 48) sb[t] = eb[t];
  __syncthreads();
  const float* lw = linW + (size_t)o * 1536;
  for (int i = t; i < 512; i += 256) {
    int n = i >> 4, p = i & 15;
    float s = 0.f;
    const float* l2 = lw + n*48;
#pragma unroll 8
    for (int m = 0; m < 48; ++m) s += l2[m] * sW[m*16 + p];
    unsigned hb = bfh_u(s);
    W2H[(size_t)o*512 + i] = (ushort)hb;
    W2L[(size_t)o*512 + i] = (ushort)bfh_u(s - bf2f(hb));
  }
  float c = 0.f;
  for (int i = t; i < 1536; i += 256) c += lw[i] * sb[i % 48];
  rbuf[t] = c; __syncthreads();
  for (int off = 128; off > 0; off >>= 1) { if (t < off) rbuf[t] += rbuf[t+off]; __syncthreads(); }
  if (t == 0) cst[o] = rbuf[0] + linb[o];
}

__global__ void k_splitw(const float* __restrict__ src, ushort* __restrict__ H,
                         ushort* __restrict__ L, int n) {
  int i = blockIdx.x*256 + threadIdx.x;
  if (i < n) {
    float v = src[i];
    unsigned hb = bfh_u(v);
    H[i] = (ushort)hb;
    L[i] = (ushort)bfh_u(v - bf2f(hb));
  }
}

__global__ void k_v(const float* __restrict__ eW, const float* __restrict__ eb,
                    const float* __restrict__ dw, const float* __restrict__ db,
                    float* __restrict__ V, float* __restrict__ c2)
{
  int n = blockIdx.x, t = threadIdx.x;
  int p = t >> 4, q = t & 15;
  float s = 0.f;
#pragma unroll
  for (int j = 0; j < 3; ++j) s += eW[(p*3+j)*16 + q] * dw[n*3+j];
  V[(size_t)n*256 + p*16 + q] = s;
  if (q == 0) {
    float c = 0.f;
#pragma unroll
    for (int j = 0; j < 3; ++j) c += eb[p*3+j] * dw[n*3+j];
    c2[n*16+p] = c + db[n];
  }
}

// ---------------- transpose [B,L,D] -> [B*D, L]  + fused per-(b,d) energy ----------------
// energy (Parseval): en = 2L*sum(x^2) + 2*(sum x)^2
__global__ __launch_bounds__(256) void k_transpose(const float* __restrict__ x,
                                                   float* __restrict__ xp,
                                                   float* __restrict__ en) {
  __shared__ float s[3584];
  int b = blockIdx.x;
  const float* src = x + (size_t)b*3584;
  for (int c = threadIdx.x; c < 896; c += 256) {
    float4 v = *(const float4*)&src[c*4];
    s[c*4+0]=v.x; s[c*4+1]=v.y; s[c*4+2]=v.z; s[c*4+3]=v.w;
  }
  __syncthreads();
  for (int c = threadIdx.x; c < 896; c += 256) {
    int d = c >> 7, cg = c & 127;
    float4 v;
    v.x = s[(cg*4+0)*7 + d]; v.y = s[(cg*4+1)*7 + d];
    v.z = s[(cg*4+2)*7 + d]; v.w = s[(cg*4+3)*7 + d];
    *(float4*)&xp[((size_t)b*7 + d)*512 + cg*4] = v;
  }
  // fused energy: 32 threads per d (7 d's -> 224 threads), 16 cols each
  int t = threadIdx.x;
  if (t < 224) {
    int d = t >> 5, c0 = (t & 31) * 16;
    double ss = 0.0, qq = 0.0;
    for (int l = c0; l < c0 + 16; ++l) {
      double v = s[l*7 + d];
      ss += v; qq += v*v;
    }
#pragma unroll
    for (int o = 16; o > 0; o >>= 1) {
      ss += __shfl_down(ss, o, 32);
      qq += __shfl_down(qq, o, 32);
    }
    if ((t & 31) == 0) en[b*7 + d] = (float)(1024.0*qq + 2.0*ss*ss);
  }
}

// ---------------- MFMA bf16-split GEMM: C[M,512] = A[M,512] @ B[512,512] ----------------
// BM=64, BN=256, BK=32; 512 threads = 8 waves, each 32 rows x 64 cols (2x4 frags of 16x16x32);
// 3-term bf16 split.
// MODE 2: A from f32 (split at stage); epilogue g=gelu(acc*mask*w+b) -> GH/GL planes + row stats
// MODE 1: A from GH/GL planes; epilogue z1 = aR*acc + cR*csum + xp*w + b -> f32
template<int MODE>
__global__ __launch_bounds__(512) void k_mfma(
    const float* __restrict__ Af32,
    const ushort* __restrict__ AHg, const ushort* __restrict__ ALg,
    const ushort* __restrict__ BHg, const ushort* __restrict__ BLg,
    float* __restrict__ z1out, ushort* __restrict__ GH, ushort* __restrict__ GL,
    const float* __restrict__ bnac, const float* __restrict__ csum,
    const float* __restrict__ xp,
    const float* __restrict__ cw, const float* __restrict__ cb,
    const float* __restrict__ ne, const float* __restrict__ thr,
    float* __restrict__ rs, float* __restrict__ rq)
{
  __shared__ ushort AhS[64*40], AlS[64*40];
  __shared__ ushort BhS[256*40], BlS[256*40];
  const int t = threadIdx.x;
  const int lane = t & 63, w = t >> 6;        // 8 waves
  const int l15 = lane & 15, l4 = lane >> 4;
  const int rg = w & 1, cg = w >> 1;          // wave: rows rg*32.., cols cg*64..
  const int r0 = blockIdx.x * 64, c0 = blockIdx.y * 256;

  f4 acc[2][4];
#pragma unroll
  for (int i = 0; i < 2; ++i)
#pragma unroll
    for (int j = 0; j < 4; ++j) acc[i][j] = (f4){0.f,0.f,0.f,0.f};

  const int arow = t >> 3, ak0 = (t & 7) * 4;   // A: 64 rows, 8 thr/row, 4 elems

  for (int kt = 0; kt < 512; kt += 32) {
    // ---- stage A (64x32) ----
    if (MODE == 2) {
      const float* src = Af32 + (size_t)(r0+arow)*512 + kt + ak0;
      float4 v0 = *(const float4*)src;
      float va[4] = {v0.x,v0.y,v0.z,v0.w};
      sh4 hv, lv;
#pragma unroll
      for (int j = 0; j < 4; ++j) {
        unsigned hb = bfh_u(va[j]);
        hv[j] = (short)hb;
        lv[j] = (short)bfh_u(va[j] - bf2f(hb));
      }
      *(sh4*)&AhS[arow*40 + ak0] = hv;
      *(sh4*)&AlS[arow*40 + ak0] = lv;
    } else {
      *(sh4*)&AhS[arow*40 + ak0] = *(const sh4*)&AHg[(size_t)(r0+arow)*512 + kt + ak0];
      *(sh4*)&AlS[arow*40 + ak0] = *(const sh4*)&ALg[(size_t)(r0+arow)*512 + kt + ak0];
    }
    // ---- stage B (256 cols x 32 k, transposed source) ----
#pragma unroll
    for (int h = 0; h < 2; ++h) {
      int c = t + h*512;
      int brow = c >> 2, bk0 = (c & 3) * 8;
      *(bf8*)&BhS[brow*40 + bk0] = *(const bf8*)&BHg[(size_t)(c0+brow)*512 + kt + bk0];
      *(bf8*)&BlS[brow*40 + bk0] = *(const bf8*)&BLg[(size_t)(c0+brow)*512 + kt + bk0];
    }
    __syncthreads();
    // ---- compute ----
    bf8 ah[2], al[2], bh[4], bl[4];
#pragma unroll
    for (int fr = 0; fr < 2; ++fr) {
      int off = (rg*32 + fr*16 + l15)*40 + l4*8;
      ah[fr] = *(const bf8*)&AhS[off];
      al[fr] = *(const bf8*)&AlS[off];
    }
#pragma unroll
    for (int fc = 0; fc < 4; ++fc) {
      int off = (cg*64 + fc*16 + l15)*40 + l4*8;
      bh[fc] = *(const bf8*)&BhS[off];
      bl[fc] = *(const bf8*)&BlS[off];
    }
#pragma unroll
    for (int fr = 0; fr < 2; ++fr)
#pragma unroll
      for (int fc = 0; fc < 4; ++fc) {
        acc[fr][fc] = __builtin_amdgcn_mfma_f32_16x16x32_bf16(ah[fr], bh[fc], acc[fr][fc], 0, 0, 0);
        acc[fr][fc] = __builtin_amdgcn_mfma_f32_16x16x32_bf16(ah[fr], bl[fc], acc[fr][fc], 0, 0, 0);
        acc[fr][fc] = __builtin_amdgcn_mfma_f32_16x16x32_bf16(al[fr], bh[fc], acc[fr][fc], 0, 0, 0);
      }
    __syncthreads();
  }

  // ---- epilogue ----
  const float thv = (MODE == 2) ? thr[0] : 0.f;
#pragma unroll
  for (int fr = 0; fr < 2; ++fr)
#pragma unroll
    for (int j = 0; j < 4; ++j) {
      const int r = r0 + rg*32 + fr*16 + l4*4 + j;
      const int d = r % 7;
      if (MODE == 1) {
        const float aR = bnac[d], cR = bnac[7+d], wv = cw[d], bvv = cb[d];
#pragma unroll
        for (int fc = 0; fc < 4; ++fc) {
          int col = c0 + cg*64 + fc*16 + l15;
          float val = acc[fr][fc][j];
          z1out[(size_t)r*512 + col] = aR*val + cR*csum[col] + xp[(size_t)r*512 + col]*wv + bvv;
        }
      } else {
        float m = (ne[r] > thv) ? 1.0f : 0.0f;
        float wm = cw[d] * m, bvv = cb[d];
        float s = 0.f, q = 0.f;
#pragma unroll
        for (int fc = 0; fc < 4; ++fc) {
          int col = c0 + cg*64 + fc*16 + l15;
          float g = gelu_f(acc[fr][fc][j]*wm + bvv);
          unsigned hb = bfh_u(g);
          GH[(size_t)r*512 + col] = (ushort)hb;
          GL[(size_t)r*512 + col] = (ushort)bfh_u(g - bf2f(hb));
          s += g; q += g*g;
        }
#pragma unroll
        for (int off = 8; off > 0; off >>= 1) {
          s += __shfl_down(s, off, 16);
          q += __shfl_down(q, off, 16);
        }
        if (l15 == 0) { atomicAdd(&rs[r], s); atomicAdd(&rq[r], q); }
      }
    }
}

// ---------------- MFMA bf16-split NT GEMM: out[M,NCOLS] = A[M,512] @ W[NCOLS,512]^T + bias ----
// BM=64 (4 waves x 16 rows), all NCOLS/16 col-frags per wave, BK=32, 3-term split.
// MODE 0: plain store (ZRES). MODE 1: A <- gelu(ta[d]*x+tc[d]) at stage; out gelu(v)*v; row stats.
template<int NCOLS, int MODE>
__global__ __launch_bounds__(256) void k_mfma_nt(
    const float* __restrict__ Af32,
    const ushort* __restrict__ WH, const ushort* __restrict__ WL,
    const float* __restrict__ bias, float* __restrict__ outp,
    const float* __restrict__ ta, const float* __restrict__ tc,
    float* __restrict__ rs, float* __restrict__ rq)
{
  constexpr int NF = NCOLS / 16;
  __shared__ ushort AhS[64*40], AlS[64*40];
  __shared__ ushort BhS[NCOLS*40], BlS[NCOLS*40];
  const int t = threadIdx.x;
  const int lane = t & 63, w = t >> 6;
  const int l15 = lane & 15, l4 = lane >> 4;
  const int r0 = blockIdx.x * 64;

  f4 acc[NF];
#pragma unroll
  for (int fc = 0; fc < NF; ++fc) acc[fc] = (f4){0.f,0.f,0.f,0.f};

  const int arow = t >> 2, ak0 = (t & 3) * 8;
  float taa = 0.f, tcc = 0.f;
  if (MODE == 1) { int d = (r0 + arow) % 7; taa = ta[d]; tcc = tc[d]; }

  for (int kt = 0; kt < 512; kt += 32) {
    // ---- stage A (64x32), split (+ optional gelu transform) ----
    {
      const float* src = Af32 + (size_t)(r0+arow)*512 + kt + ak0;
      float4 v0 = *(const float4*)src;
      float4 v1 = *(const float4*)(src+4);
      float va[8] = {v0.x,v0.y,v0.z,v0.w,v1.x,v1.y,v1.z,v1.w};
      bf8 hv, lv;
#pragma unroll
      for (int j = 0; j < 8; ++j) {
        float x = va[j];
        if (MODE == 1) x = gelu_f(taa*x + tcc);
        unsigned hb = bfh_u(x);
        hv[j] = (short)hb;
        lv[j] = (short)bfh_u(x - bf2f(hb));
      }
      *(bf8*)&AhS[arow*40 + ak0] = hv;
      *(bf8*)&AlS[arow*40 + ak0] = lv;
    }
    // ---- stage B (NCOLS x 32) ----
    for (int c = t; c < NCOLS*4; c += 256) {
      int brow = c >> 2, bk0 = (c & 3) * 8;
      *(bf8*)&BhS[brow*40 + bk0] = *(const bf8*)&WH[(size_t)brow*512 + kt + bk0];
      *(bf8*)&BlS[brow*40 + bk0] = *(const bf8*)&WL[(size_t)brow*512 + kt + bk0];
    }
    __syncthreads();
    // ---- compute: wave w owns rows w*16..w*16+15 ----
    bf8 ah, al;
    {
      int off = (w*16 + l15)*40 + l4*8;
      ah = *(const bf8*)&AhS[off];
      al = *(const bf8*)&AlS[off];
    }
#pragma unroll
    for (int fc = 0; fc < NF; ++fc) {
      int off = (fc*16 + l15)*40 + l4*8;
      bf8 bh = *(const bf8*)&BhS[off];
      bf8 bl = *(const bf8*)&BlS[off];
      acc[fc] = __builtin_amdgcn_mfma_f32_16x16x32_bf16(ah, bh, acc[fc], 0, 0, 0);
      acc[fc] = __builtin_amdgcn_mfma_f32_16x16x32_bf16(ah, bl, acc[fc], 0, 0, 0);
      acc[fc] = __builtin_amdgcn_mfma_f32_16x16x32_bf16(al, bh, acc[fc], 0, 0, 0);
    }
    __syncthreads();
  }

  // ---- epilogue ----
#pragma unroll
  for (int j = 0; j < 4; ++j) {
    const int r = r0 + w*16 + l4*4 + j;
    float s = 0.f, q = 0.f;
#pragma unroll
    for (int fc = 0; fc < NF; ++fc) {
      int col = fc*16 + l15;
      float v = acc[fc][j] + bias[col];
      if (MODE == 1) { float g = gelu_f(v); v = g*v; }
      outp[(size_t)r*NCOLS + col] = v;
      if (MODE == 1) { s += v; q += v*v; }
    }
    if (MODE == 1) {
#pragma unroll
      for (int off = 8; off > 0; off >>= 1) {
        s += __shfl_down(s, off, 16);
        q += __shfl_down(q, off, 16);
      }
      if (l15 == 0) { rs[r] = s; rq[r] = q; }
    }
  }
}

__global__ void k_ne(const float* __restrict__ en, float* __restrict__ ne) {
  int b = blockIdx.x*256 + threadIdx.x;
  if (b >= 2048) return;
  float e[7], s7[7];
#pragma unroll
  for (int d = 0; d < 7; ++d) { e[d] = en[b*7+d]; s7[d] = e[d]; }
#pragma unroll
  for (int i = 1; i < 7; ++i) {
    float key = s7[i]; int j = i-1;
    while (j >= 0 && s7[j] > key) { s7[j+1] = s7[j]; --j; }
    s7[j+1] = key;
  }
  float med = s7[3] + 1e-6f;
#pragma unroll
  for (int d = 0; d < 7; ++d) ne[b*7+d] = e[d] / med;
}

// exact k-th-smallest via register-resident 4-bit radix select.
__global__ __launch_bounds__(1024) void k_thr(const float* __restrict__ ne,
                                              const float* __restrict__ qp, float* __restrict__ out)
{
  __shared__ unsigned s_part[16][8];
  __shared__ unsigned s_bsel, s_R;
  const int t = threadIdx.x;
  const int lane = t & 63, wv = t >> 6;
  unsigned key[14];
#pragma unroll
  for (int j = 0; j < 14; ++j) key[j] = __float_as_uint(ne[t + j*1024]);

  float q = qp[0];
  float pos = q * 14335.0f;
  int lo = (int)floorf(pos);
  if (lo < 0) lo = 0; if (lo > 14335) lo = 14335;
  int hi = lo + 1; if (hi > 14335) hi = 14335;
  float frac = pos - (float)lo;

  unsigned prefix = 0;
  unsigned R = (unsigned)lo;
#pragma unroll 1
  for (int shift = 28; shift >= 0; shift -= 4) {
    unsigned pb = prefix >> shift;
    unsigned long long accb = 0ull;
#pragma unroll
    for (int j = 0; j < 14; ++j) {
      unsigned diff = (key[j] >> shift) - pb;
      accb += (diff < 16u) ? (1ull << (diff*4)) : 0ull;
    }
    unsigned pk[8];
#pragma unroll
    for (int b = 0; b < 8; ++b) {
      unsigned clo = (unsigned)(accb >> (b*4)) & 15u;
      unsigned chi = (unsigned)(accb >> (b*4+32)) & 15u;
      pk[b] = clo | (chi << 16);
    }
#pragma unroll
    for (int b = 0; b < 8; ++b)
#pragma unroll
      for (int o = 32; o > 0; o >>= 1) pk[b] += __shfl_down(pk[b], o);
    if (lane == 0) {
#pragma unroll
      for (int b = 0; b < 8; ++b) s_part[wv][b] = pk[b];
    }
    __syncthreads();
    if (t == 0) {
      unsigned tot[16];
#pragma unroll
      for (int i = 0; i < 8; ++i) {
        unsigned s = 0;
#pragma unroll
        for (int w2 = 0; w2 < 16; ++w2) s += s_part[w2][i];
        tot[i] = s & 0xFFFFu; tot[i+8] = s >> 16;
      }
      unsigned cum = 0, bsel = 15;
#pragma unroll 1
      for (int b = 0; b < 16; ++b) {
        if (cum + tot[b] > R) { bsel = (unsigned)b; break; }
        cum += tot[b];
      }
      s_bsel = bsel; s_R = R - cum;
    }
    __syncthreads();
    prefix |= (s_bsel << shift);
    R = s_R;
    __syncthreads();
  }
  unsigned cle = 0, mn = 0xFFFFFFFFu;
#pragma unroll
  for (int j = 0; j < 14; ++j) {
    cle += (key[j] <= prefix) ? 1u : 0u;
    if (key[j] > prefix && key[j] < mn) mn = key[j];
  }
#pragma unroll
  for (int o = 32; o > 0; o >>= 1) {
    cle += __shfl_down(cle, o);
    unsigned m2 = __shfl_down(mn, o);
    mn = (m2 < mn) ? m2 : mn;
  }
  if (lane == 0) { s_part[wv][0] = cle; s_part[wv][1] = mn; }
  __syncthreads();
  if (t == 0) {
    unsigned C = 0, M = 0xFFFFFFFFu;
#pragma unroll
    for (int w2 = 0; w2 < 16; ++w2) {
      C += s_part[w2][0];
      if (s_part[w2][1] < M) M = s_part[w2][1];
    }
    unsigned vhiKey = (C > (unsigned)hi) ? prefix : M;
    if (vhiKey == 0xFFFFFFFFu) vhiKey = prefix;
    float vlo = __uint_as_float(prefix);
    float vhi = __uint_as_float(vhiKey);
    out[0] = vlo*(1.0f-frac) + vhi*frac;
  }
}

// ---------------- BN finalize from per-row sums ----------------
__global__ __launch_bounds__(256) void k_bnfin_rows(const float* __restrict__ rs,
    const float* __restrict__ rq, int nch, int nrows, double count,
    const float* __restrict__ gamma, const float* __restrict__ beta, float* __restrict__ out)
{
  __shared__ double sd[256];
  int ch = blockIdx.x, t = threadIdx.x;
  double s = 0.0, q = 0.0;
  for (int i = ch + t*nch; i < nrows; i += 256*nch) { s += rs[i]; q += rq[i]; }
  sd[t] = s; __syncthreads();
  for (int o = 128; o > 0; o >>= 1) { if (t < o) sd[t] += sd[t+o]; __syncthreads(); }
  double S = sd[0]; __syncthreads();
  sd[t] = q; __syncthreads();
  for (int o = 128; o > 0; o >>= 1) { if (t < o) sd[t] += sd[t+o]; __syncthreads(); }
  if (t == 0) {
    double m = S / count;
    double v = sd[0] / count - m*m; if (v < 0.0) v = 0.0;
    double inv = 1.0 / sqrt(v + 1e-5);
    out[ch]       = (float)(gamma[ch] * inv);
    out[nch + ch] = (float)(beta[ch] - m * gamma[ch] * inv);
  }
}

__global__ __launch_bounds__(256) void k_bnfin_part(const float* __restrict__ pS,
    const float* __restrict__ pQ, int nparts, int nch, double count,
    const float* __restrict__ gamma, const float* __restrict__ beta, float* __restrict__ out)
{
  __shared__ double sd[256];
  int ch = blockIdx.x, t = threadIdx.x;
  double s = 0.0, q = 0.0;
  for (int i = t; i < nparts; i += 256) { s += pS[(size_t)i*nch + ch]; q += pQ[(size_t)i*nch + ch]; }
  sd[t] = s; __syncthreads();
  for (int o = 128; o > 0; o >>= 1) { if (t < o) sd[t] += sd[t+o]; __syncthreads(); }
  double S = sd[0]; __syncthreads();
  sd[t] = q; __syncthreads();
  for (int o = 128; o > 0; o >>= 1) { if (t < o) sd[t] += sd[t+o]; __syncthreads(); }
  if (t == 0) {
    double m = S / count;
    double v = sd[0] / count - m*m; if (v < 0.0) v = 0.0;
    double inv = 1.0 / sqrt(v + 1e-5);
    out[ch]       = (float)(gamma[ch] * inv);
    out[nch + ch] = (float)(beta[ch] - m * gamma[ch] * inv);
  }
}

// ---------------- patch path: z1r = V[n] @ xp-patch + c2 ----------------
__global__ __launch_bounds__(256) void k_patch(const float* __restrict__ xp,
    const float* __restrict__ V, const float* __restrict__ c2,
    float* __restrict__ z1r, float* __restrict__ pS, float* __restrict__ pQ)
{
  __shared__ float sx[8][512];
  __shared__ float aS[32], aQ[32];
  int t = threadIdx.x;
  int r0 = blockIdx.x * 8;
  for (int c = t; c < 1024; c += 256) {
    int row = c >> 7, cg = c & 127;
    *(float4*)&sx[row][cg*4] = *(const float4*)&xp[(size_t)(r0+row)*512 + cg*4];
  }
  if (t < 32) { aS[t] = 0.f; aQ[t] = 0.f; }
  __syncthreads();
  float vreg[2][16]; float cc[2]; int nn_[2], oo[2];
#pragma unroll
  for (int h = 0; h < 2; ++h) {
    int o = t + h*256;
    oo[h] = o;
    int n = o >> 4, p = o & 15;
    nn_[h] = n;
#pragma unroll
    for (int qg = 0; qg < 4; ++qg) {
      float4 v4 = *(const float4*)&V[(size_t)n*256 + p*16 + qg*4];
      vreg[h][qg*4+0]=v4.x; vreg[h][qg*4+1]=v4.y; vreg[h][qg*4+2]=v4.z; vreg[h][qg*4+3]=v4.w;
    }
    cc[h] = c2[o];
  }
  float sum[2] = {0.f,0.f}, sq[2] = {0.f,0.f};
  for (int row = 0; row < 8; ++row) {
#pragma unroll
    for (int h = 0; h < 2; ++h) {
      const float* xr = &sx[row][nn_[h]*16];
      float val = cc[h];
#pragma unroll
      for (int qq = 0; qq < 16; ++qq) val += vreg[h][qq] * xr[qq];
      z1r[(size_t)(r0+row)*512 + oo[h]] = val;
      sum[h] += val; sq[h] += val*val;
    }
  }
#pragma unroll
  for (int h = 0; h < 2; ++h) {
    atomicAdd(&aS[nn_[h]], sum[h]);
    atomicAdd(&aQ[nn_[h]], sq[h]);
  }
  __syncthreads();
  if (t < 32) { pS[(size_t)blockIdx.x*32 + t] = aS[t]; pQ[(size_t)blockIdx.x*32 + t] = aQ[t]; }
}

// ---------------- TopKFreq ----------------
__global__ void k_att(const float* __restrict__ z1, const float* __restrict__ z1r,
    const float* __restrict__ bn2, const float* __restrict__ u, const float* __restrict__ fcb,
    float* __restrict__ att)
{
  int r = blockIdx.x*4 + (threadIdx.x >> 6);
  int lane = threadIdx.x & 63;
  const float* z1p = z1 + (size_t)r*512;
  const float* zrp = z1r + (size_t)r*512;
  float s = 0.f;
#pragma unroll
  for (int h = 0; h < 2; ++h) {
    int i = lane*4 + h*256;
    int n = i >> 4;
    float a2n = bn2[n], c2n = bn2[32+n];
    float4 zr = *(const float4*)&zrp[i];
    float4 zv = *(const float4*)&z1p[i];
    float4 uv = *(const float4*)&u[i];
    s += (zv.x + gelu_f(a2n*zr.x + c2n)) * uv.x;
    s += (zv.y + gelu_f(a2n*zr.y + c2n)) * uv.y;
    s += (zv.z + gelu_f(a2n*zr.z + c2n)) * uv.z;
    s += (zv.w + gelu_f(a2n*zr.w + c2n)) * uv.w;
  }
  s = wred(s);
  if (lane == 0) att[r] = s + fcb[0];
}

__global__ __launch_bounds__(1024) void k_tf(const float* __restrict__ att,
    const float* __restrict__ pg, const float* __restrict__ pb,
    const float* __restrict__ pwc, const float* __restrict__ pbc,
    const float* __restrict__ pfb, float* __restrict__ a1, float* __restrict__ a2)
{
  __shared__ double sd[1024];
  __shared__ float sh[4];
  const int t = threadIdx.x;
  float g = pg[0], b = pb[0], wc = pwc[0], bc = pbc[0], fb = pfb[0];
  double s = 0.0, q = 0.0;
  for (int i = t; i < BD; i += 1024) { double v = att[i]; s += v; q += v*v; }
  sd[t] = s; __syncthreads();
  for (int o = 512; o > 0; o >>= 1) { if (t < o) sd[t] += sd[t+o]; __syncthreads(); }
  double S1 = sd[0]; __syncthreads();
  sd[t] = q; __syncthreads();
  for (int o = 512; o > 0; o >>= 1) { if (t < o) sd[t] += sd[t+o]; __syncthreads(); }
  if (t == 0) {
    double m = S1 / 14336.0;
    double v = sd[0] / 14336.0 - m*m; if (v < 0.0) v = 0.0;
    sh[0] = (float)m; sh[1] = (float)(1.0 / sqrt(v + 1e-5));
  }
  __syncthreads();
  float m1 = sh[0], i1 = sh[1];
  s = 0.0; q = 0.0;
  for (int i = t; i < BD; i += 1024) {
    float v = att[i];
    float an = (v - m1) * i1 * g + b;
    float av = sigm_f(gelu_f(an) * wc + bc);
    a1[i] = av;
    float t2 = av * (v - fb) + fb;
    s += t2; q += (double)t2 * t2;
  }
  __syncthreads();
  sd[t] = s; __syncthreads();
  for (int o = 512; o > 0; o >>= 1) { if (t < o) sd[t] += sd[t+o]; __syncthreads(); }
  double S2 = sd[0]; __syncthreads();
  sd[t] = q; __syncthreads();
  for (int o = 512; o > 0; o >>= 1) { if (t < o) sd[t] += sd[t+o]; __syncthreads(); }
  if (t == 0) {
    double m = S2 / 14336.0;
    double v = sd[0] / 14336.0 - m*m; if (v < 0.0) v = 0.0;
    sh[2] = (float)m; sh[3] = (float)(1.0 / sqrt(v + 1e-5));
  }
  __syncthreads();
  float m2 = sh[2], i2 = sh[3];
  for (int i = t; i < BD; i += 1024) {
    float t2 = a1[i] * (att[i] - fb) + fb;
    float an = (t2 - m2) * i2 * g + b;
    a2[i] = sigm_f(gelu_f(an) * wc + bc);
  }
}

// ---------------- elementwise stats passes (float4) ----------------
__global__ void k_statsA(const float* __restrict__ z1, const float* __restrict__ z1r,
    const float* __restrict__ bn2, const float* __restrict__ a1,
    float* __restrict__ rs, float* __restrict__ rq)
{
  int r = blockIdx.x*4 + (threadIdx.x >> 6);
  int lane = threadIdx.x & 63;
  float av = a1[r];
  const float* z1p = z1 + (size_t)r*512;
  const float* zrp = z1r + (size_t)r*512;
  float s = 0.f, q = 0.f;
#pragma unroll
  for (int h = 0; h < 2; ++h) {
    int i = lane*4 + h*256;
    int n = i >> 4;
    float a2n = bn2[n], c2n = bn2[32+n];
    float4 zr = *(const float4*)&zrp[i];
    float4 zv = *(const float4*)&z1p[i];
    float A0 = (zv.x + gelu_f(a2n*zr.x + c2n)) * av;
    float A1 = (zv.y + gelu_f(a2n*zr.y + c2n)) * av;
    float A2 = (zv.z + gelu_f(a2n*zr.z + c2n)) * av;
    float A3 = (zv.w + gelu_f(a2n*zr.w + c2n)) * av;
    s += A0+A1+A2+A3; q += A0*A0+A1*A1+A2*A2+A3*A3;
  }
  s = wred(s); q = wred(q);
  if (lane == 0) { rs[r] = s; rq[r] = q; }
}

__global__ void k_statsC(const float* __restrict__ z1, const float* __restrict__ z1r,
    const float* __restrict__ bn2, const float* __restrict__ a1,
    const float* __restrict__ bn3, const float* __restrict__ cw, const float* __restrict__ cb,
    float* __restrict__ rs, float* __restrict__ rq)
{
  int r = blockIdx.x*4 + (threadIdx.x >> 6);
  int lane = threadIdx.x & 63;
  int d = r % 7;
  float av = a1[r];
  float b3a = bn3[d], b3c = bn3[7+d], wv = cw[d], bv = cb[d];
  const float* z1p = z1 + (size_t)r*512;
  const float* zrp = z1r + (size_t)r*512;
  float s = 0.f, q = 0.f;
#pragma unroll
  for (int h = 0; h < 2; ++h) {
    int i = lane*4 + h*256;
    int n = i >> 4;
    float a2n = bn2[n], c2n = bn2[32+n];
    float4 zr = *(const float4*)&zrp[i];
    float4 zv = *(const float4*)&z1p[i];
#pragma unroll
    for (int e = 0; e < 4; ++e) {
      float ze = (e==0?zr.x:e==1?zr.y:e==2?zr.z:zr.w);
      float z1e = (e==0?zv.x:e==1?zv.y:e==2?zv.z:zv.w);
      float A = (z1e + gelu_f(a2n*ze + c2n)) * av;
      float C = wv*gelu_f(b3a*A + b3c) + bv;
      s += C; q += C*C;
    }
  }
  s = wred(s); q = wred(q);
  if (lane == 0) { rs[r] = s; rq[r] = q; }
}

__global__ void k_final(const float* __restrict__ z1, const float* __restrict__ z1r,
    const float* __restrict__ bn2, const float* __restrict__ a1, const float* __restrict__ a2,
    const float* __restrict__ bn3, const float* __restrict__ bn4,
    const float* __restrict__ cw, const float* __restrict__ cb,
    float* __restrict__ zf, float* __restrict__ rs, float* __restrict__ rq)
{
  int r = blockIdx.x*4 + (threadIdx.x >> 6);
  int lane = threadIdx.x & 63;
  int d = r % 7;
  float av = a1[r], a2v = a2[r];
  float b3a = bn3[d], b3c = bn3[7+d], b4a = bn4[d], b4c = bn4[7+d];
  float wv = cw[d], bv = cb[d];
  const float* z1p = z1 + (size_t)r*512;
  const float* zrp = z1r + (size_t)r*512;
  float* zfp = zf + (size_t)r*512;
  float s = 0.f, q = 0.f;
#pragma unroll
  for (int h = 0; h < 2; ++h) {
    int i = lane*4 + h*256;
    int n = i >> 4;
    float a2n = bn2[n], c2n = bn2[32+n];
    float4 zr = *(const float4*)&zrp[i];
    float4 zv = *(const float4*)&z1p[i];
    float4 ov;
#pragma unroll
    for (int e = 0; e < 4; ++e) {
      float ze = (e==0?zr.x:e==1?zr.y:e==2?zr.z:zr.w);
      float z1e = (e==0?zv.x:e==1?zv.y:e==2?zv.z:zv.w);
      float z1v = z1e * av;
      float z2v = gelu_f(a2n*ze + c2n) * av;
      float A = z1v + z2v;
      float C = wv*gelu_f(b3a*A + b3c) + bv;
      float inter = gelu_f(b4a*C + b4c) * a2v;
      float z1n = z1v*inter + z2v;
      float z2n = z2v*inter + z1n;
      float zfv = z1n*z2n + z1n + z2n;
      (e==0?ov.x:e==1?ov.y:e==2?ov.z:ov.w) = zfv;
      s += zfv; q += zfv*zfv;
    }
    *(float4*)&zfp[i] = ov;
  }
  s = wred(s); q = wred(q);
  if (lane == 0) { rs[r] = s; rq[r] = q; }
}

// ---------------- output: fc2 + bias + z_res + transpose ----------------
__global__ __launch_bounds__(256) void k_out(const float* __restrict__ h2,
    const float* __restrict__ bn6, const float* __restrict__ w2, const float* __restrict__ b2,
    const float* __restrict__ zres, float* __restrict__ out)
{
  int idx = blockIdx.x*256 + threadIdx.x;
  int r = idx / 96, o = idx - r*96;
  int d = r % 7, b = r / 7;
  float a6 = bn6[d], c6 = bn6[7+d];
  const float* hp = h2 + (size_t)r*48;
  const float* wp = w2 + o*48;
  float s = 0.f;
#pragma unroll
  for (int j4 = 0; j4 < 12; ++j4) {
    float4 hv = *(const float4*)&hp[j4*4];
    float4 wv = *(const float4*)&wp[j4*4];
    s += (a6*hv.x + c6)*wv.x + (a6*hv.y + c6)*wv.y
       + (a6*hv.z + c6)*wv.z + (a6*hv.w + c6)*wv.w;
  }
  out[(size_t)b*672 + o*7 + d] = s + b2[o] + zres[(size_t)r*96 + o];
}

// ================= host =================
extern "C" void kernel_launch(void* const* d_in, const int* in_sizes, int n_in,
                              void* d_out, int out_size, void* d_ws, size_t ws_size,
                              hipStream_t stream) {
  const float* x          = (const float*)d_in[0];
  const float* dctconv_w  = (const float*)d_in[1];
  const float* dctconv_b  = (const float*)d_in[2];
  const float* dctnorm_g  = (const float*)d_in[3];
  const float* dctnorm_b  = (const float*)d_in[4];
  const float* threshold  = (const float*)d_in[5];
  const float* embed_W    = (const float*)d_in[6];
  const float* embed_b    = (const float*)d_in[7];
  const float* linres_W   = (const float*)d_in[8];
  const float* linres_b   = (const float*)d_in[9];
  const float* depth1_w   = (const float*)d_in[10];
  const float* depth1_b   = (const float*)d_in[11];
  const float* depthnorm_g= (const float*)d_in[12];
  const float* depthnorm_b= (const float*)d_in[13];
  const float* tf_fc_w    = (const float*)d_in[14];
  const float* tf_fc_b    = (const float*)d_in[15];
  const float* tf_norm_g  = (const float*)d_in[16];
  const float* tf_norm_b  = (const float*)d_in[17];
  const float* tf_conv_w  = (const float*)d_in[18];
  const float* tf_conv_b  = (const float*)d_in[19];
  const float* mlp_w1     = (const float*)d_in[20];
  const float* mlp_b1     = (const float*)d_in[21];
  const float* mlp_w2     = (const float*)d_in[22];
  const float* mlp_b2     = (const float*)d_in[23];
  const float* mlpnorm_g  = (const float*)d_in[24];
  const float* mlpnorm_b  = (const float*)d_in[25];
  float* out = (float*)d_out;
  float* ws  = (float*)d_ws;

  float* XP   = ws + F_XP;
  float* ZG   = ws + F_ZG;        // z1r f32 (after GEMM2); GH/GL planes before
  ushort* ZGH = (ushort*)(ws + F_ZG);
  ushort* ZGL = ZGH + (size_t)BD*512;
  float* Z1   = ws + F_Z1;
  ushort* B1H = (ushort*)(ws + F_CLK);
  ushort* B1L = B1H + 512*512;
  // upper half of CLK region (B1 planes use only 131072 of 262144 floats): W split planes
  ushort* W2H = (ushort*)(ws + F_CLK + 131072);
  ushort* W2L = W2H + 96*512;
  ushort* W1H = W2L + 96*512;
  ushort* W1L = W1H + 48*512;
  ushort* B2H = (ushort*)(ws + F_MKL);
  ushort* B2L = B2H + 512*512;
  float* U    = ws + F_U;
  float* CSUM = ws + F_CSUM;
  float* CSTp = ws + F_CST;
  float* Vp   = ws + F_V;
  float* C2p  = ws + F_C2;
  float* ZRES = ws + F_ZRES;
  float* H2p  = ws + F_H2;
  float* EN   = ws + F_EN;
  float* NEp  = ws + F_NE;
  float* ATTp = ws + F_ATT;
  float* A1p  = ws + F_A1;
  float* A2p  = ws + F_A2;
  float* RS   = ws + F_RS;
  float* RQ   = ws + F_RQ;
  float* PS   = ws + F_PS;
  float* PQ   = ws + F_PQ;
  float* BN0  = ws + F_BN;        // a[7], c[7]
  float* BN2  = ws + F_BN + 16;   // a[32], c[32]
  float* BN3  = ws + F_BN + 80;
  float* BN4  = ws + F_BN + 96;
  float* BN5  = ws + F_BN + 112;
  float* BN6  = ws + F_BN + 128;
  float* THRp = ws + F_THR;

  k_gen_b<<<512, 256, 0, stream>>>(B1H, B1L, B2H, B2L);
  k_ucsum2<<<2, 256, 0, stream>>>(U, CSUM, tf_fc_w);
  k_w2<<<96, 256, 0, stream>>>(linres_W, linres_b, embed_W, embed_b, W2H, W2L, CSTp);
  k_splitw<<<96, 256, 0, stream>>>(mlp_w1, W1H, W1L, 48*512);
  k_v<<<32, 256, 0, stream>>>(embed_W, embed_b, depth1_w, depth1_b, Vp, C2p);
  k_transpose<<<2048, 256, 0, stream>>>(x, XP, EN);
  k_ne<<<8, 256, 0, stream>>>(EN, NEp);
  k_thr<<<1, 1024, 0, stream>>>(NEp, threshold, THRp);
  hipMemsetAsync(RS, 0, 2*BD*sizeof(float), stream);
  // GEMM1: z_dct -> masked dctconv -> gelu -> GH/GL planes (+ row stats)
  k_mfma<2><<<dim3(224,2), 512, 0, stream>>>(XP, nullptr, nullptr, B1H, B1L,
      nullptr, ZGH, ZGL, nullptr, nullptr, nullptr, dctconv_w, dctconv_b,
      NEp, THRp, RS, RQ);
  k_bnfin_rows<<<7, 256, 0, stream>>>(RS, RQ, 7, BD, 1048576.0, dctnorm_g, dctnorm_b, BN0);
  // GEMM2: z1 = BN(g) @ M + x_res  (BN folded via column sums)
  k_mfma<1><<<dim3(224,2), 512, 0, stream>>>(nullptr, ZGH, ZGL, B2H, B2L,
      Z1, nullptr, nullptr, BN0, CSUM, XP, dctconv_w, dctconv_b,
      nullptr, nullptr, nullptr, nullptr);
  k_patch<<<1792, 256, 0, stream>>>(XP, Vp, C2p, ZG, PS, PQ);
  k_bnfin_part<<<32, 256, 0, stream>>>(PS, PQ, 1792, 32, 229376.0, depthnorm_g, depthnorm_b, BN2);
  // ZRES = XP @ W2^T + cst   (MFMA bf16-split)
  k_mfma_nt<96,0><<<224, 256, 0, stream>>>(XP, W2H, W2L, CSTp, ZRES,
      nullptr, nullptr, nullptr, nullptr);
  k_att<<<3584, 256, 0, stream>>>(Z1, ZG, BN2, U, tf_fc_b, ATTp);
  k_tf<<<1, 1024, 0, stream>>>(ATTp, tf_norm_g, tf_norm_b, tf_conv_w, tf_conv_b, tf_fc_b, A1p, A2p);
  k_statsA<<<3584, 256, 0, stream>>>(Z1, ZG, BN2, A1p, RS, RQ);
  k_bnfin_rows<<<7, 256, 0, stream>>>(RS, RQ, 7, BD, 1048576.0, dctnorm_g, dctnorm_b, BN3);
  k_statsC<<<3584, 256, 0, stream>>>(Z1, ZG, BN2, A1p, BN3, dctconv_w, dctconv_b, RS, RQ);
  k_bnfin_rows<<<7, 256, 0, stream>>>(RS, RQ, 7, BD, 1048576.0, dctnorm_g, dctnorm_b, BN4);
  k_final<<<3584, 256, 0, stream>>>(Z1, ZG, BN2, A1p, A2p, BN3, BN4, dctconv_w, dctconv_b, XP, RS, RQ);
  k_bnfin_rows<<<7, 256, 0, stream>>>(RS, RQ, 7, BD, 1048576.0, dctnorm_g, dctnorm_b, BN5);
  // MLP fc1: h2 = gelu(v)*v with v = gelu(BN5(zf)) @ w1^T + b1   (MFMA bf16-split, fused stats)
  k_mfma_nt<48,1><<<224, 256, 0, stream>>>(XP, W1H, W1L, mlp_b1, H2p,
      BN5, BN5+7, RS, RQ);
  k_bnfin_rows<<<7, 256, 0, stream>>>(RS, RQ, 7, BD, 98304.0, mlpnorm_g, mlpnorm_b, BN6);
  k_out<<<5376, 256, 0, stream>>>(H2p, BN6, mlp_w2, mlp_b2, ZRES, out);
}

// Round 9
// 356.036 us; speedup vs baseline: 2.3296x; 1.0668x over previous
//
#include <hip/hip_runtime.h>
#include <math.h>

#define BB 2048
#define LL 512
#define DD 7
#define BD 14336   // BB*DD

// ---------------- ws layout (floats) ----------------
constexpr size_t F_XP   = 0;                          // xp, later ZFH/ZFL planes
constexpr size_t F_ZG   = F_XP  + (size_t)BD*512;     // ZGH/ZGL planes -> z1r f32
constexpr size_t F_Z1   = F_ZG  + (size_t)BD*512;     // z1
constexpr size_t F_CLK  = F_Z1  + (size_t)BD*512;     // B1H/B1L (fills region exactly)
constexpr size_t F_MKL  = F_CLK + 512*512;            // B2H/B2L (fills region exactly)
constexpr size_t F_U    = F_MKL + 512*512;
constexpr size_t F_CSUM = F_U + 512;
constexpr size_t F_W2   = F_CSUM + 512;               // W2H/W2L ushort planes (exact fit)
constexpr size_t F_CST  = F_W2 + 96*512;
constexpr size_t F_V    = F_CST + 96;                 // 32x16x16
constexpr size_t F_C2   = F_V + 32*256;               // 32x16
constexpr size_t F_ZRES = F_C2 + 512;                 // BD x 96
constexpr size_t F_H2   = F_ZRES + (size_t)BD*96;     // BD x 48
constexpr size_t F_EN   = F_H2 + (size_t)BD*48;       // (unused)
constexpr size_t F_NE   = F_EN + BD;
constexpr size_t F_ATT  = F_NE + BD;
constexpr size_t F_A1   = F_ATT + BD;
constexpr size_t F_A2   = F_A1 + BD;
constexpr size_t F_RS   = F_A2 + BD;
constexpr size_t F_RQ   = F_RS + BD;                  // adjacent to F_RS (one memset)
constexpr size_t F_PS   = F_RQ + BD;                  // 1792 x 32
constexpr size_t F_PQ   = F_PS + 1792*32;
constexpr size_t F_BN   = F_PQ + 1792*32;             // bn affine params
constexpr size_t F_THR  = F_BN + 256;
constexpr size_t F_W1   = F_THR + 16;                 // W1H/W1L ushort planes (24576 floats)

typedef __attribute__((ext_vector_type(8))) short bf8;
typedef __attribute__((ext_vector_type(4))) short sh4;
typedef __attribute__((ext_vector_type(4))) float f4;

__device__ __forceinline__ float gelu_f(float x) {
  return 0.5f * x * (1.0f + erff(x * 0.70710678118654752440f));
}
__device__ __forceinline__ float sigm_f(float x) {
  return 1.0f / (1.0f + expf(-x));
}
__device__ __forceinline__ float wred(float v) {
#pragma unroll
  for (int o = 32; o > 0; o >>= 1) v += __shfl_down(v, o);
  return v;
}
__device__ __forceinline__ unsigned bfh_u(float v) {
  unsigned u = __float_as_uint(v);
  return (u + 0x7FFFu + ((u >> 16) & 1u)) >> 16;
}
__device__ __forceinline__ float bf2f(unsigned h) { return __uint_as_float(h << 16); }

#define PI1024 0.00306796157577128218f   // pi/1024

// ---------------- fused setup: gen_b + ucsum + v + splitw + w2 ----------------
// blocks 0..511: B planes (exact int phase reduction, f32 cos)
// 512..513: u/csum; 514..545: V; 546..641: split mlp_w1; 642..737: W2 fold
__global__ __launch_bounds__(256) void k_setup(
    ushort* __restrict__ B1H, ushort* __restrict__ B1L,
    ushort* __restrict__ B2H, ushort* __restrict__ B2L,
    float* __restrict__ u, float* __restrict__ csum, const float* __restrict__ wf,
    const float* __restrict__ eW, const float* __restrict__ eb,
    const float* __restrict__ dw, const float* __restrict__ db,
    float* __restrict__ V, float* __restrict__ c2,
    const float* __restrict__ mlpw1, ushort* __restrict__ W1H, ushort* __restrict__ W1L,
    const float* __restrict__ linW, const float* __restrict__ linb,
    ushort* __restrict__ W2H, ushort* __restrict__ W2L, float* __restrict__ cst)
{
  __shared__ float sW[768];
  __shared__ float sb[48];
  __shared__ float rbuf[256];
  const int bid = blockIdx.x, t = threadIdx.x;
  if (bid < 512) {
    int c = bid;
    for (int r = t; r < 512; r += 256) {
      int n1 = ((2*r + 1) * c) & 2047;
      float v1 = 2.0f * cosf((float)n1 * PI1024);
      unsigned h = bfh_u(v1);
      B1H[(size_t)c*512 + r] = (ushort)h;
      B1L[(size_t)c*512 + r] = (ushort)bfh_u(v1 - bf2f(h));
      int n2 = ((2*c + 1) * r) & 2047;
      float v2 = cosf((float)n2 * PI1024) * (r == 0 ? (1.0f/1024.0f) : (1.0f/512.0f));
      h = bfh_u(v2);
      B2H[(size_t)c*512 + r] = (ushort)h;
      B2L[(size_t)c*512 + r] = (ushort)bfh_u(v2 - bf2f(h));
    }
  } else if (bid < 514) {
    int l = (bid - 512)*256 + t;
    if (l < 512) {
      double th2 = 3.14159265358979323846 * (double)(2*l + 1) / 2048.0;
      double s = (l & 1) ? -1.0 : 1.0;
      double S = 0.5*s/tan(th2) - 0.5;
      csum[l] = (float)(1.0/1024.0 + S/512.0);
      double uu = (double)wf[0] * 45.25483399593904156 / 1024.0;
      for (int k = 1; k < 5; ++k)
        uu += (double)wf[k] * 32.0 * cos(3.14159265358979323846*(l+0.5)*k/512.0) / 512.0;
      u[l] = (float)uu;
    }
  } else if (bid < 546) {
    int n = bid - 514;
    int p = t >> 4, q = t & 15;
    float s = 0.f;
#pragma unroll
    for (int j = 0; j < 3; ++j) s += eW[(p*3+j)*16 + q] * dw[n*3+j];
    V[(size_t)n*256 + p*16 + q] = s;
    if (q == 0) {
      float c = 0.f;
#pragma unroll
      for (int j = 0; j < 3; ++j) c += eb[p*3+j] * dw[n*3+j];
      c2[n*16+p] = c + db[n];
    }
  } else if (bid < 642) {
    int i = (bid - 546)*256 + t;
    if (i < 48*512) {
      float v = mlpw1[i];
      unsigned hb = bfh_u(v);
      W1H[i] = (ushort)hb;
      W1L[i] = (ushort)bfh_u(v - bf2f(hb));
    }
  } else {
    int o = bid - 642;
    for (int i = t; i < 768; i += 256) sW[i] = eW[i];
    if (t < 48) sb[t] = eb[t];
    __syncthreads();
    const float* lw = linW + (size_t)o * 1536;
    for (int i = t; i < 512; i += 256) {
      int n = i >> 4, p = i & 15;
      float s = 0.f;
      const float* l2 = lw + n*48;
#pragma unroll 8
      for (int m = 0; m < 48; ++m) s += l2[m] * sW[m*16 + p];
      unsigned hb = bfh_u(s);
      W2H[(size_t)o*512 + i] = (ushort)hb;
      W2L[(size_t)o*512 + i] = (ushort)bfh_u(s - bf2f(hb));
    }
    float c = 0.f;
    for (int i = t; i < 1536; i += 256) c += lw[i] * sb[i % 48];
    rbuf[t] = c; __syncthreads();
    for (int off = 128; off > 0; off >>= 1) { if (t < off) rbuf[t] += rbuf[t+off]; __syncthreads(); }
    if (t == 0) cst[o] = rbuf[0] + linb[o];
  }
}

// ---------------- transpose [B,L,D] -> [B*D, L] + fused energy + median -> ne ----------------
__global__ __launch_bounds__(256) void k_transpose(const float* __restrict__ x,
                                                   float* __restrict__ xp,
                                                   float* __restrict__ ne) {
  __shared__ float s[3584];
  __shared__ float sEn[7];
  int b = blockIdx.x;
  const float* src = x + (size_t)b*3584;
  for (int c = threadIdx.x; c < 896; c += 256) {
    float4 v = *(const float4*)&src[c*4];
    s[c*4+0]=v.x; s[c*4+1]=v.y; s[c*4+2]=v.z; s[c*4+3]=v.w;
  }
  __syncthreads();
  for (int c = threadIdx.x; c < 896; c += 256) {
    int d = c >> 7, cg = c & 127;
    float4 v;
    v.x = s[(cg*4+0)*7 + d]; v.y = s[(cg*4+1)*7 + d];
    v.z = s[(cg*4+2)*7 + d]; v.w = s[(cg*4+3)*7 + d];
    *(float4*)&xp[((size_t)b*7 + d)*512 + cg*4] = v;
  }
  int t = threadIdx.x;
  if (t < 224) {
    int d = t >> 5, c0 = (t & 31) * 16;
    double ss = 0.0, qq = 0.0;
    for (int l = c0; l < c0 + 16; ++l) {
      double v = s[l*7 + d];
      ss += v; qq += v*v;
    }
#pragma unroll
    for (int o = 16; o > 0; o >>= 1) {
      ss += __shfl_down(ss, o, 32);
      qq += __shfl_down(qq, o, 32);
    }
    if ((t & 31) == 0) sEn[d] = (float)(1024.0*qq + 2.0*ss*ss);
  }
  __syncthreads();
  if (t == 0) {
    float e[7], s7[7];
#pragma unroll
    for (int d = 0; d < 7; ++d) { e[d] = sEn[d]; s7[d] = e[d]; }
#pragma unroll
    for (int i = 1; i < 7; ++i) {
      float key = s7[i]; int j = i-1;
      while (j >= 0 && s7[j] > key) { s7[j+1] = s7[j]; --j; }
      s7[j+1] = key;
    }
    float med = s7[3] + 1e-6f;
#pragma unroll
    for (int d = 0; d < 7; ++d) ne[b*7 + d] = e[d] / med;
  }
}

// ---------------- MFMA bf16-split GEMM: C[M,512] = A[M,512] @ B[512,512] ----------------
// BM=128, BN=128, BK=32; 256 threads = 4 waves, each 64x64 (4x4 frags of 16x16x32);
// 3-term bf16 split. Grid (112, 4).
// MODE 2: A from f32 (split at stage); epilogue g=gelu(acc*mask*w+b) -> GH/GL planes + row stats
// MODE 1: A from GH/GL planes; epilogue z1 = aR*acc + cR*csum + xp*w + b -> f32
template<int MODE>
__global__ __launch_bounds__(256) void k_mfma(
    const float* __restrict__ Af32,
    const ushort* __restrict__ AHg, const ushort* __restrict__ ALg,
    const ushort* __restrict__ BHg, const ushort* __restrict__ BLg,
    float* __restrict__ z1out, ushort* __restrict__ GH, ushort* __restrict__ GL,
    const float* __restrict__ bnac, const float* __restrict__ csum,
    const float* __restrict__ xp,
    const float* __restrict__ cw, const float* __restrict__ cb,
    const float* __restrict__ ne, const float* __restrict__ thr,
    float* __restrict__ rs, float* __restrict__ rq)
{
  __shared__ ushort AhS[128*40], AlS[128*40];
  __shared__ ushort BhS[128*40], BlS[128*40];
  const int t = threadIdx.x;
  const int lane = t & 63, w = t >> 6;
  const int l15 = lane & 15, l4 = lane >> 4;
  const int wr = (w & 1)*64, wc = (w >> 1)*64;
  const int r0 = blockIdx.x * 128, c0 = blockIdx.y * 128;

  f4 acc[4][4];
#pragma unroll
  for (int i = 0; i < 4; ++i)
#pragma unroll
    for (int j = 0; j < 4; ++j) acc[i][j] = (f4){0.f,0.f,0.f,0.f};

  const int arow = t >> 1, ak0 = (t & 1) * 16;   // 128 rows, 2 thr/row, 16 elems each

  for (int kt = 0; kt < 512; kt += 32) {
    // ---- stage A (128x32) ----
    if (MODE == 2) {
#pragma unroll
      for (int g = 0; g < 2; ++g) {
        const float* src = Af32 + (size_t)(r0+arow)*512 + kt + ak0 + g*8;
        float4 v0 = *(const float4*)src;
        float4 v1 = *(const float4*)(src+4);
        float va[8] = {v0.x,v0.y,v0.z,v0.w,v1.x,v1.y,v1.z,v1.w};
        bf8 hv, lv;
#pragma unroll
        for (int j = 0; j < 8; ++j) {
          unsigned hb = bfh_u(va[j]);
          hv[j] = (short)hb;
          lv[j] = (short)bfh_u(va[j] - bf2f(hb));
        }
        *(bf8*)&AhS[arow*40 + ak0 + g*8] = hv;
        *(bf8*)&AlS[arow*40 + ak0 + g*8] = lv;
      }
    } else {
#pragma unroll
      for (int g = 0; g < 2; ++g) {
        *(bf8*)&AhS[arow*40 + ak0 + g*8] = *(const bf8*)&AHg[(size_t)(r0+arow)*512 + kt + ak0 + g*8];
        *(bf8*)&AlS[arow*40 + ak0 + g*8] = *(const bf8*)&ALg[(size_t)(r0+arow)*512 + kt + ak0 + g*8];
      }
    }
    // ---- stage B (128 cols x 32 k, transposed source) ----
#pragma unroll
    for (int g = 0; g < 2; ++g) {
      *(bf8*)&BhS[arow*40 + ak0 + g*8] = *(const bf8*)&BHg[(size_t)(c0+arow)*512 + kt + ak0 + g*8];
      *(bf8*)&BlS[arow*40 + ak0 + g*8] = *(const bf8*)&BLg[(size_t)(c0+arow)*512 + kt + ak0 + g*8];
    }
    __syncthreads();
    // ---- compute ----
    bf8 ah[4], al[4], bh[4], bl[4];
#pragma unroll
    for (int fr = 0; fr < 4; ++fr) {
      int off = (wr + fr*16 + l15)*40 + l4*8;
      ah[fr] = *(const bf8*)&AhS[off];
      al[fr] = *(const bf8*)&AlS[off];
    }
#pragma unroll
    for (int fc = 0; fc < 4; ++fc) {
      int off = (wc + fc*16 + l15)*40 + l4*8;
      bh[fc] = *(const bf8*)&BhS[off];
      bl[fc] = *(const bf8*)&BlS[off];
    }
#pragma unroll
    for (int fr = 0; fr < 4; ++fr)
#pragma unroll
      for (int fc = 0; fc < 4; ++fc) {
        acc[fr][fc] = __builtin_amdgcn_mfma_f32_16x16x32_bf16(ah[fr], bh[fc], acc[fr][fc], 0, 0, 0);
        acc[fr][fc] = __builtin_amdgcn_mfma_f32_16x16x32_bf16(ah[fr], bl[fc], acc[fr][fc], 0, 0, 0);
        acc[fr][fc] = __builtin_amdgcn_mfma_f32_16x16x32_bf16(al[fr], bh[fc], acc[fr][fc], 0, 0, 0);
      }
    __syncthreads();
  }

  // ---- epilogue ----
  const float thv = (MODE == 2) ? thr[0] : 0.f;
#pragma unroll
  for (int fr = 0; fr < 4; ++fr)
#pragma unroll
    for (int j = 0; j < 4; ++j) {
      const int r = r0 + wr + fr*16 + l4*4 + j;
      const int d = r % 7;
      if (MODE == 1) {
        const float aR = bnac[d], cR = bnac[7+d], wv = cw[d], bvv = cb[d];
#pragma unroll
        for (int fc = 0; fc < 4; ++fc) {
          int col = c0 + wc + fc*16 + l15;
          float val = acc[fr][fc][j];
          z1out[(size_t)r*512 + col] = aR*val + cR*csum[col] + xp[(size_t)r*512 + col]*wv + bvv;
        }
      } else {
        float m = (ne[r] > thv) ? 1.0f : 0.0f;
        float wm = cw[d] * m, bvv = cb[d];
        float s = 0.f, q = 0.f;
#pragma unroll
        for (int fc = 0; fc < 4; ++fc) {
          int col = c0 + wc + fc*16 + l15;
          float g = gelu_f(acc[fr][fc][j]*wm + bvv);
          unsigned hb = bfh_u(g);
          GH[(size_t)r*512 + col] = (ushort)hb;
          GL[(size_t)r*512 + col] = (ushort)bfh_u(g - bf2f(hb));
          s += g; q += g*g;
        }
#pragma unroll
        for (int off = 8; off > 0; off >>= 1) {
          s += __shfl_down(s, off, 16);
          q += __shfl_down(q, off, 16);
        }
        if (l15 == 0) { atomicAdd(&rs[r], s); atomicAdd(&rq[r], q); }
      }
    }
}

// ---------------- MFMA bf16-split NT GEMM: out[M,NCOLS] = A[M,512] @ W[NCOLS,512]^T + bias ----
// BM=64 (4 waves x 16 rows), all NCOLS/16 col-frags per wave, BK=32, 3-term split.
// MODE 0: A from f32, plain store (ZRES).
// MODE 2: A from bf16 hi/lo planes -> gelu(ta[d]*x+tc[d]); out gelu(v)*v; row stats.
template<int NCOLS, int MODE>
__global__ __launch_bounds__(256) void k_mfma_nt(
    const float* __restrict__ Af32,
    const ushort* __restrict__ AHp, const ushort* __restrict__ ALp,
    const ushort* __restrict__ WH, const ushort* __restrict__ WL,
    const float* __restrict__ bias, float* __restrict__ outp,
    const float* __restrict__ ta, const float* __restrict__ tc,
    float* __restrict__ rs, float* __restrict__ rq)
{
  constexpr int NF = NCOLS / 16;
  __shared__ ushort AhS[64*40], AlS[64*40];
  __shared__ ushort BhS[NCOLS*40], BlS[NCOLS*40];
  const int t = threadIdx.x;
  const int lane = t & 63, w = t >> 6;
  const int l15 = lane & 15, l4 = lane >> 4;
  const int r0 = blockIdx.x * 64;

  f4 acc[NF];
#pragma unroll
  for (int fc = 0; fc < NF; ++fc) acc[fc] = (f4){0.f,0.f,0.f,0.f};

  const int arow = t >> 2, ak0 = (t & 3) * 8;
  float taa = 0.f, tcc = 0.f;
  if (MODE == 2) { int d = (r0 + arow) % 7; taa = ta[d]; tcc = tc[d]; }

  for (int kt = 0; kt < 512; kt += 32) {
    // ---- stage A (64x32) ----
    {
      float va[8];
      if (MODE == 0) {
        const float* src = Af32 + (size_t)(r0+arow)*512 + kt + ak0;
        float4 v0 = *(const float4*)src;
        float4 v1 = *(const float4*)(src+4);
        va[0]=v0.x; va[1]=v0.y; va[2]=v0.z; va[3]=v0.w;
        va[4]=v1.x; va[5]=v1.y; va[6]=v1.z; va[7]=v1.w;
      } else {
        bf8 hv8 = *(const bf8*)&AHp[(size_t)(r0+arow)*512 + kt + ak0];
        bf8 lv8 = *(const bf8*)&ALp[(size_t)(r0+arow)*512 + kt + ak0];
#pragma unroll
        for (int j = 0; j < 8; ++j) {
          float xv = bf2f((unsigned)(ushort)hv8[j]) + bf2f((unsigned)(ushort)lv8[j]);
          va[j] = gelu_f(taa*xv + tcc);
        }
      }
      bf8 hv, lv;
#pragma unroll
      for (int j = 0; j < 8; ++j) {
        unsigned hb = bfh_u(va[j]);
        hv[j] = (short)hb;
        lv[j] = (short)bfh_u(va[j] - bf2f(hb));
      }
      *(bf8*)&AhS[arow*40 + ak0] = hv;
      *(bf8*)&AlS[arow*40 + ak0] = lv;
    }
    // ---- stage B (NCOLS x 32) ----
    for (int c = t; c < NCOLS*4; c += 256) {
      int brow = c >> 2, bk0 = (c & 3) * 8;
      *(bf8*)&BhS[brow*40 + bk0] = *(const bf8*)&WH[(size_t)brow*512 + kt + bk0];
      *(bf8*)&BlS[brow*40 + bk0] = *(const bf8*)&WL[(size_t)brow*512 + kt + bk0];
    }
    __syncthreads();
    // ---- compute: wave w owns rows w*16..w*16+15 ----
    bf8 ah, al;
    {
      int off = (w*16 + l15)*40 + l4*8;
      ah = *(const bf8*)&AhS[off];
      al = *(const bf8*)&AlS[off];
    }
#pragma unroll
    for (int fc = 0; fc < NF; ++fc) {
      int off = (fc*16 + l15)*40 + l4*8;
      bf8 bh = *(const bf8*)&BhS[off];
      bf8 bl = *(const bf8*)&BlS[off];
      acc[fc] = __builtin_amdgcn_mfma_f32_16x16x32_bf16(ah, bh, acc[fc], 0, 0, 0);
      acc[fc] = __builtin_amdgcn_mfma_f32_16x16x32_bf16(ah, bl, acc[fc], 0, 0, 0);
      acc[fc] = __builtin_amdgcn_mfma_f32_16x16x32_bf16(al, bh, acc[fc], 0, 0, 0);
    }
    __syncthreads();
  }

  // ---- epilogue ----
#pragma unroll
  for (int j = 0; j < 4; ++j) {
    const int r = r0 + w*16 + l4*4 + j;
    float s = 0.f, q = 0.f;
#pragma unroll
    for (int fc = 0; fc < NF; ++fc) {
      int col = fc*16 + l15;
      float v = acc[fc][j] + bias[col];
      if (MODE == 2) { float g = gelu_f(v); v = g*v; }
      outp[(size_t)r*NCOLS + col] = v;
      if (MODE == 2) { s += v; q += v*v; }
    }
    if (MODE == 2) {
#pragma unroll
      for (int off = 8; off > 0; off >>= 1) {
        s += __shfl_down(s, off, 16);
        q += __shfl_down(q, off, 16);
      }
      if (l15 == 0) { rs[r] = s; rq[r] = q; }
    }
  }
}

// exact k-th-smallest via register-resident 4-bit radix select.
__global__ __launch_bounds__(1024) void k_thr(const float* __restrict__ ne,
                                              const float* __restrict__ qp, float* __restrict__ out)
{
  __shared__ unsigned s_part[16][8];
  __shared__ unsigned s_bsel, s_R;
  const int t = threadIdx.x;
  const int lane = t & 63, wv = t >> 6;
  unsigned key[14];
#pragma unroll
  for (int j = 0; j < 14; ++j) key[j] = __float_as_uint(ne[t + j*1024]);

  float q = qp[0];
  float pos = q * 14335.0f;
  int lo = (int)floorf(pos);
  if (lo < 0) lo = 0; if (lo > 14335) lo = 14335;
  int hi = lo + 1; if (hi > 14335) hi = 14335;
  float frac = pos - (float)lo;

  unsigned prefix = 0;
  unsigned R = (unsigned)lo;
#pragma unroll 1
  for (int shift = 28; shift >= 0; shift -= 4) {
    unsigned pb = prefix >> shift;
    unsigned long long accb = 0ull;
#pragma unroll
    for (int j = 0; j < 14; ++j) {
      unsigned diff = (key[j] >> shift) - pb;
      accb += (diff < 16u) ? (1ull << (diff*4)) : 0ull;
    }
    unsigned pk[8];
#pragma unroll
    for (int b = 0; b < 8; ++b) {
      unsigned clo = (unsigned)(accb >> (b*4)) & 15u;
      unsigned chi = (unsigned)(accb >> (b*4+32)) & 15u;
      pk[b] = clo | (chi << 16);
    }
#pragma unroll
    for (int b = 0; b < 8; ++b)
#pragma unroll
      for (int o = 32; o > 0; o >>= 1) pk[b] += __shfl_down(pk[b], o);
    if (lane == 0) {
#pragma unroll
      for (int b = 0; b < 8; ++b) s_part[wv][b] = pk[b];
    }
    __syncthreads();
    if (t == 0) {
      unsigned tot[16];
#pragma unroll
      for (int i = 0; i < 8; ++i) {
        unsigned s = 0;
#pragma unroll
        for (int w2 = 0; w2 < 16; ++w2) s += s_part[w2][i];
        tot[i] = s & 0xFFFFu; tot[i+8] = s >> 16;
      }
      unsigned cum = 0, bsel = 15;
#pragma unroll 1
      for (int b = 0; b < 16; ++b) {
        if (cum + tot[b] > R) { bsel = (unsigned)b; break; }
        cum += tot[b];
      }
      s_bsel = bsel; s_R = R - cum;
    }
    __syncthreads();
    prefix |= (s_bsel << shift);
    R = s_R;
    __syncthreads();
  }
  unsigned cle = 0, mn = 0xFFFFFFFFu;
#pragma unroll
  for (int j = 0; j < 14; ++j) {
    cle += (key[j] <= prefix) ? 1u : 0u;
    if (key[j] > prefix && key[j] < mn) mn = key[j];
  }
#pragma unroll
  for (int o = 32; o > 0; o >>= 1) {
    cle += __shfl_down(cle, o);
    unsigned m2 = __shfl_down(mn, o);
    mn = (m2 < mn) ? m2 : mn;
  }
  if (lane == 0) { s_part[wv][0] = cle; s_part[wv][1] = mn; }
  __syncthreads();
  if (t == 0) {
    unsigned C = 0, M = 0xFFFFFFFFu;
#pragma unroll
    for (int w2 = 0; w2 < 16; ++w2) {
      C += s_part[w2][0];
      if (s_part[w2][1] < M) M = s_part[w2][1];
    }
    unsigned vhiKey = (C > (unsigned)hi) ? prefix : M;
    if (vhiKey == 0xFFFFFFFFu) vhiKey = prefix;
    float vlo = __uint_as_float(prefix);
    float vhi = __uint_as_float(vhiKey);
    out[0] = vlo*(1.0f-frac) + vhi*frac;
  }
}

// ---------------- BN finalize from per-row sums ----------------
__global__ __launch_bounds__(256) void k_bnfin_rows(const float* __restrict__ rs,
    const float* __restrict__ rq, int nch, int nrows, double count,
    const float* __restrict__ gamma, const float* __restrict__ beta, float* __restrict__ out)
{
  __shared__ double sd[256];
  int ch = blockIdx.x, t = threadIdx.x;
  double s = 0.0, q = 0.0;
  for (int i = ch + t*nch; i < nrows; i += 256*nch) { s += rs[i]; q += rq[i]; }
  sd[t] = s; __syncthreads();
  for (int o = 128; o > 0; o >>= 1) { if (t < o) sd[t] += sd[t+o]; __syncthreads(); }
  double S = sd[0]; __syncthreads();
  sd[t] = q; __syncthreads();
  for (int o = 128; o > 0; o >>= 1) { if (t < o) sd[t] += sd[t+o]; __syncthreads(); }
  if (t == 0) {
    double m = S / count;
    double v = sd[0] / count - m*m; if (v < 0.0) v = 0.0;
    double inv = 1.0 / sqrt(v + 1e-5);
    out[ch]       = (float)(gamma[ch] * inv);
    out[nch + ch] = (float)(beta[ch] - m * gamma[ch] * inv);
  }
}

// BN3 from per-row S1/Q1 of (z1+z2) scaled by a1 per row
__global__ __launch_bounds__(256) void k_bnfin_scaled(const float* __restrict__ S1,
    const float* __restrict__ Q1, const float* __restrict__ a1,
    const float* __restrict__ gamma, const float* __restrict__ beta, float* __restrict__ out)
{
  __shared__ double sd[256];
  int ch = blockIdx.x, t = threadIdx.x;
  double s = 0.0, q = 0.0;
  for (int i = ch + t*7; i < BD; i += 256*7) {
    double a = a1[i];
    s += a * S1[i];
    q += a*a * Q1[i];
  }
  sd[t] = s; __syncthreads();
  for (int o = 128; o > 0; o >>= 1) { if (t < o) sd[t] += sd[t+o]; __syncthreads(); }
  double S = sd[0]; __syncthreads();
  sd[t] = q; __syncthreads();
  for (int o = 128; o > 0; o >>= 1) { if (t < o) sd[t] += sd[t+o]; __syncthreads(); }
  if (t == 0) {
    double m = S / 1048576.0;
    double v = sd[0] / 1048576.0 - m*m; if (v < 0.0) v = 0.0;
    double inv = 1.0 / sqrt(v + 1e-5);
    out[ch]     = (float)(gamma[ch] * inv);
    out[7 + ch] = (float)(beta[ch] - m * gamma[ch] * inv);
  }
}

__global__ __launch_bounds__(256) void k_bnfin_part(const float* __restrict__ pS,
    const float* __restrict__ pQ, int nparts, int nch, double count,
    const float* __restrict__ gamma, const float* __restrict__ beta, float* __restrict__ out)
{
  __shared__ double sd[256];
  int ch = blockIdx.x, t = threadIdx.x;
  double s = 0.0, q = 0.0;
  for (int i = t; i < nparts; i += 256) { s += pS[(size_t)i*nch + ch]; q += pQ[(size_t)i*nch + ch]; }
  sd[t] = s; __syncthreads();
  for (int o = 128; o > 0; o >>= 1) { if (t < o) sd[t] += sd[t+o]; __syncthreads(); }
  double S = sd[0]; __syncthreads();
  sd[t] = q; __syncthreads();
  for (int o = 128; o > 0; o >>= 1) { if (t < o) sd[t] += sd[t+o]; __syncthreads(); }
  if (t == 0) {
    double m = S / count;
    double v = sd[0] / count - m*m; if (v < 0.0) v = 0.0;
    double inv = 1.0 / sqrt(v + 1e-5);
    out[ch]       = (float)(gamma[ch] * inv);
    out[nch + ch] = (float)(beta[ch] - m * gamma[ch] * inv);
  }
}

// ---------------- patch path: z1r = V[n] @ xp-patch + c2 ----------------
__global__ __launch_bounds__(256) void k_patch(const float* __restrict__ xp,
    const float* __restrict__ V, const float* __restrict__ c2,
    float* __restrict__ z1r, float* __restrict__ pS, float* __restrict__ pQ)
{
  __shared__ float sx[8][512];
  __shared__ float aS[32], aQ[32];
  int t = threadIdx.x;
  int r0 = blockIdx.x * 8;
  for (int c = t; c < 1024; c += 256) {
    int row = c >> 7, cg = c & 127;
    *(float4*)&sx[row][cg*4] = *(const float4*)&xp[(size_t)(r0+row)*512 + cg*4];
  }
  if (t < 32) { aS[t] = 0.f; aQ[t] = 0.f; }
  __syncthreads();
  float vreg[2][16]; float cc[2]; int nn_[2], oo[2];
#pragma unroll
  for (int h = 0; h < 2; ++h) {
    int o = t + h*256;
    oo[h] = o;
    int n = o >> 4, p = o & 15;
    nn_[h] = n;
#pragma unroll
    for (int qg = 0; qg < 4; ++qg) {
      float4 v4 = *(const float4*)&V[(size_t)n*256 + p*16 + qg*4];
      vreg[h][qg*4+0]=v4.x; vreg[h][qg*4+1]=v4.y; vreg[h][qg*4+2]=v4.z; vreg[h][qg*4+3]=v4.w;
    }
    cc[h] = c2[o];
  }
  float sum[2] = {0.f,0.f}, sq[2] = {0.f,0.f};
  for (int row = 0; row < 8; ++row) {
#pragma unroll
    for (int h = 0; h < 2; ++h) {
      const float* xr = &sx[row][nn_[h]*16];
      float val = cc[h];
#pragma unroll
      for (int qq = 0; qq < 16; ++qq) val += vreg[h][qq] * xr[qq];
      z1r[(size_t)(r0+row)*512 + oo[h]] = val;
      sum[h] += val; sq[h] += val*val;
    }
  }
#pragma unroll
  for (int h = 0; h < 2; ++h) {
    atomicAdd(&aS[nn_[h]], sum[h]);
    atomicAdd(&aQ[nn_[h]], sq[h]);
  }
  __syncthreads();
  if (t < 32) { pS[(size_t)blockIdx.x*32 + t] = aS[t]; pQ[(size_t)blockIdx.x*32 + t] = aQ[t]; }
}

// ---------------- TopKFreq att + per-row S1/Q1 of (z1+z2) ----------------
__global__ void k_att(const float* __restrict__ z1, const float* __restrict__ z1r,
    const float* __restrict__ bn2, const float* __restrict__ u, const float* __restrict__ fcb,
    float* __restrict__ att, float* __restrict__ S1o, float* __restrict__ Q1o)
{
  int r = blockIdx.x*4 + (threadIdx.x >> 6);
  int lane = threadIdx.x & 63;
  const float* z1p = z1 + (size_t)r*512;
  const float* zrp = z1r + (size_t)r*512;
  float s = 0.f, s1 = 0.f, q1 = 0.f;
#pragma unroll
  for (int h = 0; h < 2; ++h) {
    int i = lane*4 + h*256;
    int n = i >> 4;
    float a2n = bn2[n], c2n = bn2[32+n];
    float4 zr = *(const float4*)&zrp[i];
    float4 zv = *(const float4*)&z1p[i];
    float4 uv = *(const float4*)&u[i];
#pragma unroll
    for (int e = 0; e < 4; ++e) {
      float ze = (e==0?zr.x:e==1?zr.y:e==2?zr.z:zr.w);
      float z1e = (e==0?zv.x:e==1?zv.y:e==2?zv.z:zv.w);
      float ue = (e==0?uv.x:e==1?uv.y:e==2?uv.z:uv.w);
      float tv = z1e + gelu_f(a2n*ze + c2n);
      s += tv * ue; s1 += tv; q1 += tv*tv;
    }
  }
  s = wred(s); s1 = wred(s1); q1 = wred(q1);
  if (lane == 0) { att[r] = s + fcb[0]; S1o[r] = s1; Q1o[r] = q1; }
}

__global__ __launch_bounds__(1024) void k_tf(const float* __restrict__ att,
    const float* __restrict__ pg, const float* __restrict__ pb,
    const float* __restrict__ pwc, const float* __restrict__ pbc,
    const float* __restrict__ pfb, float* __restrict__ a1, float* __restrict__ a2)
{
  __shared__ double sd[1024];
  __shared__ float sh[4];
  const int t = threadIdx.x;
  float g = pg[0], b = pb[0], wc = pwc[0], bc = pbc[0], fb = pfb[0];
  double s = 0.0, q = 0.0;
  for (int i = t; i < BD; i += 1024) { double v = att[i]; s += v; q += v*v; }
  sd[t] = s; __syncthreads();
  for (int o = 512; o > 0; o >>= 1) { if (t < o) sd[t] += sd[t+o]; __syncthreads(); }
  double S1 = sd[0]; __syncthreads();
  sd[t] = q; __syncthreads();
  for (int o = 512; o > 0; o >>= 1) { if (t < o) sd[t] += sd[t+o]; __syncthreads(); }
  if (t == 0) {
    double m = S1 / 14336.0;
    double v = sd[0] / 14336.0 - m*m; if (v < 0.0) v = 0.0;
    sh[0] = (float)m; sh[1] = (float)(1.0 / sqrt(v + 1e-5));
  }
  __syncthreads();
  float m1 = sh[0], i1 = sh[1];
  s = 0.0; q = 0.0;
  for (int i = t; i < BD; i += 1024) {
    float v = att[i];
    float an = (v - m1) * i1 * g + b;
    float av = sigm_f(gelu_f(an) * wc + bc);
    a1[i] = av;
    float t2 = av * (v - fb) + fb;
    s += t2; q += (double)t2 * t2;
  }
  __syncthreads();
  sd[t] = s; __syncthreads();
  for (int o = 512; o > 0; o >>= 1) { if (t < o) sd[t] += sd[t+o]; __syncthreads(); }
  double S2 = sd[0]; __syncthreads();
  sd[t] = q; __syncthreads();
  for (int o = 512; o > 0; o >>= 1) { if (t < o) sd[t] += sd[t+o]; __syncthreads(); }
  if (t == 0) {
    double m = S2 / 14336.0;
    double v = sd[0] / 14336.0 - m*m; if (v < 0.0) v = 0.0;
    sh[2] = (float)m; sh[3] = (float)(1.0 / sqrt(v + 1e-5));
  }
  __syncthreads();
  float m2 = sh[2], i2 = sh[3];
  for (int i = t; i < BD; i += 1024) {
    float t2 = a1[i] * (att[i] - fb) + fb;
    float an = (t2 - m2) * i2 * g + b;
    a2[i] = sigm_f(gelu_f(an) * wc + bc);
  }
}

// ---------------- statsC (float4) ----------------
__global__ void k_statsC(const float* __restrict__ z1, const float* __restrict__ z1r,
    const float* __restrict__ bn2, const float* __restrict__ a1,
    const float* __restrict__ bn3, const float* __restrict__ cw, const float* __restrict__ cb,
    float* __restrict__ rs, float* __restrict__ rq)
{
  int r = blockIdx.x*4 + (threadIdx.x >> 6);
  int lane = threadIdx.x & 63;
  int d = r % 7;
  float av = a1[r];
  float b3a = bn3[d], b3c = bn3[7+d], wv = cw[d], bv = cb[d];
  const float* z1p = z1 + (size_t)r*512;
  const float* zrp = z1r + (size_t)r*512;
  float s = 0.f, q = 0.f;
#pragma unroll
  for (int h = 0; h < 2; ++h) {
    int i = lane*4 + h*256;
    int n = i >> 4;
    float a2n = bn2[n], c2n = bn2[32+n];
    float4 zr = *(const float4*)&zrp[i];
    float4 zv = *(const float4*)&z1p[i];
#pragma unroll
    for (int e = 0; e < 4; ++e) {
      float ze = (e==0?zr.x:e==1?zr.y:e==2?zr.z:zr.w);
      float z1e = (e==0?zv.x:e==1?zv.y:e==2?zv.z:zv.w);
      float A = (z1e + gelu_f(a2n*ze + c2n)) * av;
      float C = wv*gelu_f(b3a*A + b3c) + bv;
      s += C; q += C*C;
    }
  }
  s = wred(s); q = wred(q);
  if (lane == 0) { rs[r] = s; rq[r] = q; }
}

// ---------------- final mix: writes zf as bf16 hi/lo planes + row stats ----------------
__global__ void k_final(const float* __restrict__ z1, const float* __restrict__ z1r,
    const float* __restrict__ bn2, const float* __restrict__ a1, const float* __restrict__ a2,
    const float* __restrict__ bn3, const float* __restrict__ bn4,
    const float* __restrict__ cw, const float* __restrict__ cb,
    ushort* __restrict__ zfh, ushort* __restrict__ zfl,
    float* __restrict__ rs, float* __restrict__ rq)
{
  int r = blockIdx.x*4 + (threadIdx.x >> 6);
  int lane = threadIdx.x & 63;
  int d = r % 7;
  float av = a1[r], a2v = a2[r];
  float b3a = bn3[d], b3c = bn3[7+d], b4a = bn4[d], b4c = bn4[7+d];
  float wv = cw[d], bv = cb[d];
  const float* z1p = z1 + (size_t)r*512;
  const float* zrp = z1r + (size_t)r*512;
  float s = 0.f, q = 0.f;
#pragma unroll
  for (int h = 0; h < 2; ++h) {
    int i = lane*4 + h*256;
    int n = i >> 4;
    float a2n = bn2[n], c2n = bn2[32+n];
    float4 zr = *(const float4*)&zrp[i];
    float4 zv = *(const float4*)&z1p[i];
    sh4 hv, lv;
#pragma unroll
    for (int e = 0; e < 4; ++e) {
      float ze = (e==0?zr.x:e==1?zr.y:e==2?zr.z:zr.w);
      float z1e = (e==0?zv.x:e==1?zv.y:e==2?zv.z:zv.w);
      float z1v = z1e * av;
      float z2v = gelu_f(a2n*ze + c2n) * av;
      float A = z1v + z2v;
      float C = wv*gelu_f(b3a*A + b3c) + bv;
      float inter = gelu_f(b4a*C + b4c) * a2v;
      float z1n = z1v*inter + z2v;
      float z2n = z2v*inter + z1n;
      float zfv = z1n*z2n + z1n + z2n;
      unsigned hb = bfh_u(zfv);
      hv[e] = (short)hb;
      lv[e] = (short)bfh_u(zfv - bf2f(hb));
      s += zfv; q += zfv*zfv;
    }
    *(sh4*)&zfh[(size_t)r*512 + i] = hv;
    *(sh4*)&zfl[(size_t)r*512 + i] = lv;
  }
  s = wred(s); q = wred(q);
  if (lane == 0) { rs[r] = s; rq[r] = q; }
}

// ---------------- output: fc2 + bias + z_res + transpose ----------------
__global__ __launch_bounds__(256) void k_out(const float* __restrict__ h2,
    const float* __restrict__ bn6, const float* __restrict__ w2, const float* __restrict__ b2,
    const float* __restrict__ zres, float* __restrict__ out)
{
  int idx = blockIdx.x*256 + threadIdx.x;
  int r = idx / 96, o = idx - r*96;
  int d = r % 7, b = r / 7;
  float a6 = bn6[d], c6 = bn6[7+d];
  const float* hp = h2 + (size_t)r*48;
  const float* wp = w2 + o*48;
  float s = 0.f;
#pragma unroll
  for (int j4 = 0; j4 < 12; ++j4) {
    float4 hv = *(const float4*)&hp[j4*4];
    float4 wv = *(const float4*)&wp[j4*4];
    s += (a6*hv.x + c6)*wv.x + (a6*hv.y + c6)*wv.y
       + (a6*hv.z + c6)*wv.z + (a6*hv.w + c6)*wv.w;
  }
  out[(size_t)b*672 + o*7 + d] = s + b2[o] + zres[(size_t)r*96 + o];
}

// ================= host =================
extern "C" void kernel_launch(void* const* d_in, const int* in_sizes, int n_in,
                              void* d_out, int out_size, void* d_ws, size_t ws_size,
                              hipStream_t stream) {
  const float* x          = (const float*)d_in[0];
  const float* dctconv_w  = (const float*)d_in[1];
  const float* dctconv_b  = (const float*)d_in[2];
  const float* dctnorm_g  = (const float*)d_in[3];
  const float* dctnorm_b  = (const float*)d_in[4];
  const float* threshold  = (const float*)d_in[5];
  const float* embed_W    = (const float*)d_in[6];
  const float* embed_b    = (const float*)d_in[7];
  const float* linres_W   = (const float*)d_in[8];
  const float* linres_b   = (const float*)d_in[9];
  const float* depth1_w   = (const float*)d_in[10];
  const float* depth1_b   = (const float*)d_in[11];
  const float* depthnorm_g= (const float*)d_in[12];
  const float* depthnorm_b= (const float*)d_in[13];
  const float* tf_fc_w    = (const float*)d_in[14];
  const float* tf_fc_b    = (const float*)d_in[15];
  const float* tf_norm_g  = (const float*)d_in[16];
  const float* tf_norm_b  = (const float*)d_in[17];
  const float* tf_conv_w  = (const float*)d_in[18];
  const float* tf_conv_b  = (const float*)d_in[19];
  const float* mlp_w1     = (const float*)d_in[20];
  const float* mlp_b1     = (const float*)d_in[21];
  const float* mlp_w2     = (const float*)d_in[22];
  const float* mlp_b2     = (const float*)d_in[23];
  const float* mlpnorm_g  = (const float*)d_in[24];
  const float* mlpnorm_b  = (const float*)d_in[25];
  float* out = (float*)d_out;
  float* ws  = (float*)d_ws;

  float* XP   = ws + F_XP;
  ushort* ZFH = (ushort*)(ws + F_XP);             // zf planes (overwrite xp at k_final)
  ushort* ZFL = ZFH + (size_t)BD*512;
  float* ZG   = ws + F_ZG;                        // z1r f32 (after GEMM2); GH/GL planes before
  ushort* ZGH = (ushort*)(ws + F_ZG);
  ushort* ZGL = ZGH + (size_t)BD*512;
  float* Z1   = ws + F_Z1;
  ushort* B1H = (ushort*)(ws + F_CLK);            // B1H+B1L fill the CLK region exactly
  ushort* B1L = B1H + 512*512;
  ushort* B2H = (ushort*)(ws + F_MKL);            // B2H+B2L fill the MKL region exactly
  ushort* B2L = B2H + 512*512;
  ushort* W2H = (ushort*)(ws + F_W2);             // dedicated region — no aliasing
  ushort* W2L = W2H + 96*512;
  ushort* W1H = (ushort*)(ws + F_W1);             // dedicated region — no aliasing
  ushort* W1L = W1H + 48*512;
  float* U    = ws + F_U;
  float* CSUM = ws + F_CSUM;
  float* CSTp = ws + F_CST;
  float* Vp   = ws + F_V;
  float* C2p  = ws + F_C2;
  float* ZRES = ws + F_ZRES;
  float* H2p  = ws + F_H2;
  float* NEp  = ws + F_NE;
  float* ATTp = ws + F_ATT;
  float* A1p  = ws + F_A1;
  float* A2p  = ws + F_A2;
  float* RS   = ws + F_RS;
  float* RQ   = ws + F_RQ;
  float* PS   = ws + F_PS;
  float* PQ   = ws + F_PQ;
  float* BN0  = ws + F_BN;        // a[7], c[7]
  float* BN2  = ws + F_BN + 16;   // a[32], c[32]
  float* BN3  = ws + F_BN + 80;
  float* BN4  = ws + F_BN + 96;
  float* BN5  = ws + F_BN + 112;
  float* BN6  = ws + F_BN + 128;
  float* THRp = ws + F_THR;

  k_setup<<<738, 256, 0, stream>>>(B1H, B1L, B2H, B2L, U, CSUM, tf_fc_w,
      embed_W, embed_b, depth1_w, depth1_b, Vp, C2p,
      mlp_w1, W1H, W1L, linres_W, linres_b, W2H, W2L, CSTp);
  k_transpose<<<2048, 256, 0, stream>>>(x, XP, NEp);
  k_thr<<<1, 1024, 0, stream>>>(NEp, threshold, THRp);
  hipMemsetAsync(RS, 0, 2*BD*sizeof(float), stream);
  // GEMM1: z_dct -> masked dctconv -> gelu -> GH/GL planes (+ row stats)
  k_mfma<2><<<dim3(112,4), 256, 0, stream>>>(XP, nullptr, nullptr, B1H, B1L,
      nullptr, ZGH, ZGL, nullptr, nullptr, nullptr, dctconv_w, dctconv_b,
      NEp, THRp, RS, RQ);
  k_bnfin_rows<<<7, 256, 0, stream>>>(RS, RQ, 7, BD, 1048576.0, dctnorm_g, dctnorm_b, BN0);
  // GEMM2: z1 = BN(g) @ M + x_res  (BN folded via column sums)
  k_mfma<1><<<dim3(112,4), 256, 0, stream>>>(nullptr, ZGH, ZGL, B2H, B2L,
      Z1, nullptr, nullptr, BN0, CSUM, XP, dctconv_w, dctconv_b,
      nullptr, nullptr, nullptr, nullptr);
  k_patch<<<1792, 256, 0, stream>>>(XP, Vp, C2p, ZG, PS, PQ);
  k_bnfin_part<<<32, 256, 0, stream>>>(PS, PQ, 1792, 32, 229376.0, depthnorm_g, depthnorm_b, BN2);
  // ZRES = XP @ W2^T + cst   (MFMA bf16-split)
  k_mfma_nt<96,0><<<224, 256, 0, stream>>>(XP, nullptr, nullptr, W2H, W2L, CSTp, ZRES,
      nullptr, nullptr, nullptr, nullptr);
  // att + per-row S1/Q1 of (z1+z2)
  k_att<<<3584, 256, 0, stream>>>(Z1, ZG, BN2, U, tf_fc_b, ATTp, RS, RQ);
  k_tf<<<1, 1024, 0, stream>>>(ATTp, tf_norm_g, tf_norm_b, tf_conv_w, tf_conv_b, tf_fc_b, A1p, A2p);
  // BN3 from a1-scaled per-row sums (statsA pass eliminated)
  k_bnfin_scaled<<<7, 256, 0, stream>>>(RS, RQ, A1p, dctnorm_g, dctnorm_b, BN3);
  k_statsC<<<3584, 256, 0, stream>>>(Z1, ZG, BN2, A1p, BN3, dctconv_w, dctconv_b, RS, RQ);
  k_bnfin_rows<<<7, 256, 0, stream>>>(RS, RQ, 7, BD, 1048576.0, dctnorm_g, dctnorm_b, BN4);
  k_final<<<3584, 256, 0, stream>>>(Z1, ZG, BN2, A1p, A2p, BN3, BN4, dctconv_w, dctconv_b,
      ZFH, ZFL, RS, RQ);
  k_bnfin_rows<<<7, 256, 0, stream>>>(RS, RQ, 7, BD, 1048576.0, dctnorm_g, dctnorm_b, BN5);
  // MLP fc1: h2 = gelu(v)*v with v = gelu(BN5(zf)) @ w1^T + b1   (reads zf planes)
  k_mfma_nt<48,2><<<224, 256, 0, stream>>>(nullptr, ZFH, ZFL, W1H, W1L, mlp_b1, H2p,
      BN5, BN5+7, RS, RQ);
  k_bnfin_rows<<<7, 256, 0, stream>>>(RS, RQ, 7, BD, 98304.0, mlpnorm_g, mlpnorm_b, BN6);
  k_out<<<5376, 256, 0, stream>>>(H2p, BN6, mlp_w2, mlp_b2, ZRES, out);
}

// Round 11
// 348.972 us; speedup vs baseline: 2.3767x; 1.0202x over previous
//
#include <hip/hip_runtime.h>
#include <math.h>

#define BB 2048
#define LL 512
#define DD 7
#define BD 14336   // BB*DD

// ---------------- ws layout (floats) ----------------
constexpr size_t F_XP   = 0;                          // XPH/XPL planes, later ZFH/ZFL planes
constexpr size_t F_ZG   = F_XP  + (size_t)BD*512;     // ZGH/ZGL planes -> z1r f32
constexpr size_t F_Z1   = F_ZG  + (size_t)BD*512;     // z1
constexpr size_t F_CLK  = F_Z1  + (size_t)BD*512;     // B1H/B1L (fills region exactly)
constexpr size_t F_MKL  = F_CLK + 512*512;            // B2H/B2L (fills region exactly)
constexpr size_t F_U    = F_MKL + 512*512;
constexpr size_t F_CSUM = F_U + 512;
constexpr size_t F_W2   = F_CSUM + 512;               // W2H/W2L ushort planes (exact fit)
constexpr size_t F_CST  = F_W2 + 96*512;
constexpr size_t F_V    = F_CST + 96;                 // 32x16x16
constexpr size_t F_C2   = F_V + 32*256;               // 32x16
constexpr size_t F_ZRES = F_C2 + 512;                 // BD x 96
constexpr size_t F_H2   = F_ZRES + (size_t)BD*96;     // BD x 48
constexpr size_t F_EN   = F_H2 + (size_t)BD*48;       // (unused)
constexpr size_t F_NE   = F_EN + BD;
constexpr size_t F_ATT  = F_NE + BD;
constexpr size_t F_A1   = F_ATT + BD;
constexpr size_t F_A2   = F_A1 + BD;
constexpr size_t F_RS   = F_A2 + BD;
constexpr size_t F_RQ   = F_RS + BD;                  // adjacent to F_RS (one memset)
constexpr size_t F_PS   = F_RQ + BD;                  // 1792 x 32
constexpr size_t F_PQ   = F_PS + 1792*32;
constexpr size_t F_BN   = F_PQ + 1792*32;             // bn affine params
constexpr size_t F_THR  = F_BN + 256;
constexpr size_t F_W1   = F_THR + 16;                 // W1H/W1L ushort planes (24576 floats)

typedef __attribute__((ext_vector_type(8))) short bf8;
typedef __attribute__((ext_vector_type(4))) short sh4;
typedef __attribute__((ext_vector_type(4))) float f4;

__device__ __forceinline__ float gelu_f(float x) {
  return 0.5f * x * (1.0f + erff(x * 0.70710678118654752440f));
}
__device__ __forceinline__ float sigm_f(float x) {
  return 1.0f / (1.0f + expf(-x));
}
__device__ __forceinline__ float wred(float v) {
#pragma unroll
  for (int o = 32; o > 0; o >>= 1) v += __shfl_down(v, o);
  return v;
}
__device__ __forceinline__ unsigned bfh_u(float v) {     // round-to-nearest (setup only)
  unsigned u = __float_as_uint(v);
  return (u + 0x7FFFu + ((u >> 16) & 1u)) >> 16;
}
__device__ __forceinline__ float bf2f(unsigned h) { return __uint_as_float(h << 16); }
// truncation split: 4 VALU ops, error ~2^-16 rel
__device__ __forceinline__ void tsplit(float v, short &h, short &l) {
  unsigned u = __float_as_uint(v);
  h = (short)(u >> 16);
  float lo = v - bf2f(u >> 16);
  l = (short)(__float_as_uint(lo) >> 16);
}

#define PI1024 0.00306796157577128218f   // pi/1024

// ---------------- fused setup: gen_b + ucsum + v + splitw + w2 ----------------
__global__ __launch_bounds__(256) void k_setup(
    ushort* __restrict__ B1H, ushort* __restrict__ B1L,
    ushort* __restrict__ B2H, ushort* __restrict__ B2L,
    float* __restrict__ u, float* __restrict__ csum, const float* __restrict__ wf,
    const float* __restrict__ eW, const float* __restrict__ eb,
    const float* __restrict__ dw, const float* __restrict__ db,
    float* __restrict__ V, float* __restrict__ c2,
    const float* __restrict__ mlpw1, ushort* __restrict__ W1H, ushort* __restrict__ W1L,
    const float* __restrict__ linW, const float* __restrict__ linb,
    ushort* __restrict__ W2H, ushort* __restrict__ W2L, float* __restrict__ cst)
{
  __shared__ float sW[768];
  __shared__ float sb[48];
  __shared__ float rbuf[256];
  const int bid = blockIdx.x, t = threadIdx.x;
  if (bid < 512) {
    int c = bid;
    for (int r = t; r < 512; r += 256) {
      int n1 = ((2*r + 1) * c) & 2047;
      float v1 = 2.0f * cosf((float)n1 * PI1024);
      unsigned h = bfh_u(v1);
      B1H[(size_t)c*512 + r] = (ushort)h;
      B1L[(size_t)c*512 + r] = (ushort)bfh_u(v1 - bf2f(h));
      int n2 = ((2*c + 1) * r) & 2047;
      float v2 = cosf((float)n2 * PI1024) * (r == 0 ? (1.0f/1024.0f) : (1.0f/512.0f));
      h = bfh_u(v2);
      B2H[(size_t)c*512 + r] = (ushort)h;
      B2L[(size_t)c*512 + r] = (ushort)bfh_u(v2 - bf2f(h));
    }
  } else if (bid < 514) {
    int l = (bid - 512)*256 + t;
    if (l < 512) {
      double th2 = 3.14159265358979323846 * (double)(2*l + 1) / 2048.0;
      double s = (l & 1) ? -1.0 : 1.0;
      double S = 0.5*s/tan(th2) - 0.5;
      csum[l] = (float)(1.0/1024.0 + S/512.0);
      double uu = (double)wf[0] * 45.25483399593904156 / 1024.0;
      for (int k = 1; k < 5; ++k)
        uu += (double)wf[k] * 32.0 * cos(3.14159265358979323846*(l+0.5)*k/512.0) / 512.0;
      u[l] = (float)uu;
    }
  } else if (bid < 546) {
    int n = bid - 514;
    int p = t >> 4, q = t & 15;
    float s = 0.f;
#pragma unroll
    for (int j = 0; j < 3; ++j) s += eW[(p*3+j)*16 + q] * dw[n*3+j];
    V[(size_t)n*256 + p*16 + q] = s;
    if (q == 0) {
      float c = 0.f;
#pragma unroll
      for (int j = 0; j < 3; ++j) c += eb[p*3+j] * dw[n*3+j];
      c2[n*16+p] = c + db[n];
    }
  } else if (bid < 642) {
    int i = (bid - 546)*256 + t;
    if (i < 48*512) {
      float v = mlpw1[i];
      unsigned hb = bfh_u(v);
      W1H[i] = (ushort)hb;
      W1L[i] = (ushort)bfh_u(v - bf2f(hb));
    }
  } else {
    int o = bid - 642;
    for (int i = t; i < 768; i += 256) sW[i] = eW[i];
    if (t < 48) sb[t] = eb[t];
    __syncthreads();
    const float* lw = linW + (size_t)o * 1536;
    for (int i = t; i < 512; i += 256) {
      int n = i >> 4, p = i & 15;
      float s = 0.f;
      const float* l2 = lw + n*48;
#pragma unroll 8
      for (int m = 0; m < 48; ++m) s += l2[m] * sW[m*16 + p];
      unsigned hb = bfh_u(s);
      W2H[(size_t)o*512 + i] = (ushort)hb;
      W2L[(size_t)o*512 + i] = (ushort)bfh_u(s - bf2f(hb));
    }
    float c = 0.f;
    for (int i = t; i < 1536; i += 256) c += lw[i] * sb[i % 48];
    rbuf[t] = c; __syncthreads();
    for (int off = 128; off > 0; off >>= 1) { if (t < off) rbuf[t] += rbuf[t+off]; __syncthreads(); }
    if (t == 0) cst[o] = rbuf[0] + linb[o];
  }
}

// ---------------- transpose [B,L,D] -> bf16 hi/lo planes + fused energy/median -> ne --------
__global__ __launch_bounds__(256) void k_transpose(const float* __restrict__ x,
                                                   ushort* __restrict__ xph,
                                                   ushort* __restrict__ xpl,
                                                   float* __restrict__ ne) {
  __shared__ float s[3584];
  __shared__ float sEn[7];
  int b = blockIdx.x;
  const float* src = x + (size_t)b*3584;
  for (int c = threadIdx.x; c < 896; c += 256) {
    float4 v = *(const float4*)&src[c*4];
    s[c*4+0]=v.x; s[c*4+1]=v.y; s[c*4+2]=v.z; s[c*4+3]=v.w;
  }
  __syncthreads();
  for (int c = threadIdx.x; c < 896; c += 256) {
    int d = c >> 7, cg = c & 127;
    sh4 hv, lv;
#pragma unroll
    for (int e = 0; e < 4; ++e) {
      float v = s[(cg*4+e)*7 + d];
      short hh, ll;
      tsplit(v, hh, ll);
      hv[e] = hh; lv[e] = ll;
    }
    size_t idx = ((size_t)b*7 + d)*512 + cg*4;
    *(sh4*)&xph[idx] = hv;
    *(sh4*)&xpl[idx] = lv;
  }
  int t = threadIdx.x;
  if (t < 224) {
    int d = t >> 5, c0 = (t & 31) * 16;
    double ss = 0.0, qq = 0.0;
    for (int l = c0; l < c0 + 16; ++l) {
      double v = s[l*7 + d];
      ss += v; qq += v*v;
    }
#pragma unroll
    for (int o = 16; o > 0; o >>= 1) {
      ss += __shfl_down(ss, o, 32);
      qq += __shfl_down(qq, o, 32);
    }
    if ((t & 31) == 0) sEn[d] = (float)(1024.0*qq + 2.0*ss*ss);
  }
  __syncthreads();
  if (t == 0) {
    float e[7], s7[7];
#pragma unroll
    for (int d = 0; d < 7; ++d) { e[d] = sEn[d]; s7[d] = e[d]; }
#pragma unroll
    for (int i = 1; i < 7; ++i) {
      float key = s7[i]; int j = i-1;
      while (j >= 0 && s7[j] > key) { s7[j+1] = s7[j]; --j; }
      s7[j+1] = key;
    }
    float med = s7[3] + 1e-6f;
#pragma unroll
    for (int d = 0; d < 7; ++d) ne[b*7 + d] = e[d] / med;
  }
}

// ---------------- MFMA bf16-split GEMM: C[M,512] = A[M,512] @ B[512,512] ----------------
// BM=128, BN=128, BK=32; 4 waves x (64x64); 3-term split; A ALWAYS from hi/lo planes (copy).
// MODE 2: epilogue g=gelu(acc*mask*w+b) -> GH/GL planes (truncation split) + row stats
// MODE 1: epilogue z1 = aR*acc + cR*csum + (hi+lo)(xp)*w + b -> f32
template<int MODE>
__global__ __launch_bounds__(256) void k_mfma(
    const ushort* __restrict__ AHg, const ushort* __restrict__ ALg,
    const ushort* __restrict__ BHg, const ushort* __restrict__ BLg,
    float* __restrict__ z1out, ushort* __restrict__ GH, ushort* __restrict__ GL,
    const float* __restrict__ bnac, const float* __restrict__ csum,
    const ushort* __restrict__ xph, const ushort* __restrict__ xpl,
    const float* __restrict__ cw, const float* __restrict__ cb,
    const float* __restrict__ ne, const float* __restrict__ thr,
    float* __restrict__ rs, float* __restrict__ rq)
{
  __shared__ ushort AhS[128*40], AlS[128*40];
  __shared__ ushort BhS[128*40], BlS[128*40];
  const int t = threadIdx.x;
  const int lane = t & 63, w = t >> 6;
  const int l15 = lane & 15, l4 = lane >> 4;
  const int wr = (w & 1)*64, wc = (w >> 1)*64;
  const int r0 = blockIdx.x * 128, c0 = blockIdx.y * 128;

  f4 acc[4][4];
#pragma unroll
  for (int i = 0; i < 4; ++i)
#pragma unroll
    for (int j = 0; j < 4; ++j) acc[i][j] = (f4){0.f,0.f,0.f,0.f};

  const int arow = t >> 1, ak0 = (t & 1) * 16;   // 128 rows, 2 thr/row, 16 elems each

  for (int kt = 0; kt < 512; kt += 32) {
    // ---- stage A (128x32) : plane copy ----
#pragma unroll
    for (int g = 0; g < 2; ++g) {
      *(bf8*)&AhS[arow*40 + ak0 + g*8] = *(const bf8*)&AHg[(size_t)(r0+arow)*512 + kt + ak0 + g*8];
      *(bf8*)&AlS[arow*40 + ak0 + g*8] = *(const bf8*)&ALg[(size_t)(r0+arow)*512 + kt + ak0 + g*8];
    }
    // ---- stage B (128 cols x 32 k, transposed source) ----
#pragma unroll
    for (int g = 0; g < 2; ++g) {
      *(bf8*)&BhS[arow*40 + ak0 + g*8] = *(const bf8*)&BHg[(size_t)(c0+arow)*512 + kt + ak0 + g*8];
      *(bf8*)&BlS[arow*40 + ak0 + g*8] = *(const bf8*)&BLg[(size_t)(c0+arow)*512 + kt + ak0 + g*8];
    }
    __syncthreads();
    // ---- compute ----
    bf8 ah[4], al[4], bh[4], bl[4];
#pragma unroll
    for (int fr = 0; fr < 4; ++fr) {
      int off = (wr + fr*16 + l15)*40 + l4*8;
      ah[fr] = *(const bf8*)&AhS[off];
      al[fr] = *(const bf8*)&AlS[off];
    }
#pragma unroll
    for (int fc = 0; fc < 4; ++fc) {
      int off = (wc + fc*16 + l15)*40 + l4*8;
      bh[fc] = *(const bf8*)&BhS[off];
      bl[fc] = *(const bf8*)&BlS[off];
    }
#pragma unroll
    for (int fr = 0; fr < 4; ++fr)
#pragma unroll
      for (int fc = 0; fc < 4; ++fc) {
        acc[fr][fc] = __builtin_amdgcn_mfma_f32_16x16x32_bf16(ah[fr], bh[fc], acc[fr][fc], 0, 0, 0);
        acc[fr][fc] = __builtin_amdgcn_mfma_f32_16x16x32_bf16(ah[fr], bl[fc], acc[fr][fc], 0, 0, 0);
        acc[fr][fc] = __builtin_amdgcn_mfma_f32_16x16x32_bf16(al[fr], bh[fc], acc[fr][fc], 0, 0, 0);
      }
    __syncthreads();
  }

  // ---- epilogue ----
  const float thv = (MODE == 2) ? thr[0] : 0.f;
#pragma unroll
  for (int fr = 0; fr < 4; ++fr)
#pragma unroll
    for (int j = 0; j < 4; ++j) {
      const int r = r0 + wr + fr*16 + l4*4 + j;
      const int d = r % 7;
      if (MODE == 1) {
        const float aR = bnac[d], cR = bnac[7+d], wv = cw[d], bvv = cb[d];
#pragma unroll
        for (int fc = 0; fc < 4; ++fc) {
          int col = c0 + wc + fc*16 + l15;
          size_t idx = (size_t)r*512 + col;
          float xv = bf2f(xph[idx]) + bf2f(xpl[idx]);
          float val = acc[fr][fc][j];
          z1out[idx] = aR*val + cR*csum[col] + xv*wv + bvv;
        }
      } else {
        float m = (ne[r] > thv) ? 1.0f : 0.0f;
        float wm = cw[d] * m, bvv = cb[d];
        float s = 0.f, q = 0.f;
#pragma unroll
        for (int fc = 0; fc < 4; ++fc) {
          int col = c0 + wc + fc*16 + l15;
          float g = gelu_f(acc[fr][fc][j]*wm + bvv);
          short hh, ll;
          tsplit(g, hh, ll);
          GH[(size_t)r*512 + col] = (ushort)hh;
          GL[(size_t)r*512 + col] = (ushort)ll;
          s += g; q += g*g;
        }
#pragma unroll
        for (int off = 8; off > 0; off >>= 1) {
          s += __shfl_down(s, off, 16);
          q += __shfl_down(q, off, 16);
        }
        if (l15 == 0) { atomicAdd(&rs[r], s); atomicAdd(&rq[r], q); }
      }
    }
}

// ---------------- MFMA bf16-split NT GEMM: out[M,NCOLS] = A[M,512] @ W[NCOLS,512]^T + bias ----
// BM=64 (4 waves x 16 rows), BK=32, 3-term split; A from hi/lo planes.
// MODE 0: plane copy, plain store (ZRES).
// MODE 2: reconstruct -> gelu(ta*x+tc) -> truncation split; out gelu(v)*v; row stats.
template<int NCOLS, int MODE>
__global__ __launch_bounds__(256) void k_mfma_nt(
    const ushort* __restrict__ AHp, const ushort* __restrict__ ALp,
    const ushort* __restrict__ WH, const ushort* __restrict__ WL,
    const float* __restrict__ bias, float* __restrict__ outp,
    const float* __restrict__ ta, const float* __restrict__ tc,
    float* __restrict__ rs, float* __restrict__ rq)
{
  constexpr int NF = NCOLS / 16;
  __shared__ ushort AhS[64*40], AlS[64*40];
  __shared__ ushort BhS[NCOLS*40], BlS[NCOLS*40];
  const int t = threadIdx.x;
  const int lane = t & 63, w = t >> 6;
  const int l15 = lane & 15, l4 = lane >> 4;
  const int r0 = blockIdx.x * 64;

  f4 acc[NF];
#pragma unroll
  for (int fc = 0; fc < NF; ++fc) acc[fc] = (f4){0.f,0.f,0.f,0.f};

  const int arow = t >> 2, ak0 = (t & 3) * 8;
  float taa = 0.f, tcc = 0.f;
  if (MODE == 2) { int d = (r0 + arow) % 7; taa = ta[d]; tcc = tc[d]; }

  for (int kt = 0; kt < 512; kt += 32) {
    // ---- stage A (64x32) ----
    if (MODE == 0) {
      *(bf8*)&AhS[arow*40 + ak0] = *(const bf8*)&AHp[(size_t)(r0+arow)*512 + kt + ak0];
      *(bf8*)&AlS[arow*40 + ak0] = *(const bf8*)&ALp[(size_t)(r0+arow)*512 + kt + ak0];
    } else {
      bf8 hv8 = *(const bf8*)&AHp[(size_t)(r0+arow)*512 + kt + ak0];
      bf8 lv8 = *(const bf8*)&ALp[(size_t)(r0+arow)*512 + kt + ak0];
      bf8 hv, lv;
#pragma unroll
      for (int j = 0; j < 8; ++j) {
        float xv = bf2f((unsigned)(ushort)hv8[j]) + bf2f((unsigned)(ushort)lv8[j]);
        float g = gelu_f(taa*xv + tcc);
        short hh, ll;
        tsplit(g, hh, ll);
        hv[j] = hh; lv[j] = ll;
      }
      *(bf8*)&AhS[arow*40 + ak0] = hv;
      *(bf8*)&AlS[arow*40 + ak0] = lv;
    }
    // ---- stage B (NCOLS x 32) ----
    for (int c = t; c < NCOLS*4; c += 256) {
      int brow = c >> 2, bk0 = (c & 3) * 8;
      *(bf8*)&BhS[brow*40 + bk0] = *(const bf8*)&WH[(size_t)brow*512 + kt + bk0];
      *(bf8*)&BlS[brow*40 + bk0] = *(const bf8*)&WL[(size_t)brow*512 + kt + bk0];
    }
    __syncthreads();
    // ---- compute: wave w owns rows w*16..w*16+15 ----
    bf8 ah, al;
    {
      int off = (w*16 + l15)*40 + l4*8;
      ah = *(const bf8*)&AhS[off];
      al = *(const bf8*)&AlS[off];
    }
#pragma unroll
    for (int fc = 0; fc < NF; ++fc) {
      int off = (fc*16 + l15)*40 + l4*8;
      bf8 bh = *(const bf8*)&BhS[off];
      bf8 bl = *(const bf8*)&BlS[off];
      acc[fc] = __builtin_amdgcn_mfma_f32_16x16x32_bf16(ah, bh, acc[fc], 0, 0, 0);
      acc[fc] = __builtin_amdgcn_mfma_f32_16x16x32_bf16(ah, bl, acc[fc], 0, 0, 0);
      acc[fc] = __builtin_amdgcn_mfma_f32_16x16x32_bf16(al, bh, acc[fc], 0, 0, 0);
    }
    __syncthreads();
  }

  // ---- epilogue ----
#pragma unroll
  for (int j = 0; j < 4; ++j) {
    const int r = r0 + w*16 + l4*4 + j;
    float s = 0.f, q = 0.f;
#pragma unroll
    for (int fc = 0; fc < NF; ++fc) {
      int col = fc*16 + l15;
      float v = acc[fc][j] + bias[col];
      if (MODE == 2) { float g = gelu_f(v); v = g*v; }
      outp[(size_t)r*NCOLS + col] = v;
      if (MODE == 2) { s += v; q += v*v; }
    }
    if (MODE == 2) {
#pragma unroll
      for (int off = 8; off > 0; off >>= 1) {
        s += __shfl_down(s, off, 16);
        q += __shfl_down(q, off, 16);
      }
      if (l15 == 0) { rs[r] = s; rq[r] = q; }
    }
  }
}

// exact k-th-smallest via register-resident 4-bit radix select.
__global__ __launch_bounds__(1024) void k_thr(const float* __restrict__ ne,
                                              const float* __restrict__ qp, float* __restrict__ out)
{
  __shared__ unsigned s_part[16][8];
  __shared__ unsigned s_bsel, s_R;
  const int t = threadIdx.x;
  const int lane = t & 63, wv = t >> 6;
  unsigned key[14];
#pragma unroll
  for (int j = 0; j < 14; ++j) key[j] = __float_as_uint(ne[t + j*1024]);

  float q = qp[0];
  float pos = q * 14335.0f;
  int lo = (int)floorf(pos);
  if (lo < 0) lo = 0; if (lo > 14335) lo = 14335;
  int hi = lo + 1; if (hi > 14335) hi = 14335;
  float frac = pos - (float)lo;

  unsigned prefix = 0;
  unsigned R = (unsigned)lo;
#pragma unroll 1
  for (int shift = 28; shift >= 0; shift -= 4) {
    unsigned pb = prefix >> shift;
    unsigned long long accb = 0ull;
#pragma unroll
    for (int j = 0; j < 14; ++j) {
      unsigned diff = (key[j] >> shift) - pb;
      accb += (diff < 16u) ? (1ull << (diff*4)) : 0ull;
    }
    unsigned pk[8];
#pragma unroll
    for (int b = 0; b < 8; ++b) {
      unsigned clo = (unsigned)(accb >> (b*4)) & 15u;
      unsigned chi = (unsigned)(accb >> (b*4+32)) & 15u;
      pk[b] = clo | (chi << 16);
    }
#pragma unroll
    for (int b = 0; b < 8; ++b)
#pragma unroll
      for (int o = 32; o > 0; o >>= 1) pk[b] += __shfl_down(pk[b], o);
    if (lane == 0) {
#pragma unroll
      for (int b = 0; b < 8; ++b) s_part[wv][b] = pk[b];
    }
    __syncthreads();
    if (t == 0) {
      unsigned tot[16];
#pragma unroll
      for (int i = 0; i < 8; ++i) {
        unsigned s = 0;
#pragma unroll
        for (int w2 = 0; w2 < 16; ++w2) s += s_part[w2][i];
        tot[i] = s & 0xFFFFu; tot[i+8] = s >> 16;
      }
      unsigned cum = 0, bsel = 15;
#pragma unroll 1
      for (int b = 0; b < 16; ++b) {
        if (cum + tot[b] > R) { bsel = (unsigned)b; break; }
        cum += tot[b];
      }
      s_bsel = bsel; s_R = R - cum;
    }
    __syncthreads();
    prefix |= (s_bsel << shift);
    R = s_R;
    __syncthreads();
  }
  unsigned cle = 0, mn = 0xFFFFFFFFu;
#pragma unroll
  for (int j = 0; j < 14; ++j) {
    cle += (key[j] <= prefix) ? 1u : 0u;
    if (key[j] > prefix && key[j] < mn) mn = key[j];
  }
#pragma unroll
  for (int o = 32; o > 0; o >>= 1) {
    cle += __shfl_down(cle, o);
    unsigned m2 = __shfl_down(mn, o);
    mn = (m2 < mn) ? m2 : mn;
  }
  if (lane == 0) { s_part[wv][0] = cle; s_part[wv][1] = mn; }
  __syncthreads();
  if (t == 0) {
    unsigned C = 0, M = 0xFFFFFFFFu;
#pragma unroll
    for (int w2 = 0; w2 < 16; ++w2) {
      C += s_part[w2][0];
      if (s_part[w2][1] < M) M = s_part[w2][1];
    }
    unsigned vhiKey = (C > (unsigned)hi) ? prefix : M;
    if (vhiKey == 0xFFFFFFFFu) vhiKey = prefix;
    float vlo = __uint_as_float(prefix);
    float vhi = __uint_as_float(vhiKey);
    out[0] = vlo*(1.0f-frac) + vhi*frac;
  }
}

// ---------------- BN finalize from per-row sums ----------------
__global__ __launch_bounds__(256) void k_bnfin_rows(const float* __restrict__ rs,
    const float* __restrict__ rq, int nch, int nrows, double count,
    const float* __restrict__ gamma, const float* __restrict__ beta, float* __restrict__ out)
{
  __shared__ double sd[256];
  int ch = blockIdx.x, t = threadIdx.x;
  double s = 0.0, q = 0.0;
  for (int i = ch + t*nch; i < nrows; i += 256*nch) { s += rs[i]; q += rq[i]; }
  sd[t] = s; __syncthreads();
  for (int o = 128; o > 0; o >>= 1) { if (t < o) sd[t] += sd[t+o]; __syncthreads(); }
  double S = sd[0]; __syncthreads();
  sd[t] = q; __syncthreads();
  for (int o = 128; o > 0; o >>= 1) { if (t < o) sd[t] += sd[t+o]; __syncthreads(); }
  if (t == 0) {
    double m = S / count;
    double v = sd[0] / count - m*m; if (v < 0.0) v = 0.0;
    double inv = 1.0 / sqrt(v + 1e-5);
    out[ch]       = (float)(gamma[ch] * inv);
    out[nch + ch] = (float)(beta[ch] - m * gamma[ch] * inv);
  }
}

// BN3 from per-row S1/Q1 of (z1+z2) scaled by a1 per row
__global__ __launch_bounds__(256) void k_bnfin_scaled(const float* __restrict__ S1,
    const float* __restrict__ Q1, const float* __restrict__ a1,
    const float* __restrict__ gamma, const float* __restrict__ beta, float* __restrict__ out)
{
  __shared__ double sd[256];
  int ch = blockIdx.x, t = threadIdx.x;
  double s = 0.0, q = 0.0;
  for (int i = ch + t*7; i < BD; i += 256*7) {
    double a = a1[i];
    s += a * S1[i];
    q += a*a * Q1[i];
  }
  sd[t] = s; __syncthreads();
  for (int o = 128; o > 0; o >>= 1) { if (t < o) sd[t] += sd[t+o]; __syncthreads(); }
  double S = sd[0]; __syncthreads();
  sd[t] = q; __syncthreads();
  for (int o = 128; o > 0; o >>= 1) { if (t < o) sd[t] += sd[t+o]; __syncthreads(); }
  if (t == 0) {
    double m = S / 1048576.0;
    double v = sd[0] / 1048576.0 - m*m; if (v < 0.0) v = 0.0;
    double inv = 1.0 / sqrt(v + 1e-5);
    out[ch]     = (float)(gamma[ch] * inv);
    out[7 + ch] = (float)(beta[ch] - m * gamma[ch] * inv);
  }
}

__global__ __launch_bounds__(256) void k_bnfin_part(const float* __restrict__ pS,
    const float* __restrict__ pQ, int nparts, int nch, double count,
    const float* __restrict__ gamma, const float* __restrict__ beta, float* __restrict__ out)
{
  __shared__ double sd[256];
  int ch = blockIdx.x, t = threadIdx.x;
  double s = 0.0, q = 0.0;
  for (int i = t; i < nparts; i += 256) { s += pS[(size_t)i*nch + ch]; q += pQ[(size_t)i*nch + ch]; }
  sd[t] = s; __syncthreads();
  for (int o = 128; o > 0; o >>= 1) { if (t < o) sd[t] += sd[t+o]; __syncthreads(); }
  double S = sd[0]; __syncthreads();
  sd[t] = q; __syncthreads();
  for (int o = 128; o > 0; o >>= 1) { if (t < o) sd[t] += sd[t+o]; __syncthreads(); }
  if (t == 0) {
    double m = S / count;
    double v = sd[0] / count - m*m; if (v < 0.0) v = 0.0;
    double inv = 1.0 / sqrt(v + 1e-5);
    out[ch]       = (float)(gamma[ch] * inv);
    out[nch + ch] = (float)(beta[ch] - m * gamma[ch] * inv);
  }
}

// ---------------- patch path: z1r = V[n] @ xp-patch + c2 (xp from planes) ----------------
__global__ __launch_bounds__(256) void k_patch(const ushort* __restrict__ xph,
    const ushort* __restrict__ xpl,
    const float* __restrict__ V, const float* __restrict__ c2,
    float* __restrict__ z1r, float* __restrict__ pS, float* __restrict__ pQ)
{
  __shared__ float sx[8][512];
  __shared__ float aS[32], aQ[32];
  int t = threadIdx.x;
  int r0 = blockIdx.x * 8;
  for (int c = t; c < 1024; c += 256) {
    int row = c >> 7, cg = c & 127;
    size_t idx = (size_t)(r0+row)*512 + cg*4;
    sh4 hv = *(const sh4*)&xph[idx];
    sh4 lv = *(const sh4*)&xpl[idx];
#pragma unroll
    for (int e = 0; e < 4; ++e)
      sx[row][cg*4+e] = bf2f((unsigned)(ushort)hv[e]) + bf2f((unsigned)(ushort)lv[e]);
  }
  if (t < 32) { aS[t] = 0.f; aQ[t] = 0.f; }
  __syncthreads();
  float vreg[2][16]; float cc[2]; int nn_[2], oo[2];
#pragma unroll
  for (int h = 0; h < 2; ++h) {
    int o = t + h*256;
    oo[h] = o;
    int n = o >> 4, p = o & 15;
    nn_[h] = n;
#pragma unroll
    for (int qg = 0; qg < 4; ++qg) {
      float4 v4 = *(const float4*)&V[(size_t)n*256 + p*16 + qg*4];
      vreg[h][qg*4+0]=v4.x; vreg[h][qg*4+1]=v4.y; vreg[h][qg*4+2]=v4.z; vreg[h][qg*4+3]=v4.w;
    }
    cc[h] = c2[o];
  }
  float sum[2] = {0.f,0.f}, sq[2] = {0.f,0.f};
  for (int row = 0; row < 8; ++row) {
#pragma unroll
    for (int h = 0; h < 2; ++h) {
      const float* xr = &sx[row][nn_[h]*16];
      float val = cc[h];
#pragma unroll
      for (int qq = 0; qq < 16; ++qq) val += vreg[h][qq] * xr[qq];
      z1r[(size_t)(r0+row)*512 + oo[h]] = val;
      sum[h] += val; sq[h] += val*val;
    }
  }
#pragma unroll
  for (int h = 0; h < 2; ++h) {
    atomicAdd(&aS[nn_[h]], sum[h]);
    atomicAdd(&aQ[nn_[h]], sq[h]);
  }
  __syncthreads();
  if (t < 32) { pS[(size_t)blockIdx.x*32 + t] = aS[t]; pQ[(size_t)blockIdx.x*32 + t] = aQ[t]; }
}

// ---------------- TopKFreq att + per-row S1/Q1 of (z1+z2) ----------------
__global__ void k_att(const float* __restrict__ z1, const float* __restrict__ z1r,
    const float* __restrict__ bn2, const float* __restrict__ u, const float* __restrict__ fcb,
    float* __restrict__ att, float* __restrict__ S1o, float* __restrict__ Q1o)
{
  int r = blockIdx.x*4 + (threadIdx.x >> 6);
  int lane = threadIdx.x & 63;
  const float* z1p = z1 + (size_t)r*512;
  const float* zrp = z1r + (size_t)r*512;
  float s = 0.f, s1 = 0.f, q1 = 0.f;
#pragma unroll
  for (int h = 0; h < 2; ++h) {
    int i = lane*4 + h*256;
    int n = i >> 4;
    float a2n = bn2[n], c2n = bn2[32+n];
    float4 zr = *(const float4*)&zrp[i];
    float4 zv = *(const float4*)&z1p[i];
    float4 uv = *(const float4*)&u[i];
#pragma unroll
    for (int e = 0; e < 4; ++e) {
      float ze = (e==0?zr.x:e==1?zr.y:e==2?zr.z:zr.w);
      float z1e = (e==0?zv.x:e==1?zv.y:e==2?zv.z:zv.w);
      float ue = (e==0?uv.x:e==1?uv.y:e==2?uv.z:uv.w);
      float tv = z1e + gelu_f(a2n*ze + c2n);
      s += tv * ue; s1 += tv; q1 += tv*tv;
    }
  }
  s = wred(s); s1 = wred(s1); q1 = wred(q1);
  if (lane == 0) { att[r] = s + fcb[0]; S1o[r] = s1; Q1o[r] = q1; }
}

__global__ __launch_bounds__(1024) void k_tf(const float* __restrict__ att,
    const float* __restrict__ pg, const float* __restrict__ pb,
    const float* __restrict__ pwc, const float* __restrict__ pbc,
    const float* __restrict__ pfb, float* __restrict__ a1, float* __restrict__ a2)
{
  __shared__ double sd[1024];
  __shared__ float sh[4];
  const int t = threadIdx.x;
  float g = pg[0], b = pb[0], wc = pwc[0], bc = pbc[0], fb = pfb[0];
  double s = 0.0, q = 0.0;
  for (int i = t; i < BD; i += 1024) { double v = att[i]; s += v; q += v*v; }
  sd[t] = s; __syncthreads();
  for (int o = 512; o > 0; o >>= 1) { if (t < o) sd[t] += sd[t+o]; __syncthreads(); }
  double S1 = sd[0]; __syncthreads();
  sd[t] = q; __syncthreads();
  for (int o = 512; o > 0; o >>= 1) { if (t < o) sd[t] += sd[t+o]; __syncthreads(); }
  if (t == 0) {
    double m = S1 / 14336.0;
    double v = sd[0] / 14336.0 - m*m; if (v < 0.0) v = 0.0;
    sh[0] = (float)m; sh[1] = (float)(1.0 / sqrt(v + 1e-5));
  }
  __syncthreads();
  float m1 = sh[0], i1 = sh[1];
  s = 0.0; q = 0.0;
  for (int i = t; i < BD; i += 1024) {
    float v = att[i];
    float an = (v - m1) * i1 * g + b;
    float av = sigm_f(gelu_f(an) * wc + bc);
    a1[i] = av;
    float t2 = av * (v - fb) + fb;
    s += t2; q += (double)t2 * t2;
  }
  __syncthreads();
  sd[t] = s; __syncthreads();
  for (int o = 512; o > 0; o >>= 1) { if (t < o) sd[t] += sd[t+o]; __syncthreads(); }
  double S2 = sd[0]; __syncthreads();
  sd[t] = q; __syncthreads();
  for (int o = 512; o > 0; o >>= 1) { if (t < o) sd[t] += sd[t+o]; __syncthreads(); }
  if (t == 0) {
    double m = S2 / 14336.0;
    double v = sd[0] / 14336.0 - m*m; if (v < 0.0) v = 0.0;
    sh[2] = (float)m; sh[3] = (float)(1.0 / sqrt(v + 1e-5));
  }
  __syncthreads();
  float m2 = sh[2], i2 = sh[3];
  for (int i = t; i < BD; i += 1024) {
    float t2 = a1[i] * (att[i] - fb) + fb;
    float an = (t2 - m2) * i2 * g + b;
    a2[i] = sigm_f(gelu_f(an) * wc + bc);
  }
}

// ---------------- statsC (float4) ----------------
__global__ void k_statsC(const float* __restrict__ z1, const float* __restrict__ z1r,
    const float* __restrict__ bn2, const float* __restrict__ a1,
    const float* __restrict__ bn3, const float* __restrict__ cw, const float* __restrict__ cb,
    float* __restrict__ rs, float* __restrict__ rq)
{
  int r = blockIdx.x*4 + (threadIdx.x >> 6);
  int lane = threadIdx.x & 63;
  int d = r % 7;
  float av = a1[r];
  float b3a = bn3[d], b3c = bn3[7+d], wv = cw[d], bv = cb[d];
  const float* z1p = z1 + (size_t)r*512;
  const float* zrp = z1r + (size_t)r*512;
  float s = 0.f, q = 0.f;
#pragma unroll
  for (int h = 0; h < 2; ++h) {
    int i = lane*4 + h*256;
    int n = i >> 4;
    float a2n = bn2[n], c2n = bn2[32+n];
    float4 zr = *(const float4*)&zrp[i];
    float4 zv = *(const float4*)&z1p[i];
#pragma unroll
    for (int e = 0; e < 4; ++e) {
      float ze = (e==0?zr.x:e==1?zr.y:e==2?zr.z:zr.w);
      float z1e = (e==0?zv.x:e==1?zv.y:e==2?zv.z:zv.w);
      float A = (z1e + gelu_f(a2n*ze + c2n)) * av;
      float C = wv*gelu_f(b3a*A + b3c) + bv;
      s += C; q += C*C;
    }
  }
  s = wred(s); q = wred(q);
  if (lane == 0) { rs[r] = s; rq[r] = q; }
}

// ---------------- final mix: writes zf as bf16 hi/lo planes + row stats ----------------
__global__ void k_final(const float* __restrict__ z1, const float* __restrict__ z1r,
    const float* __restrict__ bn2, const float* __restrict__ a1, const float* __restrict__ a2,
    const float* __restrict__ bn3, const float* __restrict__ bn4,
    const float* __restrict__ cw, const float* __restrict__ cb,
    ushort* __restrict__ zfh, ushort* __restrict__ zfl,
    float* __restrict__ rs, float* __restrict__ rq)
{
  int r = blockIdx.x*4 + (threadIdx.x >> 6);
  int lane = threadIdx.x & 63;
  int d = r % 7;
  float av = a1[r], a2v = a2[r];
  float b3a = bn3[d], b3c = bn3[7+d], b4a = bn4[d], b4c = bn4[7+d];
  float wv = cw[d], bv = cb[d];
  const float* z1p = z1 + (size_t)r*512;
  const float* zrp = z1r + (size_t)r*512;
  float s = 0.f, q = 0.f;
#pragma unroll
  for (int h = 0; h < 2; ++h) {
    int i = lane*4 + h*256;
    int n = i >> 4;
    float a2n = bn2[n], c2n = bn2[32+n];
    float4 zr = *(const float4*)&zrp[i];
    float4 zv = *(const float4*)&z1p[i];
    sh4 hv, lv;
#pragma unroll
    for (int e = 0; e < 4; ++e) {
      float ze = (e==0?zr.x:e==1?zr.y:e==2?zr.z:zr.w);
      float z1e = (e==0?zv.x:e==1?zv.y:e==2?zv.z:zv.w);
      float z1v = z1e * av;
      float z2v = gelu_f(a2n*ze + c2n) * av;
      float A = z1v + z2v;
      float C = wv*gelu_f(b3a*A + b3c) + bv;
      float inter = gelu_f(b4a*C + b4c) * a2v;
      float z1n = z1v*inter + z2v;
      float z2n = z2v*inter + z1n;
      float zfv = z1n*z2n + z1n + z2n;
      short hh, ll;
      tsplit(zfv, hh, ll);
      hv[e] = hh; lv[e] = ll;
      s += zfv; q += zfv*zfv;
    }
    *(sh4*)&zfh[(size_t)r*512 + i] = hv;
    *(sh4*)&zfl[(size_t)r*512 + i] = lv;
  }
  s = wred(s); q = wred(q);
  if (lane == 0) { rs[r] = s; rq[r] = q; }
}

// ---------------- output: fc2 + bias + z_res + transpose ----------------
__global__ __launch_bounds__(256) void k_out(const float* __restrict__ h2,
    const float* __restrict__ bn6, const float* __restrict__ w2, const float* __restrict__ b2,
    const float* __restrict__ zres, float* __restrict__ out)
{
  int idx = blockIdx.x*256 + threadIdx.x;
  int r = idx / 96, o = idx - r*96;
  int d = r % 7, b = r / 7;
  float a6 = bn6[d], c6 = bn6[7+d];
  const float* hp = h2 + (size_t)r*48;
  const float* wp = w2 + o*48;
  float s = 0.f;
#pragma unroll
  for (int j4 = 0; j4 < 12; ++j4) {
    float4 hv = *(const float4*)&hp[j4*4];
    float4 wv = *(const float4*)&wp[j4*4];
    s += (a6*hv.x + c6)*wv.x + (a6*hv.y + c6)*wv.y
       + (a6*hv.z + c6)*wv.z + (a6*hv.w + c6)*wv.w;
  }
  out[(size_t)b*672 + o*7 + d] = s + b2[o] + zres[(size_t)r*96 + o];
}

// ================= host =================
extern "C" void kernel_launch(void* const* d_in, const int* in_sizes, int n_in,
                              void* d_out, int out_size, void* d_ws, size_t ws_size,
                              hipStream_t stream) {
  const float* x          = (const float*)d_in[0];
  const float* dctconv_w  = (const float*)d_in[1];
  const float* dctconv_b  = (const float*)d_in[2];
  const float* dctnorm_g  = (const float*)d_in[3];
  const float* dctnorm_b  = (const float*)d_in[4];
  const float* threshold  = (const float*)d_in[5];
  const float* embed_W    = (const float*)d_in[6];
  const float* embed_b    = (const float*)d_in[7];
  const float* linres_W   = (const float*)d_in[8];
  const float* linres_b   = (const float*)d_in[9];
  const float* depth1_w   = (const float*)d_in[10];
  const float* depth1_b   = (const float*)d_in[11];
  const float* depthnorm_g= (const float*)d_in[12];
  const float* depthnorm_b= (const float*)d_in[13];
  const float* tf_fc_w    = (const float*)d_in[14];
  const float* tf_fc_b    = (const float*)d_in[15];
  const float* tf_norm_g  = (const float*)d_in[16];
  const float* tf_norm_b  = (const float*)d_in[17];
  const float* tf_conv_w  = (const float*)d_in[18];
  const float* tf_conv_b  = (const float*)d_in[19];
  const float* mlp_w1     = (const float*)d_in[20];
  const float* mlp_b1     = (const float*)d_in[21];
  const float* mlp_w2     = (const float*)d_in[22];
  const float* mlp_b2     = (const float*)d_in[23];
  const float* mlpnorm_g  = (const float*)d_in[24];
  const float* mlpnorm_b  = (const float*)d_in[25];
  float* out = (float*)d_out;
  float* ws  = (float*)d_ws;

  ushort* XPH = (ushort*)(ws + F_XP);             // xp hi/lo planes (fill F_XP exactly)
  ushort* XPL = XPH + (size_t)BD*512;
  ushort* ZFH = XPH;                              // zf planes overwrite xp planes at k_final
  ushort* ZFL = XPL;
  float* ZG   = ws + F_ZG;                        // z1r f32 (after GEMM2); GH/GL planes before
  ushort* ZGH = (ushort*)(ws + F_ZG);
  ushort* ZGL = ZGH + (size_t)BD*512;
  float* Z1   = ws + F_Z1;
  ushort* B1H = (ushort*)(ws + F_CLK);
  ushort* B1L = B1H + 512*512;
  ushort* B2H = (ushort*)(ws + F_MKL);
  ushort* B2L = B2H + 512*512;
  ushort* W2H = (ushort*)(ws + F_W2);
  ushort* W2L = W2H + 96*512;
  ushort* W1H = (ushort*)(ws + F_W1);
  ushort* W1L = W1H + 48*512;
  float* U    = ws + F_U;
  float* CSUM = ws + F_CSUM;
  float* CSTp = ws + F_CST;
  float* Vp   = ws + F_V;
  float* C2p  = ws + F_C2;
  float* ZRES = ws + F_ZRES;
  float* H2p  = ws + F_H2;
  float* NEp  = ws + F_NE;
  float* ATTp = ws + F_ATT;
  float* A1p  = ws + F_A1;
  float* A2p  = ws + F_A2;
  float* RS   = ws + F_RS;
  float* RQ   = ws + F_RQ;
  float* PS   = ws + F_PS;
  float* PQ   = ws + F_PQ;
  float* BN0  = ws + F_BN;        // a[7], c[7]
  float* BN2  = ws + F_BN + 16;   // a[32], c[32]
  float* BN3  = ws + F_BN + 80;
  float* BN4  = ws + F_BN + 96;
  float* BN5  = ws + F_BN + 112;
  float* BN6  = ws + F_BN + 128;
  float* THRp = ws + F_THR;

  k_setup<<<738, 256, 0, stream>>>(B1H, B1L, B2H, B2L, U, CSUM, tf_fc_w,
      embed_W, embed_b, depth1_w, depth1_b, Vp, C2p,
      mlp_w1, W1H, W1L, linres_W, linres_b, W2H, W2L, CSTp);
  k_transpose<<<2048, 256, 0, stream>>>(x, XPH, XPL, NEp);
  k_thr<<<1, 1024, 0, stream>>>(NEp, threshold, THRp);
  hipMemsetAsync(RS, 0, 2*BD*sizeof(float), stream);
  // GEMM1: z_dct -> masked dctconv -> gelu -> GH/GL planes (+ row stats)
  k_mfma<2><<<dim3(112,4), 256, 0, stream>>>(XPH, XPL, B1H, B1L,
      nullptr, ZGH, ZGL, nullptr, nullptr, nullptr, nullptr, dctconv_w, dctconv_b,
      NEp, THRp, RS, RQ);
  k_bnfin_rows<<<7, 256, 0, stream>>>(RS, RQ, 7, BD, 1048576.0, dctnorm_g, dctnorm_b, BN0);
  // GEMM2: z1 = BN(g) @ M + x_res  (BN folded via column sums)
  k_mfma<1><<<dim3(112,4), 256, 0, stream>>>(ZGH, ZGL, B2H, B2L,
      Z1, nullptr, nullptr, BN0, CSUM, XPH, XPL, dctconv_w, dctconv_b,
      nullptr, nullptr, nullptr, nullptr);
  k_patch<<<1792, 256, 0, stream>>>(XPH, XPL, Vp, C2p, ZG, PS, PQ);
  k_bnfin_part<<<32, 256, 0, stream>>>(PS, PQ, 1792, 32, 229376.0, depthnorm_g, depthnorm_b, BN2);
  // ZRES = XP @ W2^T + cst   (plane copy staging)
  k_mfma_nt<96,0><<<224, 256, 0, stream>>>(XPH, XPL, W2H, W2L, CSTp, ZRES,
      nullptr, nullptr, nullptr, nullptr);
  // att + per-row S1/Q1 of (z1+z2)
  k_att<<<3584, 256, 0, stream>>>(Z1, ZG, BN2, U, tf_fc_b, ATTp, RS, RQ);
  k_tf<<<1, 1024, 0, stream>>>(ATTp, tf_norm_g, tf_norm_b, tf_conv_w, tf_conv_b, tf_fc_b, A1p, A2p);
  // BN3 from a1-scaled per-row sums (statsA pass eliminated)
  k_bnfin_scaled<<<7, 256, 0, stream>>>(RS, RQ, A1p, dctnorm_g, dctnorm_b, BN3);
  k_statsC<<<3584, 256, 0, stream>>>(Z1, ZG, BN2, A1p, BN3, dctconv_w, dctconv_b, RS, RQ);
  k_bnfin_rows<<<7, 256, 0, stream>>>(RS, RQ, 7, BD, 1048576.0, dctnorm_g, dctnorm_b, BN4);
  k_final<<<3584, 256, 0, stream>>>(Z1, ZG, BN2, A1p, A2p, BN3, BN4, dctconv_w, dctconv_b,
      ZFH, ZFL, RS, RQ);
  k_bnfin_rows<<<7, 256, 0, stream>>>(RS, RQ, 7, BD, 1048576.0, dctnorm_g, dctnorm_b, BN5);
  // MLP fc1: h2 = gelu(v)*v with v = gelu(BN5(zf)) @ w1^T + b1   (reads zf planes)
  k_mfma_nt<48,2><<<224, 256, 0, stream>>>(ZFH, ZFL, W1H, W1L, mlp_b1, H2p,
      BN5, BN5+7, RS, RQ);
  k_bnfin_rows<<<7, 256, 0, stream>>>(RS, RQ, 7, BD, 98304.0, mlpnorm_g, mlpnorm_b, BN6);
  k_out<<<5376, 256, 0, stream>>>(H2p, BN6, mlp_w2, mlp_b2, ZRES, out);
}

// Round 12
// 344.332 us; speedup vs baseline: 2.4087x; 1.0135x over previous
//
#include <hip/hip_runtime.h>
#include <math.h>

#define BB 2048
#define LL 512
#define DD 7
#define BD 14336   // BB*DD

// ---------------- ws layout (floats) ----------------
constexpr size_t F_XP   = 0;                          // XPH/XPL planes, later ZFH/ZFL planes
constexpr size_t F_ZG   = F_XP  + (size_t)BD*512;     // ZGH/ZGL planes -> z1r f32
constexpr size_t F_Z1   = F_ZG  + (size_t)BD*512;     // z1
constexpr size_t F_CLK  = F_Z1  + (size_t)BD*512;     // B1H/B1L (fills region exactly)
constexpr size_t F_MKL  = F_CLK + 512*512;            // B2H/B2L (fills region exactly)
constexpr size_t F_U    = F_MKL + 512*512;
constexpr size_t F_CSUM = F_U + 512;
constexpr size_t F_W2   = F_CSUM + 512;               // W2H/W2L ushort planes (exact fit)
constexpr size_t F_CST  = F_W2 + 96*512;
constexpr size_t F_V    = F_CST + 96;                 // 32x16x16
constexpr size_t F_C2   = F_V + 32*256;               // 32x16
constexpr size_t F_ZRES = F_C2 + 512;                 // BD x 96
constexpr size_t F_H2   = F_ZRES + (size_t)BD*96;     // BD x 48
constexpr size_t F_EN   = F_H2 + (size_t)BD*48;       // (unused)
constexpr size_t F_NE   = F_EN + BD;
constexpr size_t F_ATT  = F_NE + BD;
constexpr size_t F_A1   = F_ATT + BD;
constexpr size_t F_A2   = F_A1 + BD;
constexpr size_t F_RS   = F_A2 + BD;
constexpr size_t F_RQ   = F_RS + BD;                  // adjacent to F_RS (one memset)
constexpr size_t F_PS   = F_RQ + BD;                  // 1792 x 32
constexpr size_t F_PQ   = F_PS + 1792*32;
constexpr size_t F_BN   = F_PQ + 1792*32;             // bn affine params
constexpr size_t F_THR  = F_BN + 256;
constexpr size_t F_W1   = F_THR + 16;                 // W1H/W1L ushort planes (24576 floats)

typedef __attribute__((ext_vector_type(8))) short bf8;
typedef __attribute__((ext_vector_type(4))) short sh4;
typedef __attribute__((ext_vector_type(4))) float f4;

__device__ __forceinline__ float gelu_f(float x) {
  return 0.5f * x * (1.0f + erff(x * 0.70710678118654752440f));
}
__device__ __forceinline__ float sigm_f(float x) {
  return 1.0f / (1.0f + expf(-x));
}
__device__ __forceinline__ float wred(float v) {
#pragma unroll
  for (int o = 32; o > 0; o >>= 1) v += __shfl_down(v, o);
  return v;
}
__device__ __forceinline__ unsigned bfh_u(float v) {     // round-to-nearest (setup only)
  unsigned u = __float_as_uint(v);
  return (u + 0x7FFFu + ((u >> 16) & 1u)) >> 16;
}
__device__ __forceinline__ float bf2f(unsigned h) { return __uint_as_float(h << 16); }
// truncation split: 4 VALU ops, error ~2^-16 rel
__device__ __forceinline__ void tsplit(float v, short &h, short &l) {
  unsigned u = __float_as_uint(v);
  h = (short)(u >> 16);
  float lo = v - bf2f(u >> 16);
  l = (short)(__float_as_uint(lo) >> 16);
}
// async global->LDS, 16B per lane; lds dest = wave-uniform base + lane*16
__device__ __forceinline__ void gload16(const ushort* g, ushort* l) {
  __builtin_amdgcn_global_load_lds(
      (const __attribute__((address_space(1))) void*)g,
      (__attribute__((address_space(3))) void*)l, 16, 0, 0);
}

#define PI1024 0.00306796157577128218f   // pi/1024

// ---------------- fused setup: gen_b + ucsum + v + splitw + w2 ----------------
__global__ __launch_bounds__(256) void k_setup(
    ushort* __restrict__ B1H, ushort* __restrict__ B1L,
    ushort* __restrict__ B2H, ushort* __restrict__ B2L,
    float* __restrict__ u, float* __restrict__ csum, const float* __restrict__ wf,
    const float* __restrict__ eW, const float* __restrict__ eb,
    const float* __restrict__ dw, const float* __restrict__ db,
    float* __restrict__ V, float* __restrict__ c2,
    const float* __restrict__ mlpw1, ushort* __restrict__ W1H, ushort* __restrict__ W1L,
    const float* __restrict__ linW, const float* __restrict__ linb,
    ushort* __restrict__ W2H, ushort* __restrict__ W2L, float* __restrict__ cst)
{
  __shared__ float sW[768];
  __shared__ float sb[48];
  __shared__ float rbuf[256];
  const int bid = blockIdx.x, t = threadIdx.x;
  if (bid < 512) {
    int c = bid;
    for (int r = t; r < 512; r += 256) {
      int n1 = ((2*r + 1) * c) & 2047;
      float v1 = 2.0f * cosf((float)n1 * PI1024);
      unsigned h = bfh_u(v1);
      B1H[(size_t)c*512 + r] = (ushort)h;
      B1L[(size_t)c*512 + r] = (ushort)bfh_u(v1 - bf2f(h));
      int n2 = ((2*c + 1) * r) & 2047;
      float v2 = cosf((float)n2 * PI1024) * (r == 0 ? (1.0f/1024.0f) : (1.0f/512.0f));
      h = bfh_u(v2);
      B2H[(size_t)c*512 + r] = (ushort)h;
      B2L[(size_t)c*512 + r] = (ushort)bfh_u(v2 - bf2f(h));
    }
  } else if (bid < 514) {
    int l = (bid - 512)*256 + t;
    if (l < 512) {
      double th2 = 3.14159265358979323846 * (double)(2*l + 1) / 2048.0;
      double s = (l & 1) ? -1.0 : 1.0;
      double S = 0.5*s/tan(th2) - 0.5;
      csum[l] = (float)(1.0/1024.0 + S/512.0);
      double uu = (double)wf[0] * 45.25483399593904156 / 1024.0;
      for (int k = 1; k < 5; ++k)
        uu += (double)wf[k] * 32.0 * cos(3.14159265358979323846*(l+0.5)*k/512.0) / 512.0;
      u[l] = (float)uu;
    }
  } else if (bid < 546) {
    int n = bid - 514;
    int p = t >> 4, q = t & 15;
    float s = 0.f;
#pragma unroll
    for (int j = 0; j < 3; ++j) s += eW[(p*3+j)*16 + q] * dw[n*3+j];
    V[(size_t)n*256 + p*16 + q] = s;
    if (q == 0) {
      float c = 0.f;
#pragma unroll
      for (int j = 0; j < 3; ++j) c += eb[p*3+j] * dw[n*3+j];
      c2[n*16+p] = c + db[n];
    }
  } else if (bid < 642) {
    int i = (bid - 546)*256 + t;
    if (i < 48*512) {
      float v = mlpw1[i];
      unsigned hb = bfh_u(v);
      W1H[i] = (ushort)hb;
      W1L[i] = (ushort)bfh_u(v - bf2f(hb));
    }
  } else {
    int o = bid - 642;
    for (int i = t; i < 768; i += 256) sW[i] = eW[i];
    if (t < 48) sb[t] = eb[t];
    __syncthreads();
    const float* lw = linW + (size_t)o * 1536;
    for (int i = t; i < 512; i += 256) {
      int n = i >> 4, p = i & 15;
      float s = 0.f;
      const float* l2 = lw + n*48;
#pragma unroll 8
      for (int m = 0; m < 48; ++m) s += l2[m] * sW[m*16 + p];
      unsigned hb = bfh_u(s);
      W2H[(size_t)o*512 + i] = (ushort)hb;
      W2L[(size_t)o*512 + i] = (ushort)bfh_u(s - bf2f(hb));
    }
    float c = 0.f;
    for (int i = t; i < 1536; i += 256) c += lw[i] * sb[i % 48];
    rbuf[t] = c; __syncthreads();
    for (int off = 128; off > 0; off >>= 1) { if (t < off) rbuf[t] += rbuf[t+off]; __syncthreads(); }
    if (t == 0) cst[o] = rbuf[0] + linb[o];
  }
}

// ---------------- transpose [B,L,D] -> bf16 hi/lo planes + fused energy/median -> ne --------
__global__ __launch_bounds__(256) void k_transpose(const float* __restrict__ x,
                                                   ushort* __restrict__ xph,
                                                   ushort* __restrict__ xpl,
                                                   float* __restrict__ ne) {
  __shared__ float s[3584];
  __shared__ float sEn[7];
  int b = blockIdx.x;
  const float* src = x + (size_t)b*3584;
  for (int c = threadIdx.x; c < 896; c += 256) {
    float4 v = *(const float4*)&src[c*4];
    s[c*4+0]=v.x; s[c*4+1]=v.y; s[c*4+2]=v.z; s[c*4+3]=v.w;
  }
  __syncthreads();
  for (int c = threadIdx.x; c < 896; c += 256) {
    int d = c >> 7, cg = c & 127;
    sh4 hv, lv;
#pragma unroll
    for (int e = 0; e < 4; ++e) {
      float v = s[(cg*4+e)*7 + d];
      short hh, ll;
      tsplit(v, hh, ll);
      hv[e] = hh; lv[e] = ll;
    }
    size_t idx = ((size_t)b*7 + d)*512 + cg*4;
    *(sh4*)&xph[idx] = hv;
    *(sh4*)&xpl[idx] = lv;
  }
  int t = threadIdx.x;
  if (t < 224) {
    int d = t >> 5, c0 = (t & 31) * 16;
    double ss = 0.0, qq = 0.0;
    for (int l = c0; l < c0 + 16; ++l) {
      double v = s[l*7 + d];
      ss += v; qq += v*v;
    }
#pragma unroll
    for (int o = 16; o > 0; o >>= 1) {
      ss += __shfl_down(ss, o, 32);
      qq += __shfl_down(qq, o, 32);
    }
    if ((t & 31) == 0) sEn[d] = (float)(1024.0*qq + 2.0*ss*ss);
  }
  __syncthreads();
  if (t == 0) {
    float e[7], s7[7];
#pragma unroll
    for (int d = 0; d < 7; ++d) { e[d] = sEn[d]; s7[d] = e[d]; }
#pragma unroll
    for (int i = 1; i < 7; ++i) {
      float key = s7[i]; int j = i-1;
      while (j >= 0 && s7[j] > key) { s7[j+1] = s7[j]; --j; }
      s7[j+1] = key;
    }
    float med = s7[3] + 1e-6f;
#pragma unroll
    for (int d = 0; d < 7; ++d) ne[b*7 + d] = e[d] / med;
  }
}

// ---------------- MFMA bf16-split GEMM: C[M,512] = A[M,512] @ B[512,512] ----------------
// BM=128, BN=128, BK=32; 4 waves x (64x64); 3-term split.
// Staging via global_load_lds (16B/lane DMA), LINEAR LDS [128][32] ushorts per plane,
// source pre-swizzled (slot ^= (row>>3&1)<<1) + same XOR on frag reads (8-way -> 4-way).
// MODE 2: epilogue g=gelu(acc*mask*w+b) -> GH/GL planes (truncation split) + row stats
// MODE 1: epilogue z1 = aR*acc + cR*csum + (hi+lo)(xp)*w + b -> f32
template<int MODE>
__global__ __launch_bounds__(256) void k_mfma(
    const ushort* __restrict__ AHg, const ushort* __restrict__ ALg,
    const ushort* __restrict__ BHg, const ushort* __restrict__ BLg,
    float* __restrict__ z1out, ushort* __restrict__ GH, ushort* __restrict__ GL,
    const float* __restrict__ bnac, const float* __restrict__ csum,
    const ushort* __restrict__ xph, const ushort* __restrict__ xpl,
    const float* __restrict__ cw, const float* __restrict__ cb,
    const float* __restrict__ ne, const float* __restrict__ thr,
    float* __restrict__ rs, float* __restrict__ rq)
{
  __shared__ ushort AhS[128*32], AlS[128*32];
  __shared__ ushort BhS[128*32], BlS[128*32];
  const int t = threadIdx.x;
  const int lane = t & 63, w = t >> 6;
  const int l15 = lane & 15, l4 = lane >> 4;
  const int wr = (w & 1)*64, wc = (w >> 1)*64;
  const int r0 = blockIdx.x * 128, c0 = blockIdx.y * 128;

  f4 acc[4][4];
#pragma unroll
  for (int i = 0; i < 4; ++i)
#pragma unroll
    for (int j = 0; j < 4; ++j) acc[i][j] = (f4){0.f,0.f,0.f,0.f};

  // staging geometry: segment s = w*2+h covers rows s*16..s*16+15 (1KB per plane);
  // lane writes 16B at row = s*16 + (lane>>2); source slot pre-swizzled.
  const int rl0 = lane >> 2;
  const int ssl = (lane & 3) ^ (((lane >> 5) & 1) << 1);
  // frag-read swizzle (same XOR): depends only on l15
  const int swr = ((l15 >> 3) & 1) << 1;

  for (int kt = 0; kt < 512; kt += 32) {
#pragma unroll
    for (int h = 0; h < 2; ++h) {
      const int s = w*2 + h;
      const int row = s*16 + rl0;
      const size_t gA = (size_t)(r0+row)*512 + kt + ssl*8;
      const size_t gB = (size_t)(c0+row)*512 + kt + ssl*8;
      gload16(&AHg[gA], &AhS[s*512]);
      gload16(&ALg[gA], &AlS[s*512]);
      gload16(&BHg[gB], &BhS[s*512]);
      gload16(&BLg[gB], &BlS[s*512]);
    }
    __syncthreads();
    // ---- compute ----
    bf8 ah[4], al[4], bh[4], bl[4];
    const int ko = (l4 ^ swr)*8;
#pragma unroll
    for (int fr = 0; fr < 4; ++fr) {
      int off = (wr + fr*16 + l15)*32 + ko;
      ah[fr] = *(const bf8*)&AhS[off];
      al[fr] = *(const bf8*)&AlS[off];
    }
#pragma unroll
    for (int fc = 0; fc < 4; ++fc) {
      int off = (wc + fc*16 + l15)*32 + ko;
      bh[fc] = *(const bf8*)&BhS[off];
      bl[fc] = *(const bf8*)&BlS[off];
    }
#pragma unroll
    for (int fr = 0; fr < 4; ++fr)
#pragma unroll
      for (int fc = 0; fc < 4; ++fc) {
        acc[fr][fc] = __builtin_amdgcn_mfma_f32_16x16x32_bf16(ah[fr], bh[fc], acc[fr][fc], 0, 0, 0);
        acc[fr][fc] = __builtin_amdgcn_mfma_f32_16x16x32_bf16(ah[fr], bl[fc], acc[fr][fc], 0, 0, 0);
        acc[fr][fc] = __builtin_amdgcn_mfma_f32_16x16x32_bf16(al[fr], bh[fc], acc[fr][fc], 0, 0, 0);
      }
    __syncthreads();
  }

  // ---- epilogue ----
  const float thv = (MODE == 2) ? thr[0] : 0.f;
#pragma unroll
  for (int fr = 0; fr < 4; ++fr)
#pragma unroll
    for (int j = 0; j < 4; ++j) {
      const int r = r0 + wr + fr*16 + l4*4 + j;
      const int d = r % 7;
      if (MODE == 1) {
        const float aR = bnac[d], cR = bnac[7+d], wv = cw[d], bvv = cb[d];
#pragma unroll
        for (int fc = 0; fc < 4; ++fc) {
          int col = c0 + wc + fc*16 + l15;
          size_t idx = (size_t)r*512 + col;
          float xv = bf2f(xph[idx]) + bf2f(xpl[idx]);
          float val = acc[fr][fc][j];
          z1out[idx] = aR*val + cR*csum[col] + xv*wv + bvv;
        }
      } else {
        float m = (ne[r] > thv) ? 1.0f : 0.0f;
        float wm = cw[d] * m, bvv = cb[d];
        float s = 0.f, q = 0.f;
#pragma unroll
        for (int fc = 0; fc < 4; ++fc) {
          int col = c0 + wc + fc*16 + l15;
          float g = gelu_f(acc[fr][fc][j]*wm + bvv);
          short hh, ll;
          tsplit(g, hh, ll);
          GH[(size_t)r*512 + col] = (ushort)hh;
          GL[(size_t)r*512 + col] = (ushort)ll;
          s += g; q += g*g;
        }
#pragma unroll
        for (int off = 8; off > 0; off >>= 1) {
          s += __shfl_down(s, off, 16);
          q += __shfl_down(q, off, 16);
        }
        if (l15 == 0) { atomicAdd(&rs[r], s); atomicAdd(&rq[r], q); }
      }
    }
}

// ---------------- MFMA bf16-split NT GEMM: out[M,NCOLS] = A[M,512] @ W[NCOLS,512]^T + bias ----
// BM=64 (4 waves x 16 rows), BK=32, 3-term split; A from hi/lo planes.
// MODE 0: plane copy, plain store (ZRES).
// MODE 2: reconstruct -> gelu(ta*x+tc) -> truncation split; out gelu(v)*v; row stats.
template<int NCOLS, int MODE>
__global__ __launch_bounds__(256) void k_mfma_nt(
    const ushort* __restrict__ AHp, const ushort* __restrict__ ALp,
    const ushort* __restrict__ WH, const ushort* __restrict__ WL,
    const float* __restrict__ bias, float* __restrict__ outp,
    const float* __restrict__ ta, const float* __restrict__ tc,
    float* __restrict__ rs, float* __restrict__ rq)
{
  constexpr int NF = NCOLS / 16;
  __shared__ ushort AhS[64*40], AlS[64*40];
  __shared__ ushort BhS[NCOLS*40], BlS[NCOLS*40];
  const int t = threadIdx.x;
  const int lane = t & 63, w = t >> 6;
  const int l15 = lane & 15, l4 = lane >> 4;
  const int r0 = blockIdx.x * 64;

  f4 acc[NF];
#pragma unroll
  for (int fc = 0; fc < NF; ++fc) acc[fc] = (f4){0.f,0.f,0.f,0.f};

  const int arow = t >> 2, ak0 = (t & 3) * 8;
  float taa = 0.f, tcc = 0.f;
  if (MODE == 2) { int d = (r0 + arow) % 7; taa = ta[d]; tcc = tc[d]; }

  for (int kt = 0; kt < 512; kt += 32) {
    // ---- stage A (64x32) ----
    if (MODE == 0) {
      *(bf8*)&AhS[arow*40 + ak0] = *(const bf8*)&AHp[(size_t)(r0+arow)*512 + kt + ak0];
      *(bf8*)&AlS[arow*40 + ak0] = *(const bf8*)&ALp[(size_t)(r0+arow)*512 + kt + ak0];
    } else {
      bf8 hv8 = *(const bf8*)&AHp[(size_t)(r0+arow)*512 + kt + ak0];
      bf8 lv8 = *(const bf8*)&ALp[(size_t)(r0+arow)*512 + kt + ak0];
      bf8 hv, lv;
#pragma unroll
      for (int j = 0; j < 8; ++j) {
        float xv = bf2f((unsigned)(ushort)hv8[j]) + bf2f((unsigned)(ushort)lv8[j]);
        float g = gelu_f(taa*xv + tcc);
        short hh, ll;
        tsplit(g, hh, ll);
        hv[j] = hh; lv[j] = ll;
      }
      *(bf8*)&AhS[arow*40 + ak0] = hv;
      *(bf8*)&AlS[arow*40 + ak0] = lv;
    }
    // ---- stage B (NCOLS x 32) ----
    for (int c = t; c < NCOLS*4; c += 256) {
      int brow = c >> 2, bk0 = (c & 3) * 8;
      *(bf8*)&BhS[brow*40 + bk0] = *(const bf8*)&WH[(size_t)brow*512 + kt + bk0];
      *(bf8*)&BlS[brow*40 + bk0] = *(const bf8*)&WL[(size_t)brow*512 + kt + bk0];
    }
    __syncthreads();
    // ---- compute: wave w owns rows w*16..w*16+15 ----
    bf8 ah, al;
    {
      int off = (w*16 + l15)*40 + l4*8;
      ah = *(const bf8*)&AhS[off];
      al = *(const bf8*)&AlS[off];
    }
#pragma unroll
    for (int fc = 0; fc < NF; ++fc) {
      int off = (fc*16 + l15)*40 + l4*8;
      bf8 bh = *(const bf8*)&BhS[off];
      bf8 bl = *(const bf8*)&BlS[off];
      acc[fc] = __builtin_amdgcn_mfma_f32_16x16x32_bf16(ah, bh, acc[fc], 0, 0, 0);
      acc[fc] = __builtin_amdgcn_mfma_f32_16x16x32_bf16(ah, bl, acc[fc], 0, 0, 0);
      acc[fc] = __builtin_amdgcn_mfma_f32_16x16x32_bf16(al, bh, acc[fc], 0, 0, 0);
    }
    __syncthreads();
  }

  // ---- epilogue ----
#pragma unroll
  for (int j = 0; j < 4; ++j) {
    const int r = r0 + w*16 + l4*4 + j;
    float s = 0.f, q = 0.f;
#pragma unroll
    for (int fc = 0; fc < NF; ++fc) {
      int col = fc*16 + l15;
      float v = acc[fc][j] + bias[col];
      if (MODE == 2) { float g = gelu_f(v); v = g*v; }
      outp[(size_t)r*NCOLS + col] = v;
      if (MODE == 2) { s += v; q += v*v; }
    }
    if (MODE == 2) {
#pragma unroll
      for (int off = 8; off > 0; off >>= 1) {
        s += __shfl_down(s, off, 16);
        q += __shfl_down(q, off, 16);
      }
      if (l15 == 0) { rs[r] = s; rq[r] = q; }
    }
  }
}

// exact k-th-smallest via register-resident 4-bit radix select.
__global__ __launch_bounds__(1024) void k_thr(const float* __restrict__ ne,
                                              const float* __restrict__ qp, float* __restrict__ out)
{
  __shared__ unsigned s_part[16][8];
  __shared__ unsigned s_bsel, s_R;
  const int t = threadIdx.x;
  const int lane = t & 63, wv = t >> 6;
  unsigned key[14];
#pragma unroll
  for (int j = 0; j < 14; ++j) key[j] = __float_as_uint(ne[t + j*1024]);

  float q = qp[0];
  float pos = q * 14335.0f;
  int lo = (int)floorf(pos);
  if (lo < 0) lo = 0; if (lo > 14335) lo = 14335;
  int hi = lo + 1; if (hi > 14335) hi = 14335;
  float frac = pos - (float)lo;

  unsigned prefix = 0;
  unsigned R = (unsigned)lo;
#pragma unroll 1
  for (int shift = 28; shift >= 0; shift -= 4) {
    unsigned pb = prefix >> shift;
    unsigned long long accb = 0ull;
#pragma unroll
    for (int j = 0; j < 14; ++j) {
      unsigned diff = (key[j] >> shift) - pb;
      accb += (diff < 16u) ? (1ull << (diff*4)) : 0ull;
    }
    unsigned pk[8];
#pragma unroll
    for (int b = 0; b < 8; ++b) {
      unsigned clo = (unsigned)(accb >> (b*4)) & 15u;
      unsigned chi = (unsigned)(accb >> (b*4+32)) & 15u;
      pk[b] = clo | (chi << 16);
    }
#pragma unroll
    for (int b = 0; b < 8; ++b)
#pragma unroll
      for (int o = 32; o > 0; o >>= 1) pk[b] += __shfl_down(pk[b], o);
    if (lane == 0) {
#pragma unroll
      for (int b = 0; b < 8; ++b) s_part[wv][b] = pk[b];
    }
    __syncthreads();
    if (t == 0) {
      unsigned tot[16];
#pragma unroll
      for (int i = 0; i < 8; ++i) {
        unsigned s = 0;
#pragma unroll
        for (int w2 = 0; w2 < 16; ++w2) s += s_part[w2][i];
        tot[i] = s & 0xFFFFu; tot[i+8] = s >> 16;
      }
      unsigned cum = 0, bsel = 15;
#pragma unroll 1
      for (int b = 0; b < 16; ++b) {
        if (cum + tot[b] > R) { bsel = (unsigned)b; break; }
        cum += tot[b];
      }
      s_bsel = bsel; s_R = R - cum;
    }
    __syncthreads();
    prefix |= (s_bsel << shift);
    R = s_R;
    __syncthreads();
  }
  unsigned cle = 0, mn = 0xFFFFFFFFu;
#pragma unroll
  for (int j = 0; j < 14; ++j) {
    cle += (key[j] <= prefix) ? 1u : 0u;
    if (key[j] > prefix && key[j] < mn) mn = key[j];
  }
#pragma unroll
  for (int o = 32; o > 0; o >>= 1) {
    cle += __shfl_down(cle, o);
    unsigned m2 = __shfl_down(mn, o);
    mn = (m2 < mn) ? m2 : mn;
  }
  if (lane == 0) { s_part[wv][0] = cle; s_part[wv][1] = mn; }
  __syncthreads();
  if (t == 0) {
    unsigned C = 0, M = 0xFFFFFFFFu;
#pragma unroll
    for (int w2 = 0; w2 < 16; ++w2) {
      C += s_part[w2][0];
      if (s_part[w2][1] < M) M = s_part[w2][1];
    }
    unsigned vhiKey = (C > (unsigned)hi) ? prefix : M;
    if (vhiKey == 0xFFFFFFFFu) vhiKey = prefix;
    float vlo = __uint_as_float(prefix);
    float vhi = __uint_as_float(vhiKey);
    out[0] = vlo*(1.0f-frac) + vhi*frac;
  }
}

// ---------------- BN finalize from per-row sums ----------------
__global__ __launch_bounds__(256) void k_bnfin_rows(const float* __restrict__ rs,
    const float* __restrict__ rq, int nch, int nrows, double count,
    const float* __restrict__ gamma, const float* __restrict__ beta, float* __restrict__ out)
{
  __shared__ double sd[256];
  int ch = blockIdx.x, t = threadIdx.x;
  double s = 0.0, q = 0.0;
  for (int i = ch + t*nch; i < nrows; i += 256*nch) { s += rs[i]; q += rq[i]; }
  sd[t] = s; __syncthreads();
  for (int o = 128; o > 0; o >>= 1) { if (t < o) sd[t] += sd[t+o]; __syncthreads(); }
  double S = sd[0]; __syncthreads();
  sd[t] = q; __syncthreads();
  for (int o = 128; o > 0; o >>= 1) { if (t < o) sd[t] += sd[t+o]; __syncthreads(); }
  if (t == 0) {
    double m = S / count;
    double v = sd[0] / count - m*m; if (v < 0.0) v = 0.0;
    double inv = 1.0 / sqrt(v + 1e-5);
    out[ch]       = (float)(gamma[ch] * inv);
    out[nch + ch] = (float)(beta[ch] - m * gamma[ch] * inv);
  }
}

// BN3 from per-row S1/Q1 of (z1+z2) scaled by a1 per row
__global__ __launch_bounds__(256) void k_bnfin_scaled(const float* __restrict__ S1,
    const float* __restrict__ Q1, const float* __restrict__ a1,
    const float* __restrict__ gamma, const float* __restrict__ beta, float* __restrict__ out)
{
  __shared__ double sd[256];
  int ch = blockIdx.x, t = threadIdx.x;
  double s = 0.0, q = 0.0;
  for (int i = ch + t*7; i < BD; i += 256*7) {
    double a = a1[i];
    s += a * S1[i];
    q += a*a * Q1[i];
  }
  sd[t] = s; __syncthreads();
  for (int o = 128; o > 0; o >>= 1) { if (t < o) sd[t] += sd[t+o]; __syncthreads(); }
  double S = sd[0]; __syncthreads();
  sd[t] = q; __syncthreads();
  for (int o = 128; o > 0; o >>= 1) { if (t < o) sd[t] += sd[t+o]; __syncthreads(); }
  if (t == 0) {
    double m = S / 1048576.0;
    double v = sd[0] / 1048576.0 - m*m; if (v < 0.0) v = 0.0;
    double inv = 1.0 / sqrt(v + 1e-5);
    out[ch]     = (float)(gamma[ch] * inv);
    out[7 + ch] = (float)(beta[ch] - m * gamma[ch] * inv);
  }
}

__global__ __launch_bounds__(256) void k_bnfin_part(const float* __restrict__ pS,
    const float* __restrict__ pQ, int nparts, int nch, double count,
    const float* __restrict__ gamma, const float* __restrict__ beta, float* __restrict__ out)
{
  __shared__ double sd[256];
  int ch = blockIdx.x, t = threadIdx.x;
  double s = 0.0, q = 0.0;
  for (int i = t; i < nparts; i += 256) { s += pS[(size_t)i*nch + ch]; q += pQ[(size_t)i*nch + ch]; }
  sd[t] = s; __syncthreads();
  for (int o = 128; o > 0; o >>= 1) { if (t < o) sd[t] += sd[t+o]; __syncthreads(); }
  double S = sd[0]; __syncthreads();
  sd[t] = q; __syncthreads();
  for (int o = 128; o > 0; o >>= 1) { if (t < o) sd[t] += sd[t+o]; __syncthreads(); }
  if (t == 0) {
    double m = S / count;
    double v = sd[0] / count - m*m; if (v < 0.0) v = 0.0;
    double inv = 1.0 / sqrt(v + 1e-5);
    out[ch]       = (float)(gamma[ch] * inv);
    out[nch + ch] = (float)(beta[ch] - m * gamma[ch] * inv);
  }
}

// ---------------- patch path: z1r = V[n] @ xp-patch + c2 (xp from planes) ----------------
__global__ __launch_bounds__(256) void k_patch(const ushort* __restrict__ xph,
    const ushort* __restrict__ xpl,
    const float* __restrict__ V, const float* __restrict__ c2,
    float* __restrict__ z1r, float* __restrict__ pS, float* __restrict__ pQ)
{
  __shared__ float sx[8][512];
  __shared__ float aS[32], aQ[32];
  int t = threadIdx.x;
  int r0 = blockIdx.x * 8;
  for (int c = t; c < 1024; c += 256) {
    int row = c >> 7, cg = c & 127;
    size_t idx = (size_t)(r0+row)*512 + cg*4;
    sh4 hv = *(const sh4*)&xph[idx];
    sh4 lv = *(const sh4*)&xpl[idx];
#pragma unroll
    for (int e = 0; e < 4; ++e)
      sx[row][cg*4+e] = bf2f((unsigned)(ushort)hv[e]) + bf2f((unsigned)(ushort)lv[e]);
  }
  if (t < 32) { aS[t] = 0.f; aQ[t] = 0.f; }
  __syncthreads();
  float vreg[2][16]; float cc[2]; int nn_[2], oo[2];
#pragma unroll
  for (int h = 0; h < 2; ++h) {
    int o = t + h*256;
    oo[h] = o;
    int n = o >> 4, p = o & 15;
    nn_[h] = n;
#pragma unroll
    for (int qg = 0; qg < 4; ++qg) {
      float4 v4 = *(const float4*)&V[(size_t)n*256 + p*16 + qg*4];
      vreg[h][qg*4+0]=v4.x; vreg[h][qg*4+1]=v4.y; vreg[h][qg*4+2]=v4.z; vreg[h][qg*4+3]=v4.w;
    }
    cc[h] = c2[o];
  }
  float sum[2] = {0.f,0.f}, sq[2] = {0.f,0.f};
  for (int row = 0; row < 8; ++row) {
#pragma unroll
    for (int h = 0; h < 2; ++h) {
      const float* xr = &sx[row][nn_[h]*16];
      float val = cc[h];
#pragma unroll
      for (int qq = 0; qq < 16; ++qq) val += vreg[h][qq] * xr[qq];
      z1r[(size_t)(r0+row)*512 + oo[h]] = val;
      sum[h] += val; sq[h] += val*val;
    }
  }
#pragma unroll
  for (int h = 0; h < 2; ++h) {
    atomicAdd(&aS[nn_[h]], sum[h]);
    atomicAdd(&aQ[nn_[h]], sq[h]);
  }
  __syncthreads();
  if (t < 32) { pS[(size_t)blockIdx.x*32 + t] = aS[t]; pQ[(size_t)blockIdx.x*32 + t] = aQ[t]; }
}

// ---------------- TopKFreq att + per-row S1/Q1 of (z1+z2) ----------------
__global__ void k_att(const float* __restrict__ z1, const float* __restrict__ z1r,
    const float* __restrict__ bn2, const float* __restrict__ u, const float* __restrict__ fcb,
    float* __restrict__ att, float* __restrict__ S1o, float* __restrict__ Q1o)
{
  int r = blockIdx.x*4 + (threadIdx.x >> 6);
  int lane = threadIdx.x & 63;
  const float* z1p = z1 + (size_t)r*512;
  const float* zrp = z1r + (size_t)r*512;
  float s = 0.f, s1 = 0.f, q1 = 0.f;
#pragma unroll
  for (int h = 0; h < 2; ++h) {
    int i = lane*4 + h*256;
    int n = i >> 4;
    float a2n = bn2[n], c2n = bn2[32+n];
    float4 zr = *(const float4*)&zrp[i];
    float4 zv = *(const float4*)&z1p[i];
    float4 uv = *(const float4*)&u[i];
#pragma unroll
    for (int e = 0; e < 4; ++e) {
      float ze = (e==0?zr.x:e==1?zr.y:e==2?zr.z:zr.w);
      float z1e = (e==0?zv.x:e==1?zv.y:e==2?zv.z:zv.w);
      float ue = (e==0?uv.x:e==1?uv.y:e==2?uv.z:uv.w);
      float tv = z1e + gelu_f(a2n*ze + c2n);
      s += tv * ue; s1 += tv; q1 += tv*tv;
    }
  }
  s = wred(s); s1 = wred(s1); q1 = wred(q1);
  if (lane == 0) { att[r] = s + fcb[0]; S1o[r] = s1; Q1o[r] = q1; }
}

__global__ __launch_bounds__(1024) void k_tf(const float* __restrict__ att,
    const float* __restrict__ pg, const float* __restrict__ pb,
    const float* __restrict__ pwc, const float* __restrict__ pbc,
    const float* __restrict__ pfb, float* __restrict__ a1, float* __restrict__ a2)
{
  __shared__ double sd[1024];
  __shared__ float sh[4];
  const int t = threadIdx.x;
  float g = pg[0], b = pb[0], wc = pwc[0], bc = pbc[0], fb = pfb[0];
  double s = 0.0, q = 0.0;
  for (int i = t; i < BD; i += 1024) { double v = att[i]; s += v; q += v*v; }
  sd[t] = s; __syncthreads();
  for (int o = 512; o > 0; o >>= 1) { if (t < o) sd[t] += sd[t+o]; __syncthreads(); }
  double S1 = sd[0]; __syncthreads();
  sd[t] = q; __syncthreads();
  for (int o = 512; o > 0; o >>= 1) { if (t < o) sd[t] += sd[t+o]; __syncthreads(); }
  if (t == 0) {
    double m = S1 / 14336.0;
    double v = sd[0] / 14336.0 - m*m; if (v < 0.0) v = 0.0;
    sh[0] = (float)m; sh[1] = (float)(1.0 / sqrt(v + 1e-5));
  }
  __syncthreads();
  float m1 = sh[0], i1 = sh[1];
  s = 0.0; q = 0.0;
  for (int i = t; i < BD; i += 1024) {
    float v = att[i];
    float an = (v - m1) * i1 * g + b;
    float av = sigm_f(gelu_f(an) * wc + bc);
    a1[i] = av;
    float t2 = av * (v - fb) + fb;
    s += t2; q += (double)t2 * t2;
  }
  __syncthreads();
  sd[t] = s; __syncthreads();
  for (int o = 512; o > 0; o >>= 1) { if (t < o) sd[t] += sd[t+o]; __syncthreads(); }
  double S2 = sd[0]; __syncthreads();
  sd[t] = q; __syncthreads();
  for (int o = 512; o > 0; o >>= 1) { if (t < o) sd[t] += sd[t+o]; __syncthreads(); }
  if (t == 0) {
    double m = S2 / 14336.0;
    double v = sd[0] / 14336.0 - m*m; if (v < 0.0) v = 0.0;
    sh[2] = (float)m; sh[3] = (float)(1.0 / sqrt(v + 1e-5));
  }
  __syncthreads();
  float m2 = sh[2], i2 = sh[3];
  for (int i = t; i < BD; i += 1024) {
    float t2 = a1[i] * (att[i] - fb) + fb;
    float an = (t2 - m2) * i2 * g + b;
    a2[i] = sigm_f(gelu_f(an) * wc + bc);
  }
}

// ---------------- statsC (float4) ----------------
__global__ void k_statsC(const float* __restrict__ z1, const float* __restrict__ z1r,
    const float* __restrict__ bn2, const float* __restrict__ a1,
    const float* __restrict__ bn3, const float* __restrict__ cw, const float* __restrict__ cb,
    float* __restrict__ rs, float* __restrict__ rq)
{
  int r = blockIdx.x*4 + (threadIdx.x >> 6);
  int lane = threadIdx.x & 63;
  int d = r % 7;
  float av = a1[r];
  float b3a = bn3[d], b3c = bn3[7+d], wv = cw[d], bv = cb[d];
  const float* z1p = z1 + (size_t)r*512;
  const float* zrp = z1r + (size_t)r*512;
  float s = 0.f, q = 0.f;
#pragma unroll
  for (int h = 0; h < 2; ++h) {
    int i = lane*4 + h*256;
    int n = i >> 4;
    float a2n = bn2[n], c2n = bn2[32+n];
    float4 zr = *(const float4*)&zrp[i];
    float4 zv = *(const float4*)&z1p[i];
#pragma unroll
    for (int e = 0; e < 4; ++e) {
      float ze = (e==0?zr.x:e==1?zr.y:e==2?zr.z:zr.w);
      float z1e = (e==0?zv.x:e==1?zv.y:e==2?zv.z:zv.w);
      float A = (z1e + gelu_f(a2n*ze + c2n)) * av;
      float C = wv*gelu_f(b3a*A + b3c) + bv;
      s += C; q += C*C;
    }
  }
  s = wred(s); q = wred(q);
  if (lane == 0) { rs[r] = s; rq[r] = q; }
}

// ---------------- final mix: writes zf as bf16 hi/lo planes + row stats ----------------
__global__ void k_final(const float* __restrict__ z1, const float* __restrict__ z1r,
    const float* __restrict__ bn2, const float* __restrict__ a1, const float* __restrict__ a2,
    const float* __restrict__ bn3, const float* __restrict__ bn4,
    const float* __restrict__ cw, const float* __restrict__ cb,
    ushort* __restrict__ zfh, ushort* __restrict__ zfl,
    float* __restrict__ rs, float* __restrict__ rq)
{
  int r = blockIdx.x*4 + (threadIdx.x >> 6);
  int lane = threadIdx.x & 63;
  int d = r % 7;
  float av = a1[r], a2v = a2[r];
  float b3a = bn3[d], b3c = bn3[7+d], b4a = bn4[d], b4c = bn4[7+d];
  float wv = cw[d], bv = cb[d];
  const float* z1p = z1 + (size_t)r*512;
  const float* zrp = z1r + (size_t)r*512;
  float s = 0.f, q = 0.f;
#pragma unroll
  for (int h = 0; h < 2; ++h) {
    int i = lane*4 + h*256;
    int n = i >> 4;
    float a2n = bn2[n], c2n = bn2[32+n];
    float4 zr = *(const float4*)&zrp[i];
    float4 zv = *(const float4*)&z1p[i];
    sh4 hv, lv;
#pragma unroll
    for (int e = 0; e < 4; ++e) {
      float ze = (e==0?zr.x:e==1?zr.y:e==2?zr.z:zr.w);
      float z1e = (e==0?zv.x:e==1?zv.y:e==2?zv.z:zv.w);
      float z1v = z1e * av;
      float z2v = gelu_f(a2n*ze + c2n) * av;
      float A = z1v + z2v;
      float C = wv*gelu_f(b3a*A + b3c) + bv;
      float inter = gelu_f(b4a*C + b4c) * a2v;
      float z1n = z1v*inter + z2v;
      float z2n = z2v*inter + z1n;
      float zfv = z1n*z2n + z1n + z2n;
      short hh, ll;
      tsplit(zfv, hh, ll);
      hv[e] = hh; lv[e] = ll;
      s += zfv; q += zfv*zfv;
    }
    *(sh4*)&zfh[(size_t)r*512 + i] = hv;
    *(sh4*)&zfl[(size_t)r*512 + i] = lv;
  }
  s = wred(s); q = wred(q);
  if (lane == 0) { rs[r] = s; rq[r] = q; }
}

// ---------------- output: fc2 + bias + z_res + transpose ----------------
__global__ __launch_bounds__(256) void k_out(const float* __restrict__ h2,
    const float* __restrict__ bn6, const float* __restrict__ w2, const float* __restrict__ b2,
    const float* __restrict__ zres, float* __restrict__ out)
{
  int idx = blockIdx.x*256 + threadIdx.x;
  int r = idx / 96, o = idx - r*96;
  int d = r % 7, b = r / 7;
  float a6 = bn6[d], c6 = bn6[7+d];
  const float* hp = h2 + (size_t)r*48;
  const float* wp = w2 + o*48;
  float s = 0.f;
#pragma unroll
  for (int j4 = 0; j4 < 12; ++j4) {
    float4 hv = *(const float4*)&hp[j4*4];
    float4 wv = *(const float4*)&wp[j4*4];
    s += (a6*hv.x + c6)*wv.x + (a6*hv.y + c6)*wv.y
       + (a6*hv.z + c6)*wv.z + (a6*hv.w + c6)*wv.w;
  }
  out[(size_t)b*672 + o*7 + d] = s + b2[o] + zres[(size_t)r*96 + o];
}

// ================= host =================
extern "C" void kernel_launch(void* const* d_in, const int* in_sizes, int n_in,
                              void* d_out, int out_size, void* d_ws, size_t ws_size,
                              hipStream_t stream) {
  const float* x          = (const float*)d_in[0];
  const float* dctconv_w  = (const float*)d_in[1];
  const float* dctconv_b  = (const float*)d_in[2];
  const float* dctnorm_g  = (const float*)d_in[3];
  const float* dctnorm_b  = (const float*)d_in[4];
  const float* threshold  = (const float*)d_in[5];
  const float* embed_W    = (const float*)d_in[6];
  const float* embed_b    = (const float*)d_in[7];
  const float* linres_W   = (const float*)d_in[8];
  const float* linres_b   = (const float*)d_in[9];
  const float* depth1_w   = (const float*)d_in[10];
  const float* depth1_b   = (const float*)d_in[11];
  const float* depthnorm_g= (const float*)d_in[12];
  const float* depthnorm_b= (const float*)d_in[13];
  const float* tf_fc_w    = (const float*)d_in[14];
  const float* tf_fc_b    = (const float*)d_in[15];
  const float* tf_norm_g  = (const float*)d_in[16];
  const float* tf_norm_b  = (const float*)d_in[17];
  const float* tf_conv_w  = (const float*)d_in[18];
  const float* tf_conv_b  = (const float*)d_in[19];
  const float* mlp_w1     = (const float*)d_in[20];
  const float* mlp_b1     = (const float*)d_in[21];
  const float* mlp_w2     = (const float*)d_in[22];
  const float* mlp_b2     = (const float*)d_in[23];
  const float* mlpnorm_g  = (const float*)d_in[24];
  const float* mlpnorm_b  = (const float*)d_in[25];
  float* out = (float*)d_out;
  float* ws  = (float*)d_ws;

  ushort* XPH = (ushort*)(ws + F_XP);             // xp hi/lo planes (fill F_XP exactly)
  ushort* XPL = XPH + (size_t)BD*512;
  ushort* ZFH = XPH;                              // zf planes overwrite xp planes at k_final
  ushort* ZFL = XPL;
  float* ZG   = ws + F_ZG;                        // z1r f32 (after GEMM2); GH/GL planes before
  ushort* ZGH = (ushort*)(ws + F_ZG);
  ushort* ZGL = ZGH + (size_t)BD*512;
  float* Z1   = ws + F_Z1;
  ushort* B1H = (ushort*)(ws + F_CLK);
  ushort* B1L = B1H + 512*512;
  ushort* B2H = (ushort*)(ws + F_MKL);
  ushort* B2L = B2H + 512*512;
  ushort* W2H = (ushort*)(ws + F_W2);
  ushort* W2L = W2H + 96*512;
  ushort* W1H = (ushort*)(ws + F_W1);
  ushort* W1L = W1H + 48*512;
  float* U    = ws + F_U;
  float* CSUM = ws + F_CSUM;
  float* CSTp = ws + F_CST;
  float* Vp   = ws + F_V;
  float* C2p  = ws + F_C2;
  float* ZRES = ws + F_ZRES;
  float* H2p  = ws + F_H2;
  float* NEp  = ws + F_NE;
  float* ATTp = ws + F_ATT;
  float* A1p  = ws + F_A1;
  float* A2p  = ws + F_A2;
  float* RS   = ws + F_RS;
  float* RQ   = ws + F_RQ;
  float* PS   = ws + F_PS;
  float* PQ   = ws + F_PQ;
  float* BN0  = ws + F_BN;        // a[7], c[7]
  float* BN2  = ws + F_BN + 16;   // a[32], c[32]
  float* BN3  = ws + F_BN + 80;
  float* BN4  = ws + F_BN + 96;
  float* BN5  = ws + F_BN + 112;
  float* BN6  = ws + F_BN + 128;
  float* THRp = ws + F_THR;

  k_setup<<<738, 256, 0, stream>>>(B1H, B1L, B2H, B2L, U, CSUM, tf_fc_w,
      embed_W, embed_b, depth1_w, depth1_b, Vp, C2p,
      mlp_w1, W1H, W1L, linres_W, linres_b, W2H, W2L, CSTp);
  k_transpose<<<2048, 256, 0, stream>>>(x, XPH, XPL, NEp);
  k_thr<<<1, 1024, 0, stream>>>(NEp, threshold, THRp);
  hipMemsetAsync(RS, 0, 2*BD*sizeof(float), stream);
  // GEMM1: z_dct -> masked dctconv -> gelu -> GH/GL planes (+ row stats)
  k_mfma<2><<<dim3(112,4), 256, 0, stream>>>(XPH, XPL, B1H, B1L,
      nullptr, ZGH, ZGL, nullptr, nullptr, nullptr, nullptr, dctconv_w, dctconv_b,
      NEp, THRp, RS, RQ);
  k_bnfin_rows<<<7, 256, 0, stream>>>(RS, RQ, 7, BD, 1048576.0, dctnorm_g, dctnorm_b, BN0);
  // GEMM2: z1 = BN(g) @ M + x_res  (BN folded via column sums)
  k_mfma<1><<<dim3(112,4), 256, 0, stream>>>(ZGH, ZGL, B2H, B2L,
      Z1, nullptr, nullptr, BN0, CSUM, XPH, XPL, dctconv_w, dctconv_b,
      nullptr, nullptr, nullptr, nullptr);
  k_patch<<<1792, 256, 0, stream>>>(XPH, XPL, Vp, C2p, ZG, PS, PQ);
  k_bnfin_part<<<32, 256, 0, stream>>>(PS, PQ, 1792, 32, 229376.0, depthnorm_g, depthnorm_b, BN2);
  // ZRES = XP @ W2^T + cst   (plane copy staging)
  k_mfma_nt<96,0><<<224, 256, 0, stream>>>(XPH, XPL, W2H, W2L, CSTp, ZRES,
      nullptr, nullptr, nullptr, nullptr);
  // att + per-row S1/Q1 of (z1+z2)
  k_att<<<3584, 256, 0, stream>>>(Z1, ZG, BN2, U, tf_fc_b, ATTp, RS, RQ);
  k_tf<<<1, 1024, 0, stream>>>(ATTp, tf_norm_g, tf_norm_b, tf_conv_w, tf_conv_b, tf_fc_b, A1p, A2p);
  // BN3 from a1-scaled per-row sums (statsA pass eliminated)
  k_bnfin_scaled<<<7, 256, 0, stream>>>(RS, RQ, A1p, dctnorm_g, dctnorm_b, BN3);
  k_statsC<<<3584, 256, 0, stream>>>(Z1, ZG, BN2, A1p, BN3, dctconv_w, dctconv_b, RS, RQ);
  k_bnfin_rows<<<7, 256, 0, stream>>>(RS, RQ, 7, BD, 1048576.0, dctnorm_g, dctnorm_b, BN4);
  k_final<<<3584, 256, 0, stream>>>(Z1, ZG, BN2, A1p, A2p, BN3, BN4, dctconv_w, dctconv_b,
      ZFH, ZFL, RS, RQ);
  k_bnfin_rows<<<7, 256, 0, stream>>>(RS, RQ, 7, BD, 1048576.0, dctnorm_g, dctnorm_b, BN5);
  // MLP fc1: h2 = gelu(v)*v with v = gelu(BN5(zf)) @ w1^T + b1   (reads zf planes)
  k_mfma_nt<48,2><<<224, 256, 0, stream>>>(ZFH, ZFL, W1H, W1L, mlp_b1, H2p,
      BN5, BN5+7, RS, RQ);
  k_bnfin_rows<<<7, 256, 0, stream>>>(RS, RQ, 7, BD, 98304.0, mlpnorm_g, mlpnorm_b, BN6);
  k_out<<<5376, 256, 0, stream>>>(H2p, BN6, mlp_w2, mlp_b2, ZRES, out);
}

// Round 13
// 335.428 us; speedup vs baseline: 2.4727x; 1.0265x over previous
//
#include <hip/hip_runtime.h>
#include <math.h>

#define BB 2048
#define LL 512
#define DD 7
#define BD 14336   // BB*DD

// ---------------- ws layout (floats) ----------------
constexpr size_t F_XP   = 0;                          // XPH/XPL planes, later ZFH/ZFL planes
constexpr size_t F_ZG   = F_XP  + (size_t)BD*512;     // ZGH/ZGL planes -> z1r f32
constexpr size_t F_Z1   = F_ZG  + (size_t)BD*512;     // z1
constexpr size_t F_CLK  = F_Z1  + (size_t)BD*512;     // B1H/B1L (fills region exactly)
constexpr size_t F_MKL  = F_CLK + 512*512;            // B2H/B2L (fills region exactly)
constexpr size_t F_U    = F_MKL + 512*512;
constexpr size_t F_CSUM = F_U + 512;
constexpr size_t F_W2   = F_CSUM + 512;               // W2H/W2L ushort planes (exact fit)
constexpr size_t F_CST  = F_W2 + 96*512;
constexpr size_t F_V    = F_CST + 96;                 // 32x16x16
constexpr size_t F_C2   = F_V + 32*256;               // 32x16
constexpr size_t F_ZRES = F_C2 + 512;                 // BD x 96
constexpr size_t F_H2   = F_ZRES + (size_t)BD*96;     // BD x 48
constexpr size_t F_EN   = F_H2 + (size_t)BD*48;       // (unused)
constexpr size_t F_NE   = F_EN + BD;
constexpr size_t F_ATT  = F_NE + BD;
constexpr size_t F_A1   = F_ATT + BD;
constexpr size_t F_A2   = F_A1 + BD;
constexpr size_t F_RS   = F_A2 + BD;
constexpr size_t F_RQ   = F_RS + BD;                  // adjacent to F_RS (one memset)
constexpr size_t F_PS   = F_RQ + BD;                  // 1792 x 32
constexpr size_t F_PQ   = F_PS + 1792*32;
constexpr size_t F_BN   = F_PQ + 1792*32;             // bn affine params
constexpr size_t F_THR  = F_BN + 256;
constexpr size_t F_W1   = F_THR + 16;                 // W1H/W1L ushort planes (24576 floats)

typedef __attribute__((ext_vector_type(8))) short bf8;
typedef __attribute__((ext_vector_type(4))) short sh4;
typedef __attribute__((ext_vector_type(4))) float f4;

__device__ __forceinline__ float gelu_f(float x) {
  return 0.5f * x * (1.0f + erff(x * 0.70710678118654752440f));
}
__device__ __forceinline__ float sigm_f(float x) {
  return 1.0f / (1.0f + expf(-x));
}
__device__ __forceinline__ float wred(float v) {
#pragma unroll
  for (int o = 32; o > 0; o >>= 1) v += __shfl_down(v, o);
  return v;
}
__device__ __forceinline__ unsigned bfh_u(float v) {     // round-to-nearest (setup only)
  unsigned u = __float_as_uint(v);
  return (u + 0x7FFFu + ((u >> 16) & 1u)) >> 16;
}
__device__ __forceinline__ float bf2f(unsigned h) { return __uint_as_float(h << 16); }
// truncation split: 4 VALU ops, error ~2^-16 rel
__device__ __forceinline__ void tsplit(float v, short &h, short &l) {
  unsigned u = __float_as_uint(v);
  h = (short)(u >> 16);
  float lo = v - bf2f(u >> 16);
  l = (short)(__float_as_uint(lo) >> 16);
}
// async global->LDS, 16B per lane; lds dest = wave-uniform base + lane*16
__device__ __forceinline__ void gload16(const ushort* g, ushort* l) {
  __builtin_amdgcn_global_load_lds(
      (const __attribute__((address_space(1))) void*)g,
      (__attribute__((address_space(3))) void*)l, 16, 0, 0);
}

#define PI1024 0.00306796157577128218f   // pi/1024

// ---------------- fused setup: gen_b + ucsum + v + splitw + w2 ----------------
__global__ __launch_bounds__(256) void k_setup(
    ushort* __restrict__ B1H, ushort* __restrict__ B1L,
    ushort* __restrict__ B2H, ushort* __restrict__ B2L,
    float* __restrict__ u, float* __restrict__ csum, const float* __restrict__ wf,
    const float* __restrict__ eW, const float* __restrict__ eb,
    const float* __restrict__ dw, const float* __restrict__ db,
    float* __restrict__ V, float* __restrict__ c2,
    const float* __restrict__ mlpw1, ushort* __restrict__ W1H, ushort* __restrict__ W1L,
    const float* __restrict__ linW, const float* __restrict__ linb,
    ushort* __restrict__ W2H, ushort* __restrict__ W2L, float* __restrict__ cst)
{
  __shared__ float sW[768];
  __shared__ float sb[48];
  __shared__ float rbuf[256];
  const int bid = blockIdx.x, t = threadIdx.x;
  if (bid < 512) {
    int c = bid;
    for (int r = t; r < 512; r += 256) {
      int n1 = ((2*r + 1) * c) & 2047;
      float v1 = 2.0f * cosf((float)n1 * PI1024);
      unsigned h = bfh_u(v1);
      B1H[(size_t)c*512 + r] = (ushort)h;
      B1L[(size_t)c*512 + r] = (ushort)bfh_u(v1 - bf2f(h));
      int n2 = ((2*c + 1) * r) & 2047;
      float v2 = cosf((float)n2 * PI1024) * (r == 0 ? (1.0f/1024.0f) : (1.0f/512.0f));
      h = bfh_u(v2);
      B2H[(size_t)c*512 + r] = (ushort)h;
      B2L[(size_t)c*512 + r] = (ushort)bfh_u(v2 - bf2f(h));
    }
  } else if (bid < 514) {
    int l = (bid - 512)*256 + t;
    if (l < 512) {
      double th2 = 3.14159265358979323846 * (double)(2*l + 1) / 2048.0;
      double s = (l & 1) ? -1.0 : 1.0;
      double S = 0.5*s/tan(th2) - 0.5;
      csum[l] = (float)(1.0/1024.0 + S/512.0);
      double uu = (double)wf[0] * 45.25483399593904156 / 1024.0;
      for (int k = 1; k < 5; ++k)
        uu += (double)wf[k] * 32.0 * cos(3.14159265358979323846*(l+0.5)*k/512.0) / 512.0;
      u[l] = (float)uu;
    }
  } else if (bid < 546) {
    int n = bid - 514;
    int p = t >> 4, q = t & 15;
    float s = 0.f;
#pragma unroll
    for (int j = 0; j < 3; ++j) s += eW[(p*3+j)*16 + q] * dw[n*3+j];
    V[(size_t)n*256 + p*16 + q] = s;
    if (q == 0) {
      float c = 0.f;
#pragma unroll
      for (int j = 0; j < 3; ++j) c += eb[p*3+j] * dw[n*3+j];
      c2[n*16+p] = c + db[n];
    }
  } else if (bid < 642) {
    int i = (bid - 546)*256 + t;
    if (i < 48*512) {
      float v = mlpw1[i];
      unsigned hb = bfh_u(v);
      W1H[i] = (ushort)hb;
      W1L[i] = (ushort)bfh_u(v - bf2f(hb));
    }
  } else {
    int o = bid - 642;
    for (int i = t; i < 768; i += 256) sW[i] = eW[i];
    if (t < 48) sb[t] = eb[t];
    __syncthreads();
    const float* lw = linW + (size_t)o * 1536;
    for (int i = t; i < 512; i += 256) {
      int n = i >> 4, p = i & 15;
      float s = 0.f;
      const float* l2 = lw + n*48;
#pragma unroll 8
      for (int m = 0; m < 48; ++m) s += l2[m] * sW[m*16 + p];
      unsigned hb = bfh_u(s);
      W2H[(size_t)o*512 + i] = (ushort)hb;
      W2L[(size_t)o*512 + i] = (ushort)bfh_u(s - bf2f(hb));
    }
    float c = 0.f;
    for (int i = t; i < 1536; i += 256) c += lw[i] * sb[i % 48];
    rbuf[t] = c; __syncthreads();
    for (int off = 128; off > 0; off >>= 1) { if (t < off) rbuf[t] += rbuf[t+off]; __syncthreads(); }
    if (t == 0) cst[o] = rbuf[0] + linb[o];
  }
}

// ---------------- transpose [B,L,D] -> bf16 hi/lo planes + fused energy/median -> ne --------
__global__ __launch_bounds__(256) void k_transpose(const float* __restrict__ x,
                                                   ushort* __restrict__ xph,
                                                   ushort* __restrict__ xpl,
                                                   float* __restrict__ ne) {
  __shared__ float s[3584];
  __shared__ float sEn[7];
  int b = blockIdx.x;
  const float* src = x + (size_t)b*3584;
  for (int c = threadIdx.x; c < 896; c += 256) {
    float4 v = *(const float4*)&src[c*4];
    s[c*4+0]=v.x; s[c*4+1]=v.y; s[c*4+2]=v.z; s[c*4+3]=v.w;
  }
  __syncthreads();
  for (int c = threadIdx.x; c < 896; c += 256) {
    int d = c >> 7, cg = c & 127;
    sh4 hv, lv;
#pragma unroll
    for (int e = 0; e < 4; ++e) {
      float v = s[(cg*4+e)*7 + d];
      short hh, ll;
      tsplit(v, hh, ll);
      hv[e] = hh; lv[e] = ll;
    }
    size_t idx = ((size_t)b*7 + d)*512 + cg*4;
    *(sh4*)&xph[idx] = hv;
    *(sh4*)&xpl[idx] = lv;
  }
  int t = threadIdx.x;
  if (t < 224) {
    int d = t >> 5, c0 = (t & 31) * 16;
    double ss = 0.0, qq = 0.0;
    for (int l = c0; l < c0 + 16; ++l) {
      double v = s[l*7 + d];
      ss += v; qq += v*v;
    }
#pragma unroll
    for (int o = 16; o > 0; o >>= 1) {
      ss += __shfl_down(ss, o, 32);
      qq += __shfl_down(qq, o, 32);
    }
    if ((t & 31) == 0) sEn[d] = (float)(1024.0*qq + 2.0*ss*ss);
  }
  __syncthreads();
  if (t == 0) {
    float e[7], s7[7];
#pragma unroll
    for (int d = 0; d < 7; ++d) { e[d] = sEn[d]; s7[d] = e[d]; }
#pragma unroll
    for (int i = 1; i < 7; ++i) {
      float key = s7[i]; int j = i-1;
      while (j >= 0 && s7[j] > key) { s7[j+1] = s7[j]; --j; }
      s7[j+1] = key;
    }
    float med = s7[3] + 1e-6f;
#pragma unroll
    for (int d = 0; d < 7; ++d) ne[b*7 + d] = e[d] / med;
  }
}

// ---------------- MFMA bf16-split GEMM: C[M,512] = A[M,512] @ B[512,512] ----------------
// BM=128, BN=128, BK=32; 512 threads = 8 waves, each 32x64 (2x4 frags); 3-term split.
// Staging via global_load_lds (16B/lane DMA), LINEAR LDS [128][32] ushorts per plane,
// source pre-swizzled (slot ^= (row>>3&1)<<1) + same XOR on frag reads.
// MODE 2: epilogue g=gelu(acc*mask*w+b) -> GH/GL planes (truncation split) + row stats
// MODE 1: epilogue z1 = aR*acc + cR*csum + (hi+lo)(xp)*w + b -> f32
template<int MODE>
__global__ __launch_bounds__(512) void k_mfma(
    const ushort* __restrict__ AHg, const ushort* __restrict__ ALg,
    const ushort* __restrict__ BHg, const ushort* __restrict__ BLg,
    float* __restrict__ z1out, ushort* __restrict__ GH, ushort* __restrict__ GL,
    const float* __restrict__ bnac, const float* __restrict__ csum,
    const ushort* __restrict__ xph, const ushort* __restrict__ xpl,
    const float* __restrict__ cw, const float* __restrict__ cb,
    const float* __restrict__ ne, const float* __restrict__ thr,
    float* __restrict__ rs, float* __restrict__ rq)
{
  __shared__ ushort AhS[128*32], AlS[128*32];
  __shared__ ushort BhS[128*32], BlS[128*32];
  const int t = threadIdx.x;
  const int lane = t & 63, w = t >> 6;        // 8 waves
  const int l15 = lane & 15, l4 = lane >> 4;
  const int wr = (w & 3)*32, wc = (w >> 2)*64;   // wave: 32 rows x 64 cols
  const int r0 = blockIdx.x * 128, c0 = blockIdx.y * 128;

  f4 acc[2][4];
#pragma unroll
  for (int i = 0; i < 2; ++i)
#pragma unroll
    for (int j = 0; j < 4; ++j) acc[i][j] = (f4){0.f,0.f,0.f,0.f};

  // staging: segment s = w covers rows w*16..w*16+15 (1KB per plane);
  // lane writes 16B at row = w*16 + (lane>>2); source slot pre-swizzled.
  const int rl0 = lane >> 2;
  const int ssl = (lane & 3) ^ (((lane >> 5) & 1) << 1);
  const int swr = ((l15 >> 3) & 1) << 1;   // frag-read swizzle (same XOR)

  for (int kt = 0; kt < 512; kt += 32) {
    {
      const int row = w*16 + rl0;
      const size_t gA = (size_t)(r0+row)*512 + kt + ssl*8;
      const size_t gB = (size_t)(c0+row)*512 + kt + ssl*8;
      gload16(&AHg[gA], &AhS[w*512]);
      gload16(&ALg[gA], &AlS[w*512]);
      gload16(&BHg[gB], &BhS[w*512]);
      gload16(&BLg[gB], &BlS[w*512]);
    }
    __syncthreads();
    // ---- compute ----
    bf8 ah[2], al[2], bh[4], bl[4];
    const int ko = (l4 ^ swr)*8;
#pragma unroll
    for (int fr = 0; fr < 2; ++fr) {
      int off = (wr + fr*16 + l15)*32 + ko;
      ah[fr] = *(const bf8*)&AhS[off];
      al[fr] = *(const bf8*)&AlS[off];
    }
#pragma unroll
    for (int fc = 0; fc < 4; ++fc) {
      int off = (wc + fc*16 + l15)*32 + ko;
      bh[fc] = *(const bf8*)&BhS[off];
      bl[fc] = *(const bf8*)&BlS[off];
    }
#pragma unroll
    for (int fr = 0; fr < 2; ++fr)
#pragma unroll
      for (int fc = 0; fc < 4; ++fc) {
        acc[fr][fc] = __builtin_amdgcn_mfma_f32_16x16x32_bf16(ah[fr], bh[fc], acc[fr][fc], 0, 0, 0);
        acc[fr][fc] = __builtin_amdgcn_mfma_f32_16x16x32_bf16(ah[fr], bl[fc], acc[fr][fc], 0, 0, 0);
        acc[fr][fc] = __builtin_amdgcn_mfma_f32_16x16x32_bf16(al[fr], bh[fc], acc[fr][fc], 0, 0, 0);
      }
    __syncthreads();
  }

  // ---- epilogue ----
  const float thv = (MODE == 2) ? thr[0] : 0.f;
#pragma unroll
  for (int fr = 0; fr < 2; ++fr)
#pragma unroll
    for (int j = 0; j < 4; ++j) {
      const int r = r0 + wr + fr*16 + l4*4 + j;
      const int d = r % 7;
      if (MODE == 1) {
        const float aR = bnac[d], cR = bnac[7+d], wv = cw[d], bvv = cb[d];
#pragma unroll
        for (int fc = 0; fc < 4; ++fc) {
          int col = c0 + wc + fc*16 + l15;
          size_t idx = (size_t)r*512 + col;
          float xv = bf2f(xph[idx]) + bf2f(xpl[idx]);
          float val = acc[fr][fc][j];
          z1out[idx] = aR*val + cR*csum[col] + xv*wv + bvv;
        }
      } else {
        float m = (ne[r] > thv) ? 1.0f : 0.0f;
        float wm = cw[d] * m, bvv = cb[d];
        float s = 0.f, q = 0.f;
#pragma unroll
        for (int fc = 0; fc < 4; ++fc) {
          int col = c0 + wc + fc*16 + l15;
          float g = gelu_f(acc[fr][fc][j]*wm + bvv);
          short hh, ll;
          tsplit(g, hh, ll);
          GH[(size_t)r*512 + col] = (ushort)hh;
          GL[(size_t)r*512 + col] = (ushort)ll;
          s += g; q += g*g;
        }
#pragma unroll
        for (int off = 8; off > 0; off >>= 1) {
          s += __shfl_down(s, off, 16);
          q += __shfl_down(q, off, 16);
        }
        if (l15 == 0) { atomicAdd(&rs[r], s); atomicAdd(&rq[r], q); }
      }
    }
}

// ---------------- MFMA bf16-split NT GEMM: out[M,NCOLS] = A[M,512] @ W[NCOLS,512]^T + bias ----
// BM=64 (4 waves x 16 rows), BK=32, 3-term split; A from hi/lo planes.
// MODE 0: plane copy, plain store (ZRES).
// MODE 2: reconstruct -> gelu(ta*x+tc) -> truncation split; out gelu(v)*v; row stats.
template<int NCOLS, int MODE>
__global__ __launch_bounds__(256) void k_mfma_nt(
    const ushort* __restrict__ AHp, const ushort* __restrict__ ALp,
    const ushort* __restrict__ WH, const ushort* __restrict__ WL,
    const float* __restrict__ bias, float* __restrict__ outp,
    const float* __restrict__ ta, const float* __restrict__ tc,
    float* __restrict__ rs, float* __restrict__ rq)
{
  constexpr int NF = NCOLS / 16;
  __shared__ ushort AhS[64*40], AlS[64*40];
  __shared__ ushort BhS[NCOLS*40], BlS[NCOLS*40];
  const int t = threadIdx.x;
  const int lane = t & 63, w = t >> 6;
  const int l15 = lane & 15, l4 = lane >> 4;
  const int r0 = blockIdx.x * 64;

  f4 acc[NF];
#pragma unroll
  for (int fc = 0; fc < NF; ++fc) acc[fc] = (f4){0.f,0.f,0.f,0.f};

  const int arow = t >> 2, ak0 = (t & 3) * 8;
  float taa = 0.f, tcc = 0.f;
  if (MODE == 2) { int d = (r0 + arow) % 7; taa = ta[d]; tcc = tc[d]; }

  for (int kt = 0; kt < 512; kt += 32) {
    // ---- stage A (64x32) ----
    if (MODE == 0) {
      *(bf8*)&AhS[arow*40 + ak0] = *(const bf8*)&AHp[(size_t)(r0+arow)*512 + kt + ak0];
      *(bf8*)&AlS[arow*40 + ak0] = *(const bf8*)&ALp[(size_t)(r0+arow)*512 + kt + ak0];
    } else {
      bf8 hv8 = *(const bf8*)&AHp[(size_t)(r0+arow)*512 + kt + ak0];
      bf8 lv8 = *(const bf8*)&ALp[(size_t)(r0+arow)*512 + kt + ak0];
      bf8 hv, lv;
#pragma unroll
      for (int j = 0; j < 8; ++j) {
        float xv = bf2f((unsigned)(ushort)hv8[j]) + bf2f((unsigned)(ushort)lv8[j]);
        float g = gelu_f(taa*xv + tcc);
        short hh, ll;
        tsplit(g, hh, ll);
        hv[j] = hh; lv[j] = ll;
      }
      *(bf8*)&AhS[arow*40 + ak0] = hv;
      *(bf8*)&AlS[arow*40 + ak0] = lv;
    }
    // ---- stage B (NCOLS x 32) ----
    for (int c = t; c < NCOLS*4; c += 256) {
      int brow = c >> 2, bk0 = (c & 3) * 8;
      *(bf8*)&BhS[brow*40 + bk0] = *(const bf8*)&WH[(size_t)brow*512 + kt + bk0];
      *(bf8*)&BlS[brow*40 + bk0] = *(const bf8*)&WL[(size_t)brow*512 + kt + bk0];
    }
    __syncthreads();
    // ---- compute: wave w owns rows w*16..w*16+15 ----
    bf8 ah, al;
    {
      int off = (w*16 + l15)*40 + l4*8;
      ah = *(const bf8*)&AhS[off];
      al = *(const bf8*)&AlS[off];
    }
#pragma unroll
    for (int fc = 0; fc < NF; ++fc) {
      int off = (fc*16 + l15)*40 + l4*8;
      bf8 bh = *(const bf8*)&BhS[off];
      bf8 bl = *(const bf8*)&BlS[off];
      acc[fc] = __builtin_amdgcn_mfma_f32_16x16x32_bf16(ah, bh, acc[fc], 0, 0, 0);
      acc[fc] = __builtin_amdgcn_mfma_f32_16x16x32_bf16(ah, bl, acc[fc], 0, 0, 0);
      acc[fc] = __builtin_amdgcn_mfma_f32_16x16x32_bf16(al, bh, acc[fc], 0, 0, 0);
    }
    __syncthreads();
  }

  // ---- epilogue ----
#pragma unroll
  for (int j = 0; j < 4; ++j) {
    const int r = r0 + w*16 + l4*4 + j;
    float s = 0.f, q = 0.f;
#pragma unroll
    for (int fc = 0; fc < NF; ++fc) {
      int col = fc*16 + l15;
      float v = acc[fc][j] + bias[col];
      if (MODE == 2) { float g = gelu_f(v); v = g*v; }
      outp[(size_t)r*NCOLS + col] = v;
      if (MODE == 2) { s += v; q += v*v; }
    }
    if (MODE == 2) {
#pragma unroll
      for (int off = 8; off > 0; off >>= 1) {
        s += __shfl_down(s, off, 16);
        q += __shfl_down(q, off, 16);
      }
      if (l15 == 0) { rs[r] = s; rq[r] = q; }
    }
  }
}

// exact k-th-smallest via register-resident 4-bit radix select.
__global__ __launch_bounds__(1024) void k_thr(const float* __restrict__ ne,
                                              const float* __restrict__ qp, float* __restrict__ out)
{
  __shared__ unsigned s_part[16][8];
  __shared__ unsigned s_bsel, s_R;
  const int t = threadIdx.x;
  const int lane = t & 63, wv = t >> 6;
  unsigned key[14];
#pragma unroll
  for (int j = 0; j < 14; ++j) key[j] = __float_as_uint(ne[t + j*1024]);

  float q = qp[0];
  float pos = q * 14335.0f;
  int lo = (int)floorf(pos);
  if (lo < 0) lo = 0; if (lo > 14335) lo = 14335;
  int hi = lo + 1; if (hi > 14335) hi = 14335;
  float frac = pos - (float)lo;

  unsigned prefix = 0;
  unsigned R = (unsigned)lo;
#pragma unroll 1
  for (int shift = 28; shift >= 0; shift -= 4) {
    unsigned pb = prefix >> shift;
    unsigned long long accb = 0ull;
#pragma unroll
    for (int j = 0; j < 14; ++j) {
      unsigned diff = (key[j] >> shift) - pb;
      accb += (diff < 16u) ? (1ull << (diff*4)) : 0ull;
    }
    unsigned pk[8];
#pragma unroll
    for (int b = 0; b < 8; ++b) {
      unsigned clo = (unsigned)(accb >> (b*4)) & 15u;
      unsigned chi = (unsigned)(accb >> (b*4+32)) & 15u;
      pk[b] = clo | (chi << 16);
    }
#pragma unroll
    for (int b = 0; b < 8; ++b)
#pragma unroll
      for (int o = 32; o > 0; o >>= 1) pk[b] += __shfl_down(pk[b], o);
    if (lane == 0) {
#pragma unroll
      for (int b = 0; b < 8; ++b) s_part[wv][b] = pk[b];
    }
    __syncthreads();
    if (t == 0) {
      unsigned tot[16];
#pragma unroll
      for (int i = 0; i < 8; ++i) {
        unsigned s = 0;
#pragma unroll
        for (int w2 = 0; w2 < 16; ++w2) s += s_part[w2][i];
        tot[i] = s & 0xFFFFu; tot[i+8] = s >> 16;
      }
      unsigned cum = 0, bsel = 15;
#pragma unroll 1
      for (int b = 0; b < 16; ++b) {
        if (cum + tot[b] > R) { bsel = (unsigned)b; break; }
        cum += tot[b];
      }
      s_bsel = bsel; s_R = R - cum;
    }
    __syncthreads();
    prefix |= (s_bsel << shift);
    R = s_R;
    __syncthreads();
  }
  unsigned cle = 0, mn = 0xFFFFFFFFu;
#pragma unroll
  for (int j = 0; j < 14; ++j) {
    cle += (key[j] <= prefix) ? 1u : 0u;
    if (key[j] > prefix && key[j] < mn) mn = key[j];
  }
#pragma unroll
  for (int o = 32; o > 0; o >>= 1) {
    cle += __shfl_down(cle, o);
    unsigned m2 = __shfl_down(mn, o);
    mn = (m2 < mn) ? m2 : mn;
  }
  if (lane == 0) { s_part[wv][0] = cle; s_part[wv][1] = mn; }
  __syncthreads();
  if (t == 0) {
    unsigned C = 0, M = 0xFFFFFFFFu;
#pragma unroll
    for (int w2 = 0; w2 < 16; ++w2) {
      C += s_part[w2][0];
      if (s_part[w2][1] < M) M = s_part[w2][1];
    }
    unsigned vhiKey = (C > (unsigned)hi) ? prefix : M;
    if (vhiKey == 0xFFFFFFFFu) vhiKey = prefix;
    float vlo = __uint_as_float(prefix);
    float vhi = __uint_as_float(vhiKey);
    out[0] = vlo*(1.0f-frac) + vhi*frac;
  }
}

// ---------------- BN finalize from per-row sums ----------------
__global__ __launch_bounds__(256) void k_bnfin_rows(const float* __restrict__ rs,
    const float* __restrict__ rq, int nch, int nrows, double count,
    const float* __restrict__ gamma, const float* __restrict__ beta, float* __restrict__ out)
{
  __shared__ double sd[256];
  int ch = blockIdx.x, t = threadIdx.x;
  double s = 0.0, q = 0.0;
  for (int i = ch + t*nch; i < nrows; i += 256*nch) { s += rs[i]; q += rq[i]; }
  sd[t] = s; __syncthreads();
  for (int o = 128; o > 0; o >>= 1) { if (t < o) sd[t] += sd[t+o]; __syncthreads(); }
  double S = sd[0]; __syncthreads();
  sd[t] = q; __syncthreads();
  for (int o = 128; o > 0; o >>= 1) { if (t < o) sd[t] += sd[t+o]; __syncthreads(); }
  if (t == 0) {
    double m = S / count;
    double v = sd[0] / count - m*m; if (v < 0.0) v = 0.0;
    double inv = 1.0 / sqrt(v + 1e-5);
    out[ch]       = (float)(gamma[ch] * inv);
    out[nch + ch] = (float)(beta[ch] - m * gamma[ch] * inv);
  }
}

// BN3 from per-row S1/Q1 of (z1+z2) scaled by a1 per row
__global__ __launch_bounds__(256) void k_bnfin_scaled(const float* __restrict__ S1,
    const float* __restrict__ Q1, const float* __restrict__ a1,
    const float* __restrict__ gamma, const float* __restrict__ beta, float* __restrict__ out)
{
  __shared__ double sd[256];
  int ch = blockIdx.x, t = threadIdx.x;
  double s = 0.0, q = 0.0;
  for (int i = ch + t*7; i < BD; i += 256*7) {
    double a = a1[i];
    s += a * S1[i];
    q += a*a * Q1[i];
  }
  sd[t] = s; __syncthreads();
  for (int o = 128; o > 0; o >>= 1) { if (t < o) sd[t] += sd[t+o]; __syncthreads(); }
  double S = sd[0]; __syncthreads();
  sd[t] = q; __syncthreads();
  for (int o = 128; o > 0; o >>= 1) { if (t < o) sd[t] += sd[t+o]; __syncthreads(); }
  if (t == 0) {
    double m = S / 1048576.0;
    double v = sd[0] / 1048576.0 - m*m; if (v < 0.0) v = 0.0;
    double inv = 1.0 / sqrt(v + 1e-5);
    out[ch]     = (float)(gamma[ch] * inv);
    out[7 + ch] = (float)(beta[ch] - m * gamma[ch] * inv);
  }
}

__global__ __launch_bounds__(256) void k_bnfin_part(const float* __restrict__ pS,
    const float* __restrict__ pQ, int nparts, int nch, double count,
    const float* __restrict__ gamma, const float* __restrict__ beta, float* __restrict__ out)
{
  __shared__ double sd[256];
  int ch = blockIdx.x, t = threadIdx.x;
  double s = 0.0, q = 0.0;
  for (int i = t; i < nparts; i += 256) { s += pS[(size_t)i*nch + ch]; q += pQ[(size_t)i*nch + ch]; }
  sd[t] = s; __syncthreads();
  for (int o = 128; o > 0; o >>= 1) { if (t < o) sd[t] += sd[t+o]; __syncthreads(); }
  double S = sd[0]; __syncthreads();
  sd[t] = q; __syncthreads();
  for (int o = 128; o > 0; o >>= 1) { if (t < o) sd[t] += sd[t+o]; __syncthreads(); }
  if (t == 0) {
    double m = S / count;
    double v = sd[0] / count - m*m; if (v < 0.0) v = 0.0;
    double inv = 1.0 / sqrt(v + 1e-5);
    out[ch]       = (float)(gamma[ch] * inv);
    out[nch + ch] = (float)(beta[ch] - m * gamma[ch] * inv);
  }
}

// ---------------- patch path: z1r = V[n] @ xp-patch + c2 (xp from planes) ----------------
__global__ __launch_bounds__(256) void k_patch(const ushort* __restrict__ xph,
    const ushort* __restrict__ xpl,
    const float* __restrict__ V, const float* __restrict__ c2,
    float* __restrict__ z1r, float* __restrict__ pS, float* __restrict__ pQ)
{
  __shared__ float sx[8][512];
  __shared__ float aS[32], aQ[32];
  int t = threadIdx.x;
  int r0 = blockIdx.x * 8;
  for (int c = t; c < 1024; c += 256) {
    int row = c >> 7, cg = c & 127;
    size_t idx = (size_t)(r0+row)*512 + cg*4;
    sh4 hv = *(const sh4*)&xph[idx];
    sh4 lv = *(const sh4*)&xpl[idx];
#pragma unroll
    for (int e = 0; e < 4; ++e)
      sx[row][cg*4+e] = bf2f((unsigned)(ushort)hv[e]) + bf2f((unsigned)(ushort)lv[e]);
  }
  if (t < 32) { aS[t] = 0.f; aQ[t] = 0.f; }
  __syncthreads();
  float vreg[2][16]; float cc[2]; int nn_[2], oo[2];
#pragma unroll
  for (int h = 0; h < 2; ++h) {
    int o = t + h*256;
    oo[h] = o;
    int n = o >> 4, p = o & 15;
    nn_[h] = n;
#pragma unroll
    for (int qg = 0; qg < 4; ++qg) {
      float4 v4 = *(const float4*)&V[(size_t)n*256 + p*16 + qg*4];
      vreg[h][qg*4+0]=v4.x; vreg[h][qg*4+1]=v4.y; vreg[h][qg*4+2]=v4.z; vreg[h][qg*4+3]=v4.w;
    }
    cc[h] = c2[o];
  }
  float sum[2] = {0.f,0.f}, sq[2] = {0.f,0.f};
  for (int row = 0; row < 8; ++row) {
#pragma unroll
    for (int h = 0; h < 2; ++h) {
      const float* xr = &sx[row][nn_[h]*16];
      float val = cc[h];
#pragma unroll
      for (int qq = 0; qq < 16; ++qq) val += vreg[h][qq] * xr[qq];
      z1r[(size_t)(r0+row)*512 + oo[h]] = val;
      sum[h] += val; sq[h] += val*val;
    }
  }
#pragma unroll
  for (int h = 0; h < 2; ++h) {
    atomicAdd(&aS[nn_[h]], sum[h]);
    atomicAdd(&aQ[nn_[h]], sq[h]);
  }
  __syncthreads();
  if (t < 32) { pS[(size_t)blockIdx.x*32 + t] = aS[t]; pQ[(size_t)blockIdx.x*32 + t] = aQ[t]; }
}

// ---------------- TopKFreq att + per-row S1/Q1 of (z1+z2) ----------------
__global__ void k_att(const float* __restrict__ z1, const float* __restrict__ z1r,
    const float* __restrict__ bn2, const float* __restrict__ u, const float* __restrict__ fcb,
    float* __restrict__ att, float* __restrict__ S1o, float* __restrict__ Q1o)
{
  int r = blockIdx.x*4 + (threadIdx.x >> 6);
  int lane = threadIdx.x & 63;
  const float* z1p = z1 + (size_t)r*512;
  const float* zrp = z1r + (size_t)r*512;
  float s = 0.f, s1 = 0.f, q1 = 0.f;
#pragma unroll
  for (int h = 0; h < 2; ++h) {
    int i = lane*4 + h*256;
    int n = i >> 4;
    float a2n = bn2[n], c2n = bn2[32+n];
    float4 zr = *(const float4*)&zrp[i];
    float4 zv = *(const float4*)&z1p[i];
    float4 uv = *(const float4*)&u[i];
#pragma unroll
    for (int e = 0; e < 4; ++e) {
      float ze = (e==0?zr.x:e==1?zr.y:e==2?zr.z:zr.w);
      float z1e = (e==0?zv.x:e==1?zv.y:e==2?zv.z:zv.w);
      float ue = (e==0?uv.x:e==1?uv.y:e==2?uv.z:uv.w);
      float tv = z1e + gelu_f(a2n*ze + c2n);
      s += tv * ue; s1 += tv; q1 += tv*tv;
    }
  }
  s = wred(s); s1 = wred(s1); q1 = wred(q1);
  if (lane == 0) { att[r] = s + fcb[0]; S1o[r] = s1; Q1o[r] = q1; }
}

__global__ __launch_bounds__(1024) void k_tf(const float* __restrict__ att,
    const float* __restrict__ pg, const float* __restrict__ pb,
    const float* __restrict__ pwc, const float* __restrict__ pbc,
    const float* __restrict__ pfb, float* __restrict__ a1, float* __restrict__ a2)
{
  __shared__ double sd[1024];
  __shared__ float sh[4];
  const int t = threadIdx.x;
  float g = pg[0], b = pb[0], wc = pwc[0], bc = pbc[0], fb = pfb[0];
  double s = 0.0, q = 0.0;
  for (int i = t; i < BD; i += 1024) { double v = att[i]; s += v; q += v*v; }
  sd[t] = s; __syncthreads();
  for (int o = 512; o > 0; o >>= 1) { if (t < o) sd[t] += sd[t+o]; __syncthreads(); }
  double S1 = sd[0]; __syncthreads();
  sd[t] = q; __syncthreads();
  for (int o = 512; o > 0; o >>= 1) { if (t < o) sd[t] += sd[t+o]; __syncthreads(); }
  if (t == 0) {
    double m = S1 / 14336.0;
    double v = sd[0] / 14336.0 - m*m; if (v < 0.0) v = 0.0;
    sh[0] = (float)m; sh[1] = (float)(1.0 / sqrt(v + 1e-5));
  }
  __syncthreads();
  float m1 = sh[0], i1 = sh[1];
  s = 0.0; q = 0.0;
  for (int i = t; i < BD; i += 1024) {
    float v = att[i];
    float an = (v - m1) * i1 * g + b;
    float av = sigm_f(gelu_f(an) * wc + bc);
    a1[i] = av;
    float t2 = av * (v - fb) + fb;
    s += t2; q += (double)t2 * t2;
  }
  __syncthreads();
  sd[t] = s; __syncthreads();
  for (int o = 512; o > 0; o >>= 1) { if (t < o) sd[t] += sd[t+o]; __syncthreads(); }
  double S2 = sd[0]; __syncthreads();
  sd[t] = q; __syncthreads();
  for (int o = 512; o > 0; o >>= 1) { if (t < o) sd[t] += sd[t+o]; __syncthreads(); }
  if (t == 0) {
    double m = S2 / 14336.0;
    double v = sd[0] / 14336.0 - m*m; if (v < 0.0) v = 0.0;
    sh[2] = (float)m; sh[3] = (float)(1.0 / sqrt(v + 1e-5));
  }
  __syncthreads();
  float m2 = sh[2], i2 = sh[3];
  for (int i = t; i < BD; i += 1024) {
    float t2 = a1[i] * (att[i] - fb) + fb;
    float an = (t2 - m2) * i2 * g + b;
    a2[i] = sigm_f(gelu_f(an) * wc + bc);
  }
}

// ---------------- statsC (float4) ----------------
__global__ void k_statsC(const float* __restrict__ z1, const float* __restrict__ z1r,
    const float* __restrict__ bn2, const float* __restrict__ a1,
    const float* __restrict__ bn3, const float* __restrict__ cw, const float* __restrict__ cb,
    float* __restrict__ rs, float* __restrict__ rq)
{
  int r = blockIdx.x*4 + (threadIdx.x >> 6);
  int lane = threadIdx.x & 63;
  int d = r % 7;
  float av = a1[r];
  float b3a = bn3[d], b3c = bn3[7+d], wv = cw[d], bv = cb[d];
  const float* z1p = z1 + (size_t)r*512;
  const float* zrp = z1r + (size_t)r*512;
  float s = 0.f, q = 0.f;
#pragma unroll
  for (int h = 0; h < 2; ++h) {
    int i = lane*4 + h*256;
    int n = i >> 4;
    float a2n = bn2[n], c2n = bn2[32+n];
    float4 zr = *(const float4*)&zrp[i];
    float4 zv = *(const float4*)&z1p[i];
#pragma unroll
    for (int e = 0; e < 4; ++e) {
      float ze = (e==0?zr.x:e==1?zr.y:e==2?zr.z:zr.w);
      float z1e = (e==0?zv.x:e==1?zv.y:e==2?zv.z:zv.w);
      float A = (z1e + gelu_f(a2n*ze + c2n)) * av;
      float C = wv*gelu_f(b3a*A + b3c) + bv;
      s += C; q += C*C;
    }
  }
  s = wred(s); q = wred(q);
  if (lane == 0) { rs[r] = s; rq[r] = q; }
}

// ---------------- final mix: writes zf as bf16 hi/lo planes + row stats ----------------
__global__ void k_final(const float* __restrict__ z1, const float* __restrict__ z1r,
    const float* __restrict__ bn2, const float* __restrict__ a1, const float* __restrict__ a2,
    const float* __restrict__ bn3, const float* __restrict__ bn4,
    const float* __restrict__ cw, const float* __restrict__ cb,
    ushort* __restrict__ zfh, ushort* __restrict__ zfl,
    float* __restrict__ rs, float* __restrict__ rq)
{
  int r = blockIdx.x*4 + (threadIdx.x >> 6);
  int lane = threadIdx.x & 63;
  int d = r % 7;
  float av = a1[r], a2v = a2[r];
  float b3a = bn3[d], b3c = bn3[7+d], b4a = bn4[d], b4c = bn4[7+d];
  float wv = cw[d], bv = cb[d];
  const float* z1p = z1 + (size_t)r*512;
  const float* zrp = z1r + (size_t)r*512;
  float s = 0.f, q = 0.f;
#pragma unroll
  for (int h = 0; h < 2; ++h) {
    int i = lane*4 + h*256;
    int n = i >> 4;
    float a2n = bn2[n], c2n = bn2[32+n];
    float4 zr = *(const float4*)&zrp[i];
    float4 zv = *(const float4*)&z1p[i];
    sh4 hv, lv;
#pragma unroll
    for (int e = 0; e < 4; ++e) {
      float ze = (e==0?zr.x:e==1?zr.y:e==2?zr.z:zr.w);
      float z1e = (e==0?zv.x:e==1?zv.y:e==2?zv.z:zv.w);
      float z1v = z1e * av;
      float z2v = gelu_f(a2n*ze + c2n) * av;
      float A = z1v + z2v;
      float C = wv*gelu_f(b3a*A + b3c) + bv;
      float inter = gelu_f(b4a*C + b4c) * a2v;
      float z1n = z1v*inter + z2v;
      float z2n = z2v*inter + z1n;
      float zfv = z1n*z2n + z1n + z2n;
      short hh, ll;
      tsplit(zfv, hh, ll);
      hv[e] = hh; lv[e] = ll;
      s += zfv; q += zfv*zfv;
    }
    *(sh4*)&zfh[(size_t)r*512 + i] = hv;
    *(sh4*)&zfl[(size_t)r*512 + i] = lv;
  }
  s = wred(s); q = wred(q);
  if (lane == 0) { rs[r] = s; rq[r] = q; }
}

// ---------------- output: fc2 + bias + z_res + transpose ----------------
__global__ __launch_bounds__(256) void k_out(const float* __restrict__ h2,
    const float* __restrict__ bn6, const float* __restrict__ w2, const float* __restrict__ b2,
    const float* __restrict__ zres, float* __restrict__ out)
{
  int idx = blockIdx.x*256 + threadIdx.x;
  int r = idx / 96, o = idx - r*96;
  int d = r % 7, b = r / 7;
  float a6 = bn6[d], c6 = bn6[7+d];
  const float* hp = h2 + (size_t)r*48;
  const float* wp = w2 + o*48;
  float s = 0.f;
#pragma unroll
  for (int j4 = 0; j4 < 12; ++j4) {
    float4 hv = *(const float4*)&hp[j4*4];
    float4 wv = *(const float4*)&wp[j4*4];
    s += (a6*hv.x + c6)*wv.x + (a6*hv.y + c6)*wv.y
       + (a6*hv.z + c6)*wv.z + (a6*hv.w + c6)*wv.w;
  }
  out[(size_t)b*672 + o*7 + d] = s + b2[o] + zres[(size_t)r*96 + o];
}

// ================= host =================
extern "C" void kernel_launch(void* const* d_in, const int* in_sizes, int n_in,
                              void* d_out, int out_size, void* d_ws, size_t ws_size,
                              hipStream_t stream) {
  const float* x          = (const float*)d_in[0];
  const float* dctconv_w  = (const float*)d_in[1];
  const float* dctconv_b  = (const float*)d_in[2];
  const float* dctnorm_g  = (const float*)d_in[3];
  const float* dctnorm_b  = (const float*)d_in[4];
  const float* threshold  = (const float*)d_in[5];
  const float* embed_W    = (const float*)d_in[6];
  const float* embed_b    = (const float*)d_in[7];
  const float* linres_W   = (const float*)d_in[8];
  const float* linres_b   = (const float*)d_in[9];
  const float* depth1_w   = (const float*)d_in[10];
  const float* depth1_b   = (const float*)d_in[11];
  const float* depthnorm_g= (const float*)d_in[12];
  const float* depthnorm_b= (const float*)d_in[13];
  const float* tf_fc_w    = (const float*)d_in[14];
  const float* tf_fc_b    = (const float*)d_in[15];
  const float* tf_norm_g  = (const float*)d_in[16];
  const float* tf_norm_b  = (const float*)d_in[17];
  const float* tf_conv_w  = (const float*)d_in[18];
  const float* tf_conv_b  = (const float*)d_in[19];
  const float* mlp_w1     = (const float*)d_in[20];
  const float* mlp_b1     = (const float*)d_in[21];
  const float* mlp_w2     = (const float*)d_in[22];
  const float* mlp_b2     = (const float*)d_in[23];
  const float* mlpnorm_g  = (const float*)d_in[24];
  const float* mlpnorm_b  = (const float*)d_in[25];
  float* out = (float*)d_out;
  float* ws  = (float*)d_ws;

  ushort* XPH = (ushort*)(ws + F_XP);             // xp hi/lo planes (fill F_XP exactly)
  ushort* XPL = XPH + (size_t)BD*512;
  ushort* ZFH = XPH;                              // zf planes overwrite xp planes at k_final
  ushort* ZFL = XPL;
  float* ZG   = ws + F_ZG;                        // z1r f32 (after GEMM2); GH/GL planes before
  ushort* ZGH = (ushort*)(ws + F_ZG);
  ushort* ZGL = ZGH + (size_t)BD*512;
  float* Z1   = ws + F_Z1;
  ushort* B1H = (ushort*)(ws + F_CLK);
  ushort* B1L = B1H + 512*512;
  ushort* B2H = (ushort*)(ws + F_MKL);
  ushort* B2L = B2H + 512*512;
  ushort* W2H = (ushort*)(ws + F_W2);
  ushort* W2L = W2H + 96*512;
  ushort* W1H = (ushort*)(ws + F_W1);
  ushort* W1L = W1H + 48*512;
  float* U    = ws + F_U;
  float* CSUM = ws + F_CSUM;
  float* CSTp = ws + F_CST;
  float* Vp   = ws + F_V;
  float* C2p  = ws + F_C2;
  float* ZRES = ws + F_ZRES;
  float* H2p  = ws + F_H2;
  float* NEp  = ws + F_NE;
  float* ATTp = ws + F_ATT;
  float* A1p  = ws + F_A1;
  float* A2p  = ws + F_A2;
  float* RS   = ws + F_RS;
  float* RQ   = ws + F_RQ;
  float* PS   = ws + F_PS;
  float* PQ   = ws + F_PQ;
  float* BN0  = ws + F_BN;        // a[7], c[7]
  float* BN2  = ws + F_BN + 16;   // a[32], c[32]
  float* BN3  = ws + F_BN + 80;
  float* BN4  = ws + F_BN + 96;
  float* BN5  = ws + F_BN + 112;
  float* BN6  = ws + F_BN + 128;
  float* THRp = ws + F_THR;

  k_setup<<<738, 256, 0, stream>>>(B1H, B1L, B2H, B2L, U, CSUM, tf_fc_w,
      embed_W, embed_b, depth1_w, depth1_b, Vp, C2p,
      mlp_w1, W1H, W1L, linres_W, linres_b, W2H, W2L, CSTp);
  k_transpose<<<2048, 256, 0, stream>>>(x, XPH, XPL, NEp);
  k_thr<<<1, 1024, 0, stream>>>(NEp, threshold, THRp);
  hipMemsetAsync(RS, 0, 2*BD*sizeof(float), stream);
  // GEMM1: z_dct -> masked dctconv -> gelu -> GH/GL planes (+ row stats)
  k_mfma<2><<<dim3(112,4), 512, 0, stream>>>(XPH, XPL, B1H, B1L,
      nullptr, ZGH, ZGL, nullptr, nullptr, nullptr, nullptr, dctconv_w, dctconv_b,
      NEp, THRp, RS, RQ);
  k_bnfin_rows<<<7, 256, 0, stream>>>(RS, RQ, 7, BD, 1048576.0, dctnorm_g, dctnorm_b, BN0);
  // GEMM2: z1 = BN(g) @ M + x_res  (BN folded via column sums)
  k_mfma<1><<<dim3(112,4), 512, 0, stream>>>(ZGH, ZGL, B2H, B2L,
      Z1, nullptr, nullptr, BN0, CSUM, XPH, XPL, dctconv_w, dctconv_b,
      nullptr, nullptr, nullptr, nullptr);
  k_patch<<<1792, 256, 0, stream>>>(XPH, XPL, Vp, C2p, ZG, PS, PQ);
  k_bnfin_part<<<32, 256, 0, stream>>>(PS, PQ, 1792, 32, 229376.0, depthnorm_g, depthnorm_b, BN2);
  // ZRES = XP @ W2^T + cst   (plane copy staging)
  k_mfma_nt<96,0><<<224, 256, 0, stream>>>(XPH, XPL, W2H, W2L, CSTp, ZRES,
      nullptr, nullptr, nullptr, nullptr);
  // att + per-row S1/Q1 of (z1+z2)
  k_att<<<3584, 256, 0, stream>>>(Z1, ZG, BN2, U, tf_fc_b, ATTp, RS, RQ);
  k_tf<<<1, 1024, 0, stream>>>(ATTp, tf_norm_g, tf_norm_b, tf_conv_w, tf_conv_b, tf_fc_b, A1p, A2p);
  // BN3 from a1-scaled per-row sums (statsA pass eliminated)
  k_bnfin_scaled<<<7, 256, 0, stream>>>(RS, RQ, A1p, dctnorm_g, dctnorm_b, BN3);
  k_statsC<<<3584, 256, 0, stream>>>(Z1, ZG, BN2, A1p, BN3, dctconv_w, dctconv_b, RS, RQ);
  k_bnfin_rows<<<7, 256, 0, stream>>>(RS, RQ, 7, BD, 1048576.0, dctnorm_g, dctnorm_b, BN4);
  k_final<<<3584, 256, 0, stream>>>(Z1, ZG, BN2, A1p, A2p, BN3, BN4, dctconv_w, dctconv_b,
      ZFH, ZFL, RS, RQ);
  k_bnfin_rows<<<7, 256, 0, stream>>>(RS, RQ, 7, BD, 1048576.0, dctnorm_g, dctnorm_b, BN5);
  // MLP fc1: h2 = gelu(v)*v with v = gelu(BN5(zf)) @ w1^T + b1   (reads zf planes)
  k_mfma_nt<48,2><<<224, 256, 0, stream>>>(ZFH, ZFL, W1H, W1L, mlp_b1, H2p,
      BN5, BN5+7, RS, RQ);
  k_bnfin_rows<<<7, 256, 0, stream>>>(RS, RQ, 7, BD, 98304.0, mlpnorm_g, mlpnorm_b, BN6);
  k_out<<<5376, 256, 0, stream>>>(H2p, BN6, mlp_w2, mlp_b2, ZRES, out);
}